// Round 11
// baseline (769.914 us; speedup 1.0000x reference)
//
#include <hip/hip_runtime.h>
#include <math.h>

#define NB 4
#define SS 16
#define NN 1024        // H*W

typedef short s8v __attribute__((ext_vector_type(8)));    // 8 bf16 (4 VGPR)
typedef float f4v __attribute__((ext_vector_type(4)));    // MFMA accumulator

__device__ __forceinline__ float sigm(float x) {
  return 1.0f / (1.0f + __expf(-x));
}
__device__ __forceinline__ float tanh_f(float x) {
  float e = __expf(2.0f * x);
  return 1.0f - 2.0f / (1.0f + e);
}
__device__ __forceinline__ unsigned short bf16r(float x) {   // RNE float->bf16
  unsigned int u = __float_as_uint(x);
  u = (u + 0x7FFFu + ((u >> 16) & 1u)) >> 16;
  return (unsigned short)u;
}
__device__ __forceinline__ float bf16f(unsigned short h) {
  return __uint_as_float(((unsigned int)h) << 16);
}

// ---------- prep: conv-weight split/pack + transposes + zero states ----------
__global__ void k0_prep(const float* __restrict__ conv_w, const float* __restrict__ z_w,
                        const float* __restrict__ m_w,
                        unsigned short* __restrict__ Whi, unsigned short* __restrict__ Wlo,
                        float* __restrict__ z_wT, float* __restrict__ m_wT,
                        float* __restrict__ h_A, float* __restrict__ c_st) {
  int stride = gridDim.x * blockDim.x;
  int i0 = blockIdx.x * blockDim.x + threadIdx.x;
  for (int i = i0; i < 256*1152; i += stride) {
    int oc = i / 1152, k = i - oc*1152;          // k = icComb*9 + ky*3 + kx
    float v = conv_w[i];
    unsigned short hi = bf16r(v);
    unsigned short lo = bf16r(v - bf16f(hi));
    int mt = oc >> 4, i16 = oc & 15;
    int ks = k >> 5, kk = k & 31;
    int lane = i16 | ((kk >> 3) << 4);
    int pos = ((mt*36 + ks)*64 + lane)*8 + (kk & 7);
    Whi[pos] = hi;
    Wlo[pos] = lo;
  }
  for (int i = i0; i < 128*128; i += stride) {
    int oc = i >> 7, k = i & 127;
    z_wT[k*128 + oc] = z_w[i];
  }
  for (int i = i0; i < 192*192; i += stride) {
    int oc = i / 192, k = i - oc*192;
    m_wT[k*192 + oc] = m_w[i];
  }
  for (int i = i0; i < NB*64*NN; i += stride) { h_A[i] = 0.0f; c_st[i] = 0.0f; }
}

// ---------- K0b v3: conv_x for ALL (b,t). 512 thr, 8 waves, 2 m-tiles/wave ----------
// block = (b, t, y): M=256, K=576 (ks 0..17 of Whi), N=32 (one row). grid 2048.
// Same math/layout as v1; each B-fragment read now feeds 12 MFMA (2 m-tiles).
__global__ __launch_bounds__(512, 4) void k0b_gx(
    const float* __restrict__ X,
    const unsigned short* __restrict__ Whi, const unsigned short* __restrict__ Wlo,
    float* __restrict__ gx)
{
  __shared__ __align__(16) unsigned short Xhi_l[18*2*64*8];   // [ks][nt][lane][8]
  __shared__ __align__(16) unsigned short Xlo_l[18*2*64*8];

  const int tid = threadIdx.x;
  const int bid = blockIdx.x;       // b*512 + t*32 + y
  const int y = bid & 31;
  const int t = (bid >> 5) & 15;
  const int b = bid >> 9;

  // im2col for one full row (32 outputs), x-channels only
  for (int idx = tid; idx < 64*3*34; idx += 512) {
    int col = idx % 34;
    int rest = idx / 34;
    int dy = rest % 3;
    int ic = rest / 3;
    int gy = y + dy - 1;
    int gxc = col - 1;
    float v = 0.0f;
    if ((unsigned)gy < 32u && (unsigned)gxc < 32u)
      v = X[(((b*64 + ic)*SS + t)*NN) + gy*32 + gxc];
    unsigned short hi = bf16r(v);
    unsigned short lo = bf16r(v - bf16f(hi));
    int kbase = ic*9 + dy*3;
    #pragma unroll
    for (int dx = 0; dx < 3; dx++) {
      int n = col - dx;
      if ((unsigned)n < 32u) {
        int k = kbase + dx;
        int ks = k >> 5, kk = k & 31;
        int nt = n >> 4, n16 = n & 15;
        int pos = (((ks*2 + nt)*64) + (n16 | ((kk >> 3) << 4)))*8 + (kk & 7);
        Xhi_l[pos] = hi;
        Xlo_l[pos] = lo;
      }
    }
  }
  __syncthreads();

  const int lane = tid & 63;
  const int w    = tid >> 6;        // 0..7
  const int mt0  = w*2, mt1 = w*2 + 1;
  f4v a00 = {0.f,0.f,0.f,0.f}, a01 = a00, a10 = a00, a11 = a00;
  const s8v* Ah0 = (const s8v*)Whi + (mt0*36)*64 + lane;
  const s8v* Al0 = (const s8v*)Wlo + (mt0*36)*64 + lane;
  const s8v* Ah1 = (const s8v*)Whi + (mt1*36)*64 + lane;
  const s8v* Al1 = (const s8v*)Wlo + (mt1*36)*64 + lane;
  const s8v* Bh = (const s8v*)Xhi_l + lane;
  const s8v* Bl = (const s8v*)Xlo_l + lane;
  #pragma unroll 3
  for (int ks = 0; ks < 18; ks++) {
    s8v ah0 = Ah0[ks*64];
    s8v al0 = Al0[ks*64];
    s8v ah1 = Ah1[ks*64];
    s8v al1 = Al1[ks*64];
    s8v bh0 = Bh[(ks*2 + 0)*64];
    s8v bl0 = Bl[(ks*2 + 0)*64];
    s8v bh1 = Bh[(ks*2 + 1)*64];
    s8v bl1 = Bl[(ks*2 + 1)*64];
    a00 = __builtin_amdgcn_mfma_f32_16x16x32_bf16(ah0, bh0, a00, 0, 0, 0);
    a00 = __builtin_amdgcn_mfma_f32_16x16x32_bf16(al0, bh0, a00, 0, 0, 0);
    a00 = __builtin_amdgcn_mfma_f32_16x16x32_bf16(ah0, bl0, a00, 0, 0, 0);
    a01 = __builtin_amdgcn_mfma_f32_16x16x32_bf16(ah0, bh1, a01, 0, 0, 0);
    a01 = __builtin_amdgcn_mfma_f32_16x16x32_bf16(al0, bh1, a01, 0, 0, 0);
    a01 = __builtin_amdgcn_mfma_f32_16x16x32_bf16(ah0, bl1, a01, 0, 0, 0);
    a10 = __builtin_amdgcn_mfma_f32_16x16x32_bf16(ah1, bh0, a10, 0, 0, 0);
    a10 = __builtin_amdgcn_mfma_f32_16x16x32_bf16(al1, bh0, a10, 0, 0, 0);
    a10 = __builtin_amdgcn_mfma_f32_16x16x32_bf16(ah1, bl0, a10, 0, 0, 0);
    a11 = __builtin_amdgcn_mfma_f32_16x16x32_bf16(ah1, bh1, a11, 0, 0, 0);
    a11 = __builtin_amdgcn_mfma_f32_16x16x32_bf16(al1, bh1, a11, 0, 0, 0);
    a11 = __builtin_amdgcn_mfma_f32_16x16x32_bf16(ah1, bl1, a11, 0, 0, 0);
  }
  const int c16 = lane & 15;
  const int rb  = (lane >> 4) * 4;
  float* gout = gx + (((long)b*SS + t)*256)*NN + y*32;
  #pragma unroll
  for (int r = 0; r < 4; r++) {
    gout[(mt0*16 + rb + r)*NN + c16]      = a00[r];
    gout[(mt0*16 + rb + r)*NN + 16 + c16] = a01[r];
    gout[(mt1*16 + rb + r)*NN + c16]      = a10[r];
    gout[(mt1*16 + rb + r)*NN + 16 + c16] = a11[r];
  }
}

// ---------- K1: conv_h (MFMA split-bf16) + LSTM(+gx) + projections (1024 threads) ----------
__global__ __launch_bounds__(1024, 2) void k1_conv_lstm_proj(
    int t,
    const float* __restrict__ gx,
    const unsigned short* __restrict__ Whi, const unsigned short* __restrict__ Wlo,
    const float* __restrict__ conv_b,
    const float* __restrict__ W_ci, const float* __restrict__ W_cf, const float* __restrict__ W_co,
    const float* __restrict__ qw, const float* __restrict__ qb,
    const float* __restrict__ kw, const float* __restrict__ kb,
    const float* __restrict__ k2w, const float* __restrict__ k2b,
    const float* __restrict__ vw, const float* __restrict__ vb,
    const float* __restrict__ v2w, const float* __restrict__ v2b,
    const float* __restrict__ h_cur, float* __restrict__ h_nxt,
    float* __restrict__ c_st,
    float* __restrict__ q_buf,
    unsigned short* __restrict__ kF,
    unsigned short* __restrict__ vFh, unsigned short* __restrict__ vFl)
{
  __shared__ __align__(16) unsigned short Ihi_l[18*64*8];      // h-only im2col, B-frag order
  __shared__ __align__(16) unsigned short Ilo_l[18*64*8];
  __shared__ __align__(16) float gates_l[256*17];              // [oc][x]; later proj_l[176][16]
  __shared__ __align__(16) float h_l[16*68];                   // [x][c]
  __shared__ __align__(16) float c_l[16*68];
  __shared__ __align__(16) float pw_l[176*68];                 // proj weights staged in LDS
  __shared__ __align__(16) float pb_l[176];

  const int tid = threadIdx.x;
  const int bid = blockIdx.x;
  const int b  = bid >> 6;
  const int y  = (bid >> 1) & 31;
  const int x0 = (bid & 1) * 16;
  const int mt = bid & 63;          // this block's 16-col m-tile (= n>>4)
  const int n0 = y*32 + x0;

  // ---- prefetch LSTM inputs into registers (latency hides under im2col+MFMA) ----
  const int px = tid & 15;
  const int pc = tid >> 4;          // 0..63
  const int pn = n0 + px;
  const float* gxp = gx + (((long)b*SS + t)*256)*NN + pn;
  float pf_g0 = gxp[(pc      )*NN];
  float pf_g1 = gxp[( 64 + pc)*NN];
  float pf_g2 = gxp[(128 + pc)*NN];
  float pf_g3 = gxp[(192 + pc)*NN];
  float pf_cp  = c_st[(b*64 + pc)*NN + pn];
  float pf_wci = W_ci[pc*NN + pn];
  float pf_wcf = W_cf[pc*NN + pn];
  float pf_wco = W_co[pc*NN + pn];
  float pf_b0 = conv_b[pc];
  float pf_b1 = conv_b[ 64 + pc];
  float pf_b2 = conv_b[128 + pc];
  float pf_b3 = conv_b[192 + pc];

  // ---- phase 0: h-only im2col -> B-frags  +  stage proj weights into LDS ----
  for (int idx = tid; idx < 64*3*18; idx += 1024) {
    int col = idx % 18;
    int rest = idx / 18;
    int dy = rest % 3;
    int ic = rest / 3;                    // h channel 0..63
    int gy = y + dy - 1;
    int gxc = x0 + col - 1;
    float v = 0.0f;
    if ((unsigned)gy < 32u && (unsigned)gxc < 32u)
      v = h_cur[((b*64 + ic)*NN) + gy*32 + gxc];
    unsigned short hi = bf16r(v);
    unsigned short lo = bf16r(v - bf16f(hi));
    int kbase = ic*9 + dy*3;              // local k in [0,576)
    #pragma unroll
    for (int dx = 0; dx < 3; dx++) {
      int n = col - dx;
      if ((unsigned)n < 16u) {
        int k = kbase + dx;
        int ks = k >> 5, kk = k & 31;
        int pos = (ks*64 + (n | ((kk >> 3) << 4)))*8 + (kk & 7);
        Ihi_l[pos] = hi;
        Ilo_l[pos] = lo;
      }
    }
  }
  for (int idx = tid; idx < 176*64; idx += 1024) {
    int po = idx >> 6, c = idx & 63;
    float v;
    if (po < 16)       v = qw[po*64 + c];
    else if (po < 32)  v = kw[(po-16)*64 + c];
    else if (po < 96)  v = vw[(po-32)*64 + c];
    else if (po < 112) v = k2w[(po-96)*64 + c];
    else               v = v2w[(po-112)*64 + c];
    pw_l[po*68 + c] = v;
  }
  if (tid < 176) {
    int po = tid;
    float v;
    if (po < 16)       v = qb[po];
    else if (po < 32)  v = kb[po-16];
    else if (po < 96)  v = vb[po-32];
    else if (po < 112) v = k2b[po-96];
    else               v = v2b[po-112];
    pb_l[po] = v;
  }
  __syncthreads();

  // ---- phase 1: conv_h MFMA: 16 waves, 1 m-tile each; A-frags at ks 18..35 ----
  {
    const int lane = tid & 63;
    const int wv   = tid >> 6;        // 0..15 = m-tile
    f4v acc = {0.f, 0.f, 0.f, 0.f};
    const s8v* Ah = (const s8v*)Whi + (wv*36 + 18)*64 + lane;
    const s8v* Al = (const s8v*)Wlo + (wv*36 + 18)*64 + lane;
    const s8v* Bh = (const s8v*)Ihi_l + lane;
    const s8v* Bl = (const s8v*)Ilo_l + lane;
    #pragma unroll 3
    for (int ks = 0; ks < 18; ks++) {
      s8v ah = Ah[ks*64];
      s8v al = Al[ks*64];
      s8v bh = Bh[ks*64];
      s8v bl = Bl[ks*64];
      acc = __builtin_amdgcn_mfma_f32_16x16x32_bf16(ah, bh, acc, 0, 0, 0);
      acc = __builtin_amdgcn_mfma_f32_16x16x32_bf16(al, bh, acc, 0, 0, 0);
      acc = __builtin_amdgcn_mfma_f32_16x16x32_bf16(ah, bl, acc, 0, 0, 0);
    }
    const int colx = lane & 15;
    const int rb   = (lane >> 4) * 4;
    #pragma unroll
    for (int r = 0; r < 4; r++)
      gates_l[(wv*16 + rb + r)*17 + colx] = acc[r];
  }
  __syncthreads();

  // ---- phase 2: LSTM elementwise (prefetched inputs) ----
  {
    const int x = px;
    const int c = pc;
    const int n = pn;
    float ig = gates_l[(c      )*17 + x] + pf_g0 + pf_b0;
    float fg = gates_l[( 64 + c)*17 + x] + pf_g1 + pf_b1;
    float gg = gates_l[(128 + c)*17 + x] + pf_g2 + pf_b2;
    float og = gates_l[(192 + c)*17 + x] + pf_g3 + pf_b3;
    float cp = pf_cp;
    float i_ = sigm(ig + pf_wci * cp);
    float f_ = sigm(fg + pf_wcf * cp);
    float cn = f_*cp + i_*tanh_f(gg);
    float o_ = sigm(og + pf_wco * cn);
    float hn = o_*tanh_f(cn);
    h_nxt[(b*64 + c)*NN + n] = hn;
    c_st[(b*64 + c)*NN + n] = cn;
    h_l[x*68 + c] = hn;
    c_l[x*68 + c] = cn;
  }
  __syncthreads();

  // ---- phase 3: projections (weights from LDS) -> LDS staging ----
  float* proj_l = gates_l;
  #pragma unroll
  for (int r0 = 0; r0 < 3; r0++) {
    int task = tid + r0*1024;
    if (task < 176*16) {
      int po = task >> 4, x = task & 15;
      const float* src = (po < 96) ? &h_l[x*68] : &c_l[x*68];
      const float* w = &pw_l[po*68];
      float s = pb_l[po];
      #pragma unroll
      for (int k = 0; k < 64; k += 4) {
        float4 wv = *(const float4*)&w[k];
        float4 sv = *(const float4*)&src[k];
        s = fmaf(wv.x, sv.x, s); s = fmaf(wv.y, sv.y, s);
        s = fmaf(wv.z, sv.z, s); s = fmaf(wv.w, sv.w, s);
      }
      proj_l[po*16 + x] = s;
    }
  }
  __syncthreads();

  // ---- phase 4: coalesced fragment emission ----
  if (tid < 256) {
    int d = tid >> 4, x = tid & 15;
    q_buf[(b*16 + d)*NN + n0 + x] = proj_l[d*16 + x];
  }
  if (tid < 512) {
    int brh2 = tid >> 8;            // branch
    int lh   = (tid >> 2) & 63;     // fragment "lane-half" row
    int j2   = tid & 3;             // packs d&7 = 2*j2, 2*j2+1
    int p    = lh >> 4;             // 0,1: hi planes; 2,3: lo planes
    int x    = lh & 15;
    int d0   = ((p & 1) << 3) | (j2 << 1);
    int Koff = brh2 ? 96 : 16;
    float v0 = proj_l[(Koff + d0)*16 + x];
    float v1 = proj_l[(Koff + d0 + 1)*16 + x];
    unsigned short h0 = bf16r(v0), h1 = bf16r(v1);
    unsigned short u0, u1;
    if (p < 2) { u0 = h0; u1 = h1; }
    else       { u0 = bf16r(v0 - bf16f(h0)); u1 = bf16r(v1 - bf16f(h1)); }
    unsigned int* dst = (unsigned int*)(kF + ((b*2 + brh2)*64 + mt)*512);
    dst[lh*4 + j2] = (unsigned)u0 | ((unsigned)u1 << 16);
  }
  {
    const int ks = y;
    const int g0 = x0 >> 3;         // 0 or 2
    #pragma unroll
    for (int it = 0; it < 2; it++) {
      int ct    = tid + it*1024;
      int plane = ct >> 10;         // 0 = vFh, 1 = vFl
      int brh2  = (ct >> 9) & 1;
      int nt    = (ct >> 7) & 3;
      int li    = (ct >> 2) & 31;
      int j2    = ct & 3;
      int lane2 = g0*16 + li;
      int cch   = nt*16 + (lane2 & 15);
      int xx    = ((li >> 4) << 3) | (j2 << 1);
      int Voff  = brh2 ? 112 : 32;
      float v0 = proj_l[(Voff + cch)*16 + xx];
      float v1 = proj_l[(Voff + cch)*16 + xx + 1];
      unsigned short h0 = bf16r(v0), h1 = bf16r(v1);
      unsigned short u0, u1;
      if (plane == 0) { u0 = h0; u1 = h1; }
      else            { u0 = bf16r(v0 - bf16f(h0)); u1 = bf16r(v1 - bf16f(h1)); }
      unsigned short* basep = (plane ? vFl : vFh) + (((b*2 + brh2)*32 + ks)*4 + nt)*512;
      ((unsigned int*)basep)[lane2*4 + j2] = (unsigned)u0 | ((unsigned)u1 << 16);
    }
  }
}

// ---------- K2: dual attention via MFMA + combine + gating ----------
#define RED_OFF 0        // [16 waves][16 nl][66]  = 16896
#define PS_OFF  16896    // [16 waves][16][36]     = 9216
#define SMX_OFF 26112    // [2][8][16]             = 256
#define SSM_OFF 26368    // [2][8][16]             = 256
#define INV_OFF 26624    // [2][16]                = 32
#define ZHM_OFF 26656    // [128][16]              = 2048
#define S_TOT   28704

__global__ __launch_bounds__(1024, 4) void k2_attn(
    int t,
    const float* __restrict__ q_buf,
    const unsigned short* __restrict__ kF,
    const unsigned short* __restrict__ vFh, const unsigned short* __restrict__ vFl,
    float* __restrict__ h_nxt, float* __restrict__ c_st,
    const float* __restrict__ z_wT, const float* __restrict__ z_b,
    const float* __restrict__ m_wT, const float* __restrict__ m_b,
    float* __restrict__ out)
{
  __shared__ __align__(16) float S[S_TOT];
  float* red  = S + RED_OFF;
  float* smMax= S + SMX_OFF;
  float* smSum= S + SSM_OFF;
  float* invL = S + INV_OFF;
  float* zhm  = S + ZHM_OFF;
  float* cbIn = S;              // alias red (after barrier)
  float* cbOut= S + 3072;       // alias red

  const int tid = threadIdx.x;
  const int bid = blockIdx.x;
  const int xcd = bid & 7;
  const int b = xcd >> 1;
  const int tile = ((bid >> 3) << 1) | (xcd & 1);   // 0..63
  const int n0 = tile * 16;

  const int wid  = tid >> 6;
  const int lane = tid & 63;
  const int brh  = wid >> 3;      // branch
  const int w    = wid & 7;       // wave within branch
  const int g    = lane >> 4;
  const int c16  = lane & 15;

  // ---- prefetch tail-phase inputs (latency hides under attention) ----
  const int pc2 = tid >> 4;       // 0..63
  const int pn2 = n0 + (tid & 15);
  float pf_cst = c_st[(b*64 + pc2)*NN + pn2];
  float pf_h   = h_nxt[(b*64 + pc2)*NN + pn2];

  // ---- Q A-frags: A1 = [Qh|Qh], A2 = [Ql|0] ----
  s8v qh1, ql2;
  {
    const int dbase = (g & 1) * 8;
    #pragma unroll
    for (int j = 0; j < 8; j++) {
      float qv = q_buf[(b*16 + dbase + j)*NN + n0 + c16];
      unsigned short hi = bf16r(qv);
      unsigned short lo = bf16r(qv - bf16f(hi));
      qh1[j] = (short)hi;
      ql2[j] = (g < 2) ? (short)lo : (short)0;
    }
  }

  // ---- scores: 8 m-tiles per wave, 2 MFMA each (B = [Kh|Kl]) ----
  f4v acc[8];
  {
    const unsigned short* kp = kF + (((b*2 + brh)*64 + w*8)*64 + lane)*8;
    #pragma unroll
    for (int i = 0; i < 8; i++) {
      s8v bf = *(const s8v*)(kp + i*512);
      f4v z4 = {0.f, 0.f, 0.f, 0.f};
      z4 = __builtin_amdgcn_mfma_f32_16x16x32_bf16(ql2, bf, z4, 0, 0, 0);
      acc[i] = __builtin_amdgcn_mfma_f32_16x16x32_bf16(qh1, bf, z4, 0, 0, 0);
    }
  }

  // ---- softmax (rows nl = g*4+r, this wave holds 128 m per row) ----
  float Mrow[4];
  #pragma unroll
  for (int r = 0; r < 4; r++) {
    float m = acc[0][r];
    #pragma unroll
    for (int i = 1; i < 8; i++) m = fmaxf(m, acc[i][r]);
    m = fmaxf(m, __shfl_xor(m, 1));
    m = fmaxf(m, __shfl_xor(m, 2));
    m = fmaxf(m, __shfl_xor(m, 4));
    m = fmaxf(m, __shfl_xor(m, 8));
    if (c16 == 0) smMax[(brh*8 + w)*16 + g*4 + r] = m;
  }
  __syncthreads();
  #pragma unroll
  for (int r = 0; r < 4; r++) {
    float m = smMax[(brh*8 + 0)*16 + g*4 + r];
    #pragma unroll
    for (int w2 = 1; w2 < 8; w2++) m = fmaxf(m, smMax[(brh*8 + w2)*16 + g*4 + r]);
    Mrow[r] = m;
  }
  float rsum[4] = {0.f, 0.f, 0.f, 0.f};
  #pragma unroll
  for (int i = 0; i < 8; i++) {
    #pragma unroll
    for (int r = 0; r < 4; r++) {
      float p = __expf(acc[i][r] - Mrow[r]);
      acc[i][r] = p;
      rsum[r] += p;
    }
  }
  #pragma unroll
  for (int r = 0; r < 4; r++) {
    float s = rsum[r];
    s += __shfl_xor(s, 1); s += __shfl_xor(s, 2);
    s += __shfl_xor(s, 4); s += __shfl_xor(s, 8);
    if (c16 == 0) smSum[(brh*8 + w)*16 + g*4 + r] = s;
  }
  __syncthreads();
  if (w == 0 && c16 == 0) {
    #pragma unroll
    for (int r = 0; r < 4; r++) {
      float s = 0.f;
      #pragma unroll
      for (int w2 = 0; w2 < 8; w2++) s += smSum[(brh*8 + w2)*16 + g*4 + r];
      invL[brh*16 + g*4 + r] = 1.0f / s;
    }
  }

  // ---- PV: per wave, 4 k-steps of 32 m; wave-local P transpose; 3-term split ----
  f4v z0 = {0.f,0.f,0.f,0.f}, z1 = z0, z2 = z0, z3 = z0;
  float* myPS = S + PS_OFF + wid*576;   // [16][36]
  #pragma unroll
  for (int ks4 = 0; ks4 < 4; ks4++) {
    #pragma unroll
    for (int i2 = 0; i2 < 2; i2++) {
      #pragma unroll
      for (int r = 0; r < 4; r++)
        myPS[(g*4 + r)*36 + i2*16 + c16] = acc[ks4*2 + i2][r];
    }
    float4 pa = *(const float4*)&myPS[c16*36 + g*8];
    float4 pb = *(const float4*)&myPS[c16*36 + g*8 + 4];
    s8v ph, pl;
    {
      unsigned short h0 = bf16r(pa.x); ph[0] = (short)h0; pl[0] = (short)bf16r(pa.x - bf16f(h0));
      unsigned short h1 = bf16r(pa.y); ph[1] = (short)h1; pl[1] = (short)bf16r(pa.y - bf16f(h1));
      unsigned short h2 = bf16r(pa.z); ph[2] = (short)h2; pl[2] = (short)bf16r(pa.z - bf16f(h2));
      unsigned short h3 = bf16r(pa.w); ph[3] = (short)h3; pl[3] = (short)bf16r(pa.w - bf16f(h3));
      unsigned short h4 = bf16r(pb.x); ph[4] = (short)h4; pl[4] = (short)bf16r(pb.x - bf16f(h4));
      unsigned short h5 = bf16r(pb.y); ph[5] = (short)h5; pl[5] = (short)bf16r(pb.y - bf16f(h5));
      unsigned short h6 = bf16r(pb.z); ph[6] = (short)h6; pl[6] = (short)bf16r(pb.z - bf16f(h6));
      unsigned short h7 = bf16r(pb.w); ph[7] = (short)h7; pl[7] = (short)bf16r(pb.w - bf16f(h7));
    }
    const int ks = w*4 + ks4;
    const unsigned short* vph = vFh + ((((b*2 + brh)*32 + ks)*4)*64 + lane)*8;
    const unsigned short* vpl = vFl + ((((b*2 + brh)*32 + ks)*4)*64 + lane)*8;
    s8v vh0 = *(const s8v*)(vph);
    s8v vl0 = *(const s8v*)(vpl);
    z0 = __builtin_amdgcn_mfma_f32_16x16x32_bf16(ph, vh0, z0, 0,0,0);
    z0 = __builtin_amdgcn_mfma_f32_16x16x32_bf16(ph, vl0, z0, 0,0,0);
    z0 = __builtin_amdgcn_mfma_f32_16x16x32_bf16(pl, vh0, z0, 0,0,0);
    s8v vh1 = *(const s8v*)(vph + 512);
    s8v vl1 = *(const s8v*)(vpl + 512);
    z1 = __builtin_amdgcn_mfma_f32_16x16x32_bf16(ph, vh1, z1, 0,0,0);
    z1 = __builtin_amdgcn_mfma_f32_16x16x32_bf16(ph, vl1, z1, 0,0,0);
    z1 = __builtin_amdgcn_mfma_f32_16x16x32_bf16(pl, vh1, z1, 0,0,0);
    s8v vh2 = *(const s8v*)(vph + 1024);
    s8v vl2 = *(const s8v*)(vpl + 1024);
    z2 = __builtin_amdgcn_mfma_f32_16x16x32_bf16(ph, vh2, z2, 0,0,0);
    z2 = __builtin_amdgcn_mfma_f32_16x16x32_bf16(ph, vl2, z2, 0,0,0);
    z2 = __builtin_amdgcn_mfma_f32_16x16x32_bf16(pl, vh2, z2, 0,0,0);
    s8v vh3 = *(const s8v*)(vph + 1536);
    s8v vl3 = *(const s8v*)(vpl + 1536);
    z3 = __builtin_amdgcn_mfma_f32_16x16x32_bf16(ph, vh3, z3, 0,0,0);
    z3 = __builtin_amdgcn_mfma_f32_16x16x32_bf16(ph, vl3, z3, 0,0,0);
    z3 = __builtin_amdgcn_mfma_f32_16x16x32_bf16(pl, vh3, z3, 0,0,0);
  }

  // ---- write partials, reduce 8 waves, normalize -> zhm ----
  {
    float* rw = red + wid*1056;
    #pragma unroll
    for (int r = 0; r < 4; r++) {
      rw[(g*4 + r)*66 +  0 + c16] = z0[r];
      rw[(g*4 + r)*66 + 16 + c16] = z1[r];
      rw[(g*4 + r)*66 + 32 + c16] = z2[r];
      rw[(g*4 + r)*66 + 48 + c16] = z3[r];
    }
  }
  __syncthreads();
  {
    const int br2 = tid >> 9;
    const int sub = tid & 511;
    const int nlr = sub >> 5;
    const int cc0 = (sub & 31) * 2;
    float iv = invL[br2*16 + nlr];
    #pragma unroll
    for (int u = 0; u < 2; u++) {
      int cc = cc0 + u;
      float s = 0.f;
      #pragma unroll
      for (int w2 = 0; w2 < 8; w2++)
        s += red[(br2*8 + w2)*1056 + nlr*66 + cc];
      zhm[(br2*64 + cc)*16 + nlr] = s * iv;
    }
  }
  __syncthreads();

  // ---- zz = z_w @ [zh; zm] + z_b  (+ stage hf rows); cbIn aliases red ----
  {
    const int oc  = tid & 127;
    const int nl0 = (tid >> 7) * 2;
    float s0 = z_b[oc], s1 = s0;
    for (int k = 0; k < 128; k++) {
      float ww = z_wT[k*128 + oc];
      float2 zz2 = *(const float2*)&zhm[k*16 + nl0];
      s0 = fmaf(ww, zz2.x, s0); s1 = fmaf(ww, zz2.y, s1);
    }
    cbIn[oc*16 + nl0]     = s0;
    cbIn[oc*16 + nl0 + 1] = s1;
    cbIn[(128 + pc2)*16 + (tid & 15)] = pf_h;
  }
  __syncthreads();

  // ---- comb = m_w @ [zz; hf] + m_b ----
  if (tid < 768) {
    const int oc = tid >> 2;
    const int nl0 = (tid & 3) * 4;
    float4 a; a.x = a.y = a.z = a.w = m_b[oc];
    for (int k = 0; k < 192; k++) {
      float ww = m_wT[k*192 + oc];
      float4 v = *(const float4*)&cbIn[k*16 + nl0];
      a.x = fmaf(ww, v.x, a.x); a.y = fmaf(ww, v.y, a.y);
      a.z = fmaf(ww, v.z, a.z); a.w = fmaf(ww, v.w, a.w);
    }
    *(float4*)&cbOut[oc*16 + nl0] = a;
  }
  __syncthreads();

  // ---- gating ----
  {
    const int c = pc2, nn = tid & 15;
    const int n = n0 + nn;
    float mo = cbOut[c*16 + nn];
    float mg = cbOut[(64 + c)*16 + nn];
    float mi = cbOut[(128 + c)*16 + nn];
    float mf = pf_cst;
    float mis = sigm(mi);
    float nmf = (1.0f - mis)*mf + mis*tanh_f(mg);
    float nhf = sigm(mo)*nmf;
    c_st[(b*64 + c)*NN + n] = nmf;
    h_nxt[(b*64 + c)*NN + n] = nhf;
    out[((b*64 + c)*SS + t)*NN + n] = nhf;
  }
}

extern "C" void kernel_launch(void* const* d_in, const int* in_sizes, int n_in,
                              void* d_out, int out_size, void* d_ws, size_t ws_size,
                              hipStream_t stream) {
  const float* X      = (const float*)d_in[0];
  const float* conv_w = (const float*)d_in[1];
  const float* conv_b = (const float*)d_in[2];
  const float* W_ci   = (const float*)d_in[3];
  const float* W_cf   = (const float*)d_in[4];
  const float* W_co   = (const float*)d_in[5];
  const float* qw  = (const float*)d_in[6];
  const float* qb  = (const float*)d_in[7];
  const float* kw  = (const float*)d_in[8];
  const float* kb  = (const float*)d_in[9];
  const float* k2w = (const float*)d_in[10];
  const float* k2b = (const float*)d_in[11];
  const float* vw  = (const float*)d_in[12];
  const float* vb  = (const float*)d_in[13];
  const float* v2w = (const float*)d_in[14];
  const float* v2b = (const float*)d_in[15];
  const float* z_w = (const float*)d_in[16];
  const float* z_b = (const float*)d_in[17];
  const float* m_w = (const float*)d_in[18];
  const float* m_b = (const float*)d_in[19];
  float* out = (float*)d_out;

  float* ws = (float*)d_ws;
  unsigned short* Whi = (unsigned short*)ws;  ws += 147456;   // 294912 ushorts
  unsigned short* Wlo = (unsigned short*)ws;  ws += 147456;
  float* z_wT   = ws;             ws += 128*128;
  float* m_wT   = ws;             ws += 192*192;
  float* h_A    = ws;             ws += NB*64*NN;
  float* h_B    = ws;             ws += NB*64*NN;
  float* c_st   = ws;             ws += NB*64*NN;
  float* q_buf  = ws;             ws += NB*16*NN;
  unsigned short* kF  = (unsigned short*)ws;  ws += 131072;   // 4b*2br*64mt*64*8 ushorts
  unsigned short* vFh = (unsigned short*)ws;  ws += 131072;   // 4b*2br*32ks*4nt*64*8
  unsigned short* vFl = (unsigned short*)ws;  ws += 131072;
  float* gx     = ws;             ws += NB*SS*256*NN;         // 16.8M floats, 67 MB

  hipLaunchKernelGGL(k0_prep, dim3(256), dim3(256), 0, stream,
                     conv_w, z_w, m_w, Whi, Wlo, z_wT, m_wT, h_A, c_st);
  hipLaunchKernelGGL(k0b_gx, dim3(2048), dim3(512), 0, stream,
                     X, Whi, Wlo, gx);
  for (int t = 0; t < 16; t++) {
    const float* h_cur = (t & 1) ? h_B : h_A;
    float* h_nxt       = (t & 1) ? h_A : h_B;
    hipLaunchKernelGGL(k1_conv_lstm_proj, dim3(256), dim3(1024), 0, stream,
        t, gx, Whi, Wlo, conv_b, W_ci, W_cf, W_co,
        qw, qb, kw, kb, k2w, k2b, vw, vb, v2w, v2b,
        h_cur, h_nxt, c_st, q_buf, kF, vFh, vFl);
    hipLaunchKernelGGL(k2_attn, dim3(256), dim3(1024), 0, stream,
        t, q_buf, kF, vFh, vFl, h_nxt, c_st,
        z_wT, z_b, m_wT, m_b, out);
  }
}

// Round 12
// 646.195 us; speedup vs baseline: 1.1915x; 1.1915x over previous
//
#include <hip/hip_runtime.h>
#include <math.h>

#define NB 4
#define SS 16
#define NN 1024        // H*W

typedef short s8v __attribute__((ext_vector_type(8)));    // 8 bf16 (4 VGPR)
typedef float f4v __attribute__((ext_vector_type(4)));    // MFMA accumulator

__device__ __forceinline__ float sigm(float x) {
  return 1.0f / (1.0f + __expf(-x));
}
__device__ __forceinline__ float tanh_f(float x) {
  float e = __expf(2.0f * x);
  return 1.0f - 2.0f / (1.0f + e);
}
__device__ __forceinline__ unsigned short bf16r(float x) {   // RNE float->bf16
  unsigned int u = __float_as_uint(x);
  u = (u + 0x7FFFu + ((u >> 16) & 1u)) >> 16;
  return (unsigned short)u;
}
__device__ __forceinline__ float bf16f(unsigned short h) {
  return __uint_as_float(((unsigned int)h) << 16);
}

// ---------- prep: weight split/pack (conv + z_w + m_w A-frags) + zero states ----------
__global__ void k0_prep(const float* __restrict__ conv_w, const float* __restrict__ z_w,
                        const float* __restrict__ m_w,
                        unsigned short* __restrict__ Whi, unsigned short* __restrict__ Wlo,
                        unsigned short* __restrict__ zAhi, unsigned short* __restrict__ zAlo,
                        unsigned short* __restrict__ mAhi, unsigned short* __restrict__ mAlo,
                        float* __restrict__ h_A, float* __restrict__ c_st) {
  int stride = gridDim.x * blockDim.x;
  int i0 = blockIdx.x * blockDim.x + threadIdx.x;
  for (int i = i0; i < 256*1152; i += stride) {
    int oc = i / 1152, k = i - oc*1152;          // k = icComb*9 + ky*3 + kx
    float v = conv_w[i];
    unsigned short hi = bf16r(v);
    unsigned short lo = bf16r(v - bf16f(hi));
    int mt = oc >> 4, i16 = oc & 15;
    int ks = k >> 5, kk = k & 31;
    int lane = i16 | ((kk >> 3) << 4);
    int pos = ((mt*36 + ks)*64 + lane)*8 + (kk & 7);
    Whi[pos] = hi;
    Wlo[pos] = lo;
  }
  for (int i = i0; i < 128*128; i += stride) {   // z_w A-frags: 8 mt x 4 ks
    int oc = i >> 7, k = i & 127;
    float v = z_w[i];
    unsigned short hi = bf16r(v);
    unsigned short lo = bf16r(v - bf16f(hi));
    int mt = oc >> 4, i16 = oc & 15;
    int ks = k >> 5, kk = k & 31;
    int lane = i16 | ((kk >> 3) << 4);
    int pos = ((mt*4 + ks)*64 + lane)*8 + (kk & 7);
    zAhi[pos] = hi;
    zAlo[pos] = lo;
  }
  for (int i = i0; i < 192*192; i += stride) {   // m_w A-frags: 12 mt x 6 ks
    int oc = i / 192, k = i - oc*192;
    float v = m_w[i];
    unsigned short hi = bf16r(v);
    unsigned short lo = bf16r(v - bf16f(hi));
    int mt = oc >> 4, i16 = oc & 15;
    int ks = k >> 5, kk = k & 31;
    int lane = i16 | ((kk >> 3) << 4);
    int pos = ((mt*6 + ks)*64 + lane)*8 + (kk & 7);
    mAhi[pos] = hi;
    mAlo[pos] = lo;
  }
  for (int i = i0; i < NB*64*NN; i += stride) { h_A[i] = 0.0f; c_st[i] = 0.0f; }
}

// ---------- K0b (v1): conv_x for ALL (b,t) — parallel GEMM ----------
__global__ __launch_bounds__(1024, 2) void k0b_gx(
    const float* __restrict__ X,
    const unsigned short* __restrict__ Whi, const unsigned short* __restrict__ Wlo,
    float* __restrict__ gx)
{
  __shared__ __align__(16) unsigned short Xhi_l[18*2*64*8];   // [ks][nt][lane][8]
  __shared__ __align__(16) unsigned short Xlo_l[18*2*64*8];

  const int tid = threadIdx.x;
  const int bid = blockIdx.x;       // b*512 + t*32 + y
  const int y = bid & 31;
  const int t = (bid >> 5) & 15;
  const int b = bid >> 9;

  for (int idx = tid; idx < 64*3*34; idx += 1024) {
    int col = idx % 34;
    int rest = idx / 34;
    int dy = rest % 3;
    int ic = rest / 3;
    int gy = y + dy - 1;
    int gxc = col - 1;
    float v = 0.0f;
    if ((unsigned)gy < 32u && (unsigned)gxc < 32u)
      v = X[(((b*64 + ic)*SS + t)*NN) + gy*32 + gxc];
    unsigned short hi = bf16r(v);
    unsigned short lo = bf16r(v - bf16f(hi));
    int kbase = ic*9 + dy*3;
    #pragma unroll
    for (int dx = 0; dx < 3; dx++) {
      int n = col - dx;
      if ((unsigned)n < 32u) {
        int k = kbase + dx;
        int ks = k >> 5, kk = k & 31;
        int nt = n >> 4, n16 = n & 15;
        int pos = (((ks*2 + nt)*64) + (n16 | ((kk >> 3) << 4)))*8 + (kk & 7);
        Xhi_l[pos] = hi;
        Xlo_l[pos] = lo;
      }
    }
  }
  __syncthreads();

  const int lane = tid & 63;
  const int mt = tid >> 6;          // 0..15
  f4v acc0 = {0.f,0.f,0.f,0.f}, acc1 = acc0;
  const s8v* Ah = (const s8v*)Whi + (mt*36)*64 + lane;
  const s8v* Al = (const s8v*)Wlo + (mt*36)*64 + lane;
  const s8v* Bh = (const s8v*)Xhi_l + lane;
  const s8v* Bl = (const s8v*)Xlo_l + lane;
  #pragma unroll 3
  for (int ks = 0; ks < 18; ks++) {
    s8v ah  = Ah[ks*64];
    s8v al  = Al[ks*64];
    s8v bh0 = Bh[(ks*2 + 0)*64];
    s8v bl0 = Bl[(ks*2 + 0)*64];
    s8v bh1 = Bh[(ks*2 + 1)*64];
    s8v bl1 = Bl[(ks*2 + 1)*64];
    acc0 = __builtin_amdgcn_mfma_f32_16x16x32_bf16(ah, bh0, acc0, 0, 0, 0);
    acc0 = __builtin_amdgcn_mfma_f32_16x16x32_bf16(al, bh0, acc0, 0, 0, 0);
    acc0 = __builtin_amdgcn_mfma_f32_16x16x32_bf16(ah, bl0, acc0, 0, 0, 0);
    acc1 = __builtin_amdgcn_mfma_f32_16x16x32_bf16(ah, bh1, acc1, 0, 0, 0);
    acc1 = __builtin_amdgcn_mfma_f32_16x16x32_bf16(al, bh1, acc1, 0, 0, 0);
    acc1 = __builtin_amdgcn_mfma_f32_16x16x32_bf16(ah, bl1, acc1, 0, 0, 0);
  }
  const int c16 = lane & 15;
  const int rb  = (lane >> 4) * 4;
  float* gout = gx + (((long)b*SS + t)*256)*NN + y*32;
  #pragma unroll
  for (int r = 0; r < 4; r++) {
    gout[(mt*16 + rb + r)*NN + c16]      = acc0[r];
    gout[(mt*16 + rb + r)*NN + 16 + c16] = acc1[r];
  }
}

// ---------- K1: conv_h (MFMA split-bf16) + LSTM(+gx) + projections (1024 threads) ----------
__global__ __launch_bounds__(1024, 2) void k1_conv_lstm_proj(
    int t,
    const float* __restrict__ gx,
    const unsigned short* __restrict__ Whi, const unsigned short* __restrict__ Wlo,
    const float* __restrict__ conv_b,
    const float* __restrict__ W_ci, const float* __restrict__ W_cf, const float* __restrict__ W_co,
    const float* __restrict__ qw, const float* __restrict__ qb,
    const float* __restrict__ kw, const float* __restrict__ kb,
    const float* __restrict__ k2w, const float* __restrict__ k2b,
    const float* __restrict__ vw, const float* __restrict__ vb,
    const float* __restrict__ v2w, const float* __restrict__ v2b,
    const float* __restrict__ h_cur, float* __restrict__ h_nxt,
    float* __restrict__ c_st,
    float* __restrict__ q_buf,
    unsigned short* __restrict__ kF,
    unsigned short* __restrict__ vFh, unsigned short* __restrict__ vFl)
{
  __shared__ __align__(16) unsigned short Ihi_l[18*64*8];      // h-only im2col, B-frag order
  __shared__ __align__(16) unsigned short Ilo_l[18*64*8];
  __shared__ __align__(16) float gates_l[256*17];              // [oc][x]; later proj_l[176][16]
  __shared__ __align__(16) float h_l[16*68];                   // [x][c]
  __shared__ __align__(16) float c_l[16*68];
  __shared__ __align__(16) float pw_l[176*68];                 // proj weights staged in LDS
  __shared__ __align__(16) float pb_l[176];

  const int tid = threadIdx.x;
  const int bid = blockIdx.x;
  const int b  = bid >> 6;
  const int y  = (bid >> 1) & 31;
  const int x0 = (bid & 1) * 16;
  const int mt = bid & 63;          // this block's 16-col m-tile (= n>>4)
  const int n0 = y*32 + x0;

  // ---- prefetch LSTM inputs into registers ----
  const int px = tid & 15;
  const int pc = tid >> 4;          // 0..63
  const int pn = n0 + px;
  const float* gxp = gx + (((long)b*SS + t)*256)*NN + pn;
  float pf_g0 = gxp[(pc      )*NN];
  float pf_g1 = gxp[( 64 + pc)*NN];
  float pf_g2 = gxp[(128 + pc)*NN];
  float pf_g3 = gxp[(192 + pc)*NN];
  float pf_cp  = c_st[(b*64 + pc)*NN + pn];
  float pf_wci = W_ci[pc*NN + pn];
  float pf_wcf = W_cf[pc*NN + pn];
  float pf_wco = W_co[pc*NN + pn];
  float pf_b0 = conv_b[pc];
  float pf_b1 = conv_b[ 64 + pc];
  float pf_b2 = conv_b[128 + pc];
  float pf_b3 = conv_b[192 + pc];

  // ---- phase 0: h-only im2col -> B-frags  +  stage proj weights into LDS ----
  for (int idx = tid; idx < 64*3*18; idx += 1024) {
    int col = idx % 18;
    int rest = idx / 18;
    int dy = rest % 3;
    int ic = rest / 3;                    // h channel 0..63
    int gy = y + dy - 1;
    int gxc = x0 + col - 1;
    float v = 0.0f;
    if ((unsigned)gy < 32u && (unsigned)gxc < 32u)
      v = h_cur[((b*64 + ic)*NN) + gy*32 + gxc];
    unsigned short hi = bf16r(v);
    unsigned short lo = bf16r(v - bf16f(hi));
    int kbase = ic*9 + dy*3;              // local k in [0,576)
    #pragma unroll
    for (int dx = 0; dx < 3; dx++) {
      int n = col - dx;
      if ((unsigned)n < 16u) {
        int k = kbase + dx;
        int ks = k >> 5, kk = k & 31;
        int pos = (ks*64 + (n | ((kk >> 3) << 4)))*8 + (kk & 7);
        Ihi_l[pos] = hi;
        Ilo_l[pos] = lo;
      }
    }
  }
  for (int idx = tid; idx < 176*64; idx += 1024) {
    int po = idx >> 6, c = idx & 63;
    float v;
    if (po < 16)       v = qw[po*64 + c];
    else if (po < 32)  v = kw[(po-16)*64 + c];
    else if (po < 96)  v = vw[(po-32)*64 + c];
    else if (po < 112) v = k2w[(po-96)*64 + c];
    else               v = v2w[(po-112)*64 + c];
    pw_l[po*68 + c] = v;
  }
  if (tid < 176) {
    int po = tid;
    float v;
    if (po < 16)       v = qb[po];
    else if (po < 32)  v = kb[po-16];
    else if (po < 96)  v = vb[po-32];
    else if (po < 112) v = k2b[po-96];
    else               v = v2b[po-112];
    pb_l[po] = v;
  }
  __syncthreads();

  // ---- phase 1: conv_h MFMA: 16 waves, 1 m-tile each; A-frags at ks 18..35 ----
  {
    const int lane = tid & 63;
    const int wv   = tid >> 6;        // 0..15 = m-tile
    f4v acc = {0.f, 0.f, 0.f, 0.f};
    const s8v* Ah = (const s8v*)Whi + (wv*36 + 18)*64 + lane;
    const s8v* Al = (const s8v*)Wlo + (wv*36 + 18)*64 + lane;
    const s8v* Bh = (const s8v*)Ihi_l + lane;
    const s8v* Bl = (const s8v*)Ilo_l + lane;
    #pragma unroll 3
    for (int ks = 0; ks < 18; ks++) {
      s8v ah = Ah[ks*64];
      s8v al = Al[ks*64];
      s8v bh = Bh[ks*64];
      s8v bl = Bl[ks*64];
      acc = __builtin_amdgcn_mfma_f32_16x16x32_bf16(ah, bh, acc, 0, 0, 0);
      acc = __builtin_amdgcn_mfma_f32_16x16x32_bf16(al, bh, acc, 0, 0, 0);
      acc = __builtin_amdgcn_mfma_f32_16x16x32_bf16(ah, bl, acc, 0, 0, 0);
    }
    const int colx = lane & 15;
    const int rb   = (lane >> 4) * 4;
    #pragma unroll
    for (int r = 0; r < 4; r++)
      gates_l[(wv*16 + rb + r)*17 + colx] = acc[r];
  }
  __syncthreads();

  // ---- phase 2: LSTM elementwise (prefetched inputs) ----
  {
    const int x = px;
    const int c = pc;
    const int n = pn;
    float ig = gates_l[(c      )*17 + x] + pf_g0 + pf_b0;
    float fg = gates_l[( 64 + c)*17 + x] + pf_g1 + pf_b1;
    float gg = gates_l[(128 + c)*17 + x] + pf_g2 + pf_b2;
    float og = gates_l[(192 + c)*17 + x] + pf_g3 + pf_b3;
    float cp = pf_cp;
    float i_ = sigm(ig + pf_wci * cp);
    float f_ = sigm(fg + pf_wcf * cp);
    float cn = f_*cp + i_*tanh_f(gg);
    float o_ = sigm(og + pf_wco * cn);
    float hn = o_*tanh_f(cn);
    h_nxt[(b*64 + c)*NN + n] = hn;
    c_st[(b*64 + c)*NN + n] = cn;
    h_l[x*68 + c] = hn;
    c_l[x*68 + c] = cn;
  }
  __syncthreads();

  // ---- phase 3: projections (weights from LDS) -> LDS staging ----
  float* proj_l = gates_l;
  #pragma unroll
  for (int r0 = 0; r0 < 3; r0++) {
    int task = tid + r0*1024;
    if (task < 176*16) {
      int po = task >> 4, x = task & 15;
      const float* src = (po < 96) ? &h_l[x*68] : &c_l[x*68];
      const float* w = &pw_l[po*68];
      float s = pb_l[po];
      #pragma unroll
      for (int k = 0; k < 64; k += 4) {
        float4 wv = *(const float4*)&w[k];
        float4 sv = *(const float4*)&src[k];
        s = fmaf(wv.x, sv.x, s); s = fmaf(wv.y, sv.y, s);
        s = fmaf(wv.z, sv.z, s); s = fmaf(wv.w, sv.w, s);
      }
      proj_l[po*16 + x] = s;
    }
  }
  __syncthreads();

  // ---- phase 4: coalesced fragment emission ----
  if (tid < 256) {
    int d = tid >> 4, x = tid & 15;
    q_buf[(b*16 + d)*NN + n0 + x] = proj_l[d*16 + x];
  }
  if (tid < 512) {
    int brh2 = tid >> 8;            // branch
    int lh   = (tid >> 2) & 63;     // fragment "lane-half" row
    int j2   = tid & 3;             // packs d&7 = 2*j2, 2*j2+1
    int p    = lh >> 4;             // 0,1: hi planes; 2,3: lo planes
    int x    = lh & 15;
    int d0   = ((p & 1) << 3) | (j2 << 1);
    int Koff = brh2 ? 96 : 16;
    float v0 = proj_l[(Koff + d0)*16 + x];
    float v1 = proj_l[(Koff + d0 + 1)*16 + x];
    unsigned short h0 = bf16r(v0), h1 = bf16r(v1);
    unsigned short u0, u1;
    if (p < 2) { u0 = h0; u1 = h1; }
    else       { u0 = bf16r(v0 - bf16f(h0)); u1 = bf16r(v1 - bf16f(h1)); }
    unsigned int* dst = (unsigned int*)(kF + ((b*2 + brh2)*64 + mt)*512);
    dst[lh*4 + j2] = (unsigned)u0 | ((unsigned)u1 << 16);
  }
  {
    const int ks = y;
    const int g0 = x0 >> 3;         // 0 or 2
    #pragma unroll
    for (int it = 0; it < 2; it++) {
      int ct    = tid + it*1024;
      int plane = ct >> 10;         // 0 = vFh, 1 = vFl
      int brh2  = (ct >> 9) & 1;
      int nt    = (ct >> 7) & 3;
      int li    = (ct >> 2) & 31;
      int j2    = ct & 3;
      int lane2 = g0*16 + li;
      int cch   = nt*16 + (lane2 & 15);
      int xx    = ((li >> 4) << 3) | (j2 << 1);
      int Voff  = brh2 ? 112 : 32;
      float v0 = proj_l[(Voff + cch)*16 + xx];
      float v1 = proj_l[(Voff + cch)*16 + xx + 1];
      unsigned short h0 = bf16r(v0), h1 = bf16r(v1);
      unsigned short u0, u1;
      if (plane == 0) { u0 = h0; u1 = h1; }
      else            { u0 = bf16r(v0 - bf16f(h0)); u1 = bf16r(v1 - bf16f(h1)); }
      unsigned short* basep = (plane ? vFl : vFh) + (((b*2 + brh2)*32 + ks)*4 + nt)*512;
      ((unsigned int*)basep)[lane2*4 + j2] = (unsigned)u0 | ((unsigned)u1 << 16);
    }
  }
}

// ---------- K2: dual attention via MFMA + MFMA combine + gating ----------
#define RED_OFF 0        // [16 waves][16 nl][66]  = 16896
#define PS_OFF  16896    // [16 waves][16][36]     = 9216
#define SMX_OFF 26112    // [2][8][16]             = 256
#define SSM_OFF 26368    // [2][8][16]             = 256
#define INV_OFF 26624    // [2][16]                = 32
#define ZHM_OFF 26656    // [128][16]              = 2048
#define S_TOT   28704

__global__ __launch_bounds__(1024, 4) void k2_attn(
    int t,
    const float* __restrict__ q_buf,
    const unsigned short* __restrict__ kF,
    const unsigned short* __restrict__ vFh, const unsigned short* __restrict__ vFl,
    float* __restrict__ h_nxt, float* __restrict__ c_st,
    const unsigned short* __restrict__ zAhi, const unsigned short* __restrict__ zAlo,
    const unsigned short* __restrict__ mAhi, const unsigned short* __restrict__ mAlo,
    const float* __restrict__ z_b, const float* __restrict__ m_b,
    float* __restrict__ out)
{
  __shared__ __align__(16) float S[S_TOT];
  float* red  = S + RED_OFF;
  float* smMax= S + SMX_OFF;
  float* smSum= S + SSM_OFF;
  float* invL = S + INV_OFF;
  float* zhm  = S + ZHM_OFF;
  float* cbIn = S;              // [192][16] aliases red (after barrier)
  float* cbOut= S + 3072;       // [192][16] aliases red

  const int tid = threadIdx.x;
  const int bid = blockIdx.x;
  const int xcd = bid & 7;
  const int b = xcd >> 1;
  const int tile = ((bid >> 3) << 1) | (xcd & 1);   // 0..63
  const int n0 = tile * 16;

  const int wid  = tid >> 6;
  const int lane = tid & 63;
  const int brh  = wid >> 3;      // branch
  const int w    = wid & 7;       // wave within branch
  const int g    = lane >> 4;
  const int c16  = lane & 15;

  // ---- prefetch tail-phase inputs ----
  const int pc2 = tid >> 4;       // 0..63
  const int pn2 = n0 + (tid & 15);
  float pf_cst = c_st[(b*64 + pc2)*NN + pn2];
  float pf_h   = h_nxt[(b*64 + pc2)*NN + pn2];

  // ---- Q A-frags: A1 = [Qh|Qh], A2 = [Ql|0] ----
  s8v qh1, ql2;
  {
    const int dbase = (g & 1) * 8;
    #pragma unroll
    for (int j = 0; j < 8; j++) {
      float qv = q_buf[(b*16 + dbase + j)*NN + n0 + c16];
      unsigned short hi = bf16r(qv);
      unsigned short lo = bf16r(qv - bf16f(hi));
      qh1[j] = (short)hi;
      ql2[j] = (g < 2) ? (short)lo : (short)0;
    }
  }

  // ---- scores: 8 m-tiles per wave, 2 MFMA each (B = [Kh|Kl]) ----
  f4v acc[8];
  {
    const unsigned short* kp = kF + (((b*2 + brh)*64 + w*8)*64 + lane)*8;
    #pragma unroll
    for (int i = 0; i < 8; i++) {
      s8v bf = *(const s8v*)(kp + i*512);
      f4v z4 = {0.f, 0.f, 0.f, 0.f};
      z4 = __builtin_amdgcn_mfma_f32_16x16x32_bf16(ql2, bf, z4, 0, 0, 0);
      acc[i] = __builtin_amdgcn_mfma_f32_16x16x32_bf16(qh1, bf, z4, 0, 0, 0);
    }
  }

  // ---- softmax ----
  float Mrow[4];
  #pragma unroll
  for (int r = 0; r < 4; r++) {
    float m = acc[0][r];
    #pragma unroll
    for (int i = 1; i < 8; i++) m = fmaxf(m, acc[i][r]);
    m = fmaxf(m, __shfl_xor(m, 1));
    m = fmaxf(m, __shfl_xor(m, 2));
    m = fmaxf(m, __shfl_xor(m, 4));
    m = fmaxf(m, __shfl_xor(m, 8));
    if (c16 == 0) smMax[(brh*8 + w)*16 + g*4 + r] = m;
  }
  __syncthreads();
  #pragma unroll
  for (int r = 0; r < 4; r++) {
    float m = smMax[(brh*8 + 0)*16 + g*4 + r];
    #pragma unroll
    for (int w2 = 1; w2 < 8; w2++) m = fmaxf(m, smMax[(brh*8 + w2)*16 + g*4 + r]);
    Mrow[r] = m;
  }
  float rsum[4] = {0.f, 0.f, 0.f, 0.f};
  #pragma unroll
  for (int i = 0; i < 8; i++) {
    #pragma unroll
    for (int r = 0; r < 4; r++) {
      float p = __expf(acc[i][r] - Mrow[r]);
      acc[i][r] = p;
      rsum[r] += p;
    }
  }
  #pragma unroll
  for (int r = 0; r < 4; r++) {
    float s = rsum[r];
    s += __shfl_xor(s, 1); s += __shfl_xor(s, 2);
    s += __shfl_xor(s, 4); s += __shfl_xor(s, 8);
    if (c16 == 0) smSum[(brh*8 + w)*16 + g*4 + r] = s;
  }
  __syncthreads();
  if (w == 0 && c16 == 0) {
    #pragma unroll
    for (int r = 0; r < 4; r++) {
      float s = 0.f;
      #pragma unroll
      for (int w2 = 0; w2 < 8; w2++) s += smSum[(brh*8 + w2)*16 + g*4 + r];
      invL[brh*16 + g*4 + r] = 1.0f / s;
    }
  }

  // ---- PV: per wave, 4 k-steps of 32 m; wave-local P transpose; 3-term split ----
  f4v z0 = {0.f,0.f,0.f,0.f}, z1 = z0, z2 = z0, z3 = z0;
  float* myPS = S + PS_OFF + wid*576;   // [16][36]
  #pragma unroll
  for (int ks4 = 0; ks4 < 4; ks4++) {
    #pragma unroll
    for (int i2 = 0; i2 < 2; i2++) {
      #pragma unroll
      for (int r = 0; r < 4; r++)
        myPS[(g*4 + r)*36 + i2*16 + c16] = acc[ks4*2 + i2][r];
    }
    float4 pa = *(const float4*)&myPS[c16*36 + g*8];
    float4 pb = *(const float4*)&myPS[c16*36 + g*8 + 4];
    s8v ph, pl;
    {
      unsigned short h0 = bf16r(pa.x); ph[0] = (short)h0; pl[0] = (short)bf16r(pa.x - bf16f(h0));
      unsigned short h1 = bf16r(pa.y); ph[1] = (short)h1; pl[1] = (short)bf16r(pa.y - bf16f(h1));
      unsigned short h2 = bf16r(pa.z); ph[2] = (short)h2; pl[2] = (short)bf16r(pa.z - bf16f(h2));
      unsigned short h3 = bf16r(pa.w); ph[3] = (short)h3; pl[3] = (short)bf16r(pa.w - bf16f(h3));
      unsigned short h4 = bf16r(pb.x); ph[4] = (short)h4; pl[4] = (short)bf16r(pb.x - bf16f(h4));
      unsigned short h5 = bf16r(pb.y); ph[5] = (short)h5; pl[5] = (short)bf16r(pb.y - bf16f(h5));
      unsigned short h6 = bf16r(pb.z); ph[6] = (short)h6; pl[6] = (short)bf16r(pb.z - bf16f(h6));
      unsigned short h7 = bf16r(pb.w); ph[7] = (short)h7; pl[7] = (short)bf16r(pb.w - bf16f(h7));
    }
    const int ks = w*4 + ks4;
    const unsigned short* vph = vFh + ((((b*2 + brh)*32 + ks)*4)*64 + lane)*8;
    const unsigned short* vpl = vFl + ((((b*2 + brh)*32 + ks)*4)*64 + lane)*8;
    s8v vh0 = *(const s8v*)(vph);
    s8v vl0 = *(const s8v*)(vpl);
    z0 = __builtin_amdgcn_mfma_f32_16x16x32_bf16(ph, vh0, z0, 0,0,0);
    z0 = __builtin_amdgcn_mfma_f32_16x16x32_bf16(ph, vl0, z0, 0,0,0);
    z0 = __builtin_amdgcn_mfma_f32_16x16x32_bf16(pl, vh0, z0, 0,0,0);
    s8v vh1 = *(const s8v*)(vph + 512);
    s8v vl1 = *(const s8v*)(vpl + 512);
    z1 = __builtin_amdgcn_mfma_f32_16x16x32_bf16(ph, vh1, z1, 0,0,0);
    z1 = __builtin_amdgcn_mfma_f32_16x16x32_bf16(ph, vl1, z1, 0,0,0);
    z1 = __builtin_amdgcn_mfma_f32_16x16x32_bf16(pl, vh1, z1, 0,0,0);
    s8v vh2 = *(const s8v*)(vph + 1024);
    s8v vl2 = *(const s8v*)(vpl + 1024);
    z2 = __builtin_amdgcn_mfma_f32_16x16x32_bf16(ph, vh2, z2, 0,0,0);
    z2 = __builtin_amdgcn_mfma_f32_16x16x32_bf16(ph, vl2, z2, 0,0,0);
    z2 = __builtin_amdgcn_mfma_f32_16x16x32_bf16(pl, vh2, z2, 0,0,0);
    s8v vh3 = *(const s8v*)(vph + 1536);
    s8v vl3 = *(const s8v*)(vpl + 1536);
    z3 = __builtin_amdgcn_mfma_f32_16x16x32_bf16(ph, vh3, z3, 0,0,0);
    z3 = __builtin_amdgcn_mfma_f32_16x16x32_bf16(ph, vl3, z3, 0,0,0);
    z3 = __builtin_amdgcn_mfma_f32_16x16x32_bf16(pl, vh3, z3, 0,0,0);
  }

  // ---- write partials, reduce 8 waves, normalize -> zhm ----
  {
    float* rw = red + wid*1056;
    #pragma unroll
    for (int r = 0; r < 4; r++) {
      rw[(g*4 + r)*66 +  0 + c16] = z0[r];
      rw[(g*4 + r)*66 + 16 + c16] = z1[r];
      rw[(g*4 + r)*66 + 32 + c16] = z2[r];
      rw[(g*4 + r)*66 + 48 + c16] = z3[r];
    }
  }
  __syncthreads();
  {
    const int br2 = tid >> 9;
    const int sub = tid & 511;
    const int nlr = sub >> 5;
    const int cc0 = (sub & 31) * 2;
    float iv = invL[br2*16 + nlr];
    #pragma unroll
    for (int u = 0; u < 2; u++) {
      int cc = cc0 + u;
      float s = 0.f;
      #pragma unroll
      for (int w2 = 0; w2 < 8; w2++)
        s += red[(br2*8 + w2)*1056 + nlr*66 + cc];
      zhm[(br2*64 + cc)*16 + nlr] = s * iv;
    }
  }
  __syncthreads();

  // ---- hf rows into cbIn + zz via MFMA (waves 0..7) ----
  cbIn[(128 + pc2)*16 + (tid & 15)] = pf_h;
  if (wid < 8) {
    f4v za = {0.f, 0.f, 0.f, 0.f};
    const s8v* Azh = (const s8v*)zAhi + (wid*4)*64 + lane;
    const s8v* Azl = (const s8v*)zAlo + (wid*4)*64 + lane;
    #pragma unroll
    for (int ks = 0; ks < 4; ks++) {
      s8v bh, bl;
      #pragma unroll
      for (int j = 0; j < 8; j++) {
        float v = zhm[(ks*32 + g*8 + j)*16 + c16];
        unsigned short h = bf16r(v);
        bh[j] = (short)h;
        bl[j] = (short)bf16r(v - bf16f(h));
      }
      s8v ah = Azh[ks*64];
      s8v al = Azl[ks*64];
      za = __builtin_amdgcn_mfma_f32_16x16x32_bf16(ah, bh, za, 0, 0, 0);
      za = __builtin_amdgcn_mfma_f32_16x16x32_bf16(al, bh, za, 0, 0, 0);
      za = __builtin_amdgcn_mfma_f32_16x16x32_bf16(ah, bl, za, 0, 0, 0);
    }
    #pragma unroll
    for (int r = 0; r < 4; r++) {
      int oc = wid*16 + g*4 + r;
      cbIn[oc*16 + c16] = za[r] + z_b[oc];
    }
  }
  __syncthreads();

  // ---- comb via MFMA (waves 0..11) ----
  if (wid < 12) {
    f4v ca = {0.f, 0.f, 0.f, 0.f};
    const s8v* Amh = (const s8v*)mAhi + (wid*6)*64 + lane;
    const s8v* Aml = (const s8v*)mAlo + (wid*6)*64 + lane;
    #pragma unroll
    for (int ks = 0; ks < 6; ks++) {
      s8v bh, bl;
      #pragma unroll
      for (int j = 0; j < 8; j++) {
        float v = cbIn[(ks*32 + g*8 + j)*16 + c16];
        unsigned short h = bf16r(v);
        bh[j] = (short)h;
        bl[j] = (short)bf16r(v - bf16f(h));
      }
      s8v ah = Amh[ks*64];
      s8v al = Aml[ks*64];
      ca = __builtin_amdgcn_mfma_f32_16x16x32_bf16(ah, bh, ca, 0, 0, 0);
      ca = __builtin_amdgcn_mfma_f32_16x16x32_bf16(al, bh, ca, 0, 0, 0);
      ca = __builtin_amdgcn_mfma_f32_16x16x32_bf16(ah, bl, ca, 0, 0, 0);
    }
    #pragma unroll
    for (int r = 0; r < 4; r++) {
      int oc = wid*16 + g*4 + r;
      cbOut[oc*16 + c16] = ca[r] + m_b[oc];
    }
  }
  __syncthreads();

  // ---- gating ----
  {
    const int c = pc2, nn = tid & 15;
    const int n = n0 + nn;
    float mo = cbOut[c*16 + nn];
    float mg = cbOut[(64 + c)*16 + nn];
    float mi = cbOut[(128 + c)*16 + nn];
    float mf = pf_cst;
    float mis = sigm(mi);
    float nmf = (1.0f - mis)*mf + mis*tanh_f(mg);
    float nhf = sigm(mo)*nmf;
    c_st[(b*64 + c)*NN + n] = nmf;
    h_nxt[(b*64 + c)*NN + n] = nhf;
    out[((b*64 + c)*SS + t)*NN + n] = nhf;
  }
}

extern "C" void kernel_launch(void* const* d_in, const int* in_sizes, int n_in,
                              void* d_out, int out_size, void* d_ws, size_t ws_size,
                              hipStream_t stream) {
  const float* X      = (const float*)d_in[0];
  const float* conv_w = (const float*)d_in[1];
  const float* conv_b = (const float*)d_in[2];
  const float* W_ci   = (const float*)d_in[3];
  const float* W_cf   = (const float*)d_in[4];
  const float* W_co   = (const float*)d_in[5];
  const float* qw  = (const float*)d_in[6];
  const float* qb  = (const float*)d_in[7];
  const float* kw  = (const float*)d_in[8];
  const float* kb  = (const float*)d_in[9];
  const float* k2w = (const float*)d_in[10];
  const float* k2b = (const float*)d_in[11];
  const float* vw  = (const float*)d_in[12];
  const float* vb  = (const float*)d_in[13];
  const float* v2w = (const float*)d_in[14];
  const float* v2b = (const float*)d_in[15];
  const float* z_w = (const float*)d_in[16];
  const float* z_b = (const float*)d_in[17];
  const float* m_w = (const float*)d_in[18];
  const float* m_b = (const float*)d_in[19];
  float* out = (float*)d_out;

  float* ws = (float*)d_ws;
  unsigned short* Whi  = (unsigned short*)ws;  ws += 147456;   // 294912 ushorts
  unsigned short* Wlo  = (unsigned short*)ws;  ws += 147456;
  unsigned short* zAhi = (unsigned short*)ws;  ws += 8192;     // 16384 ushorts
  unsigned short* zAlo = (unsigned short*)ws;  ws += 8192;
  unsigned short* mAhi = (unsigned short*)ws;  ws += 18432;    // 36864 ushorts
  unsigned short* mAlo = (unsigned short*)ws;  ws += 18432;
  float* h_A    = ws;             ws += NB*64*NN;
  float* h_B    = ws;             ws += NB*64*NN;
  float* c_st   = ws;             ws += NB*64*NN;
  float* q_buf  = ws;             ws += NB*16*NN;
  unsigned short* kF  = (unsigned short*)ws;  ws += 131072;   // 4b*2br*64mt*64*8 ushorts
  unsigned short* vFh = (unsigned short*)ws;  ws += 131072;   // 4b*2br*32ks*4nt*64*8
  unsigned short* vFl = (unsigned short*)ws;  ws += 131072;
  float* gx     = ws;             ws += NB*SS*256*NN;         // 16.8M floats, 67 MB

  hipLaunchKernelGGL(k0_prep, dim3(256), dim3(256), 0, stream,
                     conv_w, z_w, m_w, Whi, Wlo, zAhi, zAlo, mAhi, mAlo, h_A, c_st);
  hipLaunchKernelGGL(k0b_gx, dim3(2048), dim3(1024), 0, stream,
                     X, Whi, Wlo, gx);
  for (int t = 0; t < 16; t++) {
    const float* h_cur = (t & 1) ? h_B : h_A;
    float* h_nxt       = (t & 1) ? h_A : h_B;
    hipLaunchKernelGGL(k1_conv_lstm_proj, dim3(256), dim3(1024), 0, stream,
        t, gx, Whi, Wlo, conv_b, W_ci, W_cf, W_co,
        qw, qb, kw, kb, k2w, k2b, vw, vb, v2w, v2b,
        h_cur, h_nxt, c_st, q_buf, kF, vFh, vFl);
    hipLaunchKernelGGL(k2_attn, dim3(256), dim3(1024), 0, stream,
        t, q_buf, kF, vFh, vFl, h_nxt, c_st,
        zAhi, zAlo, mAhi, mAlo, z_b, m_b, out);
  }
}

// Round 13
// 598.490 us; speedup vs baseline: 1.2864x; 1.0797x over previous
//
#include <hip/hip_runtime.h>
#include <math.h>

#define NB 4
#define SS 16
#define NN 1024        // H*W

typedef short s8v __attribute__((ext_vector_type(8)));    // 8 bf16 (4 VGPR)
typedef float f4v __attribute__((ext_vector_type(4)));    // MFMA accumulator

__device__ __forceinline__ float sigm(float x) {
  return 1.0f / (1.0f + __expf(-x));
}
__device__ __forceinline__ float tanh_f(float x) {
  float e = __expf(2.0f * x);
  return 1.0f - 2.0f / (1.0f + e);
}
__device__ __forceinline__ unsigned short bf16r(float x) {   // RNE float->bf16
  unsigned int u = __float_as_uint(x);
  u = (u + 0x7FFFu + ((u >> 16) & 1u)) >> 16;
  return (unsigned short)u;
}
__device__ __forceinline__ float bf16f(unsigned short h) {
  return __uint_as_float(((unsigned int)h) << 16);
}

// ---------- prep: weight split/pack (conv + proj + z_w + m_w A-frags) + zero states ----------
__global__ void k0_prep(const float* __restrict__ conv_w, const float* __restrict__ z_w,
                        const float* __restrict__ m_w,
                        const float* __restrict__ qw, const float* __restrict__ kw,
                        const float* __restrict__ vw, const float* __restrict__ k2w,
                        const float* __restrict__ v2w,
                        unsigned short* __restrict__ Whi, unsigned short* __restrict__ Wlo,
                        unsigned short* __restrict__ zAhi, unsigned short* __restrict__ zAlo,
                        unsigned short* __restrict__ mAhi, unsigned short* __restrict__ mAlo,
                        unsigned short* __restrict__ pAhi, unsigned short* __restrict__ pAlo,
                        float* __restrict__ h_A, float* __restrict__ c_st) {
  int stride = gridDim.x * blockDim.x;
  int i0 = blockIdx.x * blockDim.x + threadIdx.x;
  for (int i = i0; i < 256*1152; i += stride) {
    int oc = i / 1152, k = i - oc*1152;          // k = icComb*9 + ky*3 + kx
    float v = conv_w[i];
    unsigned short hi = bf16r(v);
    unsigned short lo = bf16r(v - bf16f(hi));
    int mt = oc >> 4, i16 = oc & 15;
    int ks = k >> 5, kk = k & 31;
    int lane = i16 | ((kk >> 3) << 4);
    int pos = ((mt*36 + ks)*64 + lane)*8 + (kk & 7);
    Whi[pos] = hi;
    Wlo[pos] = lo;
  }
  for (int i = i0; i < 128*128; i += stride) {   // z_w A-frags: 8 mt x 4 ks
    int oc = i >> 7, k = i & 127;
    float v = z_w[i];
    unsigned short hi = bf16r(v);
    unsigned short lo = bf16r(v - bf16f(hi));
    int mt = oc >> 4, i16 = oc & 15;
    int ks = k >> 5, kk = k & 31;
    int lane = i16 | ((kk >> 3) << 4);
    int pos = ((mt*4 + ks)*64 + lane)*8 + (kk & 7);
    zAhi[pos] = hi;
    zAlo[pos] = lo;
  }
  for (int i = i0; i < 192*192; i += stride) {   // m_w A-frags: 12 mt x 6 ks
    int oc = i / 192, k = i - oc*192;
    float v = m_w[i];
    unsigned short hi = bf16r(v);
    unsigned short lo = bf16r(v - bf16f(hi));
    int mt = oc >> 4, i16 = oc & 15;
    int ks = k >> 5, kk = k & 31;
    int lane = i16 | ((kk >> 3) << 4);
    int pos = ((mt*6 + ks)*64 + lane)*8 + (kk & 7);
    mAhi[pos] = hi;
    mAlo[pos] = lo;
  }
  for (int i = i0; i < 176*64; i += stride) {    // proj A-frags: 11 mt x 2 ks
    int po = i >> 6, c = i & 63;
    float v;
    if (po < 16)       v = qw[po*64 + c];
    else if (po < 32)  v = kw[(po-16)*64 + c];
    else if (po < 96)  v = vw[(po-32)*64 + c];
    else if (po < 112) v = k2w[(po-96)*64 + c];
    else               v = v2w[(po-112)*64 + c];
    unsigned short hi = bf16r(v);
    unsigned short lo = bf16r(v - bf16f(hi));
    int mt = po >> 4, i16 = po & 15;
    int ks = c >> 5, kk = c & 31;
    int lane = i16 | ((kk >> 3) << 4);
    int pos = ((mt*2 + ks)*64 + lane)*8 + (kk & 7);
    pAhi[pos] = hi;
    pAlo[pos] = lo;
  }
  for (int i = i0; i < NB*64*NN; i += stride) { h_A[i] = 0.0f; c_st[i] = 0.0f; }
}

// ---------- K0b (v1): conv_x for ALL (b,t) — parallel GEMM ----------
__global__ __launch_bounds__(1024, 2) void k0b_gx(
    const float* __restrict__ X,
    const unsigned short* __restrict__ Whi, const unsigned short* __restrict__ Wlo,
    float* __restrict__ gx)
{
  __shared__ __align__(16) unsigned short Xhi_l[18*2*64*8];   // [ks][nt][lane][8]
  __shared__ __align__(16) unsigned short Xlo_l[18*2*64*8];

  const int tid = threadIdx.x;
  const int bid = blockIdx.x;       // b*512 + t*32 + y
  const int y = bid & 31;
  const int t = (bid >> 5) & 15;
  const int b = bid >> 9;

  for (int idx = tid; idx < 64*3*34; idx += 1024) {
    int col = idx % 34;
    int rest = idx / 34;
    int dy = rest % 3;
    int ic = rest / 3;
    int gy = y + dy - 1;
    int gxc = col - 1;
    float v = 0.0f;
    if ((unsigned)gy < 32u && (unsigned)gxc < 32u)
      v = X[(((b*64 + ic)*SS + t)*NN) + gy*32 + gxc];
    unsigned short hi = bf16r(v);
    unsigned short lo = bf16r(v - bf16f(hi));
    int kbase = ic*9 + dy*3;
    #pragma unroll
    for (int dx = 0; dx < 3; dx++) {
      int n = col - dx;
      if ((unsigned)n < 32u) {
        int k = kbase + dx;
        int ks = k >> 5, kk = k & 31;
        int nt = n >> 4, n16 = n & 15;
        int pos = (((ks*2 + nt)*64) + (n16 | ((kk >> 3) << 4)))*8 + (kk & 7);
        Xhi_l[pos] = hi;
        Xlo_l[pos] = lo;
      }
    }
  }
  __syncthreads();

  const int lane = tid & 63;
  const int mt = tid >> 6;          // 0..15
  f4v acc0 = {0.f,0.f,0.f,0.f}, acc1 = acc0;
  const s8v* Ah = (const s8v*)Whi + (mt*36)*64 + lane;
  const s8v* Al = (const s8v*)Wlo + (mt*36)*64 + lane;
  const s8v* Bh = (const s8v*)Xhi_l + lane;
  const s8v* Bl = (const s8v*)Xlo_l + lane;
  #pragma unroll 3
  for (int ks = 0; ks < 18; ks++) {
    s8v ah  = Ah[ks*64];
    s8v al  = Al[ks*64];
    s8v bh0 = Bh[(ks*2 + 0)*64];
    s8v bl0 = Bl[(ks*2 + 0)*64];
    s8v bh1 = Bh[(ks*2 + 1)*64];
    s8v bl1 = Bl[(ks*2 + 1)*64];
    acc0 = __builtin_amdgcn_mfma_f32_16x16x32_bf16(ah, bh0, acc0, 0, 0, 0);
    acc0 = __builtin_amdgcn_mfma_f32_16x16x32_bf16(al, bh0, acc0, 0, 0, 0);
    acc0 = __builtin_amdgcn_mfma_f32_16x16x32_bf16(ah, bl0, acc0, 0, 0, 0);
    acc1 = __builtin_amdgcn_mfma_f32_16x16x32_bf16(ah, bh1, acc1, 0, 0, 0);
    acc1 = __builtin_amdgcn_mfma_f32_16x16x32_bf16(al, bh1, acc1, 0, 0, 0);
    acc1 = __builtin_amdgcn_mfma_f32_16x16x32_bf16(ah, bl1, acc1, 0, 0, 0);
  }
  const int c16 = lane & 15;
  const int rb  = (lane >> 4) * 4;
  float* gout = gx + (((long)b*SS + t)*256)*NN + y*32;
  #pragma unroll
  for (int r = 0; r < 4; r++) {
    gout[(mt*16 + rb + r)*NN + c16]      = acc0[r];
    gout[(mt*16 + rb + r)*NN + 16 + c16] = acc1[r];
  }
}

// ---------- K1: conv_h + LSTM(+gx) + MFMA projections (1024 threads) ----------
__global__ __launch_bounds__(1024, 2) void k1_conv_lstm_proj(
    int t,
    const float* __restrict__ gx,
    const unsigned short* __restrict__ Whi, const unsigned short* __restrict__ Wlo,
    const unsigned short* __restrict__ pAhi, const unsigned short* __restrict__ pAlo,
    const float* __restrict__ conv_b,
    const float* __restrict__ W_ci, const float* __restrict__ W_cf, const float* __restrict__ W_co,
    const float* __restrict__ qb, const float* __restrict__ kb,
    const float* __restrict__ vb, const float* __restrict__ k2b,
    const float* __restrict__ v2b,
    const float* __restrict__ h_cur, float* __restrict__ h_nxt,
    float* __restrict__ c_st,
    float* __restrict__ q_buf,
    unsigned short* __restrict__ kF,
    unsigned short* __restrict__ vFh, unsigned short* __restrict__ vFl)
{
  __shared__ __align__(16) unsigned short Ihi_l[18*64*8];      // h-only im2col, B-frag order
  __shared__ __align__(16) unsigned short Ilo_l[18*64*8];
  __shared__ __align__(16) float gates_l[256*17];              // [oc][x]; later proj_l[176][16]
  __shared__ __align__(16) unsigned short hBh[2*64*8];         // h in B-frag layout (hi/lo)
  __shared__ __align__(16) unsigned short hBl[2*64*8];
  __shared__ __align__(16) unsigned short cBh[2*64*8];         // c in B-frag layout
  __shared__ __align__(16) unsigned short cBl[2*64*8];
  __shared__ __align__(16) float pb_l[176];

  const int tid = threadIdx.x;
  const int bid = blockIdx.x;
  const int b  = bid >> 6;
  const int y  = (bid >> 1) & 31;
  const int x0 = (bid & 1) * 16;
  const int mt = bid & 63;          // this block's 16-col m-tile (= n>>4)
  const int n0 = y*32 + x0;

  // ---- prefetch LSTM inputs into registers ----
  const int px = tid & 15;
  const int pc = tid >> 4;          // 0..63
  const int pn = n0 + px;
  const float* gxp = gx + (((long)b*SS + t)*256)*NN + pn;
  float pf_g0 = gxp[(pc      )*NN];
  float pf_g1 = gxp[( 64 + pc)*NN];
  float pf_g2 = gxp[(128 + pc)*NN];
  float pf_g3 = gxp[(192 + pc)*NN];
  float pf_cp  = c_st[(b*64 + pc)*NN + pn];
  float pf_wci = W_ci[pc*NN + pn];
  float pf_wcf = W_cf[pc*NN + pn];
  float pf_wco = W_co[pc*NN + pn];
  float pf_b0 = conv_b[pc];
  float pf_b1 = conv_b[ 64 + pc];
  float pf_b2 = conv_b[128 + pc];
  float pf_b3 = conv_b[192 + pc];

  // ---- phase 0: h-only im2col -> B-frags  +  stage proj biases ----
  for (int idx = tid; idx < 64*3*18; idx += 1024) {
    int col = idx % 18;
    int rest = idx / 18;
    int dy = rest % 3;
    int ic = rest / 3;                    // h channel 0..63
    int gy = y + dy - 1;
    int gxc = x0 + col - 1;
    float v = 0.0f;
    if ((unsigned)gy < 32u && (unsigned)gxc < 32u)
      v = h_cur[((b*64 + ic)*NN) + gy*32 + gxc];
    unsigned short hi = bf16r(v);
    unsigned short lo = bf16r(v - bf16f(hi));
    int kbase = ic*9 + dy*3;              // local k in [0,576)
    #pragma unroll
    for (int dx = 0; dx < 3; dx++) {
      int n = col - dx;
      if ((unsigned)n < 16u) {
        int k = kbase + dx;
        int ks = k >> 5, kk = k & 31;
        int pos = (ks*64 + (n | ((kk >> 3) << 4)))*8 + (kk & 7);
        Ihi_l[pos] = hi;
        Ilo_l[pos] = lo;
      }
    }
  }
  if (tid < 176) {
    int po = tid;
    float v;
    if (po < 16)       v = qb[po];
    else if (po < 32)  v = kb[po-16];
    else if (po < 96)  v = vb[po-32];
    else if (po < 112) v = k2b[po-96];
    else               v = v2b[po-112];
    pb_l[po] = v;
  }
  __syncthreads();

  // ---- phase 1: conv_h MFMA: 16 waves, 1 m-tile each; A-frags at ks 18..35 ----
  {
    const int lane = tid & 63;
    const int wv   = tid >> 6;        // 0..15 = m-tile
    f4v acc = {0.f, 0.f, 0.f, 0.f};
    const s8v* Ah = (const s8v*)Whi + (wv*36 + 18)*64 + lane;
    const s8v* Al = (const s8v*)Wlo + (wv*36 + 18)*64 + lane;
    const s8v* Bh = (const s8v*)Ihi_l + lane;
    const s8v* Bl = (const s8v*)Ilo_l + lane;
    #pragma unroll 3
    for (int ks = 0; ks < 18; ks++) {
      s8v ah = Ah[ks*64];
      s8v al = Al[ks*64];
      s8v bh = Bh[ks*64];
      s8v bl = Bl[ks*64];
      acc = __builtin_amdgcn_mfma_f32_16x16x32_bf16(ah, bh, acc, 0, 0, 0);
      acc = __builtin_amdgcn_mfma_f32_16x16x32_bf16(al, bh, acc, 0, 0, 0);
      acc = __builtin_amdgcn_mfma_f32_16x16x32_bf16(ah, bl, acc, 0, 0, 0);
    }
    const int colx = lane & 15;
    const int rb   = (lane >> 4) * 4;
    #pragma unroll
    for (int r = 0; r < 4; r++)
      gates_l[(wv*16 + rb + r)*17 + colx] = acc[r];
  }
  __syncthreads();

  // ---- phase 2: LSTM elementwise; write h/c into B-frag layout ----
  {
    const int x = px;
    const int c = pc;
    const int n = pn;
    float ig = gates_l[(c      )*17 + x] + pf_g0 + pf_b0;
    float fg = gates_l[( 64 + c)*17 + x] + pf_g1 + pf_b1;
    float gg = gates_l[(128 + c)*17 + x] + pf_g2 + pf_b2;
    float og = gates_l[(192 + c)*17 + x] + pf_g3 + pf_b3;
    float cp = pf_cp;
    float i_ = sigm(ig + pf_wci * cp);
    float f_ = sigm(fg + pf_wcf * cp);
    float cn = f_*cp + i_*tanh_f(gg);
    float o_ = sigm(og + pf_wco * cn);
    float hn = o_*tanh_f(cn);
    h_nxt[(b*64 + c)*NN + n] = hn;
    c_st[(b*64 + c)*NN + n] = cn;
    const int ksC = c >> 5, kkC = c & 31;
    const int posF = (ksC*64 + (x | ((kkC >> 3) << 4)))*8 + (kkC & 7);
    unsigned short hh = bf16r(hn);
    hBh[posF] = hh;
    hBl[posF] = bf16r(hn - bf16f(hh));
    unsigned short ch = bf16r(cn);
    cBh[posF] = ch;
    cBl[posF] = bf16r(cn - bf16f(ch));
  }
  __syncthreads();

  // ---- phase 3: projections via MFMA (11 waves, mt 0..5 from h, 6..10 from c) ----
  float* proj_l = gates_l;              // gates fully consumed in phase 2
  {
    const int lane = tid & 63;
    const int wv   = tid >> 6;
    if (wv < 11) {
      const s8v* Bh_ = (const s8v*)((wv < 6) ? hBh : cBh) + lane;
      const s8v* Bl_ = (const s8v*)((wv < 6) ? hBl : cBl) + lane;
      f4v acc = {0.f, 0.f, 0.f, 0.f};
      #pragma unroll
      for (int ks = 0; ks < 2; ks++) {
        s8v ah = *(const s8v*)(pAhi + ((wv*2 + ks)*64 + lane)*8);
        s8v al = *(const s8v*)(pAlo + ((wv*2 + ks)*64 + lane)*8);
        s8v bh = Bh_[ks*64];
        s8v bl = Bl_[ks*64];
        acc = __builtin_amdgcn_mfma_f32_16x16x32_bf16(ah, bh, acc, 0, 0, 0);
        acc = __builtin_amdgcn_mfma_f32_16x16x32_bf16(al, bh, acc, 0, 0, 0);
        acc = __builtin_amdgcn_mfma_f32_16x16x32_bf16(ah, bl, acc, 0, 0, 0);
      }
      const int colx = lane & 15;
      const int rb   = (lane >> 4) * 4;
      #pragma unroll
      for (int r = 0; r < 4; r++) {
        int po = wv*16 + rb + r;
        proj_l[po*16 + colx] = acc[r] + pb_l[po];
      }
    }
  }
  __syncthreads();

  // ---- phase 4: coalesced fragment emission ----
  if (tid < 256) {
    int d = tid >> 4, x = tid & 15;
    q_buf[(b*16 + d)*NN + n0 + x] = proj_l[d*16 + x];
  }
  if (tid < 512) {
    int brh2 = tid >> 8;            // branch
    int lh   = (tid >> 2) & 63;     // fragment "lane-half" row
    int j2   = tid & 3;             // packs d&7 = 2*j2, 2*j2+1
    int p    = lh >> 4;             // 0,1: hi planes; 2,3: lo planes
    int x    = lh & 15;
    int d0   = ((p & 1) << 3) | (j2 << 1);
    int Koff = brh2 ? 96 : 16;
    float v0 = proj_l[(Koff + d0)*16 + x];
    float v1 = proj_l[(Koff + d0 + 1)*16 + x];
    unsigned short h0 = bf16r(v0), h1 = bf16r(v1);
    unsigned short u0, u1;
    if (p < 2) { u0 = h0; u1 = h1; }
    else       { u0 = bf16r(v0 - bf16f(h0)); u1 = bf16r(v1 - bf16f(h1)); }
    unsigned int* dst = (unsigned int*)(kF + ((b*2 + brh2)*64 + mt)*512);
    dst[lh*4 + j2] = (unsigned)u0 | ((unsigned)u1 << 16);
  }
  {
    const int ks = y;
    const int g0 = x0 >> 3;         // 0 or 2
    #pragma unroll
    for (int it = 0; it < 2; it++) {
      int ct    = tid + it*1024;
      int plane = ct >> 10;         // 0 = vFh, 1 = vFl
      int brh2  = (ct >> 9) & 1;
      int nt    = (ct >> 7) & 3;
      int li    = (ct >> 2) & 31;
      int j2    = ct & 3;
      int lane2 = g0*16 + li;
      int cch   = nt*16 + (lane2 & 15);
      int xx    = ((li >> 4) << 3) | (j2 << 1);
      int Voff  = brh2 ? 112 : 32;
      float v0 = proj_l[(Voff + cch)*16 + xx];
      float v1 = proj_l[(Voff + cch)*16 + xx + 1];
      unsigned short h0 = bf16r(v0), h1 = bf16r(v1);
      unsigned short u0, u1;
      if (plane == 0) { u0 = h0; u1 = h1; }
      else            { u0 = bf16r(v0 - bf16f(h0)); u1 = bf16r(v1 - bf16f(h1)); }
      unsigned short* basep = (plane ? vFl : vFh) + (((b*2 + brh2)*32 + ks)*4 + nt)*512;
      ((unsigned int*)basep)[lane2*4 + j2] = (unsigned)u0 | ((unsigned)u1 << 16);
    }
  }
}

// ---------- K2: dual attention via MFMA + MFMA combine + gating ----------
#define RED_OFF 0        // [16 waves][16 nl][66]  = 16896
#define PS_OFF  16896    // [16 waves][16][36]     = 9216
#define SMX_OFF 26112    // [2][8][16]             = 256
#define SSM_OFF 26368    // [2][8][16]             = 256
#define INV_OFF 26624    // [2][16]                = 32
#define ZHM_OFF 26656    // [128][16]              = 2048
#define S_TOT   28704

__global__ __launch_bounds__(1024, 4) void k2_attn(
    int t,
    const float* __restrict__ q_buf,
    const unsigned short* __restrict__ kF,
    const unsigned short* __restrict__ vFh, const unsigned short* __restrict__ vFl,
    float* __restrict__ h_nxt, float* __restrict__ c_st,
    const unsigned short* __restrict__ zAhi, const unsigned short* __restrict__ zAlo,
    const unsigned short* __restrict__ mAhi, const unsigned short* __restrict__ mAlo,
    const float* __restrict__ z_b, const float* __restrict__ m_b,
    float* __restrict__ out)
{
  __shared__ __align__(16) float S[S_TOT];
  float* red  = S + RED_OFF;
  float* smMax= S + SMX_OFF;
  float* smSum= S + SSM_OFF;
  float* invL = S + INV_OFF;
  float* zhm  = S + ZHM_OFF;
  float* cbIn = S;              // [192][16] aliases red (after barrier)
  float* cbOut= S + 3072;       // [192][16] aliases red

  const int tid = threadIdx.x;
  const int bid = blockIdx.x;
  const int xcd = bid & 7;
  const int b = xcd >> 1;
  const int tile = ((bid >> 3) << 1) | (xcd & 1);   // 0..63
  const int n0 = tile * 16;

  const int wid  = tid >> 6;
  const int lane = tid & 63;
  const int brh  = wid >> 3;      // branch
  const int w    = wid & 7;       // wave within branch
  const int g    = lane >> 4;
  const int c16  = lane & 15;

  // ---- prefetch tail-phase inputs ----
  const int pc2 = tid >> 4;       // 0..63
  const int pn2 = n0 + (tid & 15);
  float pf_cst = c_st[(b*64 + pc2)*NN + pn2];
  float pf_h   = h_nxt[(b*64 + pc2)*NN + pn2];

  // ---- Q A-frags: A1 = [Qh|Qh], A2 = [Ql|0] ----
  s8v qh1, ql2;
  {
    const int dbase = (g & 1) * 8;
    #pragma unroll
    for (int j = 0; j < 8; j++) {
      float qv = q_buf[(b*16 + dbase + j)*NN + n0 + c16];
      unsigned short hi = bf16r(qv);
      unsigned short lo = bf16r(qv - bf16f(hi));
      qh1[j] = (short)hi;
      ql2[j] = (g < 2) ? (short)lo : (short)0;
    }
  }

  // ---- scores: 8 m-tiles per wave, 2 MFMA each (B = [Kh|Kl]) ----
  f4v acc[8];
  {
    const unsigned short* kp = kF + (((b*2 + brh)*64 + w*8)*64 + lane)*8;
    #pragma unroll
    for (int i = 0; i < 8; i++) {
      s8v bf = *(const s8v*)(kp + i*512);
      f4v z4 = {0.f, 0.f, 0.f, 0.f};
      z4 = __builtin_amdgcn_mfma_f32_16x16x32_bf16(ql2, bf, z4, 0, 0, 0);
      acc[i] = __builtin_amdgcn_mfma_f32_16x16x32_bf16(qh1, bf, z4, 0, 0, 0);
    }
  }

  // ---- softmax ----
  float Mrow[4];
  #pragma unroll
  for (int r = 0; r < 4; r++) {
    float m = acc[0][r];
    #pragma unroll
    for (int i = 1; i < 8; i++) m = fmaxf(m, acc[i][r]);
    m = fmaxf(m, __shfl_xor(m, 1));
    m = fmaxf(m, __shfl_xor(m, 2));
    m = fmaxf(m, __shfl_xor(m, 4));
    m = fmaxf(m, __shfl_xor(m, 8));
    if (c16 == 0) smMax[(brh*8 + w)*16 + g*4 + r] = m;
  }
  __syncthreads();
  #pragma unroll
  for (int r = 0; r < 4; r++) {
    float m = smMax[(brh*8 + 0)*16 + g*4 + r];
    #pragma unroll
    for (int w2 = 1; w2 < 8; w2++) m = fmaxf(m, smMax[(brh*8 + w2)*16 + g*4 + r]);
    Mrow[r] = m;
  }
  float rsum[4] = {0.f, 0.f, 0.f, 0.f};
  #pragma unroll
  for (int i = 0; i < 8; i++) {
    #pragma unroll
    for (int r = 0; r < 4; r++) {
      float p = __expf(acc[i][r] - Mrow[r]);
      acc[i][r] = p;
      rsum[r] += p;
    }
  }
  #pragma unroll
  for (int r = 0; r < 4; r++) {
    float s = rsum[r];
    s += __shfl_xor(s, 1); s += __shfl_xor(s, 2);
    s += __shfl_xor(s, 4); s += __shfl_xor(s, 8);
    if (c16 == 0) smSum[(brh*8 + w)*16 + g*4 + r] = s;
  }
  __syncthreads();
  if (w == 0 && c16 == 0) {
    #pragma unroll
    for (int r = 0; r < 4; r++) {
      float s = 0.f;
      #pragma unroll
      for (int w2 = 0; w2 < 8; w2++) s += smSum[(brh*8 + w2)*16 + g*4 + r];
      invL[brh*16 + g*4 + r] = 1.0f / s;
    }
  }

  // ---- PV: per wave, 4 k-steps of 32 m; wave-local P transpose; 3-term split ----
  f4v z0 = {0.f,0.f,0.f,0.f}, z1 = z0, z2 = z0, z3 = z0;
  float* myPS = S + PS_OFF + wid*576;   // [16][36]
  #pragma unroll
  for (int ks4 = 0; ks4 < 4; ks4++) {
    #pragma unroll
    for (int i2 = 0; i2 < 2; i2++) {
      #pragma unroll
      for (int r = 0; r < 4; r++)
        myPS[(g*4 + r)*36 + i2*16 + c16] = acc[ks4*2 + i2][r];
    }
    float4 pa = *(const float4*)&myPS[c16*36 + g*8];
    float4 pb = *(const float4*)&myPS[c16*36 + g*8 + 4];
    s8v ph, pl;
    {
      unsigned short h0 = bf16r(pa.x); ph[0] = (short)h0; pl[0] = (short)bf16r(pa.x - bf16f(h0));
      unsigned short h1 = bf16r(pa.y); ph[1] = (short)h1; pl[1] = (short)bf16r(pa.y - bf16f(h1));
      unsigned short h2 = bf16r(pa.z); ph[2] = (short)h2; pl[2] = (short)bf16r(pa.z - bf16f(h2));
      unsigned short h3 = bf16r(pa.w); ph[3] = (short)h3; pl[3] = (short)bf16r(pa.w - bf16f(h3));
      unsigned short h4 = bf16r(pb.x); ph[4] = (short)h4; pl[4] = (short)bf16r(pb.x - bf16f(h4));
      unsigned short h5 = bf16r(pb.y); ph[5] = (short)h5; pl[5] = (short)bf16r(pb.y - bf16f(h5));
      unsigned short h6 = bf16r(pb.z); ph[6] = (short)h6; pl[6] = (short)bf16r(pb.z - bf16f(h6));
      unsigned short h7 = bf16r(pb.w); ph[7] = (short)h7; pl[7] = (short)bf16r(pb.w - bf16f(h7));
    }
    const int ks = w*4 + ks4;
    const unsigned short* vph = vFh + ((((b*2 + brh)*32 + ks)*4)*64 + lane)*8;
    const unsigned short* vpl = vFl + ((((b*2 + brh)*32 + ks)*4)*64 + lane)*8;
    s8v vh0 = *(const s8v*)(vph);
    s8v vl0 = *(const s8v*)(vpl);
    z0 = __builtin_amdgcn_mfma_f32_16x16x32_bf16(ph, vh0, z0, 0,0,0);
    z0 = __builtin_amdgcn_mfma_f32_16x16x32_bf16(ph, vl0, z0, 0,0,0);
    z0 = __builtin_amdgcn_mfma_f32_16x16x32_bf16(pl, vh0, z0, 0,0,0);
    s8v vh1 = *(const s8v*)(vph + 512);
    s8v vl1 = *(const s8v*)(vpl + 512);
    z1 = __builtin_amdgcn_mfma_f32_16x16x32_bf16(ph, vh1, z1, 0,0,0);
    z1 = __builtin_amdgcn_mfma_f32_16x16x32_bf16(ph, vl1, z1, 0,0,0);
    z1 = __builtin_amdgcn_mfma_f32_16x16x32_bf16(pl, vh1, z1, 0,0,0);
    s8v vh2 = *(const s8v*)(vph + 1024);
    s8v vl2 = *(const s8v*)(vpl + 1024);
    z2 = __builtin_amdgcn_mfma_f32_16x16x32_bf16(ph, vh2, z2, 0,0,0);
    z2 = __builtin_amdgcn_mfma_f32_16x16x32_bf16(ph, vl2, z2, 0,0,0);
    z2 = __builtin_amdgcn_mfma_f32_16x16x32_bf16(pl, vh2, z2, 0,0,0);
    s8v vh3 = *(const s8v*)(vph + 1536);
    s8v vl3 = *(const s8v*)(vpl + 1536);
    z3 = __builtin_amdgcn_mfma_f32_16x16x32_bf16(ph, vh3, z3, 0,0,0);
    z3 = __builtin_amdgcn_mfma_f32_16x16x32_bf16(ph, vl3, z3, 0,0,0);
    z3 = __builtin_amdgcn_mfma_f32_16x16x32_bf16(pl, vh3, z3, 0,0,0);
  }

  // ---- write partials, reduce 8 waves, normalize -> zhm ----
  {
    float* rw = red + wid*1056;
    #pragma unroll
    for (int r = 0; r < 4; r++) {
      rw[(g*4 + r)*66 +  0 + c16] = z0[r];
      rw[(g*4 + r)*66 + 16 + c16] = z1[r];
      rw[(g*4 + r)*66 + 32 + c16] = z2[r];
      rw[(g*4 + r)*66 + 48 + c16] = z3[r];
    }
  }
  __syncthreads();
  {
    const int br2 = tid >> 9;
    const int sub = tid & 511;
    const int nlr = sub >> 5;
    const int cc0 = (sub & 31) * 2;
    float iv = invL[br2*16 + nlr];
    #pragma unroll
    for (int u = 0; u < 2; u++) {
      int cc = cc0 + u;
      float s = 0.f;
      #pragma unroll
      for (int w2 = 0; w2 < 8; w2++)
        s += red[(br2*8 + w2)*1056 + nlr*66 + cc];
      zhm[(br2*64 + cc)*16 + nlr] = s * iv;
    }
  }
  __syncthreads();

  // ---- hf rows into cbIn + zz via MFMA (waves 0..7) ----
  cbIn[(128 + pc2)*16 + (tid & 15)] = pf_h;
  if (wid < 8) {
    f4v za = {0.f, 0.f, 0.f, 0.f};
    const s8v* Azh = (const s8v*)zAhi + (wid*4)*64 + lane;
    const s8v* Azl = (const s8v*)zAlo + (wid*4)*64 + lane;
    #pragma unroll
    for (int ks = 0; ks < 4; ks++) {
      s8v bh, bl;
      #pragma unroll
      for (int j = 0; j < 8; j++) {
        float v = zhm[(ks*32 + g*8 + j)*16 + c16];
        unsigned short h = bf16r(v);
        bh[j] = (short)h;
        bl[j] = (short)bf16r(v - bf16f(h));
      }
      s8v ah = Azh[ks*64];
      s8v al = Azl[ks*64];
      za = __builtin_amdgcn_mfma_f32_16x16x32_bf16(ah, bh, za, 0, 0, 0);
      za = __builtin_amdgcn_mfma_f32_16x16x32_bf16(al, bh, za, 0, 0, 0);
      za = __builtin_amdgcn_mfma_f32_16x16x32_bf16(ah, bl, za, 0, 0, 0);
    }
    #pragma unroll
    for (int r = 0; r < 4; r++) {
      int oc = wid*16 + g*4 + r;
      cbIn[oc*16 + c16] = za[r] + z_b[oc];
    }
  }
  __syncthreads();

  // ---- comb via MFMA (waves 0..11) ----
  if (wid < 12) {
    f4v ca = {0.f, 0.f, 0.f, 0.f};
    const s8v* Amh = (const s8v*)mAhi + (wid*6)*64 + lane;
    const s8v* Aml = (const s8v*)mAlo + (wid*6)*64 + lane;
    #pragma unroll
    for (int ks = 0; ks < 6; ks++) {
      s8v bh, bl;
      #pragma unroll
      for (int j = 0; j < 8; j++) {
        float v = cbIn[(ks*32 + g*8 + j)*16 + c16];
        unsigned short h = bf16r(v);
        bh[j] = (short)h;
        bl[j] = (short)bf16r(v - bf16f(h));
      }
      s8v ah = Amh[ks*64];
      s8v al = Aml[ks*64];
      ca = __builtin_amdgcn_mfma_f32_16x16x32_bf16(ah, bh, ca, 0, 0, 0);
      ca = __builtin_amdgcn_mfma_f32_16x16x32_bf16(al, bh, ca, 0, 0, 0);
      ca = __builtin_amdgcn_mfma_f32_16x16x32_bf16(ah, bl, ca, 0, 0, 0);
    }
    #pragma unroll
    for (int r = 0; r < 4; r++) {
      int oc = wid*16 + g*4 + r;
      cbOut[oc*16 + c16] = ca[r] + m_b[oc];
    }
  }
  __syncthreads();

  // ---- gating ----
  {
    const int c = pc2, nn = tid & 15;
    const int n = n0 + nn;
    float mo = cbOut[c*16 + nn];
    float mg = cbOut[(64 + c)*16 + nn];
    float mi = cbOut[(128 + c)*16 + nn];
    float mf = pf_cst;
    float mis = sigm(mi);
    float nmf = (1.0f - mis)*mf + mis*tanh_f(mg);
    float nhf = sigm(mo)*nmf;
    c_st[(b*64 + c)*NN + n] = nmf;
    h_nxt[(b*64 + c)*NN + n] = nhf;
    out[((b*64 + c)*SS + t)*NN + n] = nhf;
  }
}

extern "C" void kernel_launch(void* const* d_in, const int* in_sizes, int n_in,
                              void* d_out, int out_size, void* d_ws, size_t ws_size,
                              hipStream_t stream) {
  const float* X      = (const float*)d_in[0];
  const float* conv_w = (const float*)d_in[1];
  const float* conv_b = (const float*)d_in[2];
  const float* W_ci   = (const float*)d_in[3];
  const float* W_cf   = (const float*)d_in[4];
  const float* W_co   = (const float*)d_in[5];
  const float* qw  = (const float*)d_in[6];
  const float* qb  = (const float*)d_in[7];
  const float* kw  = (const float*)d_in[8];
  const float* kb  = (const float*)d_in[9];
  const float* k2w = (const float*)d_in[10];
  const float* k2b = (const float*)d_in[11];
  const float* vw  = (const float*)d_in[12];
  const float* vb  = (const float*)d_in[13];
  const float* v2w = (const float*)d_in[14];
  const float* v2b = (const float*)d_in[15];
  const float* z_w = (const float*)d_in[16];
  const float* z_b = (const float*)d_in[17];
  const float* m_w = (const float*)d_in[18];
  const float* m_b = (const float*)d_in[19];
  float* out = (float*)d_out;

  float* ws = (float*)d_ws;
  unsigned short* Whi  = (unsigned short*)ws;  ws += 147456;   // 294912 ushorts
  unsigned short* Wlo  = (unsigned short*)ws;  ws += 147456;
  unsigned short* zAhi = (unsigned short*)ws;  ws += 8192;     // 16384 ushorts
  unsigned short* zAlo = (unsigned short*)ws;  ws += 8192;
  unsigned short* mAhi = (unsigned short*)ws;  ws += 18432;    // 36864 ushorts
  unsigned short* mAlo = (unsigned short*)ws;  ws += 18432;
  unsigned short* pAhi = (unsigned short*)ws;  ws += 5632;     // 11264 ushorts
  unsigned short* pAlo = (unsigned short*)ws;  ws += 5632;
  float* h_A    = ws;             ws += NB*64*NN;
  float* h_B    = ws;             ws += NB*64*NN;
  float* c_st   = ws;             ws += NB*64*NN;
  float* q_buf  = ws;             ws += NB*16*NN;
  unsigned short* kF  = (unsigned short*)ws;  ws += 131072;   // 4b*2br*64mt*64*8 ushorts
  unsigned short* vFh = (unsigned short*)ws;  ws += 131072;   // 4b*2br*32ks*4nt*64*8
  unsigned short* vFl = (unsigned short*)ws;  ws += 131072;
  float* gx     = ws;             ws += NB*SS*256*NN;         // 16.8M floats, 67 MB

  hipLaunchKernelGGL(k0_prep, dim3(256), dim3(256), 0, stream,
                     conv_w, z_w, m_w, qw, kw, vw, k2w, v2w,
                     Whi, Wlo, zAhi, zAlo, mAhi, mAlo, pAhi, pAlo, h_A, c_st);
  hipLaunchKernelGGL(k0b_gx, dim3(2048), dim3(1024), 0, stream,
                     X, Whi, Wlo, gx);
  for (int t = 0; t < 16; t++) {
    const float* h_cur = (t & 1) ? h_B : h_A;
    float* h_nxt       = (t & 1) ? h_A : h_B;
    hipLaunchKernelGGL(k1_conv_lstm_proj, dim3(256), dim3(1024), 0, stream,
        t, gx, Whi, Wlo, pAhi, pAlo, conv_b, W_ci, W_cf, W_co,
        qb, kb, vb, k2b, v2b,
        h_cur, h_nxt, c_st, q_buf, kF, vFh, vFl);
    hipLaunchKernelGGL(k2_attn, dim3(256), dim3(1024), 0, stream,
        t, q_buf, kF, vFh, vFl, h_nxt, c_st,
        zAhi, zAlo, mAhi, mAlo, z_b, m_b, out);
  }
}

// Round 14
// 526.885 us; speedup vs baseline: 1.4613x; 1.1359x over previous
//
#include <hip/hip_runtime.h>
#include <math.h>

#define NB 4
#define SS 16
#define NN 1024        // H*W

typedef short s8v __attribute__((ext_vector_type(8)));    // 8 bf16 (4 VGPR)
typedef float f4v __attribute__((ext_vector_type(4)));    // MFMA accumulator

__device__ __forceinline__ float sigm(float x) {
  return 1.0f / (1.0f + __expf(-x));
}
__device__ __forceinline__ float tanh_f(float x) {
  float e = __expf(2.0f * x);
  return 1.0f - 2.0f / (1.0f + e);
}
__device__ __forceinline__ unsigned short bf16r(float x) {   // RNE float->bf16
  unsigned int u = __float_as_uint(x);
  u = (u + 0x7FFFu + ((u >> 16) & 1u)) >> 16;
  return (unsigned short)u;
}
__device__ __forceinline__ float bf16f(unsigned short h) {
  return __uint_as_float(((unsigned int)h) << 16);
}

// ---------- prep: weight split/pack (conv + proj + z_w + m_w A-frags) + zero states ----------
__global__ void k0_prep(const float* __restrict__ conv_w, const float* __restrict__ z_w,
                        const float* __restrict__ m_w,
                        const float* __restrict__ qw, const float* __restrict__ kw,
                        const float* __restrict__ vw, const float* __restrict__ k2w,
                        const float* __restrict__ v2w,
                        unsigned short* __restrict__ Whi, unsigned short* __restrict__ Wlo,
                        unsigned short* __restrict__ zAhi, unsigned short* __restrict__ zAlo,
                        unsigned short* __restrict__ mAhi, unsigned short* __restrict__ mAlo,
                        unsigned short* __restrict__ pAhi, unsigned short* __restrict__ pAlo,
                        float* __restrict__ h_A, float* __restrict__ c_st) {
  int stride = gridDim.x * blockDim.x;
  int i0 = blockIdx.x * blockDim.x + threadIdx.x;
  for (int i = i0; i < 256*1152; i += stride) {
    int oc = i / 1152, k = i - oc*1152;          // k = icComb*9 + ky*3 + kx
    float v = conv_w[i];
    unsigned short hi = bf16r(v);
    unsigned short lo = bf16r(v - bf16f(hi));
    int mt = oc >> 4, i16 = oc & 15;
    int ks = k >> 5, kk = k & 31;
    int lane = i16 | ((kk >> 3) << 4);
    int pos = ((mt*36 + ks)*64 + lane)*8 + (kk & 7);
    Whi[pos] = hi;
    Wlo[pos] = lo;
  }
  for (int i = i0; i < 128*128; i += stride) {   // z_w A-frags: 8 mt x 4 ks
    int oc = i >> 7, k = i & 127;
    float v = z_w[i];
    unsigned short hi = bf16r(v);
    unsigned short lo = bf16r(v - bf16f(hi));
    int mt = oc >> 4, i16 = oc & 15;
    int ks = k >> 5, kk = k & 31;
    int lane = i16 | ((kk >> 3) << 4);
    int pos = ((mt*4 + ks)*64 + lane)*8 + (kk & 7);
    zAhi[pos] = hi;
    zAlo[pos] = lo;
  }
  for (int i = i0; i < 192*192; i += stride) {   // m_w A-frags: 12 mt x 6 ks
    int oc = i / 192, k = i - oc*192;
    float v = m_w[i];
    unsigned short hi = bf16r(v);
    unsigned short lo = bf16r(v - bf16f(hi));
    int mt = oc >> 4, i16 = oc & 15;
    int ks = k >> 5, kk = k & 31;
    int lane = i16 | ((kk >> 3) << 4);
    int pos = ((mt*6 + ks)*64 + lane)*8 + (kk & 7);
    mAhi[pos] = hi;
    mAlo[pos] = lo;
  }
  for (int i = i0; i < 176*64; i += stride) {    // proj A-frags: 11 mt x 2 ks
    int po = i >> 6, c = i & 63;
    float v;
    if (po < 16)       v = qw[po*64 + c];
    else if (po < 32)  v = kw[(po-16)*64 + c];
    else if (po < 96)  v = vw[(po-32)*64 + c];
    else if (po < 112) v = k2w[(po-96)*64 + c];
    else               v = v2w[(po-112)*64 + c];
    unsigned short hi = bf16r(v);
    unsigned short lo = bf16r(v - bf16f(hi));
    int mt = po >> 4, i16 = po & 15;
    int ks = c >> 5, kk = c & 31;
    int lane = i16 | ((kk >> 3) << 4);
    int pos = ((mt*2 + ks)*64 + lane)*8 + (kk & 7);
    pAhi[pos] = hi;
    pAlo[pos] = lo;
  }
  for (int i = i0; i < NB*64*NN; i += stride) { h_A[i] = 0.0f; c_st[i] = 0.0f; }
}

// ---------- K0b (v1): conv_x for ALL (b,t) — parallel GEMM ----------
__global__ __launch_bounds__(1024, 2) void k0b_gx(
    const float* __restrict__ X,
    const unsigned short* __restrict__ Whi, const unsigned short* __restrict__ Wlo,
    float* __restrict__ gx)
{
  __shared__ __align__(16) unsigned short Xhi_l[18*2*64*8];   // [ks][nt][lane][8]
  __shared__ __align__(16) unsigned short Xlo_l[18*2*64*8];

  const int tid = threadIdx.x;
  const int bid = blockIdx.x;       // b*512 + t*32 + y
  const int y = bid & 31;
  const int t = (bid >> 5) & 15;
  const int b = bid >> 9;

  for (int idx = tid; idx < 64*3*34; idx += 1024) {
    int col = idx % 34;
    int rest = idx / 34;
    int dy = rest % 3;
    int ic = rest / 3;
    int gy = y + dy - 1;
    int gxc = col - 1;
    float v = 0.0f;
    if ((unsigned)gy < 32u && (unsigned)gxc < 32u)
      v = X[(((b*64 + ic)*SS + t)*NN) + gy*32 + gxc];
    unsigned short hi = bf16r(v);
    unsigned short lo = bf16r(v - bf16f(hi));
    int kbase = ic*9 + dy*3;
    #pragma unroll
    for (int dx = 0; dx < 3; dx++) {
      int n = col - dx;
      if ((unsigned)n < 32u) {
        int k = kbase + dx;
        int ks = k >> 5, kk = k & 31;
        int nt = n >> 4, n16 = n & 15;
        int pos = (((ks*2 + nt)*64) + (n16 | ((kk >> 3) << 4)))*8 + (kk & 7);
        Xhi_l[pos] = hi;
        Xlo_l[pos] = lo;
      }
    }
  }
  __syncthreads();

  const int lane = tid & 63;
  const int mt = tid >> 6;          // 0..15
  f4v acc0 = {0.f,0.f,0.f,0.f}, acc1 = acc0;
  const s8v* Ah = (const s8v*)Whi + (mt*36)*64 + lane;
  const s8v* Al = (const s8v*)Wlo + (mt*36)*64 + lane;
  const s8v* Bh = (const s8v*)Xhi_l + lane;
  const s8v* Bl = (const s8v*)Xlo_l + lane;
  #pragma unroll 3
  for (int ks = 0; ks < 18; ks++) {
    s8v ah  = Ah[ks*64];
    s8v al  = Al[ks*64];
    s8v bh0 = Bh[(ks*2 + 0)*64];
    s8v bl0 = Bl[(ks*2 + 0)*64];
    s8v bh1 = Bh[(ks*2 + 1)*64];
    s8v bl1 = Bl[(ks*2 + 1)*64];
    acc0 = __builtin_amdgcn_mfma_f32_16x16x32_bf16(ah, bh0, acc0, 0, 0, 0);
    acc0 = __builtin_amdgcn_mfma_f32_16x16x32_bf16(al, bh0, acc0, 0, 0, 0);
    acc0 = __builtin_amdgcn_mfma_f32_16x16x32_bf16(ah, bl0, acc0, 0, 0, 0);
    acc1 = __builtin_amdgcn_mfma_f32_16x16x32_bf16(ah, bh1, acc1, 0, 0, 0);
    acc1 = __builtin_amdgcn_mfma_f32_16x16x32_bf16(al, bh1, acc1, 0, 0, 0);
    acc1 = __builtin_amdgcn_mfma_f32_16x16x32_bf16(ah, bl1, acc1, 0, 0, 0);
  }
  const int c16 = lane & 15;
  const int rb  = (lane >> 4) * 4;
  float* gout = gx + (((long)b*SS + t)*256)*NN + y*32;
  #pragma unroll
  for (int r = 0; r < 4; r++) {
    gout[(mt*16 + rb + r)*NN + c16]      = acc0[r];
    gout[(mt*16 + rb + r)*NN + 16 + c16] = acc1[r];
  }
}

// ---------- K1: conv_h + LSTM(+gx) + MFMA projections (1024 threads) ----------
__global__ __launch_bounds__(1024, 2) void k1_conv_lstm_proj(
    int t,
    const float* __restrict__ gx,
    const unsigned short* __restrict__ Whi, const unsigned short* __restrict__ Wlo,
    const unsigned short* __restrict__ pAhi, const unsigned short* __restrict__ pAlo,
    const float* __restrict__ conv_b,
    const float* __restrict__ W_ci, const float* __restrict__ W_cf, const float* __restrict__ W_co,
    const float* __restrict__ qb, const float* __restrict__ kb,
    const float* __restrict__ vb, const float* __restrict__ k2b,
    const float* __restrict__ v2b,
    const float* __restrict__ h_cur, float* __restrict__ h_nxt,
    float* __restrict__ c_st,
    float* __restrict__ q_buf,
    unsigned short* __restrict__ kF,
    unsigned short* __restrict__ vFh)
{
  __shared__ __align__(16) unsigned short Ihi_l[18*64*8];      // h-only im2col, B-frag order
  __shared__ __align__(16) unsigned short Ilo_l[18*64*8];
  __shared__ __align__(16) float gates_l[256*17];              // [oc][x]; later proj_l[176][16]
  __shared__ __align__(16) unsigned short hBh[2*64*8];         // h in B-frag layout (hi/lo)
  __shared__ __align__(16) unsigned short hBl[2*64*8];
  __shared__ __align__(16) unsigned short cBh[2*64*8];         // c in B-frag layout
  __shared__ __align__(16) unsigned short cBl[2*64*8];
  __shared__ __align__(16) float pb_l[176];

  const int tid = threadIdx.x;
  const int bid = blockIdx.x;
  const int b  = bid >> 6;
  const int y  = (bid >> 1) & 31;
  const int x0 = (bid & 1) * 16;
  const int mt = bid & 63;          // this block's 16-col m-tile (= n>>4)
  const int n0 = y*32 + x0;

  // ---- prefetch LSTM inputs into registers ----
  const int px = tid & 15;
  const int pc = tid >> 4;          // 0..63
  const int pn = n0 + px;
  const float* gxp = gx + (((long)b*SS + t)*256)*NN + pn;
  float pf_g0 = gxp[(pc      )*NN];
  float pf_g1 = gxp[( 64 + pc)*NN];
  float pf_g2 = gxp[(128 + pc)*NN];
  float pf_g3 = gxp[(192 + pc)*NN];
  float pf_cp  = c_st[(b*64 + pc)*NN + pn];
  float pf_wci = W_ci[pc*NN + pn];
  float pf_wcf = W_cf[pc*NN + pn];
  float pf_wco = W_co[pc*NN + pn];
  float pf_b0 = conv_b[pc];
  float pf_b1 = conv_b[ 64 + pc];
  float pf_b2 = conv_b[128 + pc];
  float pf_b3 = conv_b[192 + pc];

  // ---- phase 0: h-only im2col -> B-frags  +  stage proj biases ----
  for (int idx = tid; idx < 64*3*18; idx += 1024) {
    int col = idx % 18;
    int rest = idx / 18;
    int dy = rest % 3;
    int ic = rest / 3;                    // h channel 0..63
    int gy = y + dy - 1;
    int gxc = x0 + col - 1;
    float v = 0.0f;
    if ((unsigned)gy < 32u && (unsigned)gxc < 32u)
      v = h_cur[((b*64 + ic)*NN) + gy*32 + gxc];
    unsigned short hi = bf16r(v);
    unsigned short lo = bf16r(v - bf16f(hi));
    int kbase = ic*9 + dy*3;              // local k in [0,576)
    #pragma unroll
    for (int dx = 0; dx < 3; dx++) {
      int n = col - dx;
      if ((unsigned)n < 16u) {
        int k = kbase + dx;
        int ks = k >> 5, kk = k & 31;
        int pos = (ks*64 + (n | ((kk >> 3) << 4)))*8 + (kk & 7);
        Ihi_l[pos] = hi;
        Ilo_l[pos] = lo;
      }
    }
  }
  if (tid < 176) {
    int po = tid;
    float v;
    if (po < 16)       v = qb[po];
    else if (po < 32)  v = kb[po-16];
    else if (po < 96)  v = vb[po-32];
    else if (po < 112) v = k2b[po-96];
    else               v = v2b[po-112];
    pb_l[po] = v;
  }
  __syncthreads();

  // ---- phase 1: conv_h MFMA: 16 waves, 1 m-tile each; A-frags at ks 18..35 ----
  {
    const int lane = tid & 63;
    const int wv   = tid >> 6;        // 0..15 = m-tile
    f4v acc = {0.f, 0.f, 0.f, 0.f};
    const s8v* Ah = (const s8v*)Whi + (wv*36 + 18)*64 + lane;
    const s8v* Al = (const s8v*)Wlo + (wv*36 + 18)*64 + lane;
    const s8v* Bh = (const s8v*)Ihi_l + lane;
    const s8v* Bl = (const s8v*)Ilo_l + lane;
    #pragma unroll 3
    for (int ks = 0; ks < 18; ks++) {
      s8v ah = Ah[ks*64];
      s8v al = Al[ks*64];
      s8v bh = Bh[ks*64];
      s8v bl = Bl[ks*64];
      acc = __builtin_amdgcn_mfma_f32_16x16x32_bf16(ah, bh, acc, 0, 0, 0);
      acc = __builtin_amdgcn_mfma_f32_16x16x32_bf16(al, bh, acc, 0, 0, 0);
      acc = __builtin_amdgcn_mfma_f32_16x16x32_bf16(ah, bl, acc, 0, 0, 0);
    }
    const int colx = lane & 15;
    const int rb   = (lane >> 4) * 4;
    #pragma unroll
    for (int r = 0; r < 4; r++)
      gates_l[(wv*16 + rb + r)*17 + colx] = acc[r];
  }
  __syncthreads();

  // ---- phase 2: LSTM elementwise; write h/c into B-frag layout ----
  {
    const int x = px;
    const int c = pc;
    const int n = pn;
    float ig = gates_l[(c      )*17 + x] + pf_g0 + pf_b0;
    float fg = gates_l[( 64 + c)*17 + x] + pf_g1 + pf_b1;
    float gg = gates_l[(128 + c)*17 + x] + pf_g2 + pf_b2;
    float og = gates_l[(192 + c)*17 + x] + pf_g3 + pf_b3;
    float cp = pf_cp;
    float i_ = sigm(ig + pf_wci * cp);
    float f_ = sigm(fg + pf_wcf * cp);
    float cn = f_*cp + i_*tanh_f(gg);
    float o_ = sigm(og + pf_wco * cn);
    float hn = o_*tanh_f(cn);
    h_nxt[(b*64 + c)*NN + n] = hn;
    c_st[(b*64 + c)*NN + n] = cn;
    const int ksC = c >> 5, kkC = c & 31;
    const int posF = (ksC*64 + (x | ((kkC >> 3) << 4)))*8 + (kkC & 7);
    unsigned short hh = bf16r(hn);
    hBh[posF] = hh;
    hBl[posF] = bf16r(hn - bf16f(hh));
    unsigned short ch = bf16r(cn);
    cBh[posF] = ch;
    cBl[posF] = bf16r(cn - bf16f(ch));
  }
  __syncthreads();

  // ---- phase 3: projections via MFMA (11 waves, mt 0..5 from h, 6..10 from c) ----
  float* proj_l = gates_l;              // gates fully consumed in phase 2
  {
    const int lane = tid & 63;
    const int wv   = tid >> 6;
    if (wv < 11) {
      const s8v* Bh_ = (const s8v*)((wv < 6) ? hBh : cBh) + lane;
      const s8v* Bl_ = (const s8v*)((wv < 6) ? hBl : cBl) + lane;
      f4v acc = {0.f, 0.f, 0.f, 0.f};
      #pragma unroll
      for (int ks = 0; ks < 2; ks++) {
        s8v ah = *(const s8v*)(pAhi + ((wv*2 + ks)*64 + lane)*8);
        s8v al = *(const s8v*)(pAlo + ((wv*2 + ks)*64 + lane)*8);
        s8v bh = Bh_[ks*64];
        s8v bl = Bl_[ks*64];
        acc = __builtin_amdgcn_mfma_f32_16x16x32_bf16(ah, bh, acc, 0, 0, 0);
        acc = __builtin_amdgcn_mfma_f32_16x16x32_bf16(al, bh, acc, 0, 0, 0);
        acc = __builtin_amdgcn_mfma_f32_16x16x32_bf16(ah, bl, acc, 0, 0, 0);
      }
      const int colx = lane & 15;
      const int rb   = (lane >> 4) * 4;
      #pragma unroll
      for (int r = 0; r < 4; r++) {
        int po = wv*16 + rb + r;
        proj_l[po*16 + colx] = acc[r] + pb_l[po];
      }
    }
  }
  __syncthreads();

  // ---- phase 4: coalesced fragment emission (V hi-plane only) ----
  if (tid < 256) {
    int d = tid >> 4, x = tid & 15;
    q_buf[(b*16 + d)*NN + n0 + x] = proj_l[d*16 + x];
  }
  if (tid < 512) {
    int brh2 = tid >> 8;            // branch
    int lh   = (tid >> 2) & 63;     // fragment "lane-half" row
    int j2   = tid & 3;             // packs d&7 = 2*j2, 2*j2+1
    int p    = lh >> 4;             // 0,1: hi planes; 2,3: lo planes
    int x    = lh & 15;
    int d0   = ((p & 1) << 3) | (j2 << 1);
    int Koff = brh2 ? 96 : 16;
    float v0 = proj_l[(Koff + d0)*16 + x];
    float v1 = proj_l[(Koff + d0 + 1)*16 + x];
    unsigned short h0 = bf16r(v0), h1 = bf16r(v1);
    unsigned short u0, u1;
    if (p < 2) { u0 = h0; u1 = h1; }
    else       { u0 = bf16r(v0 - bf16f(h0)); u1 = bf16r(v1 - bf16f(h1)); }
    unsigned int* dst = (unsigned int*)(kF + ((b*2 + brh2)*64 + mt)*512);
    dst[lh*4 + j2] = (unsigned)u0 | ((unsigned)u1 << 16);
  }
  {
    const int ks = y;
    const int g0 = x0 >> 3;         // 0 or 2
    int ct    = tid;                // 1024 tasks: brh(2) x nt(4) x li(32) x j2(4)
    int brh2  = (ct >> 9) & 1;
    int nt    = (ct >> 7) & 3;
    int li    = (ct >> 2) & 31;
    int j2    = ct & 3;
    int lane2 = g0*16 + li;
    int cch   = nt*16 + (lane2 & 15);
    int xx    = ((li >> 4) << 3) | (j2 << 1);
    int Voff  = brh2 ? 112 : 32;
    float v0 = proj_l[(Voff + cch)*16 + xx];
    float v1 = proj_l[(Voff + cch)*16 + xx + 1];
    unsigned short u0 = bf16r(v0), u1 = bf16r(v1);
    unsigned short* basep = vFh + (((b*2 + brh2)*32 + ks)*4 + nt)*512;
    ((unsigned int*)basep)[lane2*4 + j2] = (unsigned)u0 | ((unsigned)u1 << 16);
  }
}

// ---------- K2: dual attention via MFMA + MFMA combine + gating ----------
#define RED_OFF 0        // [16 waves][16 nl][66]  = 16896
#define PS_OFF  16896    // [16 waves][16][36]     = 9216
#define SMX_OFF 26112    // [2][8][16]             = 256
#define SSM_OFF 26368    // [2][8][16]             = 256
#define INV_OFF 26624    // [2][16]                = 32
#define S_TOT   28704

__global__ __launch_bounds__(1024, 4) void k2_attn(
    int t,
    const float* __restrict__ q_buf,
    const unsigned short* __restrict__ kF,
    const unsigned short* __restrict__ vFh,
    float* __restrict__ h_nxt, float* __restrict__ c_st,
    const unsigned short* __restrict__ zAhi, const unsigned short* __restrict__ zAlo,
    const unsigned short* __restrict__ mAhi, const unsigned short* __restrict__ mAlo,
    const float* __restrict__ z_b, const float* __restrict__ m_b,
    float* __restrict__ out)
{
  __shared__ __align__(16) float S[S_TOT];
  __shared__ __align__(16) unsigned short zBh[4*512];   // zz B-frags (4 ks)
  __shared__ __align__(16) unsigned short zBl[4*512];
  __shared__ __align__(16) unsigned short cbBh[6*512];  // comb B-frags (6 ks)
  __shared__ __align__(16) unsigned short cbBl[6*512];
  float* red  = S + RED_OFF;
  float* smMax= S + SMX_OFF;
  float* smSum= S + SSM_OFF;
  float* invL = S + INV_OFF;
  float* cbOut= S + 3072;       // [192][16] aliases red (after barrier)

  const int tid = threadIdx.x;
  const int bid = blockIdx.x;
  const int xcd = bid & 7;
  const int b = xcd >> 1;
  const int tile = ((bid >> 3) << 1) | (xcd & 1);   // 0..63
  const int n0 = tile * 16;

  const int wid  = tid >> 6;
  const int lane = tid & 63;
  const int brh  = wid >> 3;      // branch
  const int w    = wid & 7;       // wave within branch
  const int g    = lane >> 4;
  const int c16  = lane & 15;

  // ---- prefetch tail-phase inputs ----
  const int pc2 = tid >> 4;       // 0..63
  const int pn2 = n0 + (tid & 15);
  float pf_cst = c_st[(b*64 + pc2)*NN + pn2];
  float pf_h   = h_nxt[(b*64 + pc2)*NN + pn2];

  // ---- Q A-frags: A1 = [Qh|Qh], A2 = [Ql|0] ----
  s8v qh1, ql2;
  {
    const int dbase = (g & 1) * 8;
    #pragma unroll
    for (int j = 0; j < 8; j++) {
      float qv = q_buf[(b*16 + dbase + j)*NN + n0 + c16];
      unsigned short hi = bf16r(qv);
      unsigned short lo = bf16r(qv - bf16f(hi));
      qh1[j] = (short)hi;
      ql2[j] = (g < 2) ? (short)lo : (short)0;
    }
  }

  // ---- scores: 8 m-tiles per wave, 2 MFMA each (B = [Kh|Kl]) ----
  f4v acc[8];
  {
    const unsigned short* kp = kF + (((b*2 + brh)*64 + w*8)*64 + lane)*8;
    #pragma unroll
    for (int i = 0; i < 8; i++) {
      s8v bf = *(const s8v*)(kp + i*512);
      f4v z4 = {0.f, 0.f, 0.f, 0.f};
      z4 = __builtin_amdgcn_mfma_f32_16x16x32_bf16(ql2, bf, z4, 0, 0, 0);
      acc[i] = __builtin_amdgcn_mfma_f32_16x16x32_bf16(qh1, bf, z4, 0, 0, 0);
    }
  }

  // ---- softmax ----
  float Mrow[4];
  #pragma unroll
  for (int r = 0; r < 4; r++) {
    float m = acc[0][r];
    #pragma unroll
    for (int i = 1; i < 8; i++) m = fmaxf(m, acc[i][r]);
    m = fmaxf(m, __shfl_xor(m, 1));
    m = fmaxf(m, __shfl_xor(m, 2));
    m = fmaxf(m, __shfl_xor(m, 4));
    m = fmaxf(m, __shfl_xor(m, 8));
    if (c16 == 0) smMax[(brh*8 + w)*16 + g*4 + r] = m;
  }
  __syncthreads();
  #pragma unroll
  for (int r = 0; r < 4; r++) {
    float m = smMax[(brh*8 + 0)*16 + g*4 + r];
    #pragma unroll
    for (int w2 = 1; w2 < 8; w2++) m = fmaxf(m, smMax[(brh*8 + w2)*16 + g*4 + r]);
    Mrow[r] = m;
  }
  float rsum[4] = {0.f, 0.f, 0.f, 0.f};
  #pragma unroll
  for (int i = 0; i < 8; i++) {
    #pragma unroll
    for (int r = 0; r < 4; r++) {
      float p = __expf(acc[i][r] - Mrow[r]);
      acc[i][r] = p;
      rsum[r] += p;
    }
  }
  #pragma unroll
  for (int r = 0; r < 4; r++) {
    float s = rsum[r];
    s += __shfl_xor(s, 1); s += __shfl_xor(s, 2);
    s += __shfl_xor(s, 4); s += __shfl_xor(s, 8);
    if (c16 == 0) smSum[(brh*8 + w)*16 + g*4 + r] = s;
  }
  __syncthreads();
  if (w == 0 && c16 == 0) {
    #pragma unroll
    for (int r = 0; r < 4; r++) {
      float s = 0.f;
      #pragma unroll
      for (int w2 = 0; w2 < 8; w2++) s += smSum[(brh*8 + w2)*16 + g*4 + r];
      invL[brh*16 + g*4 + r] = 1.0f / s;
    }
  }

  // ---- PV: per wave, 4 k-steps of 32 m; wave-local P transpose; V hi-only ----
  f4v z0 = {0.f,0.f,0.f,0.f}, z1 = z0, z2 = z0, z3 = z0;
  float* myPS = S + PS_OFF + wid*576;   // [16][36]
  #pragma unroll
  for (int ks4 = 0; ks4 < 4; ks4++) {
    #pragma unroll
    for (int i2 = 0; i2 < 2; i2++) {
      #pragma unroll
      for (int r = 0; r < 4; r++)
        myPS[(g*4 + r)*36 + i2*16 + c16] = acc[ks4*2 + i2][r];
    }
    float4 pa = *(const float4*)&myPS[c16*36 + g*8];
    float4 pb = *(const float4*)&myPS[c16*36 + g*8 + 4];
    s8v ph, pl;
    {
      unsigned short h0 = bf16r(pa.x); ph[0] = (short)h0; pl[0] = (short)bf16r(pa.x - bf16f(h0));
      unsigned short h1 = bf16r(pa.y); ph[1] = (short)h1; pl[1] = (short)bf16r(pa.y - bf16f(h1));
      unsigned short h2 = bf16r(pa.z); ph[2] = (short)h2; pl[2] = (short)bf16r(pa.z - bf16f(h2));
      unsigned short h3 = bf16r(pa.w); ph[3] = (short)h3; pl[3] = (short)bf16r(pa.w - bf16f(h3));
      unsigned short h4 = bf16r(pb.x); ph[4] = (short)h4; pl[4] = (short)bf16r(pb.x - bf16f(h4));
      unsigned short h5 = bf16r(pb.y); ph[5] = (short)h5; pl[5] = (short)bf16r(pb.y - bf16f(h5));
      unsigned short h6 = bf16r(pb.z); ph[6] = (short)h6; pl[6] = (short)bf16r(pb.z - bf16f(h6));
      unsigned short h7 = bf16r(pb.w); ph[7] = (short)h7; pl[7] = (short)bf16r(pb.w - bf16f(h7));
    }
    const int ks = w*4 + ks4;
    const unsigned short* vph = vFh + ((((b*2 + brh)*32 + ks)*4)*64 + lane)*8;
    s8v vh0 = *(const s8v*)(vph);
    z0 = __builtin_amdgcn_mfma_f32_16x16x32_bf16(ph, vh0, z0, 0,0,0);
    z0 = __builtin_amdgcn_mfma_f32_16x16x32_bf16(pl, vh0, z0, 0,0,0);
    s8v vh1 = *(const s8v*)(vph + 512);
    z1 = __builtin_amdgcn_mfma_f32_16x16x32_bf16(ph, vh1, z1, 0,0,0);
    z1 = __builtin_amdgcn_mfma_f32_16x16x32_bf16(pl, vh1, z1, 0,0,0);
    s8v vh2 = *(const s8v*)(vph + 1024);
    z2 = __builtin_amdgcn_mfma_f32_16x16x32_bf16(ph, vh2, z2, 0,0,0);
    z2 = __builtin_amdgcn_mfma_f32_16x16x32_bf16(pl, vh2, z2, 0,0,0);
    s8v vh3 = *(const s8v*)(vph + 1536);
    z3 = __builtin_amdgcn_mfma_f32_16x16x32_bf16(ph, vh3, z3, 0,0,0);
    z3 = __builtin_amdgcn_mfma_f32_16x16x32_bf16(pl, vh3, z3, 0,0,0);
  }

  // ---- write partials, reduce 8 waves, normalize -> zz B-frags ----
  {
    float* rw = red + wid*1056;
    #pragma unroll
    for (int r = 0; r < 4; r++) {
      rw[(g*4 + r)*66 +  0 + c16] = z0[r];
      rw[(g*4 + r)*66 + 16 + c16] = z1[r];
      rw[(g*4 + r)*66 + 32 + c16] = z2[r];
      rw[(g*4 + r)*66 + 48 + c16] = z3[r];
    }
  }
  __syncthreads();
  {
    const int br2 = tid >> 9;
    const int sub = tid & 511;
    const int nlr = sub >> 5;
    const int cc0 = (sub & 31) * 2;
    float iv = invL[br2*16 + nlr];
    #pragma unroll
    for (int u = 0; u < 2; u++) {
      int cc = cc0 + u;
      float s = 0.f;
      #pragma unroll
      for (int w2 = 0; w2 < 8; w2++)
        s += red[(br2*8 + w2)*1056 + nlr*66 + cc];
      float v = s * iv;
      int k = br2*64 + cc;
      int ks = k >> 5, kk = k & 31;
      int pos = (ks*64 + (nlr | ((kk >> 3) << 4)))*8 + (kk & 7);
      unsigned short h = bf16r(v);
      zBh[pos] = h;
      zBl[pos] = bf16r(v - bf16f(h));
    }
  }
  __syncthreads();

  // ---- h rows into comb B-frags + zz via MFMA (waves 0..7) ----
  {
    int k = 128 + pc2;
    int ks = k >> 5, kk = k & 31;
    int pos = (ks*64 + ((tid & 15) | ((kk >> 3) << 4)))*8 + (kk & 7);
    unsigned short h = bf16r(pf_h);
    cbBh[pos] = h;
    cbBl[pos] = bf16r(pf_h - bf16f(h));
  }
  if (wid < 8) {
    f4v za = {0.f, 0.f, 0.f, 0.f};
    const s8v* Azh = (const s8v*)zAhi + (wid*4)*64 + lane;
    const s8v* Azl = (const s8v*)zAlo + (wid*4)*64 + lane;
    const s8v* Bzh = (const s8v*)zBh + lane;
    const s8v* Bzl = (const s8v*)zBl + lane;
    #pragma unroll
    for (int ks = 0; ks < 4; ks++) {
      s8v ah = Azh[ks*64];
      s8v al = Azl[ks*64];
      s8v bh = Bzh[ks*64];
      s8v bl = Bzl[ks*64];
      za = __builtin_amdgcn_mfma_f32_16x16x32_bf16(ah, bh, za, 0, 0, 0);
      za = __builtin_amdgcn_mfma_f32_16x16x32_bf16(al, bh, za, 0, 0, 0);
      za = __builtin_amdgcn_mfma_f32_16x16x32_bf16(ah, bl, za, 0, 0, 0);
    }
    #pragma unroll
    for (int r = 0; r < 4; r++) {
      int oc = wid*16 + g*4 + r;
      float v = za[r] + z_b[oc];
      int kk = oc & 31, ks2 = oc >> 5;
      int pos = (ks2*64 + (c16 | ((kk >> 3) << 4)))*8 + (kk & 7);
      unsigned short h = bf16r(v);
      cbBh[pos] = h;
      cbBl[pos] = bf16r(v - bf16f(h));
    }
  }
  __syncthreads();

  // ---- comb via MFMA (waves 0..11) ----
  if (wid < 12) {
    f4v ca = {0.f, 0.f, 0.f, 0.f};
    const s8v* Amh = (const s8v*)mAhi + (wid*6)*64 + lane;
    const s8v* Aml = (const s8v*)mAlo + (wid*6)*64 + lane;
    const s8v* Bch = (const s8v*)cbBh + lane;
    const s8v* Bcl = (const s8v*)cbBl + lane;
    #pragma unroll
    for (int ks = 0; ks < 6; ks++) {
      s8v ah = Amh[ks*64];
      s8v al = Aml[ks*64];
      s8v bh = Bch[ks*64];
      s8v bl = Bcl[ks*64];
      ca = __builtin_amdgcn_mfma_f32_16x16x32_bf16(ah, bh, ca, 0, 0, 0);
      ca = __builtin_amdgcn_mfma_f32_16x16x32_bf16(al, bh, ca, 0, 0, 0);
      ca = __builtin_amdgcn_mfma_f32_16x16x32_bf16(ah, bl, ca, 0, 0, 0);
    }
    #pragma unroll
    for (int r = 0; r < 4; r++) {
      int oc = wid*16 + g*4 + r;
      cbOut[oc*16 + c16] = ca[r] + m_b[oc];
    }
  }
  __syncthreads();

  // ---- gating ----
  {
    const int c = pc2, nn = tid & 15;
    const int n = n0 + nn;
    float mo = cbOut[c*16 + nn];
    float mg = cbOut[(64 + c)*16 + nn];
    float mi = cbOut[(128 + c)*16 + nn];
    float mf = pf_cst;
    float mis = sigm(mi);
    float nmf = (1.0f - mis)*mf + mis*tanh_f(mg);
    float nhf = sigm(mo)*nmf;
    c_st[(b*64 + c)*NN + n] = nmf;
    h_nxt[(b*64 + c)*NN + n] = nhf;
    out[((b*64 + c)*SS + t)*NN + n] = nhf;
  }
}

extern "C" void kernel_launch(void* const* d_in, const int* in_sizes, int n_in,
                              void* d_out, int out_size, void* d_ws, size_t ws_size,
                              hipStream_t stream) {
  const float* X      = (const float*)d_in[0];
  const float* conv_w = (const float*)d_in[1];
  const float* conv_b = (const float*)d_in[2];
  const float* W_ci   = (const float*)d_in[3];
  const float* W_cf   = (const float*)d_in[4];
  const float* W_co   = (const float*)d_in[5];
  const float* qw  = (const float*)d_in[6];
  const float* qb  = (const float*)d_in[7];
  const float* kw  = (const float*)d_in[8];
  const float* kb  = (const float*)d_in[9];
  const float* k2w = (const float*)d_in[10];
  const float* k2b = (const float*)d_in[11];
  const float* vw  = (const float*)d_in[12];
  const float* vb  = (const float*)d_in[13];
  const float* v2w = (const float*)d_in[14];
  const float* v2b = (const float*)d_in[15];
  const float* z_w = (const float*)d_in[16];
  const float* z_b = (const float*)d_in[17];
  const float* m_w = (const float*)d_in[18];
  const float* m_b = (const float*)d_in[19];
  float* out = (float*)d_out;

  float* ws = (float*)d_ws;
  unsigned short* Whi  = (unsigned short*)ws;  ws += 147456;   // 294912 ushorts
  unsigned short* Wlo  = (unsigned short*)ws;  ws += 147456;
  unsigned short* zAhi = (unsigned short*)ws;  ws += 8192;     // 16384 ushorts
  unsigned short* zAlo = (unsigned short*)ws;  ws += 8192;
  unsigned short* mAhi = (unsigned short*)ws;  ws += 18432;    // 36864 ushorts
  unsigned short* mAlo = (unsigned short*)ws;  ws += 18432;
  unsigned short* pAhi = (unsigned short*)ws;  ws += 5632;     // 11264 ushorts
  unsigned short* pAlo = (unsigned short*)ws;  ws += 5632;
  float* h_A    = ws;             ws += NB*64*NN;
  float* h_B    = ws;             ws += NB*64*NN;
  float* c_st   = ws;             ws += NB*64*NN;
  float* q_buf  = ws;             ws += NB*16*NN;
  unsigned short* kF  = (unsigned short*)ws;  ws += 131072;   // 4b*2br*64mt*64*8 ushorts
  unsigned short* vFh = (unsigned short*)ws;  ws += 131072;   // 4b*2br*32ks*4nt*64*8
  unsigned short* vFl = (unsigned short*)ws;  ws += 131072;   // (unused this round)
  (void)vFl;
  float* gx     = ws;             ws += NB*SS*256*NN;         // 16.8M floats, 67 MB

  hipLaunchKernelGGL(k0_prep, dim3(256), dim3(256), 0, stream,
                     conv_w, z_w, m_w, qw, kw, vw, k2w, v2w,
                     Whi, Wlo, zAhi, zAlo, mAhi, mAlo, pAhi, pAlo, h_A, c_st);
  hipLaunchKernelGGL(k0b_gx, dim3(2048), dim3(1024), 0, stream,
                     X, Whi, Wlo, gx);
  for (int t = 0; t < 16; t++) {
    const float* h_cur = (t & 1) ? h_B : h_A;
    float* h_nxt       = (t & 1) ? h_A : h_B;
    hipLaunchKernelGGL(k1_conv_lstm_proj, dim3(256), dim3(1024), 0, stream,
        t, gx, Whi, Wlo, pAhi, pAlo, conv_b, W_ci, W_cf, W_co,
        qb, kb, vb, k2b, v2b,
        h_cur, h_nxt, c_st, q_buf, kF, vFh);
    hipLaunchKernelGGL(k2_attn, dim3(256), dim3(1024), 0, stream,
        t, q_buf, kF, vFh, h_nxt, c_st,
        zAhi, zAlo, mAhi, mAlo, z_b, m_b, out);
  }
}

// Round 15
// 519.866 us; speedup vs baseline: 1.4810x; 1.0135x over previous
//
#include <hip/hip_runtime.h>
#include <math.h>

#define NB 4
#define SS 16
#define NN 1024        // H*W

typedef short s8v __attribute__((ext_vector_type(8)));    // 8 bf16 (4 VGPR)
typedef float f4v __attribute__((ext_vector_type(4)));    // MFMA accumulator

__device__ __forceinline__ float sigm(float x) {
  return 1.0f / (1.0f + __expf(-x));
}
__device__ __forceinline__ float tanh_f(float x) {
  float e = __expf(2.0f * x);
  return 1.0f - 2.0f / (1.0f + e);
}
__device__ __forceinline__ unsigned short bf16r(float x) {   // RNE float->bf16
  unsigned int u = __float_as_uint(x);
  u = (u + 0x7FFFu + ((u >> 16) & 1u)) >> 16;
  return (unsigned short)u;
}
__device__ __forceinline__ float bf16f(unsigned short h) {
  return __uint_as_float(((unsigned int)h) << 16);
}

// ---------- prep: weight split/pack (conv + proj + z_w + m_w A-frags) + zero states ----------
__global__ void k0_prep(const float* __restrict__ conv_w, const float* __restrict__ z_w,
                        const float* __restrict__ m_w,
                        const float* __restrict__ qw, const float* __restrict__ kw,
                        const float* __restrict__ vw, const float* __restrict__ k2w,
                        const float* __restrict__ v2w,
                        unsigned short* __restrict__ Whi, unsigned short* __restrict__ Wlo,
                        unsigned short* __restrict__ zAhi, unsigned short* __restrict__ zAlo,
                        unsigned short* __restrict__ mAhi, unsigned short* __restrict__ mAlo,
                        unsigned short* __restrict__ pAhi, unsigned short* __restrict__ pAlo,
                        float* __restrict__ h_A, float* __restrict__ c_st) {
  int stride = gridDim.x * blockDim.x;
  int i0 = blockIdx.x * blockDim.x + threadIdx.x;
  for (int i = i0; i < 256*1152; i += stride) {
    int oc = i / 1152, k = i - oc*1152;          // k = icComb*9 + ky*3 + kx
    float v = conv_w[i];
    unsigned short hi = bf16r(v);
    unsigned short lo = bf16r(v - bf16f(hi));
    int mt = oc >> 4, i16 = oc & 15;
    int ks = k >> 5, kk = k & 31;
    int lane = i16 | ((kk >> 3) << 4);
    int pos = ((mt*36 + ks)*64 + lane)*8 + (kk & 7);
    Whi[pos] = hi;
    Wlo[pos] = lo;
  }
  for (int i = i0; i < 128*128; i += stride) {   // z_w A-frags: 8 mt x 4 ks
    int oc = i >> 7, k = i & 127;
    float v = z_w[i];
    unsigned short hi = bf16r(v);
    unsigned short lo = bf16r(v - bf16f(hi));
    int mt = oc >> 4, i16 = oc & 15;
    int ks = k >> 5, kk = k & 31;
    int lane = i16 | ((kk >> 3) << 4);
    int pos = ((mt*4 + ks)*64 + lane)*8 + (kk & 7);
    zAhi[pos] = hi;
    zAlo[pos] = lo;
  }
  for (int i = i0; i < 192*192; i += stride) {   // m_w A-frags: 12 mt x 6 ks
    int oc = i / 192, k = i - oc*192;
    float v = m_w[i];
    unsigned short hi = bf16r(v);
    unsigned short lo = bf16r(v - bf16f(hi));
    int mt = oc >> 4, i16 = oc & 15;
    int ks = k >> 5, kk = k & 31;
    int lane = i16 | ((kk >> 3) << 4);
    int pos = ((mt*6 + ks)*64 + lane)*8 + (kk & 7);
    mAhi[pos] = hi;
    mAlo[pos] = lo;
  }
  for (int i = i0; i < 176*64; i += stride) {    // proj A-frags: 11 mt x 2 ks
    int po = i >> 6, c = i & 63;
    float v;
    if (po < 16)       v = qw[po*64 + c];
    else if (po < 32)  v = kw[(po-16)*64 + c];
    else if (po < 96)  v = vw[(po-32)*64 + c];
    else if (po < 112) v = k2w[(po-96)*64 + c];
    else               v = v2w[(po-112)*64 + c];
    unsigned short hi = bf16r(v);
    unsigned short lo = bf16r(v - bf16f(hi));
    int mt = po >> 4, i16 = po & 15;
    int ks = c >> 5, kk = c & 31;
    int lane = i16 | ((kk >> 3) << 4);
    int pos = ((mt*2 + ks)*64 + lane)*8 + (kk & 7);
    pAhi[pos] = hi;
    pAlo[pos] = lo;
  }
  for (int i = i0; i < NB*64*NN; i += stride) { h_A[i] = 0.0f; c_st[i] = 0.0f; }
}

// ---------- K0b: conv_x for ALL (b,t) — parallel GEMM, X hi-plane only ----------
__global__ __launch_bounds__(1024, 2) void k0b_gx(
    const float* __restrict__ X,
    const unsigned short* __restrict__ Whi, const unsigned short* __restrict__ Wlo,
    float* __restrict__ gx)
{
  __shared__ __align__(16) unsigned short Xhi_l[18*2*64*8];   // [ks][nt][lane][8]

  const int tid = threadIdx.x;
  const int bid = blockIdx.x;       // b*512 + t*32 + y
  const int y = bid & 31;
  const int t = (bid >> 5) & 15;
  const int b = bid >> 9;

  for (int idx = tid; idx < 64*3*34; idx += 1024) {
    int col = idx % 34;
    int rest = idx / 34;
    int dy = rest % 3;
    int ic = rest / 3;
    int gy = y + dy - 1;
    int gxc = col - 1;
    float v = 0.0f;
    if ((unsigned)gy < 32u && (unsigned)gxc < 32u)
      v = X[(((b*64 + ic)*SS + t)*NN) + gy*32 + gxc];
    unsigned short hi = bf16r(v);
    int kbase = ic*9 + dy*3;
    #pragma unroll
    for (int dx = 0; dx < 3; dx++) {
      int n = col - dx;
      if ((unsigned)n < 32u) {
        int k = kbase + dx;
        int ks = k >> 5, kk = k & 31;
        int nt = n >> 4, n16 = n & 15;
        int pos = (((ks*2 + nt)*64) + (n16 | ((kk >> 3) << 4)))*8 + (kk & 7);
        Xhi_l[pos] = hi;
      }
    }
  }
  __syncthreads();

  const int lane = tid & 63;
  const int mt = tid >> 6;          // 0..15
  f4v acc0 = {0.f,0.f,0.f,0.f}, acc1 = acc0;
  const s8v* Ah = (const s8v*)Whi + (mt*36)*64 + lane;
  const s8v* Al = (const s8v*)Wlo + (mt*36)*64 + lane;
  const s8v* Bh = (const s8v*)Xhi_l + lane;
  #pragma unroll 3
  for (int ks = 0; ks < 18; ks++) {
    s8v ah  = Ah[ks*64];
    s8v al  = Al[ks*64];
    s8v bh0 = Bh[(ks*2 + 0)*64];
    s8v bh1 = Bh[(ks*2 + 1)*64];
    acc0 = __builtin_amdgcn_mfma_f32_16x16x32_bf16(ah, bh0, acc0, 0, 0, 0);
    acc0 = __builtin_amdgcn_mfma_f32_16x16x32_bf16(al, bh0, acc0, 0, 0, 0);
    acc1 = __builtin_amdgcn_mfma_f32_16x16x32_bf16(ah, bh1, acc1, 0, 0, 0);
    acc1 = __builtin_amdgcn_mfma_f32_16x16x32_bf16(al, bh1, acc1, 0, 0, 0);
  }
  const int c16 = lane & 15;
  const int rb  = (lane >> 4) * 4;
  float* gout = gx + (((long)b*SS + t)*256)*NN + y*32;
  #pragma unroll
  for (int r = 0; r < 4; r++) {
    gout[(mt*16 + rb + r)*NN + c16]      = acc0[r];
    gout[(mt*16 + rb + r)*NN + 16 + c16] = acc1[r];
  }
}

// ---------- K1: conv_h + LSTM(+gx) + MFMA projections (1024 threads) ----------
__global__ __launch_bounds__(1024, 2) void k1_conv_lstm_proj(
    int t,
    const float* __restrict__ gx,
    const unsigned short* __restrict__ Whi, const unsigned short* __restrict__ Wlo,
    const unsigned short* __restrict__ pAhi, const unsigned short* __restrict__ pAlo,
    const float* __restrict__ conv_b,
    const float* __restrict__ W_ci, const float* __restrict__ W_cf, const float* __restrict__ W_co,
    const float* __restrict__ qb, const float* __restrict__ kb,
    const float* __restrict__ vb, const float* __restrict__ k2b,
    const float* __restrict__ v2b,
    const float* __restrict__ h_cur, float* __restrict__ h_nxt,
    float* __restrict__ c_st,
    float* __restrict__ q_buf,
    unsigned short* __restrict__ kF,
    unsigned short* __restrict__ vFh)
{
  __shared__ __align__(16) unsigned short Ihi_l[18*64*8];      // h-only im2col, B-frag order
  __shared__ __align__(16) unsigned short Ilo_l[18*64*8];
  __shared__ __align__(16) float gates_l[256*17];              // [oc][x]; later proj_l[176][16]
  __shared__ __align__(16) unsigned short hBh[2*64*8];         // h in B-frag layout (hi/lo)
  __shared__ __align__(16) unsigned short hBl[2*64*8];
  __shared__ __align__(16) unsigned short cBh[2*64*8];         // c in B-frag layout
  __shared__ __align__(16) unsigned short cBl[2*64*8];
  __shared__ __align__(16) float pb_l[176];

  const int tid = threadIdx.x;
  const int bid = blockIdx.x;
  const int b  = bid >> 6;
  const int y  = (bid >> 1) & 31;
  const int x0 = (bid & 1) * 16;
  const int mt = bid & 63;          // this block's 16-col m-tile (= n>>4)
  const int n0 = y*32 + x0;

  // ---- prefetch LSTM inputs + projection A-frags into registers ----
  const int px = tid & 15;
  const int pc = tid >> 4;          // 0..63
  const int pn = n0 + px;
  const float* gxp = gx + (((long)b*SS + t)*256)*NN + pn;
  float pf_g0 = gxp[(pc      )*NN];
  float pf_g1 = gxp[( 64 + pc)*NN];
  float pf_g2 = gxp[(128 + pc)*NN];
  float pf_g3 = gxp[(192 + pc)*NN];
  float pf_cp  = c_st[(b*64 + pc)*NN + pn];
  float pf_wci = W_ci[pc*NN + pn];
  float pf_wcf = W_cf[pc*NN + pn];
  float pf_wco = W_co[pc*NN + pn];
  float pf_b0 = conv_b[pc];
  float pf_b1 = conv_b[ 64 + pc];
  float pf_b2 = conv_b[128 + pc];
  float pf_b3 = conv_b[192 + pc];
  const int lane_e = tid & 63;
  const int wv_e   = tid >> 6;
  const int wvc    = (wv_e < 11) ? wv_e : 0;
  s8v pf_a0h = *(const s8v*)(pAhi + ((wvc*2 + 0)*64 + lane_e)*8);
  s8v pf_a0l = *(const s8v*)(pAlo + ((wvc*2 + 0)*64 + lane_e)*8);
  s8v pf_a1h = *(const s8v*)(pAhi + ((wvc*2 + 1)*64 + lane_e)*8);
  s8v pf_a1l = *(const s8v*)(pAlo + ((wvc*2 + 1)*64 + lane_e)*8);

  // ---- phase 0: h-only im2col -> B-frags  +  stage proj biases ----
  for (int idx = tid; idx < 64*3*18; idx += 1024) {
    int col = idx % 18;
    int rest = idx / 18;
    int dy = rest % 3;
    int ic = rest / 3;                    // h channel 0..63
    int gy = y + dy - 1;
    int gxc = x0 + col - 1;
    float v = 0.0f;
    if ((unsigned)gy < 32u && (unsigned)gxc < 32u)
      v = h_cur[((b*64 + ic)*NN) + gy*32 + gxc];
    unsigned short hi = bf16r(v);
    unsigned short lo = bf16r(v - bf16f(hi));
    int kbase = ic*9 + dy*3;              // local k in [0,576)
    #pragma unroll
    for (int dx = 0; dx < 3; dx++) {
      int n = col - dx;
      if ((unsigned)n < 16u) {
        int k = kbase + dx;
        int ks = k >> 5, kk = k & 31;
        int pos = (ks*64 + (n | ((kk >> 3) << 4)))*8 + (kk & 7);
        Ihi_l[pos] = hi;
        Ilo_l[pos] = lo;
      }
    }
  }
  if (tid < 176) {
    int po = tid;
    float v;
    if (po < 16)       v = qb[po];
    else if (po < 32)  v = kb[po-16];
    else if (po < 96)  v = vb[po-32];
    else if (po < 112) v = k2b[po-96];
    else               v = v2b[po-112];
    pb_l[po] = v;
  }
  __syncthreads();

  // ---- phase 1: conv_h MFMA: 16 waves, 1 m-tile each; A-frags at ks 18..35 ----
  {
    const int lane = tid & 63;
    const int wv   = tid >> 6;        // 0..15 = m-tile
    f4v acc = {0.f, 0.f, 0.f, 0.f};
    const s8v* Ah = (const s8v*)Whi + (wv*36 + 18)*64 + lane;
    const s8v* Al = (const s8v*)Wlo + (wv*36 + 18)*64 + lane;
    const s8v* Bh = (const s8v*)Ihi_l + lane;
    const s8v* Bl = (const s8v*)Ilo_l + lane;
    #pragma unroll 3
    for (int ks = 0; ks < 18; ks++) {
      s8v ah = Ah[ks*64];
      s8v al = Al[ks*64];
      s8v bh = Bh[ks*64];
      s8v bl = Bl[ks*64];
      acc = __builtin_amdgcn_mfma_f32_16x16x32_bf16(ah, bh, acc, 0, 0, 0);
      acc = __builtin_amdgcn_mfma_f32_16x16x32_bf16(al, bh, acc, 0, 0, 0);
      acc = __builtin_amdgcn_mfma_f32_16x16x32_bf16(ah, bl, acc, 0, 0, 0);
    }
    const int colx = lane & 15;
    const int rb   = (lane >> 4) * 4;
    #pragma unroll
    for (int r = 0; r < 4; r++)
      gates_l[(wv*16 + rb + r)*17 + colx] = acc[r];
  }
  __syncthreads();

  // ---- phase 2: LSTM elementwise; write h/c into B-frag layout ----
  {
    const int x = px;
    const int c = pc;
    const int n = pn;
    float ig = gates_l[(c      )*17 + x] + pf_g0 + pf_b0;
    float fg = gates_l[( 64 + c)*17 + x] + pf_g1 + pf_b1;
    float gg = gates_l[(128 + c)*17 + x] + pf_g2 + pf_b2;
    float og = gates_l[(192 + c)*17 + x] + pf_g3 + pf_b3;
    float cp = pf_cp;
    float i_ = sigm(ig + pf_wci * cp);
    float f_ = sigm(fg + pf_wcf * cp);
    float cn = f_*cp + i_*tanh_f(gg);
    float o_ = sigm(og + pf_wco * cn);
    float hn = o_*tanh_f(cn);
    h_nxt[(b*64 + c)*NN + n] = hn;
    c_st[(b*64 + c)*NN + n] = cn;
    const int ksC = c >> 5, kkC = c & 31;
    const int posF = (ksC*64 + (x | ((kkC >> 3) << 4)))*8 + (kkC & 7);
    unsigned short hh = bf16r(hn);
    hBh[posF] = hh;
    hBl[posF] = bf16r(hn - bf16f(hh));
    unsigned short ch = bf16r(cn);
    cBh[posF] = ch;
    cBl[posF] = bf16r(cn - bf16f(ch));
  }
  __syncthreads();

  // ---- phase 3: projections via MFMA (11 waves, mt 0..5 from h, 6..10 from c) ----
  float* proj_l = gates_l;              // gates fully consumed in phase 2
  {
    const int lane = lane_e;
    const int wv   = wv_e;
    if (wv < 11) {
      const s8v* Bh_ = (const s8v*)((wv < 6) ? hBh : cBh) + lane;
      const s8v* Bl_ = (const s8v*)((wv < 6) ? hBl : cBl) + lane;
      f4v acc = {0.f, 0.f, 0.f, 0.f};
      s8v bh0 = Bh_[0];
      s8v bl0 = Bl_[0];
      s8v bh1 = Bh_[64];
      s8v bl1 = Bl_[64];
      acc = __builtin_amdgcn_mfma_f32_16x16x32_bf16(pf_a0h, bh0, acc, 0, 0, 0);
      acc = __builtin_amdgcn_mfma_f32_16x16x32_bf16(pf_a0l, bh0, acc, 0, 0, 0);
      acc = __builtin_amdgcn_mfma_f32_16x16x32_bf16(pf_a0h, bl0, acc, 0, 0, 0);
      acc = __builtin_amdgcn_mfma_f32_16x16x32_bf16(pf_a1h, bh1, acc, 0, 0, 0);
      acc = __builtin_amdgcn_mfma_f32_16x16x32_bf16(pf_a1l, bh1, acc, 0, 0, 0);
      acc = __builtin_amdgcn_mfma_f32_16x16x32_bf16(pf_a1h, bl1, acc, 0, 0, 0);
      const int colx = lane & 15;
      const int rb   = (lane >> 4) * 4;
      #pragma unroll
      for (int r = 0; r < 4; r++) {
        int po = wv*16 + rb + r;
        proj_l[po*16 + colx] = acc[r] + pb_l[po];
      }
    }
  }
  __syncthreads();

  // ---- phase 4: coalesced fragment emission (V hi-plane only) ----
  if (tid < 256) {
    int d = tid >> 4, x = tid & 15;
    q_buf[(b*16 + d)*NN + n0 + x] = proj_l[d*16 + x];
  }
  if (tid < 512) {
    int brh2 = tid >> 8;            // branch
    int lh   = (tid >> 2) & 63;     // fragment "lane-half" row
    int j2   = tid & 3;             // packs d&7 = 2*j2, 2*j2+1
    int p    = lh >> 4;             // 0,1: hi planes; 2,3: lo planes
    int x    = lh & 15;
    int d0   = ((p & 1) << 3) | (j2 << 1);
    int Koff = brh2 ? 96 : 16;
    float v0 = proj_l[(Koff + d0)*16 + x];
    float v1 = proj_l[(Koff + d0 + 1)*16 + x];
    unsigned short h0 = bf16r(v0), h1 = bf16r(v1);
    unsigned short u0, u1;
    if (p < 2) { u0 = h0; u1 = h1; }
    else       { u0 = bf16r(v0 - bf16f(h0)); u1 = bf16r(v1 - bf16f(h1)); }
    unsigned int* dst = (unsigned int*)(kF + ((b*2 + brh2)*64 + mt)*512);
    dst[lh*4 + j2] = (unsigned)u0 | ((unsigned)u1 << 16);
  }
  {
    const int ks = y;
    const int g0 = x0 >> 3;         // 0 or 2
    int ct    = tid;                // 1024 tasks: brh(2) x nt(4) x li(32) x j2(4)
    int brh2  = (ct >> 9) & 1;
    int nt    = (ct >> 7) & 3;
    int li    = (ct >> 2) & 31;
    int j2    = ct & 3;
    int lane2 = g0*16 + li;
    int cch   = nt*16 + (lane2 & 15);
    int xx    = ((li >> 4) << 3) | (j2 << 1);
    int Voff  = brh2 ? 112 : 32;
    float v0 = proj_l[(Voff + cch)*16 + xx];
    float v1 = proj_l[(Voff + cch)*16 + xx + 1];
    unsigned short u0 = bf16r(v0), u1 = bf16r(v1);
    unsigned short* basep = vFh + (((b*2 + brh2)*32 + ks)*4 + nt)*512;
    ((unsigned int*)basep)[lane2*4 + j2] = (unsigned)u0 | ((unsigned)u1 << 16);
  }
}

// ---------- K2: dual attention via MFMA + MFMA combine + gating ----------
#define RED_OFF 0        // [16 waves][16 nl][66]  = 16896
#define PS_OFF  16896    // [16 waves][16][36]     = 9216
#define SMX_OFF 26112    // [2][8][16]             = 256
#define SSM_OFF 26368    // [2][8][16]             = 256
#define INV_OFF 26624    // [2][16]                = 32
#define S_TOT   28704

__global__ __launch_bounds__(1024, 4) void k2_attn(
    int t,
    const float* __restrict__ q_buf,
    const unsigned short* __restrict__ kF,
    const unsigned short* __restrict__ vFh,
    float* __restrict__ h_nxt, float* __restrict__ c_st,
    const unsigned short* __restrict__ zAhi, const unsigned short* __restrict__ zAlo,
    const unsigned short* __restrict__ mAhi, const unsigned short* __restrict__ mAlo,
    const float* __restrict__ z_b, const float* __restrict__ m_b,
    float* __restrict__ out)
{
  __shared__ __align__(16) float S[S_TOT];
  __shared__ __align__(16) unsigned short zBh[4*512];   // zz B-frags (4 ks)
  __shared__ __align__(16) unsigned short zBl[4*512];
  __shared__ __align__(16) unsigned short cbBh[6*512];  // comb B-frags (6 ks)
  __shared__ __align__(16) unsigned short cbBl[6*512];
  float* red  = S + RED_OFF;
  float* smMax= S + SMX_OFF;
  float* smSum= S + SSM_OFF;
  float* invL = S + INV_OFF;
  float* cbOut= S + 3072;       // [192][16] aliases red (after barrier)

  const int tid = threadIdx.x;
  const int bid = blockIdx.x;
  const int xcd = bid & 7;
  const int b = xcd >> 1;
  const int tile = ((bid >> 3) << 1) | (xcd & 1);   // 0..63
  const int n0 = tile * 16;

  const int wid  = tid >> 6;
  const int lane = tid & 63;
  const int brh  = wid >> 3;      // branch
  const int w    = wid & 7;       // wave within branch
  const int g    = lane >> 4;
  const int c16  = lane & 15;

  // ---- prefetch tail-phase inputs ----
  const int pc2 = tid >> 4;       // 0..63
  const int pn2 = n0 + (tid & 15);
  float pf_cst = c_st[(b*64 + pc2)*NN + pn2];
  float pf_h   = h_nxt[(b*64 + pc2)*NN + pn2];

  // ---- Q A-frags: A1 = [Qh|Qh], A2 = [Ql|0] ----
  s8v qh1, ql2;
  {
    const int dbase = (g & 1) * 8;
    #pragma unroll
    for (int j = 0; j < 8; j++) {
      float qv = q_buf[(b*16 + dbase + j)*NN + n0 + c16];
      unsigned short hi = bf16r(qv);
      unsigned short lo = bf16r(qv - bf16f(hi));
      qh1[j] = (short)hi;
      ql2[j] = (g < 2) ? (short)lo : (short)0;
    }
  }

  // ---- scores: 8 m-tiles per wave, 2 MFMA each (B = [Kh|Kl]) ----
  f4v acc[8];
  {
    const unsigned short* kp = kF + (((b*2 + brh)*64 + w*8)*64 + lane)*8;
    #pragma unroll
    for (int i = 0; i < 8; i++) {
      s8v bf = *(const s8v*)(kp + i*512);
      f4v z4 = {0.f, 0.f, 0.f, 0.f};
      z4 = __builtin_amdgcn_mfma_f32_16x16x32_bf16(ql2, bf, z4, 0, 0, 0);
      acc[i] = __builtin_amdgcn_mfma_f32_16x16x32_bf16(qh1, bf, z4, 0, 0, 0);
    }
  }

  // ---- softmax ----
  float Mrow[4];
  #pragma unroll
  for (int r = 0; r < 4; r++) {
    float m = acc[0][r];
    #pragma unroll
    for (int i = 1; i < 8; i++) m = fmaxf(m, acc[i][r]);
    m = fmaxf(m, __shfl_xor(m, 1));
    m = fmaxf(m, __shfl_xor(m, 2));
    m = fmaxf(m, __shfl_xor(m, 4));
    m = fmaxf(m, __shfl_xor(m, 8));
    if (c16 == 0) smMax[(brh*8 + w)*16 + g*4 + r] = m;
  }
  __syncthreads();
  #pragma unroll
  for (int r = 0; r < 4; r++) {
    float m = smMax[(brh*8 + 0)*16 + g*4 + r];
    #pragma unroll
    for (int w2 = 1; w2 < 8; w2++) m = fmaxf(m, smMax[(brh*8 + w2)*16 + g*4 + r]);
    Mrow[r] = m;
  }
  float rsum[4] = {0.f, 0.f, 0.f, 0.f};
  #pragma unroll
  for (int i = 0; i < 8; i++) {
    #pragma unroll
    for (int r = 0; r < 4; r++) {
      float p = __expf(acc[i][r] - Mrow[r]);
      acc[i][r] = p;
      rsum[r] += p;
    }
  }
  #pragma unroll
  for (int r = 0; r < 4; r++) {
    float s = rsum[r];
    s += __shfl_xor(s, 1); s += __shfl_xor(s, 2);
    s += __shfl_xor(s, 4); s += __shfl_xor(s, 8);
    if (c16 == 0) smSum[(brh*8 + w)*16 + g*4 + r] = s;
  }
  __syncthreads();
  if (w == 0 && c16 == 0) {
    #pragma unroll
    for (int r = 0; r < 4; r++) {
      float s = 0.f;
      #pragma unroll
      for (int w2 = 0; w2 < 8; w2++) s += smSum[(brh*8 + w2)*16 + g*4 + r];
      invL[brh*16 + g*4 + r] = 1.0f / s;
    }
  }

  // ---- PV: per wave, 4 k-steps of 32 m; wave-local P transpose; V hi-only ----
  f4v z0 = {0.f,0.f,0.f,0.f}, z1 = z0, z2 = z0, z3 = z0;
  float* myPS = S + PS_OFF + wid*576;   // [16][36]
  #pragma unroll
  for (int ks4 = 0; ks4 < 4; ks4++) {
    #pragma unroll
    for (int i2 = 0; i2 < 2; i2++) {
      #pragma unroll
      for (int r = 0; r < 4; r++)
        myPS[(g*4 + r)*36 + i2*16 + c16] = acc[ks4*2 + i2][r];
    }
    float4 pa = *(const float4*)&myPS[c16*36 + g*8];
    float4 pb = *(const float4*)&myPS[c16*36 + g*8 + 4];
    s8v ph, pl;
    {
      unsigned short h0 = bf16r(pa.x); ph[0] = (short)h0; pl[0] = (short)bf16r(pa.x - bf16f(h0));
      unsigned short h1 = bf16r(pa.y); ph[1] = (short)h1; pl[1] = (short)bf16r(pa.y - bf16f(h1));
      unsigned short h2 = bf16r(pa.z); ph[2] = (short)h2; pl[2] = (short)bf16r(pa.z - bf16f(h2));
      unsigned short h3 = bf16r(pa.w); ph[3] = (short)h3; pl[3] = (short)bf16r(pa.w - bf16f(h3));
      unsigned short h4 = bf16r(pb.x); ph[4] = (short)h4; pl[4] = (short)bf16r(pb.x - bf16f(h4));
      unsigned short h5 = bf16r(pb.y); ph[5] = (short)h5; pl[5] = (short)bf16r(pb.y - bf16f(h5));
      unsigned short h6 = bf16r(pb.z); ph[6] = (short)h6; pl[6] = (short)bf16r(pb.z - bf16f(h6));
      unsigned short h7 = bf16r(pb.w); ph[7] = (short)h7; pl[7] = (short)bf16r(pb.w - bf16f(h7));
    }
    const int ks = w*4 + ks4;
    const unsigned short* vph = vFh + ((((b*2 + brh)*32 + ks)*4)*64 + lane)*8;
    s8v vh0 = *(const s8v*)(vph);
    z0 = __builtin_amdgcn_mfma_f32_16x16x32_bf16(ph, vh0, z0, 0,0,0);
    z0 = __builtin_amdgcn_mfma_f32_16x16x32_bf16(pl, vh0, z0, 0,0,0);
    s8v vh1 = *(const s8v*)(vph + 512);
    z1 = __builtin_amdgcn_mfma_f32_16x16x32_bf16(ph, vh1, z1, 0,0,0);
    z1 = __builtin_amdgcn_mfma_f32_16x16x32_bf16(pl, vh1, z1, 0,0,0);
    s8v vh2 = *(const s8v*)(vph + 1024);
    z2 = __builtin_amdgcn_mfma_f32_16x16x32_bf16(ph, vh2, z2, 0,0,0);
    z2 = __builtin_amdgcn_mfma_f32_16x16x32_bf16(pl, vh2, z2, 0,0,0);
    s8v vh3 = *(const s8v*)(vph + 1536);
    z3 = __builtin_amdgcn_mfma_f32_16x16x32_bf16(ph, vh3, z3, 0,0,0);
    z3 = __builtin_amdgcn_mfma_f32_16x16x32_bf16(pl, vh3, z3, 0,0,0);
  }

  // ---- write partials, reduce 8 waves, normalize -> zz B-frags ----
  {
    float* rw = red + wid*1056;
    #pragma unroll
    for (int r = 0; r < 4; r++) {
      rw[(g*4 + r)*66 +  0 + c16] = z0[r];
      rw[(g*4 + r)*66 + 16 + c16] = z1[r];
      rw[(g*4 + r)*66 + 32 + c16] = z2[r];
      rw[(g*4 + r)*66 + 48 + c16] = z3[r];
    }
  }
  __syncthreads();
  {
    const int br2 = tid >> 9;
    const int sub = tid & 511;
    const int nlr = sub >> 5;
    const int cc0 = (sub & 31) * 2;
    float iv = invL[br2*16 + nlr];
    #pragma unroll
    for (int u = 0; u < 2; u++) {
      int cc = cc0 + u;
      float s = 0.f;
      #pragma unroll
      for (int w2 = 0; w2 < 8; w2++)
        s += red[(br2*8 + w2)*1056 + nlr*66 + cc];
      float v = s * iv;
      int k = br2*64 + cc;
      int ks = k >> 5, kk = k & 31;
      int pos = (ks*64 + (nlr | ((kk >> 3) << 4)))*8 + (kk & 7);
      unsigned short h = bf16r(v);
      zBh[pos] = h;
      zBl[pos] = bf16r(v - bf16f(h));
    }
  }
  __syncthreads();

  // ---- h rows into comb B-frags + zz via MFMA (waves 0..7) ----
  {
    int k = 128 + pc2;
    int ks = k >> 5, kk = k & 31;
    int pos = (ks*64 + ((tid & 15) | ((kk >> 3) << 4)))*8 + (kk & 7);
    unsigned short h = bf16r(pf_h);
    cbBh[pos] = h;
    cbBl[pos] = bf16r(pf_h - bf16f(h));
  }
  if (wid < 8) {
    f4v za = {0.f, 0.f, 0.f, 0.f};
    const s8v* Azh = (const s8v*)zAhi + (wid*4)*64 + lane;
    const s8v* Azl = (const s8v*)zAlo + (wid*4)*64 + lane;
    const s8v* Bzh = (const s8v*)zBh + lane;
    const s8v* Bzl = (const s8v*)zBl + lane;
    #pragma unroll
    for (int ks = 0; ks < 4; ks++) {
      s8v ah = Azh[ks*64];
      s8v al = Azl[ks*64];
      s8v bh = Bzh[ks*64];
      s8v bl = Bzl[ks*64];
      za = __builtin_amdgcn_mfma_f32_16x16x32_bf16(ah, bh, za, 0, 0, 0);
      za = __builtin_amdgcn_mfma_f32_16x16x32_bf16(al, bh, za, 0, 0, 0);
      za = __builtin_amdgcn_mfma_f32_16x16x32_bf16(ah, bl, za, 0, 0, 0);
    }
    #pragma unroll
    for (int r = 0; r < 4; r++) {
      int oc = wid*16 + g*4 + r;
      float v = za[r] + z_b[oc];
      int kk = oc & 31, ks2 = oc >> 5;
      int pos = (ks2*64 + (c16 | ((kk >> 3) << 4)))*8 + (kk & 7);
      unsigned short h = bf16r(v);
      cbBh[pos] = h;
      cbBl[pos] = bf16r(v - bf16f(h));
    }
  }
  __syncthreads();

  // ---- comb via MFMA (waves 0..11) ----
  if (wid < 12) {
    f4v ca = {0.f, 0.f, 0.f, 0.f};
    const s8v* Amh = (const s8v*)mAhi + (wid*6)*64 + lane;
    const s8v* Aml = (const s8v*)mAlo + (wid*6)*64 + lane;
    const s8v* Bch = (const s8v*)cbBh + lane;
    const s8v* Bcl = (const s8v*)cbBl + lane;
    #pragma unroll
    for (int ks = 0; ks < 6; ks++) {
      s8v ah = Amh[ks*64];
      s8v al = Aml[ks*64];
      s8v bh = Bch[ks*64];
      s8v bl = Bcl[ks*64];
      ca = __builtin_amdgcn_mfma_f32_16x16x32_bf16(ah, bh, ca, 0, 0, 0);
      ca = __builtin_amdgcn_mfma_f32_16x16x32_bf16(al, bh, ca, 0, 0, 0);
      ca = __builtin_amdgcn_mfma_f32_16x16x32_bf16(ah, bl, ca, 0, 0, 0);
    }
    #pragma unroll
    for (int r = 0; r < 4; r++) {
      int oc = wid*16 + g*4 + r;
      cbOut[oc*16 + c16] = ca[r] + m_b[oc];
    }
  }
  __syncthreads();

  // ---- gating ----
  {
    const int c = pc2, nn = tid & 15;
    const int n = n0 + nn;
    float mo = cbOut[c*16 + nn];
    float mg = cbOut[(64 + c)*16 + nn];
    float mi = cbOut[(128 + c)*16 + nn];
    float mf = pf_cst;
    float mis = sigm(mi);
    float nmf = (1.0f - mis)*mf + mis*tanh_f(mg);
    float nhf = sigm(mo)*nmf;
    c_st[(b*64 + c)*NN + n] = nmf;
    h_nxt[(b*64 + c)*NN + n] = nhf;
    out[((b*64 + c)*SS + t)*NN + n] = nhf;
  }
}

extern "C" void kernel_launch(void* const* d_in, const int* in_sizes, int n_in,
                              void* d_out, int out_size, void* d_ws, size_t ws_size,
                              hipStream_t stream) {
  const float* X      = (const float*)d_in[0];
  const float* conv_w = (const float*)d_in[1];
  const float* conv_b = (const float*)d_in[2];
  const float* W_ci   = (const float*)d_in[3];
  const float* W_cf   = (const float*)d_in[4];
  const float* W_co   = (const float*)d_in[5];
  const float* qw  = (const float*)d_in[6];
  const float* qb  = (const float*)d_in[7];
  const float* kw  = (const float*)d_in[8];
  const float* kb  = (const float*)d_in[9];
  const float* k2w = (const float*)d_in[10];
  const float* k2b = (const float*)d_in[11];
  const float* vw  = (const float*)d_in[12];
  const float* vb  = (const float*)d_in[13];
  const float* v2w = (const float*)d_in[14];
  const float* v2b = (const float*)d_in[15];
  const float* z_w = (const float*)d_in[16];
  const float* z_b = (const float*)d_in[17];
  const float* m_w = (const float*)d_in[18];
  const float* m_b = (const float*)d_in[19];
  float* out = (float*)d_out;

  float* ws = (float*)d_ws;
  unsigned short* Whi  = (unsigned short*)ws;  ws += 147456;   // 294912 ushorts
  unsigned short* Wlo  = (unsigned short*)ws;  ws += 147456;
  unsigned short* zAhi = (unsigned short*)ws;  ws += 8192;     // 16384 ushorts
  unsigned short* zAlo = (unsigned short*)ws;  ws += 8192;
  unsigned short* mAhi = (unsigned short*)ws;  ws += 18432;    // 36864 ushorts
  unsigned short* mAlo = (unsigned short*)ws;  ws += 18432;
  unsigned short* pAhi = (unsigned short*)ws;  ws += 5632;     // 11264 ushorts
  unsigned short* pAlo = (unsigned short*)ws;  ws += 5632;
  float* h_A    = ws;             ws += NB*64*NN;
  float* h_B    = ws;             ws += NB*64*NN;
  float* c_st   = ws;             ws += NB*64*NN;
  float* q_buf  = ws;             ws += NB*16*NN;
  unsigned short* kF  = (unsigned short*)ws;  ws += 131072;   // 4b*2br*64mt*64*8 ushorts
  unsigned short* vFh = (unsigned short*)ws;  ws += 131072;   // 4b*2br*32ks*4nt*64*8
  float* gx     = ws;             ws += NB*SS*256*NN;         // 16.8M floats, 67 MB

  hipLaunchKernelGGL(k0_prep, dim3(256), dim3(256), 0, stream,
                     conv_w, z_w, m_w, qw, kw, vw, k2w, v2w,
                     Whi, Wlo, zAhi, zAlo, mAhi, mAlo, pAhi, pAlo, h_A, c_st);
  hipLaunchKernelGGL(k0b_gx, dim3(2048), dim3(1024), 0, stream,
                     X, Whi, Wlo, gx);
  for (int t = 0; t < 16; t++) {
    const float* h_cur = (t & 1) ? h_B : h_A;
    float* h_nxt       = (t & 1) ? h_A : h_B;
    hipLaunchKernelGGL(k1_conv_lstm_proj, dim3(256), dim3(1024), 0, stream,
        t, gx, Whi, Wlo, pAhi, pAlo, conv_b, W_ci, W_cf, W_co,
        qb, kb, vb, k2b, v2b,
        h_cur, h_nxt, c_st, q_buf, kF, vFh);
    hipLaunchKernelGGL(k2_attn, dim3(256), dim3(1024), 0, stream,
        t, q_buf, kF, vFh, h_nxt, c_st,
        zAhi, zAlo, mAhi, mAlo, z_b, m_b, out);
  }
}

// Round 16
// 504.550 us; speedup vs baseline: 1.5259x; 1.0304x over previous
//
#include <hip/hip_runtime.h>
#include <math.h>

#define NB 4
#define SS 16
#define NN 1024        // H*W

typedef short s8v __attribute__((ext_vector_type(8)));    // 8 bf16 (4 VGPR)
typedef float f4v __attribute__((ext_vector_type(4)));    // MFMA accumulator

__device__ __forceinline__ float sigm(float x) {
  return 1.0f / (1.0f + __expf(-x));
}
__device__ __forceinline__ float tanh_f(float x) {
  float e = __expf(2.0f * x);
  return 1.0f - 2.0f / (1.0f + e);
}
__device__ __forceinline__ unsigned short bf16r(float x) {   // RNE float->bf16
  unsigned int u = __float_as_uint(x);
  u = (u + 0x7FFFu + ((u >> 16) & 1u)) >> 16;
  return (unsigned short)u;
}
__device__ __forceinline__ float bf16f(unsigned short h) {
  return __uint_as_float(((unsigned int)h) << 16);
}

// ---------- prep: weight split/pack (conv + proj + z_w + m_w A-frags) + zero states ----------
__global__ void k0_prep(const float* __restrict__ conv_w, const float* __restrict__ z_w,
                        const float* __restrict__ m_w,
                        const float* __restrict__ qw, const float* __restrict__ kw,
                        const float* __restrict__ vw, const float* __restrict__ k2w,
                        const float* __restrict__ v2w,
                        unsigned short* __restrict__ Whi, unsigned short* __restrict__ Wlo,
                        unsigned short* __restrict__ zAhi, unsigned short* __restrict__ zAlo,
                        unsigned short* __restrict__ mAhi, unsigned short* __restrict__ mAlo,
                        unsigned short* __restrict__ pAhi, unsigned short* __restrict__ pAlo,
                        float* __restrict__ h_A, float* __restrict__ c_st) {
  int stride = gridDim.x * blockDim.x;
  int i0 = blockIdx.x * blockDim.x + threadIdx.x;
  for (int i = i0; i < 256*1152; i += stride) {
    int oc = i / 1152, k = i - oc*1152;          // k = icComb*9 + ky*3 + kx
    float v = conv_w[i];
    unsigned short hi = bf16r(v);
    unsigned short lo = bf16r(v - bf16f(hi));
    int mt = oc >> 4, i16 = oc & 15;
    int ks = k >> 5, kk = k & 31;
    int lane = i16 | ((kk >> 3) << 4);
    int pos = ((mt*36 + ks)*64 + lane)*8 + (kk & 7);
    Whi[pos] = hi;
    Wlo[pos] = lo;
  }
  for (int i = i0; i < 128*128; i += stride) {   // z_w A-frags: 8 mt x 4 ks
    int oc = i >> 7, k = i & 127;
    float v = z_w[i];
    unsigned short hi = bf16r(v);
    unsigned short lo = bf16r(v - bf16f(hi));
    int mt = oc >> 4, i16 = oc & 15;
    int ks = k >> 5, kk = k & 31;
    int lane = i16 | ((kk >> 3) << 4);
    int pos = ((mt*4 + ks)*64 + lane)*8 + (kk & 7);
    zAhi[pos] = hi;
    zAlo[pos] = lo;
  }
  for (int i = i0; i < 192*192; i += stride) {   // m_w A-frags: 12 mt x 6 ks
    int oc = i / 192, k = i - oc*192;
    float v = m_w[i];
    unsigned short hi = bf16r(v);
    unsigned short lo = bf16r(v - bf16f(hi));
    int mt = oc >> 4, i16 = oc & 15;
    int ks = k >> 5, kk = k & 31;
    int lane = i16 | ((kk >> 3) << 4);
    int pos = ((mt*6 + ks)*64 + lane)*8 + (kk & 7);
    mAhi[pos] = hi;
    mAlo[pos] = lo;
  }
  for (int i = i0; i < 176*64; i += stride) {    // proj A-frags: 11 mt x 2 ks
    int po = i >> 6, c = i & 63;
    float v;
    if (po < 16)       v = qw[po*64 + c];
    else if (po < 32)  v = kw[(po-16)*64 + c];
    else if (po < 96)  v = vw[(po-32)*64 + c];
    else if (po < 112) v = k2w[(po-96)*64 + c];
    else               v = v2w[(po-112)*64 + c];
    unsigned short hi = bf16r(v);
    unsigned short lo = bf16r(v - bf16f(hi));
    int mt = po >> 4, i16 = po & 15;
    int ks = c >> 5, kk = c & 31;
    int lane = i16 | ((kk >> 3) << 4);
    int pos = ((mt*2 + ks)*64 + lane)*8 + (kk & 7);
    pAhi[pos] = hi;
    pAlo[pos] = lo;
  }
  for (int i = i0; i < NB*64*NN; i += stride) { h_A[i] = 0.0f; c_st[i] = 0.0f; }
}

// ---------- K0b v4: conv_x, N=64 per block (2 rows), X hi-only, grid 1024 ----------
__global__ __launch_bounds__(1024, 2) void k0b_gx(
    const float* __restrict__ X,
    const unsigned short* __restrict__ Whi, const unsigned short* __restrict__ Wlo,
    float* __restrict__ gx)
{
  __shared__ __align__(16) unsigned short Xhi_l[18*4*64*8];   // [ks][nt 0..3][lane][8] = 73728 B

  const int tid = threadIdx.x;
  const int bid = blockIdx.x;       // b*256 + t*16 + y2
  const int y2 = bid & 15;
  const int t  = (bid >> 4) & 15;
  const int b  = bid >> 8;
  const int y0 = y2 * 2;

  // im2col for two output rows (halo rows y0-1 .. y0+2), x-channels only, hi plane
  for (int idx = tid; idx < 64*4*34; idx += 1024) {
    int col = idx % 34;
    int rest = idx / 34;
    int dy = rest % 4;               // halo row index 0..3 -> gy = y0 + dy - 1
    int ic = rest / 4;
    int gy = y0 + dy - 1;
    int gxc = col - 1;
    float v = 0.0f;
    if ((unsigned)gy < 32u && (unsigned)gxc < 32u)
      v = X[(((b*64 + ic)*SS + t)*NN) + gy*32 + gxc];
    unsigned short hi = bf16r(v);
    #pragma unroll
    for (int r = 0; r < 2; r++) {
      int dyl = dy - r;                    // kernel row for output row r
      if ((unsigned)dyl < 3u) {
        int kbase = ic*9 + dyl*3;
        #pragma unroll
        for (int dx = 0; dx < 3; dx++) {
          int x = col - dx;
          if ((unsigned)x < 32u) {
            int k = kbase + dx;
            int ks = k >> 5, kk = k & 31;
            int n = r*32 + x;              // 0..63
            int nt = n >> 4, n16 = n & 15;
            int pos = (((ks*4 + nt)*64) + (n16 | ((kk >> 3) << 4)))*8 + (kk & 7);
            Xhi_l[pos] = hi;
          }
        }
      }
    }
  }
  __syncthreads();

  const int lane = tid & 63;
  const int mt = tid >> 6;          // 0..15
  f4v acc[4];
  #pragma unroll
  for (int nt = 0; nt < 4; nt++) acc[nt] = (f4v){0.f, 0.f, 0.f, 0.f};
  const s8v* Ah = (const s8v*)Whi + (mt*36)*64 + lane;
  const s8v* Al = (const s8v*)Wlo + (mt*36)*64 + lane;
  const s8v* Bh = (const s8v*)Xhi_l + lane;
  #pragma unroll 3
  for (int ks = 0; ks < 18; ks++) {
    s8v ah = Ah[ks*64];
    s8v al = Al[ks*64];
    #pragma unroll
    for (int nt = 0; nt < 4; nt++) {
      s8v bh = Bh[(ks*4 + nt)*64];
      acc[nt] = __builtin_amdgcn_mfma_f32_16x16x32_bf16(ah, bh, acc[nt], 0, 0, 0);
      acc[nt] = __builtin_amdgcn_mfma_f32_16x16x32_bf16(al, bh, acc[nt], 0, 0, 0);
    }
  }
  const int c16 = lane & 15;
  const int rb  = (lane >> 4) * 4;
  float* gout = gx + (((long)b*SS + t)*256)*NN;
  #pragma unroll
  for (int nt = 0; nt < 4; nt++) {
    #pragma unroll
    for (int r4 = 0; r4 < 4; r4++) {
      int oc = mt*16 + rb + r4;
      int n = nt*16 + c16;
      int py = y0 + (n >> 5);
      int px2 = n & 31;
      gout[oc*NN + py*32 + px2] = acc[nt][r4];
    }
  }
}

// ---------- K1: conv_h + LSTM(+gx) + MFMA projections (1024 threads) ----------
__global__ __launch_bounds__(1024, 2) void k1_conv_lstm_proj(
    int t,
    const float* __restrict__ gx,
    const unsigned short* __restrict__ Whi, const unsigned short* __restrict__ Wlo,
    const unsigned short* __restrict__ pAhi, const unsigned short* __restrict__ pAlo,
    const float* __restrict__ conv_b,
    const float* __restrict__ W_ci, const float* __restrict__ W_cf, const float* __restrict__ W_co,
    const float* __restrict__ qb, const float* __restrict__ kb,
    const float* __restrict__ vb, const float* __restrict__ k2b,
    const float* __restrict__ v2b,
    const float* __restrict__ h_cur, float* __restrict__ h_nxt,
    float* __restrict__ c_st,
    float* __restrict__ q_buf,
    unsigned short* __restrict__ kF,
    unsigned short* __restrict__ vFh)
{
  __shared__ __align__(16) unsigned short Ihi_l[18*64*8];      // h-only im2col, B-frag order
  __shared__ __align__(16) unsigned short Ilo_l[18*64*8];
  __shared__ __align__(16) float gates_l[256*17];              // [oc][x]; later proj_l[176][16]
  __shared__ __align__(16) unsigned short hBh[2*64*8];         // h in B-frag layout (hi/lo)
  __shared__ __align__(16) unsigned short hBl[2*64*8];
  __shared__ __align__(16) unsigned short cBh[2*64*8];         // c in B-frag layout
  __shared__ __align__(16) unsigned short cBl[2*64*8];
  __shared__ __align__(16) float pb_l[176];

  const int tid = threadIdx.x;
  const int bid = blockIdx.x;
  const int b  = bid >> 6;
  const int y  = (bid >> 1) & 31;
  const int x0 = (bid & 1) * 16;
  const int mt = bid & 63;          // this block's 16-col m-tile (= n>>4)
  const int n0 = y*32 + x0;

  // ---- prefetch LSTM inputs + projection A-frags into registers ----
  const int px = tid & 15;
  const int pc = tid >> 4;          // 0..63
  const int pn = n0 + px;
  const float* gxp = gx + (((long)b*SS + t)*256)*NN + pn;
  float pf_g0 = gxp[(pc      )*NN];
  float pf_g1 = gxp[( 64 + pc)*NN];
  float pf_g2 = gxp[(128 + pc)*NN];
  float pf_g3 = gxp[(192 + pc)*NN];
  float pf_cp  = c_st[(b*64 + pc)*NN + pn];
  float pf_wci = W_ci[pc*NN + pn];
  float pf_wcf = W_cf[pc*NN + pn];
  float pf_wco = W_co[pc*NN + pn];
  float pf_b0 = conv_b[pc];
  float pf_b1 = conv_b[ 64 + pc];
  float pf_b2 = conv_b[128 + pc];
  float pf_b3 = conv_b[192 + pc];
  const int lane_e = tid & 63;
  const int wv_e   = tid >> 6;
  const int wvc    = (wv_e < 11) ? wv_e : 0;
  s8v pf_a0h = *(const s8v*)(pAhi + ((wvc*2 + 0)*64 + lane_e)*8);
  s8v pf_a0l = *(const s8v*)(pAlo + ((wvc*2 + 0)*64 + lane_e)*8);
  s8v pf_a1h = *(const s8v*)(pAhi + ((wvc*2 + 1)*64 + lane_e)*8);
  s8v pf_a1l = *(const s8v*)(pAlo + ((wvc*2 + 1)*64 + lane_e)*8);

  // ---- phase 0: h-only im2col -> B-frags  +  stage proj biases ----
  for (int idx = tid; idx < 64*3*18; idx += 1024) {
    int col = idx % 18;
    int rest = idx / 18;
    int dy = rest % 3;
    int ic = rest / 3;                    // h channel 0..63
    int gy = y + dy - 1;
    int gxc = x0 + col - 1;
    float v = 0.0f;
    if ((unsigned)gy < 32u && (unsigned)gxc < 32u)
      v = h_cur[((b*64 + ic)*NN) + gy*32 + gxc];
    unsigned short hi = bf16r(v);
    unsigned short lo = bf16r(v - bf16f(hi));
    int kbase = ic*9 + dy*3;              // local k in [0,576)
    #pragma unroll
    for (int dx = 0; dx < 3; dx++) {
      int n = col - dx;
      if ((unsigned)n < 16u) {
        int k = kbase + dx;
        int ks = k >> 5, kk = k & 31;
        int pos = (ks*64 + (n | ((kk >> 3) << 4)))*8 + (kk & 7);
        Ihi_l[pos] = hi;
        Ilo_l[pos] = lo;
      }
    }
  }
  if (tid < 176) {
    int po = tid;
    float v;
    if (po < 16)       v = qb[po];
    else if (po < 32)  v = kb[po-16];
    else if (po < 96)  v = vb[po-32];
    else if (po < 112) v = k2b[po-96];
    else               v = v2b[po-112];
    pb_l[po] = v;
  }
  __syncthreads();

  // ---- phase 1: conv_h MFMA: 16 waves, 1 m-tile each; A-frags at ks 18..35 ----
  {
    const int lane = tid & 63;
    const int wv   = tid >> 6;        // 0..15 = m-tile
    f4v acc = {0.f, 0.f, 0.f, 0.f};
    const s8v* Ah = (const s8v*)Whi + (wv*36 + 18)*64 + lane;
    const s8v* Al = (const s8v*)Wlo + (wv*36 + 18)*64 + lane;
    const s8v* Bh = (const s8v*)Ihi_l + lane;
    const s8v* Bl = (const s8v*)Ilo_l + lane;
    #pragma unroll 3
    for (int ks = 0; ks < 18; ks++) {
      s8v ah = Ah[ks*64];
      s8v al = Al[ks*64];
      s8v bh = Bh[ks*64];
      s8v bl = Bl[ks*64];
      acc = __builtin_amdgcn_mfma_f32_16x16x32_bf16(ah, bh, acc, 0, 0, 0);
      acc = __builtin_amdgcn_mfma_f32_16x16x32_bf16(al, bh, acc, 0, 0, 0);
      acc = __builtin_amdgcn_mfma_f32_16x16x32_bf16(ah, bl, acc, 0, 0, 0);
    }
    const int colx = lane & 15;
    const int rb   = (lane >> 4) * 4;
    #pragma unroll
    for (int r = 0; r < 4; r++)
      gates_l[(wv*16 + rb + r)*17 + colx] = acc[r];
  }
  __syncthreads();

  // ---- phase 2: LSTM elementwise; write h/c into B-frag layout ----
  {
    const int x = px;
    const int c = pc;
    const int n = pn;
    float ig = gates_l[(c      )*17 + x] + pf_g0 + pf_b0;
    float fg = gates_l[( 64 + c)*17 + x] + pf_g1 + pf_b1;
    float gg = gates_l[(128 + c)*17 + x] + pf_g2 + pf_b2;
    float og = gates_l[(192 + c)*17 + x] + pf_g3 + pf_b3;
    float cp = pf_cp;
    float i_ = sigm(ig + pf_wci * cp);
    float f_ = sigm(fg + pf_wcf * cp);
    float cn = f_*cp + i_*tanh_f(gg);
    float o_ = sigm(og + pf_wco * cn);
    float hn = o_*tanh_f(cn);
    h_nxt[(b*64 + c)*NN + n] = hn;
    c_st[(b*64 + c)*NN + n] = cn;
    const int ksC = c >> 5, kkC = c & 31;
    const int posF = (ksC*64 + (x | ((kkC >> 3) << 4)))*8 + (kkC & 7);
    unsigned short hh = bf16r(hn);
    hBh[posF] = hh;
    hBl[posF] = bf16r(hn - bf16f(hh));
    unsigned short ch = bf16r(cn);
    cBh[posF] = ch;
    cBl[posF] = bf16r(cn - bf16f(ch));
  }
  __syncthreads();

  // ---- phase 3: projections via MFMA (11 waves, mt 0..5 from h, 6..10 from c) ----
  float* proj_l = gates_l;              // gates fully consumed in phase 2
  {
    const int lane = lane_e;
    const int wv   = wv_e;
    if (wv < 11) {
      const s8v* Bh_ = (const s8v*)((wv < 6) ? hBh : cBh) + lane;
      const s8v* Bl_ = (const s8v*)((wv < 6) ? hBl : cBl) + lane;
      f4v acc = {0.f, 0.f, 0.f, 0.f};
      s8v bh0 = Bh_[0];
      s8v bl0 = Bl_[0];
      s8v bh1 = Bh_[64];
      s8v bl1 = Bl_[64];
      acc = __builtin_amdgcn_mfma_f32_16x16x32_bf16(pf_a0h, bh0, acc, 0, 0, 0);
      acc = __builtin_amdgcn_mfma_f32_16x16x32_bf16(pf_a0l, bh0, acc, 0, 0, 0);
      acc = __builtin_amdgcn_mfma_f32_16x16x32_bf16(pf_a0h, bl0, acc, 0, 0, 0);
      acc = __builtin_amdgcn_mfma_f32_16x16x32_bf16(pf_a1h, bh1, acc, 0, 0, 0);
      acc = __builtin_amdgcn_mfma_f32_16x16x32_bf16(pf_a1l, bh1, acc, 0, 0, 0);
      acc = __builtin_amdgcn_mfma_f32_16x16x32_bf16(pf_a1h, bl1, acc, 0, 0, 0);
      const int colx = lane & 15;
      const int rb   = (lane >> 4) * 4;
      #pragma unroll
      for (int r = 0; r < 4; r++) {
        int po = wv*16 + rb + r;
        proj_l[po*16 + colx] = acc[r] + pb_l[po];
      }
    }
  }
  __syncthreads();

  // ---- phase 4: coalesced fragment emission (V hi-plane only) ----
  if (tid < 256) {
    int d = tid >> 4, x = tid & 15;
    q_buf[(b*16 + d)*NN + n0 + x] = proj_l[d*16 + x];
  }
  if (tid < 512) {
    int brh2 = tid >> 8;            // branch
    int lh   = (tid >> 2) & 63;     // fragment "lane-half" row
    int j2   = tid & 3;             // packs d&7 = 2*j2, 2*j2+1
    int p    = lh >> 4;             // 0,1: hi planes; 2,3: lo planes
    int x    = lh & 15;
    int d0   = ((p & 1) << 3) | (j2 << 1);
    int Koff = brh2 ? 96 : 16;
    float v0 = proj_l[(Koff + d0)*16 + x];
    float v1 = proj_l[(Koff + d0 + 1)*16 + x];
    unsigned short h0 = bf16r(v0), h1 = bf16r(v1);
    unsigned short u0, u1;
    if (p < 2) { u0 = h0; u1 = h1; }
    else       { u0 = bf16r(v0 - bf16f(h0)); u1 = bf16r(v1 - bf16f(h1)); }
    unsigned int* dst = (unsigned int*)(kF + ((b*2 + brh2)*64 + mt)*512);
    dst[lh*4 + j2] = (unsigned)u0 | ((unsigned)u1 << 16);
  }
  {
    const int ks = y;
    const int g0 = x0 >> 3;         // 0 or 2
    int ct    = tid;                // 1024 tasks: brh(2) x nt(4) x li(32) x j2(4)
    int brh2  = (ct >> 9) & 1;
    int nt    = (ct >> 7) & 3;
    int li    = (ct >> 2) & 31;
    int j2    = ct & 3;
    int lane2 = g0*16 + li;
    int cch   = nt*16 + (lane2 & 15);
    int xx    = ((li >> 4) << 3) | (j2 << 1);
    int Voff  = brh2 ? 112 : 32;
    float v0 = proj_l[(Voff + cch)*16 + xx];
    float v1 = proj_l[(Voff + cch)*16 + xx + 1];
    unsigned short u0 = bf16r(v0), u1 = bf16r(v1);
    unsigned short* basep = vFh + (((b*2 + brh2)*32 + ks)*4 + nt)*512;
    ((unsigned int*)basep)[lane2*4 + j2] = (unsigned)u0 | ((unsigned)u1 << 16);
  }
}

// ---------- K2: dual attention via MFMA + MFMA combine + gating ----------
#define RED_OFF 0        // [16 waves][16 nl][66]  = 16896
#define PS_OFF  16896    // [16 waves][16][36]     = 9216
#define SMX_OFF 26112    // [2][8][16]             = 256
#define SSM_OFF 26368    // [2][8][16]             = 256
#define INV_OFF 26624    // [2][16]                = 32
#define S_TOT   28704

__global__ __launch_bounds__(1024, 4) void k2_attn(
    int t,
    const float* __restrict__ q_buf,
    const unsigned short* __restrict__ kF,
    const unsigned short* __restrict__ vFh,
    float* __restrict__ h_nxt, float* __restrict__ c_st,
    const unsigned short* __restrict__ zAhi, const unsigned short* __restrict__ zAlo,
    const unsigned short* __restrict__ mAhi, const unsigned short* __restrict__ mAlo,
    const float* __restrict__ z_b, const float* __restrict__ m_b,
    float* __restrict__ out)
{
  __shared__ __align__(16) float S[S_TOT];
  __shared__ __align__(16) unsigned short zBh[4*512];   // zz B-frags (4 ks)
  __shared__ __align__(16) unsigned short zBl[4*512];
  __shared__ __align__(16) unsigned short cbBh[6*512];  // comb B-frags (6 ks)
  __shared__ __align__(16) unsigned short cbBl[6*512];
  float* red  = S + RED_OFF;
  float* smMax= S + SMX_OFF;
  float* smSum= S + SSM_OFF;
  float* invL = S + INV_OFF;
  float* cbOut= S + 3072;       // [192][16] aliases red (after barrier)

  const int tid = threadIdx.x;
  const int bid = blockIdx.x;
  const int xcd = bid & 7;
  const int b = xcd >> 1;
  const int tile = ((bid >> 3) << 1) | (xcd & 1);   // 0..63
  const int n0 = tile * 16;

  const int wid  = tid >> 6;
  const int lane = tid & 63;
  const int brh  = wid >> 3;      // branch
  const int w    = wid & 7;       // wave within branch
  const int g    = lane >> 4;
  const int c16  = lane & 15;

  // ---- prefetch tail-phase inputs ----
  const int pc2 = tid >> 4;       // 0..63
  const int pn2 = n0 + (tid & 15);
  float pf_cst = c_st[(b*64 + pc2)*NN + pn2];
  float pf_h   = h_nxt[(b*64 + pc2)*NN + pn2];

  // ---- Q A-frags: A1 = [Qh|Qh], A2 = [Ql|0] ----
  s8v qh1, ql2;
  {
    const int dbase = (g & 1) * 8;
    #pragma unroll
    for (int j = 0; j < 8; j++) {
      float qv = q_buf[(b*16 + dbase + j)*NN + n0 + c16];
      unsigned short hi = bf16r(qv);
      unsigned short lo = bf16r(qv - bf16f(hi));
      qh1[j] = (short)hi;
      ql2[j] = (g < 2) ? (short)lo : (short)0;
    }
  }

  // ---- scores: 8 m-tiles per wave, 2 MFMA each (B = [Kh|Kl]) ----
  f4v acc[8];
  {
    const unsigned short* kp = kF + (((b*2 + brh)*64 + w*8)*64 + lane)*8;
    #pragma unroll
    for (int i = 0; i < 8; i++) {
      s8v bf = *(const s8v*)(kp + i*512);
      f4v z4 = {0.f, 0.f, 0.f, 0.f};
      z4 = __builtin_amdgcn_mfma_f32_16x16x32_bf16(ql2, bf, z4, 0, 0, 0);
      acc[i] = __builtin_amdgcn_mfma_f32_16x16x32_bf16(qh1, bf, z4, 0, 0, 0);
    }
  }

  // ---- softmax ----
  float Mrow[4];
  #pragma unroll
  for (int r = 0; r < 4; r++) {
    float m = acc[0][r];
    #pragma unroll
    for (int i = 1; i < 8; i++) m = fmaxf(m, acc[i][r]);
    m = fmaxf(m, __shfl_xor(m, 1));
    m = fmaxf(m, __shfl_xor(m, 2));
    m = fmaxf(m, __shfl_xor(m, 4));
    m = fmaxf(m, __shfl_xor(m, 8));
    if (c16 == 0) smMax[(brh*8 + w)*16 + g*4 + r] = m;
  }
  __syncthreads();
  #pragma unroll
  for (int r = 0; r < 4; r++) {
    float m = smMax[(brh*8 + 0)*16 + g*4 + r];
    #pragma unroll
    for (int w2 = 1; w2 < 8; w2++) m = fmaxf(m, smMax[(brh*8 + w2)*16 + g*4 + r]);
    Mrow[r] = m;
  }
  float rsum[4] = {0.f, 0.f, 0.f, 0.f};
  #pragma unroll
  for (int i = 0; i < 8; i++) {
    #pragma unroll
    for (int r = 0; r < 4; r++) {
      float p = __expf(acc[i][r] - Mrow[r]);
      acc[i][r] = p;
      rsum[r] += p;
    }
  }
  #pragma unroll
  for (int r = 0; r < 4; r++) {
    float s = rsum[r];
    s += __shfl_xor(s, 1); s += __shfl_xor(s, 2);
    s += __shfl_xor(s, 4); s += __shfl_xor(s, 8);
    if (c16 == 0) smSum[(brh*8 + w)*16 + g*4 + r] = s;
  }
  __syncthreads();
  if (w == 0 && c16 == 0) {
    #pragma unroll
    for (int r = 0; r < 4; r++) {
      float s = 0.f;
      #pragma unroll
      for (int w2 = 0; w2 < 8; w2++) s += smSum[(brh*8 + w2)*16 + g*4 + r];
      invL[brh*16 + g*4 + r] = 1.0f / s;
    }
  }

  // ---- PV: per wave, 4 k-steps of 32 m; wave-local P transpose; V hi-only ----
  f4v z0 = {0.f,0.f,0.f,0.f}, z1 = z0, z2 = z0, z3 = z0;
  float* myPS = S + PS_OFF + wid*576;   // [16][36]
  #pragma unroll
  for (int ks4 = 0; ks4 < 4; ks4++) {
    #pragma unroll
    for (int i2 = 0; i2 < 2; i2++) {
      #pragma unroll
      for (int r = 0; r < 4; r++)
        myPS[(g*4 + r)*36 + i2*16 + c16] = acc[ks4*2 + i2][r];
    }
    float4 pa = *(const float4*)&myPS[c16*36 + g*8];
    float4 pb = *(const float4*)&myPS[c16*36 + g*8 + 4];
    s8v ph, pl;
    {
      unsigned short h0 = bf16r(pa.x); ph[0] = (short)h0; pl[0] = (short)bf16r(pa.x - bf16f(h0));
      unsigned short h1 = bf16r(pa.y); ph[1] = (short)h1; pl[1] = (short)bf16r(pa.y - bf16f(h1));
      unsigned short h2 = bf16r(pa.z); ph[2] = (short)h2; pl[2] = (short)bf16r(pa.z - bf16f(h2));
      unsigned short h3 = bf16r(pa.w); ph[3] = (short)h3; pl[3] = (short)bf16r(pa.w - bf16f(h3));
      unsigned short h4 = bf16r(pb.x); ph[4] = (short)h4; pl[4] = (short)bf16r(pb.x - bf16f(h4));
      unsigned short h5 = bf16r(pb.y); ph[5] = (short)h5; pl[5] = (short)bf16r(pb.y - bf16f(h5));
      unsigned short h6 = bf16r(pb.z); ph[6] = (short)h6; pl[6] = (short)bf16r(pb.z - bf16f(h6));
      unsigned short h7 = bf16r(pb.w); ph[7] = (short)h7; pl[7] = (short)bf16r(pb.w - bf16f(h7));
    }
    const int ks = w*4 + ks4;
    const unsigned short* vph = vFh + ((((b*2 + brh)*32 + ks)*4)*64 + lane)*8;
    s8v vh0 = *(const s8v*)(vph);
    z0 = __builtin_amdgcn_mfma_f32_16x16x32_bf16(ph, vh0, z0, 0,0,0);
    z0 = __builtin_amdgcn_mfma_f32_16x16x32_bf16(pl, vh0, z0, 0,0,0);
    s8v vh1 = *(const s8v*)(vph + 512);
    z1 = __builtin_amdgcn_mfma_f32_16x16x32_bf16(ph, vh1, z1, 0,0,0);
    z1 = __builtin_amdgcn_mfma_f32_16x16x32_bf16(pl, vh1, z1, 0,0,0);
    s8v vh2 = *(const s8v*)(vph + 1024);
    z2 = __builtin_amdgcn_mfma_f32_16x16x32_bf16(ph, vh2, z2, 0,0,0);
    z2 = __builtin_amdgcn_mfma_f32_16x16x32_bf16(pl, vh2, z2, 0,0,0);
    s8v vh3 = *(const s8v*)(vph + 1536);
    z3 = __builtin_amdgcn_mfma_f32_16x16x32_bf16(ph, vh3, z3, 0,0,0);
    z3 = __builtin_amdgcn_mfma_f32_16x16x32_bf16(pl, vh3, z3, 0,0,0);
  }

  // ---- write partials, reduce 8 waves, normalize -> zz B-frags ----
  {
    float* rw = red + wid*1056;
    #pragma unroll
    for (int r = 0; r < 4; r++) {
      rw[(g*4 + r)*66 +  0 + c16] = z0[r];
      rw[(g*4 + r)*66 + 16 + c16] = z1[r];
      rw[(g*4 + r)*66 + 32 + c16] = z2[r];
      rw[(g*4 + r)*66 + 48 + c16] = z3[r];
    }
  }
  __syncthreads();
  {
    const int br2 = tid >> 9;
    const int sub = tid & 511;
    const int nlr = sub >> 5;
    const int cc0 = (sub & 31) * 2;
    float iv = invL[br2*16 + nlr];
    #pragma unroll
    for (int u = 0; u < 2; u++) {
      int cc = cc0 + u;
      float s = 0.f;
      #pragma unroll
      for (int w2 = 0; w2 < 8; w2++)
        s += red[(br2*8 + w2)*1056 + nlr*66 + cc];
      float v = s * iv;
      int k = br2*64 + cc;
      int ks = k >> 5, kk = k & 31;
      int pos = (ks*64 + (nlr | ((kk >> 3) << 4)))*8 + (kk & 7);
      unsigned short h = bf16r(v);
      zBh[pos] = h;
      zBl[pos] = bf16r(v - bf16f(h));
    }
  }
  __syncthreads();

  // ---- h rows into comb B-frags + zz via MFMA (waves 0..7) ----
  {
    int k = 128 + pc2;
    int ks = k >> 5, kk = k & 31;
    int pos = (ks*64 + ((tid & 15) | ((kk >> 3) << 4)))*8 + (kk & 7);
    unsigned short h = bf16r(pf_h);
    cbBh[pos] = h;
    cbBl[pos] = bf16r(pf_h - bf16f(h));
  }
  if (wid < 8) {
    f4v za = {0.f, 0.f, 0.f, 0.f};
    const s8v* Azh = (const s8v*)zAhi + (wid*4)*64 + lane;
    const s8v* Azl = (const s8v*)zAlo + (wid*4)*64 + lane;
    const s8v* Bzh = (const s8v*)zBh + lane;
    const s8v* Bzl = (const s8v*)zBl + lane;
    #pragma unroll
    for (int ks = 0; ks < 4; ks++) {
      s8v ah = Azh[ks*64];
      s8v al = Azl[ks*64];
      s8v bh = Bzh[ks*64];
      s8v bl = Bzl[ks*64];
      za = __builtin_amdgcn_mfma_f32_16x16x32_bf16(ah, bh, za, 0, 0, 0);
      za = __builtin_amdgcn_mfma_f32_16x16x32_bf16(al, bh, za, 0, 0, 0);
      za = __builtin_amdgcn_mfma_f32_16x16x32_bf16(ah, bl, za, 0, 0, 0);
    }
    #pragma unroll
    for (int r = 0; r < 4; r++) {
      int oc = wid*16 + g*4 + r;
      float v = za[r] + z_b[oc];
      int kk = oc & 31, ks2 = oc >> 5;
      int pos = (ks2*64 + (c16 | ((kk >> 3) << 4)))*8 + (kk & 7);
      unsigned short h = bf16r(v);
      cbBh[pos] = h;
      cbBl[pos] = bf16r(v - bf16f(h));
    }
  }
  __syncthreads();

  // ---- comb via MFMA (waves 0..11) ----
  if (wid < 12) {
    f4v ca = {0.f, 0.f, 0.f, 0.f};
    const s8v* Amh = (const s8v*)mAhi + (wid*6)*64 + lane;
    const s8v* Aml = (const s8v*)mAlo + (wid*6)*64 + lane;
    const s8v* Bch = (const s8v*)cbBh + lane;
    const s8v* Bcl = (const s8v*)cbBl + lane;
    #pragma unroll
    for (int ks = 0; ks < 6; ks++) {
      s8v ah = Amh[ks*64];
      s8v al = Aml[ks*64];
      s8v bh = Bch[ks*64];
      s8v bl = Bcl[ks*64];
      ca = __builtin_amdgcn_mfma_f32_16x16x32_bf16(ah, bh, ca, 0, 0, 0);
      ca = __builtin_amdgcn_mfma_f32_16x16x32_bf16(al, bh, ca, 0, 0, 0);
      ca = __builtin_amdgcn_mfma_f32_16x16x32_bf16(ah, bl, ca, 0, 0, 0);
    }
    #pragma unroll
    for (int r = 0; r < 4; r++) {
      int oc = wid*16 + g*4 + r;
      cbOut[oc*16 + c16] = ca[r] + m_b[oc];
    }
  }
  __syncthreads();

  // ---- gating ----
  {
    const int c = pc2, nn = tid & 15;
    const int n = n0 + nn;
    float mo = cbOut[c*16 + nn];
    float mg = cbOut[(64 + c)*16 + nn];
    float mi = cbOut[(128 + c)*16 + nn];
    float mf = pf_cst;
    float mis = sigm(mi);
    float nmf = (1.0f - mis)*mf + mis*tanh_f(mg);
    float nhf = sigm(mo)*nmf;
    c_st[(b*64 + c)*NN + n] = nmf;
    h_nxt[(b*64 + c)*NN + n] = nhf;
    out[((b*64 + c)*SS + t)*NN + n] = nhf;
  }
}

extern "C" void kernel_launch(void* const* d_in, const int* in_sizes, int n_in,
                              void* d_out, int out_size, void* d_ws, size_t ws_size,
                              hipStream_t stream) {
  const float* X      = (const float*)d_in[0];
  const float* conv_w = (const float*)d_in[1];
  const float* conv_b = (const float*)d_in[2];
  const float* W_ci   = (const float*)d_in[3];
  const float* W_cf   = (const float*)d_in[4];
  const float* W_co   = (const float*)d_in[5];
  const float* qw  = (const float*)d_in[6];
  const float* qb  = (const float*)d_in[7];
  const float* kw  = (const float*)d_in[8];
  const float* kb  = (const float*)d_in[9];
  const float* k2w = (const float*)d_in[10];
  const float* k2b = (const float*)d_in[11];
  const float* vw  = (const float*)d_in[12];
  const float* vb  = (const float*)d_in[13];
  const float* v2w = (const float*)d_in[14];
  const float* v2b = (const float*)d_in[15];
  const float* z_w = (const float*)d_in[16];
  const float* z_b = (const float*)d_in[17];
  const float* m_w = (const float*)d_in[18];
  const float* m_b = (const float*)d_in[19];
  float* out = (float*)d_out;

  float* ws = (float*)d_ws;
  unsigned short* Whi  = (unsigned short*)ws;  ws += 147456;   // 294912 ushorts
  unsigned short* Wlo  = (unsigned short*)ws;  ws += 147456;
  unsigned short* zAhi = (unsigned short*)ws;  ws += 8192;     // 16384 ushorts
  unsigned short* zAlo = (unsigned short*)ws;  ws += 8192;
  unsigned short* mAhi = (unsigned short*)ws;  ws += 18432;    // 36864 ushorts
  unsigned short* mAlo = (unsigned short*)ws;  ws += 18432;
  unsigned short* pAhi = (unsigned short*)ws;  ws += 5632;     // 11264 ushorts
  unsigned short* pAlo = (unsigned short*)ws;  ws += 5632;
  float* h_A    = ws;             ws += NB*64*NN;
  float* h_B    = ws;             ws += NB*64*NN;
  float* c_st   = ws;             ws += NB*64*NN;
  float* q_buf  = ws;             ws += NB*16*NN;
  unsigned short* kF  = (unsigned short*)ws;  ws += 131072;   // 4b*2br*64mt*64*8 ushorts
  unsigned short* vFh = (unsigned short*)ws;  ws += 131072;   // 4b*2br*32ks*4nt*64*8
  float* gx     = ws;             ws += NB*SS*256*NN;         // 16.8M floats, 67 MB

  hipLaunchKernelGGL(k0_prep, dim3(256), dim3(256), 0, stream,
                     conv_w, z_w, m_w, qw, kw, vw, k2w, v2w,
                     Whi, Wlo, zAhi, zAlo, mAhi, mAlo, pAhi, pAlo, h_A, c_st);
  hipLaunchKernelGGL(k0b_gx, dim3(1024), dim3(1024), 0, stream,
                     X, Whi, Wlo, gx);
  for (int t = 0; t < 16; t++) {
    const float* h_cur = (t & 1) ? h_B : h_A;
    float* h_nxt       = (t & 1) ? h_A : h_B;
    hipLaunchKernelGGL(k1_conv_lstm_proj, dim3(256), dim3(1024), 0, stream,
        t, gx, Whi, Wlo, pAhi, pAlo, conv_b, W_ci, W_cf, W_co,
        qb, kb, vb, k2b, v2b,
        h_cur, h_nxt, c_st, q_buf, kF, vFh);
    hipLaunchKernelGGL(k2_attn, dim3(256), dim3(1024), 0, stream,
        t, q_buf, kF, vFh, h_nxt, c_st,
        zAhi, zAlo, mAhi, mAlo, z_b, m_b, out);
  }
}

// Round 17
// 497.347 us; speedup vs baseline: 1.5480x; 1.0145x over previous
//
#include <hip/hip_runtime.h>
#include <math.h>

#define NB 4
#define SS 16
#define NN 1024        // H*W

typedef short s8v __attribute__((ext_vector_type(8)));    // 8 bf16 (4 VGPR)
typedef float f4v __attribute__((ext_vector_type(4)));    // MFMA accumulator

__device__ __forceinline__ float sigm(float x) {
  return 1.0f / (1.0f + __expf(-x));
}
__device__ __forceinline__ float tanh_f(float x) {
  float e = __expf(2.0f * x);
  return 1.0f - 2.0f / (1.0f + e);
}
__device__ __forceinline__ unsigned short bf16r(float x) {   // RNE float->bf16
  unsigned int u = __float_as_uint(x);
  u = (u + 0x7FFFu + ((u >> 16) & 1u)) >> 16;
  return (unsigned short)u;
}
__device__ __forceinline__ float bf16f(unsigned short h) {
  return __uint_as_float(((unsigned int)h) << 16);
}

// ---------- prep: weight split/pack (conv + proj + z_w + m_w A-frags) + zero states ----------
__global__ void k0_prep(const float* __restrict__ conv_w, const float* __restrict__ z_w,
                        const float* __restrict__ m_w,
                        const float* __restrict__ qw, const float* __restrict__ kw,
                        const float* __restrict__ vw, const float* __restrict__ k2w,
                        const float* __restrict__ v2w,
                        unsigned short* __restrict__ Whi, unsigned short* __restrict__ Wlo,
                        unsigned short* __restrict__ zAhi, unsigned short* __restrict__ zAlo,
                        unsigned short* __restrict__ mAhi, unsigned short* __restrict__ mAlo,
                        unsigned short* __restrict__ pAhi, unsigned short* __restrict__ pAlo,
                        float* __restrict__ h_A, float* __restrict__ c_st) {
  int stride = gridDim.x * blockDim.x;
  int i0 = blockIdx.x * blockDim.x + threadIdx.x;
  for (int i = i0; i < 256*1152; i += stride) {
    int oc = i / 1152, k = i - oc*1152;          // k = icComb*9 + ky*3 + kx
    float v = conv_w[i];
    unsigned short hi = bf16r(v);
    unsigned short lo = bf16r(v - bf16f(hi));
    int mt = oc >> 4, i16 = oc & 15;
    int ks = k >> 5, kk = k & 31;
    int lane = i16 | ((kk >> 3) << 4);
    int pos = ((mt*36 + ks)*64 + lane)*8 + (kk & 7);
    Whi[pos] = hi;
    Wlo[pos] = lo;
  }
  for (int i = i0; i < 128*128; i += stride) {   // z_w A-frags: 8 mt x 4 ks
    int oc = i >> 7, k = i & 127;
    float v = z_w[i];
    unsigned short hi = bf16r(v);
    unsigned short lo = bf16r(v - bf16f(hi));
    int mt = oc >> 4, i16 = oc & 15;
    int ks = k >> 5, kk = k & 31;
    int lane = i16 | ((kk >> 3) << 4);
    int pos = ((mt*4 + ks)*64 + lane)*8 + (kk & 7);
    zAhi[pos] = hi;
    zAlo[pos] = lo;
  }
  for (int i = i0; i < 192*192; i += stride) {   // m_w A-frags: 12 mt x 6 ks
    int oc = i / 192, k = i - oc*192;
    float v = m_w[i];
    unsigned short hi = bf16r(v);
    unsigned short lo = bf16r(v - bf16f(hi));
    int mt = oc >> 4, i16 = oc & 15;
    int ks = k >> 5, kk = k & 31;
    int lane = i16 | ((kk >> 3) << 4);
    int pos = ((mt*6 + ks)*64 + lane)*8 + (kk & 7);
    mAhi[pos] = hi;
    mAlo[pos] = lo;
  }
  for (int i = i0; i < 176*64; i += stride) {    // proj A-frags: 11 mt x 2 ks
    int po = i >> 6, c = i & 63;
    float v;
    if (po < 16)       v = qw[po*64 + c];
    else if (po < 32)  v = kw[(po-16)*64 + c];
    else if (po < 96)  v = vw[(po-32)*64 + c];
    else if (po < 112) v = k2w[(po-96)*64 + c];
    else               v = v2w[(po-112)*64 + c];
    unsigned short hi = bf16r(v);
    unsigned short lo = bf16r(v - bf16f(hi));
    int mt = po >> 4, i16 = po & 15;
    int ks = c >> 5, kk = c & 31;
    int lane = i16 | ((kk >> 3) << 4);
    int pos = ((mt*2 + ks)*64 + lane)*8 + (kk & 7);
    pAhi[pos] = hi;
    pAlo[pos] = lo;
  }
  for (int i = i0; i < NB*64*NN; i += stride) { h_A[i] = 0.0f; c_st[i] = 0.0f; }
}

// ---------- K0b v5: conv_x, N=64/block, X hi-only, W hi-only ----------
__global__ __launch_bounds__(1024, 2) void k0b_gx(
    const float* __restrict__ X,
    const unsigned short* __restrict__ Whi,
    float* __restrict__ gx)
{
  __shared__ __align__(16) unsigned short Xhi_l[18*4*64*8];   // [ks][nt 0..3][lane][8] = 73728 B

  const int tid = threadIdx.x;
  const int bid = blockIdx.x;       // b*256 + t*16 + y2
  const int y2 = bid & 15;
  const int t  = (bid >> 4) & 15;
  const int b  = bid >> 8;
  const int y0 = y2 * 2;

  // im2col for two output rows (halo rows y0-1 .. y0+2), x-channels only, hi plane
  for (int idx = tid; idx < 64*4*34; idx += 1024) {
    int col = idx % 34;
    int rest = idx / 34;
    int dy = rest % 4;               // halo row index 0..3 -> gy = y0 + dy - 1
    int ic = rest / 4;
    int gy = y0 + dy - 1;
    int gxc = col - 1;
    float v = 0.0f;
    if ((unsigned)gy < 32u && (unsigned)gxc < 32u)
      v = X[(((b*64 + ic)*SS + t)*NN) + gy*32 + gxc];
    unsigned short hi = bf16r(v);
    #pragma unroll
    for (int r = 0; r < 2; r++) {
      int dyl = dy - r;                    // kernel row for output row r
      if ((unsigned)dyl < 3u) {
        int kbase = ic*9 + dyl*3;
        #pragma unroll
        for (int dx = 0; dx < 3; dx++) {
          int x = col - dx;
          if ((unsigned)x < 32u) {
            int k = kbase + dx;
            int ks = k >> 5, kk = k & 31;
            int n = r*32 + x;              // 0..63
            int nt = n >> 4, n16 = n & 15;
            int pos = (((ks*4 + nt)*64) + (n16 | ((kk >> 3) << 4)))*8 + (kk & 7);
            Xhi_l[pos] = hi;
          }
        }
      }
    }
  }
  __syncthreads();

  const int lane = tid & 63;
  const int mt = tid >> 6;          // 0..15
  f4v acc[4];
  #pragma unroll
  for (int nt = 0; nt < 4; nt++) acc[nt] = (f4v){0.f, 0.f, 0.f, 0.f};
  const s8v* Ah = (const s8v*)Whi + (mt*36)*64 + lane;
  const s8v* Bh = (const s8v*)Xhi_l + lane;
  #pragma unroll 3
  for (int ks = 0; ks < 18; ks++) {
    s8v ah = Ah[ks*64];
    #pragma unroll
    for (int nt = 0; nt < 4; nt++) {
      s8v bh = Bh[(ks*4 + nt)*64];
      acc[nt] = __builtin_amdgcn_mfma_f32_16x16x32_bf16(ah, bh, acc[nt], 0, 0, 0);
    }
  }
  const int c16 = lane & 15;
  const int rb  = (lane >> 4) * 4;
  float* gout = gx + (((long)b*SS + t)*256)*NN;
  #pragma unroll
  for (int nt = 0; nt < 4; nt++) {
    #pragma unroll
    for (int r4 = 0; r4 < 4; r4++) {
      int oc = mt*16 + rb + r4;
      int n = nt*16 + c16;
      int py = y0 + (n >> 5);
      int px2 = n & 31;
      gout[oc*NN + py*32 + px2] = acc[nt][r4];
    }
  }
}

// ---------- K1: conv_h + LSTM(+gx) + MFMA projections (1024 threads) ----------
__global__ __launch_bounds__(1024, 2) void k1_conv_lstm_proj(
    int t,
    const float* __restrict__ gx,
    const unsigned short* __restrict__ Whi, const unsigned short* __restrict__ Wlo,
    const unsigned short* __restrict__ pAhi, const unsigned short* __restrict__ pAlo,
    const float* __restrict__ conv_b,
    const float* __restrict__ W_ci, const float* __restrict__ W_cf, const float* __restrict__ W_co,
    const float* __restrict__ qb, const float* __restrict__ kb,
    const float* __restrict__ vb, const float* __restrict__ k2b,
    const float* __restrict__ v2b,
    const float* __restrict__ h_cur, float* __restrict__ h_nxt,
    float* __restrict__ c_st,
    float* __restrict__ q_buf,
    unsigned short* __restrict__ kF,
    unsigned short* __restrict__ vFh)
{
  __shared__ __align__(16) unsigned short Ihi_l[18*64*8];      // h-only im2col, B-frag order
  __shared__ __align__(16) unsigned short Ilo_l[18*64*8];
  __shared__ __align__(16) float gates_l[256*17];              // [oc][x]; later proj_l[176][16]
  __shared__ __align__(16) unsigned short hBh[2*64*8];         // h in B-frag layout (hi/lo)
  __shared__ __align__(16) unsigned short hBl[2*64*8];
  __shared__ __align__(16) unsigned short cBh[2*64*8];         // c in B-frag layout
  __shared__ __align__(16) unsigned short cBl[2*64*8];
  __shared__ __align__(16) float pb_l[176];

  const int tid = threadIdx.x;
  const int bid = blockIdx.x;
  const int b  = bid >> 6;
  const int y  = (bid >> 1) & 31;
  const int x0 = (bid & 1) * 16;
  const int mt = bid & 63;          // this block's 16-col m-tile (= n>>4)
  const int n0 = y*32 + x0;

  // ---- prefetch LSTM inputs + projection A-frags into registers ----
  const int px = tid & 15;
  const int pc = tid >> 4;          // 0..63
  const int pn = n0 + px;
  const float* gxp = gx + (((long)b*SS + t)*256)*NN + pn;
  float pf_g0 = gxp[(pc      )*NN];
  float pf_g1 = gxp[( 64 + pc)*NN];
  float pf_g2 = gxp[(128 + pc)*NN];
  float pf_g3 = gxp[(192 + pc)*NN];
  float pf_cp  = c_st[(b*64 + pc)*NN + pn];
  float pf_wci = W_ci[pc*NN + pn];
  float pf_wcf = W_cf[pc*NN + pn];
  float pf_wco = W_co[pc*NN + pn];
  float pf_b0 = conv_b[pc];
  float pf_b1 = conv_b[ 64 + pc];
  float pf_b2 = conv_b[128 + pc];
  float pf_b3 = conv_b[192 + pc];
  const int lane_e = tid & 63;
  const int wv_e   = tid >> 6;
  const int wvc    = (wv_e < 11) ? wv_e : 0;
  s8v pf_a0h = *(const s8v*)(pAhi + ((wvc*2 + 0)*64 + lane_e)*8);
  s8v pf_a0l = *(const s8v*)(pAlo + ((wvc*2 + 0)*64 + lane_e)*8);
  s8v pf_a1h = *(const s8v*)(pAhi + ((wvc*2 + 1)*64 + lane_e)*8);
  s8v pf_a1l = *(const s8v*)(pAlo + ((wvc*2 + 1)*64 + lane_e)*8);

  // ---- phase 0: h-only im2col -> B-frags  +  stage proj biases ----
  for (int idx = tid; idx < 64*3*18; idx += 1024) {
    int col = idx % 18;
    int rest = idx / 18;
    int dy = rest % 3;
    int ic = rest / 3;                    // h channel 0..63
    int gy = y + dy - 1;
    int gxc = x0 + col - 1;
    float v = 0.0f;
    if ((unsigned)gy < 32u && (unsigned)gxc < 32u)
      v = h_cur[((b*64 + ic)*NN) + gy*32 + gxc];
    unsigned short hi = bf16r(v);
    unsigned short lo = bf16r(v - bf16f(hi));
    int kbase = ic*9 + dy*3;              // local k in [0,576)
    #pragma unroll
    for (int dx = 0; dx < 3; dx++) {
      int n = col - dx;
      if ((unsigned)n < 16u) {
        int k = kbase + dx;
        int ks = k >> 5, kk = k & 31;
        int pos = (ks*64 + (n | ((kk >> 3) << 4)))*8 + (kk & 7);
        Ihi_l[pos] = hi;
        Ilo_l[pos] = lo;
      }
    }
  }
  if (tid < 176) {
    int po = tid;
    float v;
    if (po < 16)       v = qb[po];
    else if (po < 32)  v = kb[po-16];
    else if (po < 96)  v = vb[po-32];
    else if (po < 112) v = k2b[po-96];
    else               v = v2b[po-112];
    pb_l[po] = v;
  }
  __syncthreads();

  // ---- phase 1: conv_h MFMA: 16 waves, 1 m-tile each; A-frags at ks 18..35 ----
  {
    const int lane = tid & 63;
    const int wv   = tid >> 6;        // 0..15 = m-tile
    f4v acc = {0.f, 0.f, 0.f, 0.f};
    const s8v* Ah = (const s8v*)Whi + (wv*36 + 18)*64 + lane;
    const s8v* Al = (const s8v*)Wlo + (wv*36 + 18)*64 + lane;
    const s8v* Bh = (const s8v*)Ihi_l + lane;
    const s8v* Bl = (const s8v*)Ilo_l + lane;
    #pragma unroll 3
    for (int ks = 0; ks < 18; ks++) {
      s8v ah = Ah[ks*64];
      s8v al = Al[ks*64];
      s8v bh = Bh[ks*64];
      s8v bl = Bl[ks*64];
      acc = __builtin_amdgcn_mfma_f32_16x16x32_bf16(ah, bh, acc, 0, 0, 0);
      acc = __builtin_amdgcn_mfma_f32_16x16x32_bf16(al, bh, acc, 0, 0, 0);
      acc = __builtin_amdgcn_mfma_f32_16x16x32_bf16(ah, bl, acc, 0, 0, 0);
    }
    const int colx = lane & 15;
    const int rb   = (lane >> 4) * 4;
    #pragma unroll
    for (int r = 0; r < 4; r++)
      gates_l[(wv*16 + rb + r)*17 + colx] = acc[r];
  }
  __syncthreads();

  // ---- phase 2: LSTM elementwise; write h/c into B-frag layout ----
  {
    const int x = px;
    const int c = pc;
    const int n = pn;
    float ig = gates_l[(c      )*17 + x] + pf_g0 + pf_b0;
    float fg = gates_l[( 64 + c)*17 + x] + pf_g1 + pf_b1;
    float gg = gates_l[(128 + c)*17 + x] + pf_g2 + pf_b2;
    float og = gates_l[(192 + c)*17 + x] + pf_g3 + pf_b3;
    float cp = pf_cp;
    float i_ = sigm(ig + pf_wci * cp);
    float f_ = sigm(fg + pf_wcf * cp);
    float cn = f_*cp + i_*tanh_f(gg);
    float o_ = sigm(og + pf_wco * cn);
    float hn = o_*tanh_f(cn);
    h_nxt[(b*64 + c)*NN + n] = hn;
    c_st[(b*64 + c)*NN + n] = cn;
    const int ksC = c >> 5, kkC = c & 31;
    const int posF = (ksC*64 + (x | ((kkC >> 3) << 4)))*8 + (kkC & 7);
    unsigned short hh = bf16r(hn);
    hBh[posF] = hh;
    hBl[posF] = bf16r(hn - bf16f(hh));
    unsigned short ch = bf16r(cn);
    cBh[posF] = ch;
    cBl[posF] = bf16r(cn - bf16f(ch));
  }
  __syncthreads();

  // ---- phase 3: projections via MFMA (11 waves, mt 0..5 from h, 6..10 from c) ----
  float* proj_l = gates_l;              // gates fully consumed in phase 2
  {
    const int lane = lane_e;
    const int wv   = wv_e;
    if (wv < 11) {
      const s8v* Bh_ = (const s8v*)((wv < 6) ? hBh : cBh) + lane;
      const s8v* Bl_ = (const s8v*)((wv < 6) ? hBl : cBl) + lane;
      f4v acc = {0.f, 0.f, 0.f, 0.f};
      s8v bh0 = Bh_[0];
      s8v bl0 = Bl_[0];
      s8v bh1 = Bh_[64];
      s8v bl1 = Bl_[64];
      acc = __builtin_amdgcn_mfma_f32_16x16x32_bf16(pf_a0h, bh0, acc, 0, 0, 0);
      acc = __builtin_amdgcn_mfma_f32_16x16x32_bf16(pf_a0l, bh0, acc, 0, 0, 0);
      acc = __builtin_amdgcn_mfma_f32_16x16x32_bf16(pf_a0h, bl0, acc, 0, 0, 0);
      acc = __builtin_amdgcn_mfma_f32_16x16x32_bf16(pf_a1h, bh1, acc, 0, 0, 0);
      acc = __builtin_amdgcn_mfma_f32_16x16x32_bf16(pf_a1l, bh1, acc, 0, 0, 0);
      acc = __builtin_amdgcn_mfma_f32_16x16x32_bf16(pf_a1h, bl1, acc, 0, 0, 0);
      const int colx = lane & 15;
      const int rb   = (lane >> 4) * 4;
      #pragma unroll
      for (int r = 0; r < 4; r++) {
        int po = wv*16 + rb + r;
        proj_l[po*16 + colx] = acc[r] + pb_l[po];
      }
    }
  }
  __syncthreads();

  // ---- phase 4: coalesced fragment emission (V hi-plane only) ----
  if (tid < 256) {
    int d = tid >> 4, x = tid & 15;
    q_buf[(b*16 + d)*NN + n0 + x] = proj_l[d*16 + x];
  }
  if (tid < 512) {
    int brh2 = tid >> 8;            // branch
    int lh   = (tid >> 2) & 63;     // fragment "lane-half" row
    int j2   = tid & 3;             // packs d&7 = 2*j2, 2*j2+1
    int p    = lh >> 4;             // 0,1: hi planes; 2,3: lo planes
    int x    = lh & 15;
    int d0   = ((p & 1) << 3) | (j2 << 1);
    int Koff = brh2 ? 96 : 16;
    float v0 = proj_l[(Koff + d0)*16 + x];
    float v1 = proj_l[(Koff + d0 + 1)*16 + x];
    unsigned short h0 = bf16r(v0), h1 = bf16r(v1);
    unsigned short u0, u1;
    if (p < 2) { u0 = h0; u1 = h1; }
    else       { u0 = bf16r(v0 - bf16f(h0)); u1 = bf16r(v1 - bf16f(h1)); }
    unsigned int* dst = (unsigned int*)(kF + ((b*2 + brh2)*64 + mt)*512);
    dst[lh*4 + j2] = (unsigned)u0 | ((unsigned)u1 << 16);
  }
  {
    const int ks = y;
    const int g0 = x0 >> 3;         // 0 or 2
    int ct    = tid;                // 1024 tasks: brh(2) x nt(4) x li(32) x j2(4)
    int brh2  = (ct >> 9) & 1;
    int nt    = (ct >> 7) & 3;
    int li    = (ct >> 2) & 31;
    int j2    = ct & 3;
    int lane2 = g0*16 + li;
    int cch   = nt*16 + (lane2 & 15);
    int xx    = ((li >> 4) << 3) | (j2 << 1);
    int Voff  = brh2 ? 112 : 32;
    float v0 = proj_l[(Voff + cch)*16 + xx];
    float v1 = proj_l[(Voff + cch)*16 + xx + 1];
    unsigned short u0 = bf16r(v0), u1 = bf16r(v1);
    unsigned short* basep = vFh + (((b*2 + brh2)*32 + ks)*4 + nt)*512;
    ((unsigned int*)basep)[lane2*4 + j2] = (unsigned)u0 | ((unsigned)u1 << 16);
  }
}

// ---------- K2: dual attention via MFMA + MFMA combine + gating ----------
#define RED_OFF 0        // [16 waves][16 nl][66]  = 16896
#define PS_OFF  16896    // [16 waves][16][36]     = 9216
#define SMX_OFF 26112    // [2][8][16]             = 256
#define SSM_OFF 26368    // [2][8][16]             = 256
#define INV_OFF 26624    // [2][16]                = 32
#define S_TOT   28704

__global__ __launch_bounds__(1024, 4) void k2_attn(
    int t,
    const float* __restrict__ q_buf,
    const unsigned short* __restrict__ kF,
    const unsigned short* __restrict__ vFh,
    float* __restrict__ h_nxt, float* __restrict__ c_st,
    const unsigned short* __restrict__ zAhi, const unsigned short* __restrict__ zAlo,
    const unsigned short* __restrict__ mAhi, const unsigned short* __restrict__ mAlo,
    const float* __restrict__ z_b, const float* __restrict__ m_b,
    float* __restrict__ out)
{
  __shared__ __align__(16) float S[S_TOT];
  __shared__ __align__(16) unsigned short zBh[4*512];   // zz B-frags (4 ks)
  __shared__ __align__(16) unsigned short zBl[4*512];
  __shared__ __align__(16) unsigned short cbBh[6*512];  // comb B-frags (6 ks)
  __shared__ __align__(16) unsigned short cbBl[6*512];
  float* red  = S + RED_OFF;
  float* smMax= S + SMX_OFF;
  float* smSum= S + SSM_OFF;
  float* invL = S + INV_OFF;
  float* cbOut= S + 3072;       // [192][16] aliases red (after barrier)

  const int tid = threadIdx.x;
  const int bid = blockIdx.x;
  const int xcd = bid & 7;
  const int b = xcd >> 1;
  const int tile = ((bid >> 3) << 1) | (xcd & 1);   // 0..63
  const int n0 = tile * 16;

  const int wid  = tid >> 6;
  const int lane = tid & 63;
  const int brh  = wid >> 3;      // branch
  const int w    = wid & 7;       // wave within branch
  const int g    = lane >> 4;
  const int c16  = lane & 15;

  // ---- prefetch tail-phase inputs ----
  const int pc2 = tid >> 4;       // 0..63
  const int pn2 = n0 + (tid & 15);
  float pf_cst = c_st[(b*64 + pc2)*NN + pn2];
  float pf_h   = h_nxt[(b*64 + pc2)*NN + pn2];

  // ---- Q A-frags: A1 = [Qh|Qh], A2 = [Ql|0] ----
  s8v qh1, ql2;
  {
    const int dbase = (g & 1) * 8;
    #pragma unroll
    for (int j = 0; j < 8; j++) {
      float qv = q_buf[(b*16 + dbase + j)*NN + n0 + c16];
      unsigned short hi = bf16r(qv);
      unsigned short lo = bf16r(qv - bf16f(hi));
      qh1[j] = (short)hi;
      ql2[j] = (g < 2) ? (short)lo : (short)0;
    }
  }

  // ---- scores: 8 m-tiles per wave, 2 MFMA each (B = [Kh|Kl]) ----
  f4v acc[8];
  {
    const unsigned short* kp = kF + (((b*2 + brh)*64 + w*8)*64 + lane)*8;
    #pragma unroll
    for (int i = 0; i < 8; i++) {
      s8v bf = *(const s8v*)(kp + i*512);
      f4v z4 = {0.f, 0.f, 0.f, 0.f};
      z4 = __builtin_amdgcn_mfma_f32_16x16x32_bf16(ql2, bf, z4, 0, 0, 0);
      acc[i] = __builtin_amdgcn_mfma_f32_16x16x32_bf16(qh1, bf, z4, 0, 0, 0);
    }
  }

  // ---- softmax ----
  float Mrow[4];
  #pragma unroll
  for (int r = 0; r < 4; r++) {
    float m = acc[0][r];
    #pragma unroll
    for (int i = 1; i < 8; i++) m = fmaxf(m, acc[i][r]);
    m = fmaxf(m, __shfl_xor(m, 1));
    m = fmaxf(m, __shfl_xor(m, 2));
    m = fmaxf(m, __shfl_xor(m, 4));
    m = fmaxf(m, __shfl_xor(m, 8));
    if (c16 == 0) smMax[(brh*8 + w)*16 + g*4 + r] = m;
  }
  __syncthreads();
  #pragma unroll
  for (int r = 0; r < 4; r++) {
    float m = smMax[(brh*8 + 0)*16 + g*4 + r];
    #pragma unroll
    for (int w2 = 1; w2 < 8; w2++) m = fmaxf(m, smMax[(brh*8 + w2)*16 + g*4 + r]);
    Mrow[r] = m;
  }
  float rsum[4] = {0.f, 0.f, 0.f, 0.f};
  #pragma unroll
  for (int i = 0; i < 8; i++) {
    #pragma unroll
    for (int r = 0; r < 4; r++) {
      float p = __expf(acc[i][r] - Mrow[r]);
      acc[i][r] = p;
      rsum[r] += p;
    }
  }
  #pragma unroll
  for (int r = 0; r < 4; r++) {
    float s = rsum[r];
    s += __shfl_xor(s, 1); s += __shfl_xor(s, 2);
    s += __shfl_xor(s, 4); s += __shfl_xor(s, 8);
    if (c16 == 0) smSum[(brh*8 + w)*16 + g*4 + r] = s;
  }
  __syncthreads();
  if (w == 0 && c16 == 0) {
    #pragma unroll
    for (int r = 0; r < 4; r++) {
      float s = 0.f;
      #pragma unroll
      for (int w2 = 0; w2 < 8; w2++) s += smSum[(brh*8 + w2)*16 + g*4 + r];
      invL[brh*16 + g*4 + r] = 1.0f / s;
    }
  }

  // ---- PV: per wave, 4 k-steps of 32 m; wave-local P transpose; V hi-only ----
  f4v z0 = {0.f,0.f,0.f,0.f}, z1 = z0, z2 = z0, z3 = z0;
  float* myPS = S + PS_OFF + wid*576;   // [16][36]
  #pragma unroll
  for (int ks4 = 0; ks4 < 4; ks4++) {
    #pragma unroll
    for (int i2 = 0; i2 < 2; i2++) {
      #pragma unroll
      for (int r = 0; r < 4; r++)
        myPS[(g*4 + r)*36 + i2*16 + c16] = acc[ks4*2 + i2][r];
    }
    float4 pa = *(const float4*)&myPS[c16*36 + g*8];
    float4 pb = *(const float4*)&myPS[c16*36 + g*8 + 4];
    s8v ph, pl;
    {
      unsigned short h0 = bf16r(pa.x); ph[0] = (short)h0; pl[0] = (short)bf16r(pa.x - bf16f(h0));
      unsigned short h1 = bf16r(pa.y); ph[1] = (short)h1; pl[1] = (short)bf16r(pa.y - bf16f(h1));
      unsigned short h2 = bf16r(pa.z); ph[2] = (short)h2; pl[2] = (short)bf16r(pa.z - bf16f(h2));
      unsigned short h3 = bf16r(pa.w); ph[3] = (short)h3; pl[3] = (short)bf16r(pa.w - bf16f(h3));
      unsigned short h4 = bf16r(pb.x); ph[4] = (short)h4; pl[4] = (short)bf16r(pb.x - bf16f(h4));
      unsigned short h5 = bf16r(pb.y); ph[5] = (short)h5; pl[5] = (short)bf16r(pb.y - bf16f(h5));
      unsigned short h6 = bf16r(pb.z); ph[6] = (short)h6; pl[6] = (short)bf16r(pb.z - bf16f(h6));
      unsigned short h7 = bf16r(pb.w); ph[7] = (short)h7; pl[7] = (short)bf16r(pb.w - bf16f(h7));
    }
    const int ks = w*4 + ks4;
    const unsigned short* vph = vFh + ((((b*2 + brh)*32 + ks)*4)*64 + lane)*8;
    s8v vh0 = *(const s8v*)(vph);
    z0 = __builtin_amdgcn_mfma_f32_16x16x32_bf16(ph, vh0, z0, 0,0,0);
    z0 = __builtin_amdgcn_mfma_f32_16x16x32_bf16(pl, vh0, z0, 0,0,0);
    s8v vh1 = *(const s8v*)(vph + 512);
    z1 = __builtin_amdgcn_mfma_f32_16x16x32_bf16(ph, vh1, z1, 0,0,0);
    z1 = __builtin_amdgcn_mfma_f32_16x16x32_bf16(pl, vh1, z1, 0,0,0);
    s8v vh2 = *(const s8v*)(vph + 1024);
    z2 = __builtin_amdgcn_mfma_f32_16x16x32_bf16(ph, vh2, z2, 0,0,0);
    z2 = __builtin_amdgcn_mfma_f32_16x16x32_bf16(pl, vh2, z2, 0,0,0);
    s8v vh3 = *(const s8v*)(vph + 1536);
    z3 = __builtin_amdgcn_mfma_f32_16x16x32_bf16(ph, vh3, z3, 0,0,0);
    z3 = __builtin_amdgcn_mfma_f32_16x16x32_bf16(pl, vh3, z3, 0,0,0);
  }

  // ---- write partials, reduce 8 waves, normalize -> zz B-frags ----
  {
    float* rw = red + wid*1056;
    #pragma unroll
    for (int r = 0; r < 4; r++) {
      rw[(g*4 + r)*66 +  0 + c16] = z0[r];
      rw[(g*4 + r)*66 + 16 + c16] = z1[r];
      rw[(g*4 + r)*66 + 32 + c16] = z2[r];
      rw[(g*4 + r)*66 + 48 + c16] = z3[r];
    }
  }
  __syncthreads();
  {
    const int br2 = tid >> 9;
    const int sub = tid & 511;
    const int nlr = sub >> 5;
    const int cc0 = (sub & 31) * 2;
    float iv = invL[br2*16 + nlr];
    #pragma unroll
    for (int u = 0; u < 2; u++) {
      int cc = cc0 + u;
      float s = 0.f;
      #pragma unroll
      for (int w2 = 0; w2 < 8; w2++)
        s += red[(br2*8 + w2)*1056 + nlr*66 + cc];
      float v = s * iv;
      int k = br2*64 + cc;
      int ks = k >> 5, kk = k & 31;
      int pos = (ks*64 + (nlr | ((kk >> 3) << 4)))*8 + (kk & 7);
      unsigned short h = bf16r(v);
      zBh[pos] = h;
      zBl[pos] = bf16r(v - bf16f(h));
    }
  }
  __syncthreads();

  // ---- h rows into comb B-frags + zz via MFMA (waves 0..7) ----
  {
    int k = 128 + pc2;
    int ks = k >> 5, kk = k & 31;
    int pos = (ks*64 + ((tid & 15) | ((kk >> 3) << 4)))*8 + (kk & 7);
    unsigned short h = bf16r(pf_h);
    cbBh[pos] = h;
    cbBl[pos] = bf16r(pf_h - bf16f(h));
  }
  if (wid < 8) {
    f4v za = {0.f, 0.f, 0.f, 0.f};
    const s8v* Azh = (const s8v*)zAhi + (wid*4)*64 + lane;
    const s8v* Azl = (const s8v*)zAlo + (wid*4)*64 + lane;
    const s8v* Bzh = (const s8v*)zBh + lane;
    const s8v* Bzl = (const s8v*)zBl + lane;
    #pragma unroll
    for (int ks = 0; ks < 4; ks++) {
      s8v ah = Azh[ks*64];
      s8v al = Azl[ks*64];
      s8v bh = Bzh[ks*64];
      s8v bl = Bzl[ks*64];
      za = __builtin_amdgcn_mfma_f32_16x16x32_bf16(ah, bh, za, 0, 0, 0);
      za = __builtin_amdgcn_mfma_f32_16x16x32_bf16(al, bh, za, 0, 0, 0);
      za = __builtin_amdgcn_mfma_f32_16x16x32_bf16(ah, bl, za, 0, 0, 0);
    }
    #pragma unroll
    for (int r = 0; r < 4; r++) {
      int oc = wid*16 + g*4 + r;
      float v = za[r] + z_b[oc];
      int kk = oc & 31, ks2 = oc >> 5;
      int pos = (ks2*64 + (c16 | ((kk >> 3) << 4)))*8 + (kk & 7);
      unsigned short h = bf16r(v);
      cbBh[pos] = h;
      cbBl[pos] = bf16r(v - bf16f(h));
    }
  }
  __syncthreads();

  // ---- comb via MFMA (waves 0..11) ----
  if (wid < 12) {
    f4v ca = {0.f, 0.f, 0.f, 0.f};
    const s8v* Amh = (const s8v*)mAhi + (wid*6)*64 + lane;
    const s8v* Aml = (const s8v*)mAlo + (wid*6)*64 + lane;
    const s8v* Bch = (const s8v*)cbBh + lane;
    const s8v* Bcl = (const s8v*)cbBl + lane;
    #pragma unroll
    for (int ks = 0; ks < 6; ks++) {
      s8v ah = Amh[ks*64];
      s8v al = Aml[ks*64];
      s8v bh = Bch[ks*64];
      s8v bl = Bcl[ks*64];
      ca = __builtin_amdgcn_mfma_f32_16x16x32_bf16(ah, bh, ca, 0, 0, 0);
      ca = __builtin_amdgcn_mfma_f32_16x16x32_bf16(al, bh, ca, 0, 0, 0);
      ca = __builtin_amdgcn_mfma_f32_16x16x32_bf16(ah, bl, ca, 0, 0, 0);
    }
    #pragma unroll
    for (int r = 0; r < 4; r++) {
      int oc = wid*16 + g*4 + r;
      cbOut[oc*16 + c16] = ca[r] + m_b[oc];
    }
  }
  __syncthreads();

  // ---- gating ----
  {
    const int c = pc2, nn = tid & 15;
    const int n = n0 + nn;
    float mo = cbOut[c*16 + nn];
    float mg = cbOut[(64 + c)*16 + nn];
    float mi = cbOut[(128 + c)*16 + nn];
    float mf = pf_cst;
    float mis = sigm(mi);
    float nmf = (1.0f - mis)*mf + mis*tanh_f(mg);
    float nhf = sigm(mo)*nmf;
    c_st[(b*64 + c)*NN + n] = nmf;
    h_nxt[(b*64 + c)*NN + n] = nhf;
    out[((b*64 + c)*SS + t)*NN + n] = nhf;
  }
}

extern "C" void kernel_launch(void* const* d_in, const int* in_sizes, int n_in,
                              void* d_out, int out_size, void* d_ws, size_t ws_size,
                              hipStream_t stream) {
  const float* X      = (const float*)d_in[0];
  const float* conv_w = (const float*)d_in[1];
  const float* conv_b = (const float*)d_in[2];
  const float* W_ci   = (const float*)d_in[3];
  const float* W_cf   = (const float*)d_in[4];
  const float* W_co   = (const float*)d_in[5];
  const float* qw  = (const float*)d_in[6];
  const float* qb  = (const float*)d_in[7];
  const float* kw  = (const float*)d_in[8];
  const float* kb  = (const float*)d_in[9];
  const float* k2w = (const float*)d_in[10];
  const float* k2b = (const float*)d_in[11];
  const float* vw  = (const float*)d_in[12];
  const float* vb  = (const float*)d_in[13];
  const float* v2w = (const float*)d_in[14];
  const float* v2b = (const float*)d_in[15];
  const float* z_w = (const float*)d_in[16];
  const float* z_b = (const float*)d_in[17];
  const float* m_w = (const float*)d_in[18];
  const float* m_b = (const float*)d_in[19];
  float* out = (float*)d_out;

  float* ws = (float*)d_ws;
  unsigned short* Whi  = (unsigned short*)ws;  ws += 147456;   // 294912 ushorts
  unsigned short* Wlo  = (unsigned short*)ws;  ws += 147456;
  unsigned short* zAhi = (unsigned short*)ws;  ws += 8192;     // 16384 ushorts
  unsigned short* zAlo = (unsigned short*)ws;  ws += 8192;
  unsigned short* mAhi = (unsigned short*)ws;  ws += 18432;    // 36864 ushorts
  unsigned short* mAlo = (unsigned short*)ws;  ws += 18432;
  unsigned short* pAhi = (unsigned short*)ws;  ws += 5632;     // 11264 ushorts
  unsigned short* pAlo = (unsigned short*)ws;  ws += 5632;
  float* h_A    = ws;             ws += NB*64*NN;
  float* h_B    = ws;             ws += NB*64*NN;
  float* c_st   = ws;             ws += NB*64*NN;
  float* q_buf  = ws;             ws += NB*16*NN;
  unsigned short* kF  = (unsigned short*)ws;  ws += 131072;   // 4b*2br*64mt*64*8 ushorts
  unsigned short* vFh = (unsigned short*)ws;  ws += 131072;   // 4b*2br*32ks*4nt*64*8
  float* gx     = ws;             ws += NB*SS*256*NN;         // 16.8M floats, 67 MB

  hipLaunchKernelGGL(k0_prep, dim3(256), dim3(256), 0, stream,
                     conv_w, z_w, m_w, qw, kw, vw, k2w, v2w,
                     Whi, Wlo, zAhi, zAlo, mAhi, mAlo, pAhi, pAlo, h_A, c_st);
  hipLaunchKernelGGL(k0b_gx, dim3(1024), dim3(1024), 0, stream,
                     X, Whi, gx);
  for (int t = 0; t < 16; t++) {
    const float* h_cur = (t & 1) ? h_B : h_A;
    float* h_nxt       = (t & 1) ? h_A : h_B;
    hipLaunchKernelGGL(k1_conv_lstm_proj, dim3(256), dim3(1024), 0, stream,
        t, gx, Whi, Wlo, pAhi, pAlo, conv_b, W_ci, W_cf, W_co,
        qb, kb, vb, k2b, v2b,
        h_cur, h_nxt, c_st, q_buf, kF, vFh);
    hipLaunchKernelGGL(k2_attn, dim3(256), dim3(1024), 0, stream,
        t, q_buf, kF, vFh, h_nxt, c_st,
        zAhi, zAlo, mAhi, mAlo, z_b, m_b, out);
  }
}

// Round 18
// 495.042 us; speedup vs baseline: 1.5552x; 1.0047x over previous
//
#include <hip/hip_runtime.h>
#include <math.h>

#define NB 4
#define SS 16
#define NN 1024        // H*W

typedef short s8v __attribute__((ext_vector_type(8)));    // 8 bf16 (4 VGPR)
typedef float f4v __attribute__((ext_vector_type(4)));    // MFMA accumulator

__device__ __forceinline__ float sigm(float x) {
  return 1.0f / (1.0f + __expf(-x));
}
__device__ __forceinline__ float tanh_f(float x) {
  float e = __expf(2.0f * x);
  return 1.0f - 2.0f / (1.0f + e);
}
__device__ __forceinline__ unsigned short bf16r(float x) {   // RNE float->bf16
  unsigned int u = __float_as_uint(x);
  u = (u + 0x7FFFu + ((u >> 16) & 1u)) >> 16;
  return (unsigned short)u;
}
__device__ __forceinline__ float bf16f(unsigned short h) {
  return __uint_as_float(((unsigned int)h) << 16);
}

// ---------- prep: weight split/pack (conv + proj + z_w + m_w A-frags) + zero states ----------
__global__ void k0_prep(const float* __restrict__ conv_w, const float* __restrict__ z_w,
                        const float* __restrict__ m_w,
                        const float* __restrict__ qw, const float* __restrict__ kw,
                        const float* __restrict__ vw, const float* __restrict__ k2w,
                        const float* __restrict__ v2w,
                        unsigned short* __restrict__ Whi, unsigned short* __restrict__ Wlo,
                        unsigned short* __restrict__ zAhi, unsigned short* __restrict__ zAlo,
                        unsigned short* __restrict__ mAhi, unsigned short* __restrict__ mAlo,
                        unsigned short* __restrict__ pAhi, unsigned short* __restrict__ pAlo,
                        float* __restrict__ h_A, float* __restrict__ c_st) {
  int stride = gridDim.x * blockDim.x;
  int i0 = blockIdx.x * blockDim.x + threadIdx.x;
  for (int i = i0; i < 256*1152; i += stride) {
    int oc = i / 1152, k = i - oc*1152;          // k = icComb*9 + ky*3 + kx
    float v = conv_w[i];
    unsigned short hi = bf16r(v);
    unsigned short lo = bf16r(v - bf16f(hi));
    int mt = oc >> 4, i16 = oc & 15;
    int ks = k >> 5, kk = k & 31;
    int lane = i16 | ((kk >> 3) << 4);
    int pos = ((mt*36 + ks)*64 + lane)*8 + (kk & 7);
    Whi[pos] = hi;
    Wlo[pos] = lo;
  }
  for (int i = i0; i < 128*128; i += stride) {   // z_w A-frags: 8 mt x 4 ks
    int oc = i >> 7, k = i & 127;
    float v = z_w[i];
    unsigned short hi = bf16r(v);
    unsigned short lo = bf16r(v - bf16f(hi));
    int mt = oc >> 4, i16 = oc & 15;
    int ks = k >> 5, kk = k & 31;
    int lane = i16 | ((kk >> 3) << 4);
    int pos = ((mt*4 + ks)*64 + lane)*8 + (kk & 7);
    zAhi[pos] = hi;
    zAlo[pos] = lo;
  }
  for (int i = i0; i < 192*192; i += stride) {   // m_w A-frags: 12 mt x 6 ks
    int oc = i / 192, k = i - oc*192;
    float v = m_w[i];
    unsigned short hi = bf16r(v);
    unsigned short lo = bf16r(v - bf16f(hi));
    int mt = oc >> 4, i16 = oc & 15;
    int ks = k >> 5, kk = k & 31;
    int lane = i16 | ((kk >> 3) << 4);
    int pos = ((mt*6 + ks)*64 + lane)*8 + (kk & 7);
    mAhi[pos] = hi;
    mAlo[pos] = lo;
  }
  for (int i = i0; i < 176*64; i += stride) {    // proj A-frags: 11 mt x 2 ks
    int po = i >> 6, c = i & 63;
    float v;
    if (po < 16)       v = qw[po*64 + c];
    else if (po < 32)  v = kw[(po-16)*64 + c];
    else if (po < 96)  v = vw[(po-32)*64 + c];
    else if (po < 112) v = k2w[(po-96)*64 + c];
    else               v = v2w[(po-112)*64 + c];
    unsigned short hi = bf16r(v);
    unsigned short lo = bf16r(v - bf16f(hi));
    int mt = po >> 4, i16 = po & 15;
    int ks = c >> 5, kk = c & 31;
    int lane = i16 | ((kk >> 3) << 4);
    int pos = ((mt*2 + ks)*64 + lane)*8 + (kk & 7);
    pAhi[pos] = hi;
    pAlo[pos] = lo;
  }
  for (int i = i0; i < NB*64*NN; i += stride) { h_A[i] = 0.0f; c_st[i] = 0.0f; }
}

// ---------- K0b v6: conv_x, N=64/block, hi-only, row-owned im2col ----------
__global__ __launch_bounds__(1024, 2) void k0b_gx(
    const float* __restrict__ X,
    const unsigned short* __restrict__ Whi,
    float* __restrict__ gx)
{
  __shared__ __align__(16) unsigned short Xhi_l[18*4*64*8];   // [ks][nt 0..3][lane][8] = 73728 B

  const int tid = threadIdx.x;
  const int bid = blockIdx.x;       // b*256 + t*16 + y2
  const int y2 = bid & 15;
  const int t  = (bid >> 4) & 15;
  const int b  = bid >> 8;
  const int y0 = y2 * 2;

  // ---- im2col: thread owns (row = ic*4+dy, quarter); 6 scatter targets have
  //      per-thread constant bases; inner loop is incremental in col. ----
  {
    const int row = tid >> 2;          // 0..255
    const int qtr = tid & 3;           // 0..3
    const int ic  = row >> 2;
    const int dy  = row & 3;           // halo row; gy = y0 + dy - 1
    const int gy  = y0 + dy - 1;
    const bool rowOk = ((unsigned)gy < 32u);
    const float* Xrow = X + (((b*64 + ic)*SS + t)*NN) + gy*32;
    // precompute 6 combo constants: r in {0,1}, dx in {0,1,2}
    int Kc[2][3];
    bool rv[2];
    #pragma unroll
    for (int r = 0; r < 2; r++) {
      int dyl = dy - r;
      rv[r] = ((unsigned)dyl < 3u);
      #pragma unroll
      for (int dx = 0; dx < 3; dx++) {
        int k = ic*9 + dyl*3 + dx;
        int ks = k >> 5, kk = k & 31;
        Kc[r][dx] = ks*2048 + ((kk >> 3) << 4)*8 + (kk & 7) + r*1024;
      }
    }
    const int c0 = qtr*9;
    const int c1 = (qtr == 3) ? 34 : c0 + 9;
    for (int col = c0; col < c1; col++) {
      int gxc = col - 1;
      float v = (rowOk && (unsigned)gxc < 32u) ? Xrow[gxc] : 0.0f;
      unsigned short hi = bf16r(v);
      #pragma unroll
      for (int r = 0; r < 2; r++) {
        if (rv[r]) {
          #pragma unroll
          for (int dx = 0; dx < 3; dx++) {
            int x = col - dx;
            if ((unsigned)x < 32u)
              Xhi_l[Kc[r][dx] + (x >> 4)*512 + (x & 15)*8] = hi;
          }
        }
      }
    }
  }
  __syncthreads();

  const int lane = tid & 63;
  const int mt = tid >> 6;          // 0..15
  f4v acc[4];
  #pragma unroll
  for (int nt = 0; nt < 4; nt++) acc[nt] = (f4v){0.f, 0.f, 0.f, 0.f};
  const s8v* Ah = (const s8v*)Whi + (mt*36)*64 + lane;
  const s8v* Bh = (const s8v*)Xhi_l + lane;
  #pragma unroll 3
  for (int ks = 0; ks < 18; ks++) {
    s8v ah = Ah[ks*64];
    #pragma unroll
    for (int nt = 0; nt < 4; nt++) {
      s8v bh = Bh[(ks*4 + nt)*64];
      acc[nt] = __builtin_amdgcn_mfma_f32_16x16x32_bf16(ah, bh, acc[nt], 0, 0, 0);
    }
  }
  const int c16 = lane & 15;
  const int rb  = (lane >> 4) * 4;
  float* gout = gx + (((long)b*SS + t)*256)*NN;
  #pragma unroll
  for (int nt = 0; nt < 4; nt++) {
    #pragma unroll
    for (int r4 = 0; r4 < 4; r4++) {
      int oc = mt*16 + rb + r4;
      int n = nt*16 + c16;
      int py = y0 + (n >> 5);
      int px2 = n & 31;
      gout[oc*NN + py*32 + px2] = acc[nt][r4];
    }
  }
}

// ---------- K1: conv_h + LSTM(+gx) + MFMA projections (1024 threads) ----------
__global__ __launch_bounds__(1024, 2) void k1_conv_lstm_proj(
    int t,
    const float* __restrict__ gx,
    const unsigned short* __restrict__ Whi, const unsigned short* __restrict__ Wlo,
    const unsigned short* __restrict__ pAhi, const unsigned short* __restrict__ pAlo,
    const float* __restrict__ conv_b,
    const float* __restrict__ W_ci, const float* __restrict__ W_cf, const float* __restrict__ W_co,
    const float* __restrict__ qb, const float* __restrict__ kb,
    const float* __restrict__ vb, const float* __restrict__ k2b,
    const float* __restrict__ v2b,
    const float* __restrict__ h_cur, float* __restrict__ h_nxt,
    float* __restrict__ c_st,
    unsigned short* __restrict__ qFh, unsigned short* __restrict__ qFl,
    unsigned short* __restrict__ kF,
    unsigned short* __restrict__ vFh)
{
  __shared__ __align__(16) unsigned short Ihi_l[18*64*8];      // h-only im2col, B-frag order
  __shared__ __align__(16) unsigned short Ilo_l[18*64*8];
  __shared__ __align__(16) float gates_l[256*17];              // [oc][x]; later proj_l[176][16]
  __shared__ __align__(16) unsigned short hBh[2*64*8];         // h in B-frag layout (hi/lo)
  __shared__ __align__(16) unsigned short hBl[2*64*8];
  __shared__ __align__(16) unsigned short cBh[2*64*8];         // c in B-frag layout
  __shared__ __align__(16) unsigned short cBl[2*64*8];
  __shared__ __align__(16) float pb_l[176];

  const int tid = threadIdx.x;
  const int bid = blockIdx.x;
  const int b  = bid >> 6;
  const int y  = (bid >> 1) & 31;
  const int x0 = (bid & 1) * 16;
  const int mt = bid & 63;          // this block's 16-col m-tile (= n>>4)
  const int n0 = y*32 + x0;

  // ---- prefetch LSTM inputs + projection A-frags into registers ----
  const int px = tid & 15;
  const int pc = tid >> 4;          // 0..63
  const int pn = n0 + px;
  const float* gxp = gx + (((long)b*SS + t)*256)*NN + pn;
  float pf_g0 = gxp[(pc      )*NN];
  float pf_g1 = gxp[( 64 + pc)*NN];
  float pf_g2 = gxp[(128 + pc)*NN];
  float pf_g3 = gxp[(192 + pc)*NN];
  float pf_cp  = c_st[(b*64 + pc)*NN + pn];
  float pf_wci = W_ci[pc*NN + pn];
  float pf_wcf = W_cf[pc*NN + pn];
  float pf_wco = W_co[pc*NN + pn];
  float pf_b0 = conv_b[pc];
  float pf_b1 = conv_b[ 64 + pc];
  float pf_b2 = conv_b[128 + pc];
  float pf_b3 = conv_b[192 + pc];
  const int lane_e = tid & 63;
  const int wv_e   = tid >> 6;
  const int wvc    = (wv_e < 11) ? wv_e : 0;
  s8v pf_a0h = *(const s8v*)(pAhi + ((wvc*2 + 0)*64 + lane_e)*8);
  s8v pf_a0l = *(const s8v*)(pAlo + ((wvc*2 + 0)*64 + lane_e)*8);
  s8v pf_a1h = *(const s8v*)(pAhi + ((wvc*2 + 1)*64 + lane_e)*8);
  s8v pf_a1l = *(const s8v*)(pAlo + ((wvc*2 + 1)*64 + lane_e)*8);

  // ---- phase 0: h-only im2col -> B-frags  +  stage proj biases ----
  for (int idx = tid; idx < 64*3*18; idx += 1024) {
    int col = idx % 18;
    int rest = idx / 18;
    int dy = rest % 3;
    int ic = rest / 3;                    // h channel 0..63
    int gy = y + dy - 1;
    int gxc = x0 + col - 1;
    float v = 0.0f;
    if ((unsigned)gy < 32u && (unsigned)gxc < 32u)
      v = h_cur[((b*64 + ic)*NN) + gy*32 + gxc];
    unsigned short hi = bf16r(v);
    unsigned short lo = bf16r(v - bf16f(hi));
    int kbase = ic*9 + dy*3;              // local k in [0,576)
    #pragma unroll
    for (int dx = 0; dx < 3; dx++) {
      int n = col - dx;
      if ((unsigned)n < 16u) {
        int k = kbase + dx;
        int ks = k >> 5, kk = k & 31;
        int pos = (ks*64 + (n | ((kk >> 3) << 4)))*8 + (kk & 7);
        Ihi_l[pos] = hi;
        Ilo_l[pos] = lo;
      }
    }
  }
  if (tid < 176) {
    int po = tid;
    float v;
    if (po < 16)       v = qb[po];
    else if (po < 32)  v = kb[po-16];
    else if (po < 96)  v = vb[po-32];
    else if (po < 112) v = k2b[po-96];
    else               v = v2b[po-112];
    pb_l[po] = v;
  }
  __syncthreads();

  // ---- phase 1: conv_h MFMA: 16 waves, 1 m-tile each; A-frags at ks 18..35 ----
  {
    const int lane = tid & 63;
    const int wv   = tid >> 6;        // 0..15 = m-tile
    f4v acc = {0.f, 0.f, 0.f, 0.f};
    const s8v* Ah = (const s8v*)Whi + (wv*36 + 18)*64 + lane;
    const s8v* Al = (const s8v*)Wlo + (wv*36 + 18)*64 + lane;
    const s8v* Bh = (const s8v*)Ihi_l + lane;
    const s8v* Bl = (const s8v*)Ilo_l + lane;
    #pragma unroll 3
    for (int ks = 0; ks < 18; ks++) {
      s8v ah = Ah[ks*64];
      s8v al = Al[ks*64];
      s8v bh = Bh[ks*64];
      s8v bl = Bl[ks*64];
      acc = __builtin_amdgcn_mfma_f32_16x16x32_bf16(ah, bh, acc, 0, 0, 0);
      acc = __builtin_amdgcn_mfma_f32_16x16x32_bf16(al, bh, acc, 0, 0, 0);
      acc = __builtin_amdgcn_mfma_f32_16x16x32_bf16(ah, bl, acc, 0, 0, 0);
    }
    const int colx = lane & 15;
    const int rb   = (lane >> 4) * 4;
    #pragma unroll
    for (int r = 0; r < 4; r++)
      gates_l[(wv*16 + rb + r)*17 + colx] = acc[r];
  }
  __syncthreads();

  // ---- phase 2: LSTM elementwise; write h/c into B-frag layout ----
  {
    const int x = px;
    const int c = pc;
    const int n = pn;
    float ig = gates_l[(c      )*17 + x] + pf_g0 + pf_b0;
    float fg = gates_l[( 64 + c)*17 + x] + pf_g1 + pf_b1;
    float gg = gates_l[(128 + c)*17 + x] + pf_g2 + pf_b2;
    float og = gates_l[(192 + c)*17 + x] + pf_g3 + pf_b3;
    float cp = pf_cp;
    float i_ = sigm(ig + pf_wci * cp);
    float f_ = sigm(fg + pf_wcf * cp);
    float cn = f_*cp + i_*tanh_f(gg);
    float o_ = sigm(og + pf_wco * cn);
    float hn = o_*tanh_f(cn);
    h_nxt[(b*64 + c)*NN + n] = hn;
    c_st[(b*64 + c)*NN + n] = cn;
    const int ksC = c >> 5, kkC = c & 31;
    const int posF = (ksC*64 + (x | ((kkC >> 3) << 4)))*8 + (kkC & 7);
    unsigned short hh = bf16r(hn);
    hBh[posF] = hh;
    hBl[posF] = bf16r(hn - bf16f(hh));
    unsigned short ch = bf16r(cn);
    cBh[posF] = ch;
    cBl[posF] = bf16r(cn - bf16f(ch));
  }
  __syncthreads();

  // ---- phase 3: projections via MFMA (11 waves, mt 0..5 from h, 6..10 from c) ----
  float* proj_l = gates_l;              // gates fully consumed in phase 2
  {
    const int lane = lane_e;
    const int wv   = wv_e;
    if (wv < 11) {
      const s8v* Bh_ = (const s8v*)((wv < 6) ? hBh : cBh) + lane;
      const s8v* Bl_ = (const s8v*)((wv < 6) ? hBl : cBl) + lane;
      f4v acc = {0.f, 0.f, 0.f, 0.f};
      s8v bh0 = Bh_[0];
      s8v bl0 = Bl_[0];
      s8v bh1 = Bh_[64];
      s8v bl1 = Bl_[64];
      acc = __builtin_amdgcn_mfma_f32_16x16x32_bf16(pf_a0h, bh0, acc, 0, 0, 0);
      acc = __builtin_amdgcn_mfma_f32_16x16x32_bf16(pf_a0l, bh0, acc, 0, 0, 0);
      acc = __builtin_amdgcn_mfma_f32_16x16x32_bf16(pf_a0h, bl0, acc, 0, 0, 0);
      acc = __builtin_amdgcn_mfma_f32_16x16x32_bf16(pf_a1h, bh1, acc, 0, 0, 0);
      acc = __builtin_amdgcn_mfma_f32_16x16x32_bf16(pf_a1l, bh1, acc, 0, 0, 0);
      acc = __builtin_amdgcn_mfma_f32_16x16x32_bf16(pf_a1h, bl1, acc, 0, 0, 0);
      const int colx = lane & 15;
      const int rb   = (lane >> 4) * 4;
      #pragma unroll
      for (int r = 0; r < 4; r++) {
        int po = wv*16 + rb + r;
        proj_l[po*16 + colx] = acc[r] + pb_l[po];
      }
    }
  }
  __syncthreads();

  // ---- phase 4: coalesced fragment emission ----
  // Q in A-frag layout (tid 512..1023)
  if (tid >= 512) {
    int qt = tid - 512;               // 0..511
    int lane = qt >> 3, j = qt & 7;
    int g = lane >> 4, c16l = lane & 15;
    int d = ((g & 1) << 3) + j;
    float qv = proj_l[d*16 + c16l];
    unsigned short hi = bf16r(qv);
    unsigned short lo = (g < 2) ? bf16r(qv - bf16f(hi)) : (unsigned short)0;
    long base = ((long)(b*64 + mt)*64 + lane)*8 + j;
    qFh[base] = hi;
    qFl[base] = lo;
  }
  if (tid < 512) {
    int brh2 = tid >> 8;            // branch
    int lh   = (tid >> 2) & 63;     // fragment "lane-half" row
    int j2   = tid & 3;             // packs d&7 = 2*j2, 2*j2+1
    int p    = lh >> 4;             // 0,1: hi planes; 2,3: lo planes
    int x    = lh & 15;
    int d0   = ((p & 1) << 3) | (j2 << 1);
    int Koff = brh2 ? 96 : 16;
    float v0 = proj_l[(Koff + d0)*16 + x];
    float v1 = proj_l[(Koff + d0 + 1)*16 + x];
    unsigned short h0 = bf16r(v0), h1 = bf16r(v1);
    unsigned short u0, u1;
    if (p < 2) { u0 = h0; u1 = h1; }
    else       { u0 = bf16r(v0 - bf16f(h0)); u1 = bf16r(v1 - bf16f(h1)); }
    unsigned int* dst = (unsigned int*)(kF + ((b*2 + brh2)*64 + mt)*512);
    dst[lh*4 + j2] = (unsigned)u0 | ((unsigned)u1 << 16);
  }
  {
    const int ks = y;
    const int g0 = x0 >> 3;         // 0 or 2
    int ct    = tid;                // 1024 tasks: brh(2) x nt(4) x li(32) x j2(4)
    int brh2  = (ct >> 9) & 1;
    int nt    = (ct >> 7) & 3;
    int li    = (ct >> 2) & 31;
    int j2    = ct & 3;
    int lane2 = g0*16 + li;
    int cch   = nt*16 + (lane2 & 15);
    int xx    = ((li >> 4) << 3) | (j2 << 1);
    int Voff  = brh2 ? 112 : 32;
    float v0 = proj_l[(Voff + cch)*16 + xx];
    float v1 = proj_l[(Voff + cch)*16 + xx + 1];
    unsigned short u0 = bf16r(v0), u1 = bf16r(v1);
    unsigned short* basep = vFh + (((b*2 + brh2)*32 + ks)*4 + nt)*512;
    ((unsigned int*)basep)[lane2*4 + j2] = (unsigned)u0 | ((unsigned)u1 << 16);
  }
}

// ---------- K2: dual attention via MFMA + MFMA combine + gating ----------
#define RED_OFF 0        // [16 waves][16 nl][66]  = 16896
#define PS_OFF  16896    // [16 waves][16][36]     = 9216
#define SMX_OFF 26112    // [2][8][16]             = 256
#define SSM_OFF 26368    // [2][8][16]             = 256
#define INV_OFF 26624    // [2][16]                = 32
#define S_TOT   28704

__global__ __launch_bounds__(1024, 4) void k2_attn(
    int t,
    const unsigned short* __restrict__ qFh, const unsigned short* __restrict__ qFl,
    const unsigned short* __restrict__ kF,
    const unsigned short* __restrict__ vFh,
    float* __restrict__ h_nxt, float* __restrict__ c_st,
    const unsigned short* __restrict__ zAhi, const unsigned short* __restrict__ zAlo,
    const unsigned short* __restrict__ mAhi, const unsigned short* __restrict__ mAlo,
    const float* __restrict__ z_b, const float* __restrict__ m_b,
    float* __restrict__ out)
{
  __shared__ __align__(16) float S[S_TOT];
  __shared__ __align__(16) unsigned short zBh[4*512];   // zz B-frags (4 ks)
  __shared__ __align__(16) unsigned short zBl[4*512];
  __shared__ __align__(16) unsigned short cbBh[6*512];  // comb B-frags (6 ks)
  __shared__ __align__(16) unsigned short cbBl[6*512];
  float* red  = S + RED_OFF;
  float* smMax= S + SMX_OFF;
  float* smSum= S + SSM_OFF;
  float* invL = S + INV_OFF;
  float* cbOut= S + 3072;       // [192][16] aliases red (after barrier)

  const int tid = threadIdx.x;
  const int bid = blockIdx.x;
  const int xcd = bid & 7;
  const int b = xcd >> 1;
  const int tile = ((bid >> 3) << 1) | (xcd & 1);   // 0..63
  const int n0 = tile * 16;

  const int wid  = tid >> 6;
  const int lane = tid & 63;
  const int brh  = wid >> 3;      // branch
  const int w    = wid & 7;       // wave within branch
  const int g    = lane >> 4;
  const int c16  = lane & 15;

  // ---- prefetch tail-phase inputs ----
  const int pc2 = tid >> 4;       // 0..63
  const int pn2 = n0 + (tid & 15);
  float pf_cst = c_st[(b*64 + pc2)*NN + pn2];
  float pf_h   = h_nxt[(b*64 + pc2)*NN + pn2];

  // ---- Q A-frags: direct b128 loads (pre-packed by k1) ----
  s8v qh1 = *(const s8v*)(qFh + ((long)(b*64 + tile)*64 + lane)*8);
  s8v ql2 = *(const s8v*)(qFl + ((long)(b*64 + tile)*64 + lane)*8);

  // ---- scores: 8 m-tiles per wave, 2 MFMA each (B = [Kh|Kl]) ----
  f4v acc[8];
  {
    const unsigned short* kp = kF + (((b*2 + brh)*64 + w*8)*64 + lane)*8;
    #pragma unroll
    for (int i = 0; i < 8; i++) {
      s8v bf = *(const s8v*)(kp + i*512);
      f4v z4 = {0.f, 0.f, 0.f, 0.f};
      z4 = __builtin_amdgcn_mfma_f32_16x16x32_bf16(ql2, bf, z4, 0, 0, 0);
      acc[i] = __builtin_amdgcn_mfma_f32_16x16x32_bf16(qh1, bf, z4, 0, 0, 0);
    }
  }

  // ---- softmax ----
  float Mrow[4];
  #pragma unroll
  for (int r = 0; r < 4; r++) {
    float m = acc[0][r];
    #pragma unroll
    for (int i = 1; i < 8; i++) m = fmaxf(m, acc[i][r]);
    m = fmaxf(m, __shfl_xor(m, 1));
    m = fmaxf(m, __shfl_xor(m, 2));
    m = fmaxf(m, __shfl_xor(m, 4));
    m = fmaxf(m, __shfl_xor(m, 8));
    if (c16 == 0) smMax[(brh*8 + w)*16 + g*4 + r] = m;
  }
  __syncthreads();
  #pragma unroll
  for (int r = 0; r < 4; r++) {
    float m = smMax[(brh*8 + 0)*16 + g*4 + r];
    #pragma unroll
    for (int w2 = 1; w2 < 8; w2++) m = fmaxf(m, smMax[(brh*8 + w2)*16 + g*4 + r]);
    Mrow[r] = m;
  }
  float rsum[4] = {0.f, 0.f, 0.f, 0.f};
  #pragma unroll
  for (int i = 0; i < 8; i++) {
    #pragma unroll
    for (int r = 0; r < 4; r++) {
      float p = __expf(acc[i][r] - Mrow[r]);
      acc[i][r] = p;
      rsum[r] += p;
    }
  }
  #pragma unroll
  for (int r = 0; r < 4; r++) {
    float s = rsum[r];
    s += __shfl_xor(s, 1); s += __shfl_xor(s, 2);
    s += __shfl_xor(s, 4); s += __shfl_xor(s, 8);
    if (c16 == 0) smSum[(brh*8 + w)*16 + g*4 + r] = s;
  }
  __syncthreads();
  if (w == 0 && c16 == 0) {
    #pragma unroll
    for (int r = 0; r < 4; r++) {
      float s = 0.f;
      #pragma unroll
      for (int w2 = 0; w2 < 8; w2++) s += smSum[(brh*8 + w2)*16 + g*4 + r];
      invL[brh*16 + g*4 + r] = 1.0f / s;
    }
  }

  // ---- PV: per wave, 4 k-steps of 32 m; wave-local P transpose; V hi-only ----
  f4v z0 = {0.f,0.f,0.f,0.f}, z1 = z0, z2 = z0, z3 = z0;
  float* myPS = S + PS_OFF + wid*576;   // [16][36]
  #pragma unroll
  for (int ks4 = 0; ks4 < 4; ks4++) {
    #pragma unroll
    for (int i2 = 0; i2 < 2; i2++) {
      #pragma unroll
      for (int r = 0; r < 4; r++)
        myPS[(g*4 + r)*36 + i2*16 + c16] = acc[ks4*2 + i2][r];
    }
    float4 pa = *(const float4*)&myPS[c16*36 + g*8];
    float4 pb = *(const float4*)&myPS[c16*36 + g*8 + 4];
    s8v ph, pl;
    {
      unsigned short h0 = bf16r(pa.x); ph[0] = (short)h0; pl[0] = (short)bf16r(pa.x - bf16f(h0));
      unsigned short h1 = bf16r(pa.y); ph[1] = (short)h1; pl[1] = (short)bf16r(pa.y - bf16f(h1));
      unsigned short h2 = bf16r(pa.z); ph[2] = (short)h2; pl[2] = (short)bf16r(pa.z - bf16f(h2));
      unsigned short h3 = bf16r(pa.w); ph[3] = (short)h3; pl[3] = (short)bf16r(pa.w - bf16f(h3));
      unsigned short h4 = bf16r(pb.x); ph[4] = (short)h4; pl[4] = (short)bf16r(pb.x - bf16f(h4));
      unsigned short h5 = bf16r(pb.y); ph[5] = (short)h5; pl[5] = (short)bf16r(pb.y - bf16f(h5));
      unsigned short h6 = bf16r(pb.z); ph[6] = (short)h6; pl[6] = (short)bf16r(pb.z - bf16f(h6));
      unsigned short h7 = bf16r(pb.w); ph[7] = (short)h7; pl[7] = (short)bf16r(pb.w - bf16f(h7));
    }
    const int ks = w*4 + ks4;
    const unsigned short* vph = vFh + ((((b*2 + brh)*32 + ks)*4)*64 + lane)*8;
    s8v vh0 = *(const s8v*)(vph);
    z0 = __builtin_amdgcn_mfma_f32_16x16x32_bf16(ph, vh0, z0, 0,0,0);
    z0 = __builtin_amdgcn_mfma_f32_16x16x32_bf16(pl, vh0, z0, 0,0,0);
    s8v vh1 = *(const s8v*)(vph + 512);
    z1 = __builtin_amdgcn_mfma_f32_16x16x32_bf16(ph, vh1, z1, 0,0,0);
    z1 = __builtin_amdgcn_mfma_f32_16x16x32_bf16(pl, vh1, z1, 0,0,0);
    s8v vh2 = *(const s8v*)(vph + 1024);
    z2 = __builtin_amdgcn_mfma_f32_16x16x32_bf16(ph, vh2, z2, 0,0,0);
    z2 = __builtin_amdgcn_mfma_f32_16x16x32_bf16(pl, vh2, z2, 0,0,0);
    s8v vh3 = *(const s8v*)(vph + 1536);
    z3 = __builtin_amdgcn_mfma_f32_16x16x32_bf16(ph, vh3, z3, 0,0,0);
    z3 = __builtin_amdgcn_mfma_f32_16x16x32_bf16(pl, vh3, z3, 0,0,0);
  }

  // ---- write partials, reduce 8 waves, normalize -> zz B-frags ----
  {
    float* rw = red + wid*1056;
    #pragma unroll
    for (int r = 0; r < 4; r++) {
      rw[(g*4 + r)*66 +  0 + c16] = z0[r];
      rw[(g*4 + r)*66 + 16 + c16] = z1[r];
      rw[(g*4 + r)*66 + 32 + c16] = z2[r];
      rw[(g*4 + r)*66 + 48 + c16] = z3[r];
    }
  }
  __syncthreads();
  {
    const int br2 = tid >> 9;
    const int sub = tid & 511;
    const int nlr = sub >> 5;
    const int cc0 = (sub & 31) * 2;
    float iv = invL[br2*16 + nlr];
    #pragma unroll
    for (int u = 0; u < 2; u++) {
      int cc = cc0 + u;
      float s = 0.f;
      #pragma unroll
      for (int w2 = 0; w2 < 8; w2++)
        s += red[(br2*8 + w2)*1056 + nlr*66 + cc];
      float v = s * iv;
      int k = br2*64 + cc;
      int ks = k >> 5, kk = k & 31;
      int pos = (ks*64 + (nlr | ((kk >> 3) << 4)))*8 + (kk & 7);
      unsigned short h = bf16r(v);
      zBh[pos] = h;
      zBl[pos] = bf16r(v - bf16f(h));
    }
  }
  __syncthreads();

  // ---- h rows into comb B-frags + zz via MFMA (waves 0..7) ----
  {
    int k = 128 + pc2;
    int ks = k >> 5, kk = k & 31;
    int pos = (ks*64 + ((tid & 15) | ((kk >> 3) << 4)))*8 + (kk & 7);
    unsigned short h = bf16r(pf_h);
    cbBh[pos] = h;
    cbBl[pos] = bf16r(pf_h - bf16f(h));
  }
  if (wid < 8) {
    f4v za = {0.f, 0.f, 0.f, 0.f};
    const s8v* Azh = (const s8v*)zAhi + (wid*4)*64 + lane;
    const s8v* Azl = (const s8v*)zAlo + (wid*4)*64 + lane;
    const s8v* Bzh = (const s8v*)zBh + lane;
    const s8v* Bzl = (const s8v*)zBl + lane;
    #pragma unroll
    for (int ks = 0; ks < 4; ks++) {
      s8v ah = Azh[ks*64];
      s8v al = Azl[ks*64];
      s8v bh = Bzh[ks*64];
      s8v bl = Bzl[ks*64];
      za = __builtin_amdgcn_mfma_f32_16x16x32_bf16(ah, bh, za, 0, 0, 0);
      za = __builtin_amdgcn_mfma_f32_16x16x32_bf16(al, bh, za, 0, 0, 0);
      za = __builtin_amdgcn_mfma_f32_16x16x32_bf16(ah, bl, za, 0, 0, 0);
    }
    #pragma unroll
    for (int r = 0; r < 4; r++) {
      int oc = wid*16 + g*4 + r;
      float v = za[r] + z_b[oc];
      int kk = oc & 31, ks2 = oc >> 5;
      int pos = (ks2*64 + (c16 | ((kk >> 3) << 4)))*8 + (kk & 7);
      unsigned short h = bf16r(v);
      cbBh[pos] = h;
      cbBl[pos] = bf16r(v - bf16f(h));
    }
  }
  __syncthreads();

  // ---- comb via MFMA (waves 0..11) ----
  if (wid < 12) {
    f4v ca = {0.f, 0.f, 0.f, 0.f};
    const s8v* Amh = (const s8v*)mAhi + (wid*6)*64 + lane;
    const s8v* Aml = (const s8v*)mAlo + (wid*6)*64 + lane;
    const s8v* Bch = (const s8v*)cbBh + lane;
    const s8v* Bcl = (const s8v*)cbBl + lane;
    #pragma unroll
    for (int ks = 0; ks < 6; ks++) {
      s8v ah = Amh[ks*64];
      s8v al = Aml[ks*64];
      s8v bh = Bch[ks*64];
      s8v bl = Bcl[ks*64];
      ca = __builtin_amdgcn_mfma_f32_16x16x32_bf16(ah, bh, ca, 0, 0, 0);
      ca = __builtin_amdgcn_mfma_f32_16x16x32_bf16(al, bh, ca, 0, 0, 0);
      ca = __builtin_amdgcn_mfma_f32_16x16x32_bf16(ah, bl, ca, 0, 0, 0);
    }
    #pragma unroll
    for (int r = 0; r < 4; r++) {
      int oc = wid*16 + g*4 + r;
      cbOut[oc*16 + c16] = ca[r] + m_b[oc];
    }
  }
  __syncthreads();

  // ---- gating ----
  {
    const int c = pc2, nn = tid & 15;
    const int n = n0 + nn;
    float mo = cbOut[c*16 + nn];
    float mg = cbOut[(64 + c)*16 + nn];
    float mi = cbOut[(128 + c)*16 + nn];
    float mf = pf_cst;
    float mis = sigm(mi);
    float nmf = (1.0f - mis)*mf + mis*tanh_f(mg);
    float nhf = sigm(mo)*nmf;
    c_st[(b*64 + c)*NN + n] = nmf;
    h_nxt[(b*64 + c)*NN + n] = nhf;
    out[((b*64 + c)*SS + t)*NN + n] = nhf;
  }
}

extern "C" void kernel_launch(void* const* d_in, const int* in_sizes, int n_in,
                              void* d_out, int out_size, void* d_ws, size_t ws_size,
                              hipStream_t stream) {
  const float* X      = (const float*)d_in[0];
  const float* conv_w = (const float*)d_in[1];
  const float* conv_b = (const float*)d_in[2];
  const float* W_ci   = (const float*)d_in[3];
  const float* W_cf   = (const float*)d_in[4];
  const float* W_co   = (const float*)d_in[5];
  const float* qw  = (const float*)d_in[6];
  const float* qb  = (const float*)d_in[7];
  const float* kw  = (const float*)d_in[8];
  const float* kb  = (const float*)d_in[9];
  const float* k2w = (const float*)d_in[10];
  const float* k2b = (const float*)d_in[11];
  const float* vw  = (const float*)d_in[12];
  const float* vb  = (const float*)d_in[13];
  const float* v2w = (const float*)d_in[14];
  const float* v2b = (const float*)d_in[15];
  const float* z_w = (const float*)d_in[16];
  const float* z_b = (const float*)d_in[17];
  const float* m_w = (const float*)d_in[18];
  const float* m_b = (const float*)d_in[19];
  float* out = (float*)d_out;

  float* ws = (float*)d_ws;
  unsigned short* Whi  = (unsigned short*)ws;  ws += 147456;   // 294912 ushorts
  unsigned short* Wlo  = (unsigned short*)ws;  ws += 147456;
  unsigned short* zAhi = (unsigned short*)ws;  ws += 8192;     // 16384 ushorts
  unsigned short* zAlo = (unsigned short*)ws;  ws += 8192;
  unsigned short* mAhi = (unsigned short*)ws;  ws += 18432;    // 36864 ushorts
  unsigned short* mAlo = (unsigned short*)ws;  ws += 18432;
  unsigned short* pAhi = (unsigned short*)ws;  ws += 5632;     // 11264 ushorts
  unsigned short* pAlo = (unsigned short*)ws;  ws += 5632;
  float* h_A    = ws;             ws += NB*64*NN;
  float* h_B    = ws;             ws += NB*64*NN;
  float* c_st   = ws;             ws += NB*64*NN;
  unsigned short* qFh = (unsigned short*)ws;  ws += 65536;    // 131072 ushorts
  unsigned short* qFl = (unsigned short*)ws;  ws += 65536;
  unsigned short* kF  = (unsigned short*)ws;  ws += 131072;   // 4b*2br*64mt*64*8 ushorts
  unsigned short* vFh = (unsigned short*)ws;  ws += 131072;   // 4b*2br*32ks*4nt*64*8
  float* gx     = ws;             ws += NB*SS*256*NN;         // 16.8M floats, 67 MB

  hipLaunchKernelGGL(k0_prep, dim3(256), dim3(256), 0, stream,
                     conv_w, z_w, m_w, qw, kw, vw, k2w, v2w,
                     Whi, Wlo, zAhi, zAlo, mAhi, mAlo, pAhi, pAlo, h_A, c_st);
  hipLaunchKernelGGL(k0b_gx, dim3(1024), dim3(1024), 0, stream,
                     X, Whi, gx);
  for (int t = 0; t < 16; t++) {
    const float* h_cur = (t & 1) ? h_B : h_A;
    float* h_nxt       = (t & 1) ? h_A : h_B;
    hipLaunchKernelGGL(k1_conv_lstm_proj, dim3(256), dim3(1024), 0, stream,
        t, gx, Whi, Wlo, pAhi, pAlo, conv_b, W_ci, W_cf, W_co,
        qb, kb, vb, k2b, v2b,
        h_cur, h_nxt, c_st, qFh, qFl, kF, vFh);
    hipLaunchKernelGGL(k2_attn, dim3(256), dim3(1024), 0, stream,
        t, qFh, qFl, kF, vFh, h_nxt, c_st,
        zAhi, zAlo, mAhi, mAlo, z_b, m_b, out);
  }
}

// Round 19
// 490.484 us; speedup vs baseline: 1.5697x; 1.0093x over previous
//
#include <hip/hip_runtime.h>
#include <math.h>

#define NB 4
#define SS 16
#define NN 1024        // H*W

typedef short s8v __attribute__((ext_vector_type(8)));    // 8 bf16 (4 VGPR)
typedef float f4v __attribute__((ext_vector_type(4)));    // MFMA accumulator

__device__ __forceinline__ float sigm(float x) {
  return 1.0f / (1.0f + __expf(-x));
}
__device__ __forceinline__ float tanh_f(float x) {
  float e = __expf(2.0f * x);
  return 1.0f - 2.0f / (1.0f + e);
}
__device__ __forceinline__ unsigned short bf16r(float x) {   // RNE float->bf16
  unsigned int u = __float_as_uint(x);
  u = (u + 0x7FFFu + ((u >> 16) & 1u)) >> 16;
  return (unsigned short)u;
}
__device__ __forceinline__ float bf16f(unsigned short h) {
  return __uint_as_float(((unsigned int)h) << 16);
}

// ---------- prep: weight split/pack (conv + proj + z_w + m_w A-frags) + zero states ----------
__global__ void k0_prep(const float* __restrict__ conv_w, const float* __restrict__ z_w,
                        const float* __restrict__ m_w,
                        const float* __restrict__ qw, const float* __restrict__ kw,
                        const float* __restrict__ vw, const float* __restrict__ k2w,
                        const float* __restrict__ v2w,
                        unsigned short* __restrict__ Whi, unsigned short* __restrict__ Wlo,
                        unsigned short* __restrict__ zAhi, unsigned short* __restrict__ zAlo,
                        unsigned short* __restrict__ mAhi, unsigned short* __restrict__ mAlo,
                        unsigned short* __restrict__ pAhi, unsigned short* __restrict__ pAlo,
                        float* __restrict__ h_A, float* __restrict__ c_st) {
  int stride = gridDim.x * blockDim.x;
  int i0 = blockIdx.x * blockDim.x + threadIdx.x;
  for (int i = i0; i < 256*1152; i += stride) {
    int oc = i / 1152, k = i - oc*1152;          // k = icComb*9 + ky*3 + kx
    float v = conv_w[i];
    unsigned short hi = bf16r(v);
    unsigned short lo = bf16r(v - bf16f(hi));
    int mt = oc >> 4, i16 = oc & 15;
    int ks = k >> 5, kk = k & 31;
    int lane = i16 | ((kk >> 3) << 4);
    int pos = ((mt*36 + ks)*64 + lane)*8 + (kk & 7);
    Whi[pos] = hi;
    Wlo[pos] = lo;
  }
  for (int i = i0; i < 128*128; i += stride) {   // z_w A-frags: 8 mt x 4 ks
    int oc = i >> 7, k = i & 127;
    float v = z_w[i];
    unsigned short hi = bf16r(v);
    unsigned short lo = bf16r(v - bf16f(hi));
    int mt = oc >> 4, i16 = oc & 15;
    int ks = k >> 5, kk = k & 31;
    int lane = i16 | ((kk >> 3) << 4);
    int pos = ((mt*4 + ks)*64 + lane)*8 + (kk & 7);
    zAhi[pos] = hi;
    zAlo[pos] = lo;
  }
  for (int i = i0; i < 192*192; i += stride) {   // m_w A-frags: 12 mt x 6 ks
    int oc = i / 192, k = i - oc*192;
    float v = m_w[i];
    unsigned short hi = bf16r(v);
    unsigned short lo = bf16r(v - bf16f(hi));
    int mt = oc >> 4, i16 = oc & 15;
    int ks = k >> 5, kk = k & 31;
    int lane = i16 | ((kk >> 3) << 4);
    int pos = ((mt*6 + ks)*64 + lane)*8 + (kk & 7);
    mAhi[pos] = hi;
    mAlo[pos] = lo;
  }
  for (int i = i0; i < 176*64; i += stride) {    // proj A-frags: 11 mt x 2 ks
    int po = i >> 6, c = i & 63;
    float v;
    if (po < 16)       v = qw[po*64 + c];
    else if (po < 32)  v = kw[(po-16)*64 + c];
    else if (po < 96)  v = vw[(po-32)*64 + c];
    else if (po < 112) v = k2w[(po-96)*64 + c];
    else               v = v2w[(po-112)*64 + c];
    unsigned short hi = bf16r(v);
    unsigned short lo = bf16r(v - bf16f(hi));
    int mt = po >> 4, i16 = po & 15;
    int ks = c >> 5, kk = c & 31;
    int lane = i16 | ((kk >> 3) << 4);
    int pos = ((mt*2 + ks)*64 + lane)*8 + (kk & 7);
    pAhi[pos] = hi;
    pAlo[pos] = lo;
  }
  for (int i = i0; i < NB*64*NN; i += stride) { h_A[i] = 0.0f; c_st[i] = 0.0f; }
}

// ---------- K0b v7: conv_x, N=64/block, hi-only, row-owned im2col, bf16 gx ----------
__global__ __launch_bounds__(1024, 2) void k0b_gx(
    const float* __restrict__ X,
    const unsigned short* __restrict__ Whi,
    unsigned short* __restrict__ gxh)
{
  __shared__ __align__(16) unsigned short Xhi_l[18*4*64*8];   // [ks][nt 0..3][lane][8] = 73728 B

  const int tid = threadIdx.x;
  const int bid = blockIdx.x;       // b*256 + t*16 + y2
  const int y2 = bid & 15;
  const int t  = (bid >> 4) & 15;
  const int b  = bid >> 8;
  const int y0 = y2 * 2;

  // ---- im2col: thread owns (row = ic*4+dy, quarter); constant bases per combo ----
  {
    const int row = tid >> 2;          // 0..255
    const int qtr = tid & 3;           // 0..3
    const int ic  = row >> 2;
    const int dy  = row & 3;           // halo row; gy = y0 + dy - 1
    const int gy  = y0 + dy - 1;
    const bool rowOk = ((unsigned)gy < 32u);
    const float* Xrow = X + (((b*64 + ic)*SS + t)*NN) + gy*32;
    int Kc[2][3];
    bool rv[2];
    #pragma unroll
    for (int r = 0; r < 2; r++) {
      int dyl = dy - r;
      rv[r] = ((unsigned)dyl < 3u);
      #pragma unroll
      for (int dx = 0; dx < 3; dx++) {
        int k = ic*9 + dyl*3 + dx;
        int ks = k >> 5, kk = k & 31;
        Kc[r][dx] = ks*2048 + ((kk >> 3) << 4)*8 + (kk & 7) + r*1024;
      }
    }
    const int c0 = qtr*9;
    const int c1 = (qtr == 3) ? 34 : c0 + 9;
    for (int col = c0; col < c1; col++) {
      int gxc = col - 1;
      float v = (rowOk && (unsigned)gxc < 32u) ? Xrow[gxc] : 0.0f;
      unsigned short hi = bf16r(v);
      #pragma unroll
      for (int r = 0; r < 2; r++) {
        if (rv[r]) {
          #pragma unroll
          for (int dx = 0; dx < 3; dx++) {
            int x = col - dx;
            if ((unsigned)x < 32u)
              Xhi_l[Kc[r][dx] + (x >> 4)*512 + (x & 15)*8] = hi;
          }
        }
      }
    }
  }
  __syncthreads();

  const int lane = tid & 63;
  const int mt = tid >> 6;          // 0..15
  f4v acc[4];
  #pragma unroll
  for (int nt = 0; nt < 4; nt++) acc[nt] = (f4v){0.f, 0.f, 0.f, 0.f};
  const s8v* Ah = (const s8v*)Whi + (mt*36)*64 + lane;
  const s8v* Bh = (const s8v*)Xhi_l + lane;
  #pragma unroll 3
  for (int ks = 0; ks < 18; ks++) {
    s8v ah = Ah[ks*64];
    #pragma unroll
    for (int nt = 0; nt < 4; nt++) {
      s8v bh = Bh[(ks*4 + nt)*64];
      acc[nt] = __builtin_amdgcn_mfma_f32_16x16x32_bf16(ah, bh, acc[nt], 0, 0, 0);
    }
  }
  const int c16 = lane & 15;
  const int rb  = (lane >> 4) * 4;
  unsigned short* gout = gxh + (((long)b*SS + t)*256)*NN;
  #pragma unroll
  for (int nt = 0; nt < 4; nt++) {
    #pragma unroll
    for (int r4 = 0; r4 < 4; r4++) {
      int oc = mt*16 + rb + r4;
      int n = nt*16 + c16;
      int py = y0 + (n >> 5);
      int px2 = n & 31;
      gout[oc*NN + py*32 + px2] = bf16r(acc[nt][r4]);
    }
  }
}

// ---------- K1: conv_h + LSTM(+gx) + MFMA projections (1024 threads) ----------
__global__ __launch_bounds__(1024, 2) void k1_conv_lstm_proj(
    int t,
    const unsigned short* __restrict__ gxh,
    const unsigned short* __restrict__ Whi, const unsigned short* __restrict__ Wlo,
    const unsigned short* __restrict__ pAhi, const unsigned short* __restrict__ pAlo,
    const float* __restrict__ conv_b,
    const float* __restrict__ W_ci, const float* __restrict__ W_cf, const float* __restrict__ W_co,
    const float* __restrict__ qb, const float* __restrict__ kb,
    const float* __restrict__ vb, const float* __restrict__ k2b,
    const float* __restrict__ v2b,
    const float* __restrict__ h_cur, float* __restrict__ h_nxt,
    float* __restrict__ c_st,
    unsigned short* __restrict__ qFh, unsigned short* __restrict__ qFl,
    unsigned short* __restrict__ kF,
    unsigned short* __restrict__ vFh)
{
  __shared__ __align__(16) unsigned short Ihi_l[18*64*8];      // h-only im2col, B-frag order
  __shared__ __align__(16) unsigned short Ilo_l[18*64*8];
  __shared__ __align__(16) float gates_l[256*17];              // [oc][x]; later proj_l[176][16]
  __shared__ __align__(16) unsigned short hBh[2*64*8];         // h in B-frag layout (hi/lo)
  __shared__ __align__(16) unsigned short hBl[2*64*8];
  __shared__ __align__(16) unsigned short cBh[2*64*8];         // c in B-frag layout
  __shared__ __align__(16) unsigned short cBl[2*64*8];
  __shared__ __align__(16) float pb_l[176];

  const int tid = threadIdx.x;
  const int bid = blockIdx.x;
  const int b  = bid >> 6;
  const int y  = (bid >> 1) & 31;
  const int x0 = (bid & 1) * 16;
  const int mt = bid & 63;          // this block's 16-col m-tile (= n>>4)
  const int n0 = y*32 + x0;

  // ---- prefetch LSTM inputs + projection A-frags into registers ----
  const int px = tid & 15;
  const int pc = tid >> 4;          // 0..63
  const int pn = n0 + px;
  const unsigned short* gxp = gxh + (((long)b*SS + t)*256)*NN + pn;
  float pf_g0 = bf16f(gxp[(pc      )*NN]);
  float pf_g1 = bf16f(gxp[( 64 + pc)*NN]);
  float pf_g2 = bf16f(gxp[(128 + pc)*NN]);
  float pf_g3 = bf16f(gxp[(192 + pc)*NN]);
  float pf_cp  = c_st[(b*64 + pc)*NN + pn];
  float pf_wci = W_ci[pc*NN + pn];
  float pf_wcf = W_cf[pc*NN + pn];
  float pf_wco = W_co[pc*NN + pn];
  float pf_b0 = conv_b[pc];
  float pf_b1 = conv_b[ 64 + pc];
  float pf_b2 = conv_b[128 + pc];
  float pf_b3 = conv_b[192 + pc];
  const int lane_e = tid & 63;
  const int wv_e   = tid >> 6;
  const int wvc    = (wv_e < 11) ? wv_e : 0;
  s8v pf_a0h = *(const s8v*)(pAhi + ((wvc*2 + 0)*64 + lane_e)*8);
  s8v pf_a0l = *(const s8v*)(pAlo + ((wvc*2 + 0)*64 + lane_e)*8);
  s8v pf_a1h = *(const s8v*)(pAhi + ((wvc*2 + 1)*64 + lane_e)*8);
  s8v pf_a1l = *(const s8v*)(pAlo + ((wvc*2 + 1)*64 + lane_e)*8);

  // ---- phase 0: h-only im2col -> B-frags  +  stage proj biases ----
  for (int idx = tid; idx < 64*3*18; idx += 1024) {
    int col = idx % 18;
    int rest = idx / 18;
    int dy = rest % 3;
    int ic = rest / 3;                    // h channel 0..63
    int gy = y + dy - 1;
    int gxc = x0 + col - 1;
    float v = 0.0f;
    if ((unsigned)gy < 32u && (unsigned)gxc < 32u)
      v = h_cur[((b*64 + ic)*NN) + gy*32 + gxc];
    unsigned short hi = bf16r(v);
    unsigned short lo = bf16r(v - bf16f(hi));
    int kbase = ic*9 + dy*3;              // local k in [0,576)
    #pragma unroll
    for (int dx = 0; dx < 3; dx++) {
      int n = col - dx;
      if ((unsigned)n < 16u) {
        int k = kbase + dx;
        int ks = k >> 5, kk = k & 31;
        int pos = (ks*64 + (n | ((kk >> 3) << 4)))*8 + (kk & 7);
        Ihi_l[pos] = hi;
        Ilo_l[pos] = lo;
      }
    }
  }
  if (tid < 176) {
    int po = tid;
    float v;
    if (po < 16)       v = qb[po];
    else if (po < 32)  v = kb[po-16];
    else if (po < 96)  v = vb[po-32];
    else if (po < 112) v = k2b[po-96];
    else               v = v2b[po-112];
    pb_l[po] = v;
  }
  __syncthreads();

  // ---- phase 1: conv_h MFMA: 16 waves, 1 m-tile each; A-frags at ks 18..35 ----
  {
    const int lane = tid & 63;
    const int wv   = tid >> 6;        // 0..15 = m-tile
    f4v acc = {0.f, 0.f, 0.f, 0.f};
    const s8v* Ah = (const s8v*)Whi + (wv*36 + 18)*64 + lane;
    const s8v* Al = (const s8v*)Wlo + (wv*36 + 18)*64 + lane;
    const s8v* Bh = (const s8v*)Ihi_l + lane;
    const s8v* Bl = (const s8v*)Ilo_l + lane;
    #pragma unroll 3
    for (int ks = 0; ks < 18; ks++) {
      s8v ah = Ah[ks*64];
      s8v al = Al[ks*64];
      s8v bh = Bh[ks*64];
      s8v bl = Bl[ks*64];
      acc = __builtin_amdgcn_mfma_f32_16x16x32_bf16(ah, bh, acc, 0, 0, 0);
      acc = __builtin_amdgcn_mfma_f32_16x16x32_bf16(al, bh, acc, 0, 0, 0);
      acc = __builtin_amdgcn_mfma_f32_16x16x32_bf16(ah, bl, acc, 0, 0, 0);
    }
    const int colx = lane & 15;
    const int rb   = (lane >> 4) * 4;
    #pragma unroll
    for (int r = 0; r < 4; r++)
      gates_l[(wv*16 + rb + r)*17 + colx] = acc[r];
  }
  __syncthreads();

  // ---- phase 2: LSTM elementwise; write h/c into B-frag layout ----
  {
    const int x = px;
    const int c = pc;
    const int n = pn;
    float ig = gates_l[(c      )*17 + x] + pf_g0 + pf_b0;
    float fg = gates_l[( 64 + c)*17 + x] + pf_g1 + pf_b1;
    float gg = gates_l[(128 + c)*17 + x] + pf_g2 + pf_b2;
    float og = gates_l[(192 + c)*17 + x] + pf_g3 + pf_b3;
    float cp = pf_cp;
    float i_ = sigm(ig + pf_wci * cp);
    float f_ = sigm(fg + pf_wcf * cp);
    float cn = f_*cp + i_*tanh_f(gg);
    float o_ = sigm(og + pf_wco * cn);
    float hn = o_*tanh_f(cn);
    h_nxt[(b*64 + c)*NN + n] = hn;
    c_st[(b*64 + c)*NN + n] = cn;
    const int ksC = c >> 5, kkC = c & 31;
    const int posF = (ksC*64 + (x | ((kkC >> 3) << 4)))*8 + (kkC & 7);
    unsigned short hh = bf16r(hn);
    hBh[posF] = hh;
    hBl[posF] = bf16r(hn - bf16f(hh));
    unsigned short ch = bf16r(cn);
    cBh[posF] = ch;
    cBl[posF] = bf16r(cn - bf16f(ch));
  }
  __syncthreads();

  // ---- phase 3: projections via MFMA (11 waves, mt 0..5 from h, 6..10 from c) ----
  float* proj_l = gates_l;              // gates fully consumed in phase 2
  {
    const int lane = lane_e;
    const int wv   = wv_e;
    if (wv < 11) {
      const s8v* Bh_ = (const s8v*)((wv < 6) ? hBh : cBh) + lane;
      const s8v* Bl_ = (const s8v*)((wv < 6) ? hBl : cBl) + lane;
      f4v acc = {0.f, 0.f, 0.f, 0.f};
      s8v bh0 = Bh_[0];
      s8v bl0 = Bl_[0];
      s8v bh1 = Bh_[64];
      s8v bl1 = Bl_[64];
      acc = __builtin_amdgcn_mfma_f32_16x16x32_bf16(pf_a0h, bh0, acc, 0, 0, 0);
      acc = __builtin_amdgcn_mfma_f32_16x16x32_bf16(pf_a0l, bh0, acc, 0, 0, 0);
      acc = __builtin_amdgcn_mfma_f32_16x16x32_bf16(pf_a0h, bl0, acc, 0, 0, 0);
      acc = __builtin_amdgcn_mfma_f32_16x16x32_bf16(pf_a1h, bh1, acc, 0, 0, 0);
      acc = __builtin_amdgcn_mfma_f32_16x16x32_bf16(pf_a1l, bh1, acc, 0, 0, 0);
      acc = __builtin_amdgcn_mfma_f32_16x16x32_bf16(pf_a1h, bl1, acc, 0, 0, 0);
      const int colx = lane & 15;
      const int rb   = (lane >> 4) * 4;
      #pragma unroll
      for (int r = 0; r < 4; r++) {
        int po = wv*16 + rb + r;
        proj_l[po*16 + colx] = acc[r] + pb_l[po];
      }
    }
  }
  __syncthreads();

  // ---- phase 4: coalesced fragment emission ----
  // Q in A-frag layout (tid 512..1023)
  if (tid >= 512) {
    int qt = tid - 512;               // 0..511
    int lane = qt >> 3, j = qt & 7;
    int g = lane >> 4, c16l = lane & 15;
    int d = ((g & 1) << 3) + j;
    float qv = proj_l[d*16 + c16l];
    unsigned short hi = bf16r(qv);
    unsigned short lo = (g < 2) ? bf16r(qv - bf16f(hi)) : (unsigned short)0;
    long base = ((long)(b*64 + mt)*64 + lane)*8 + j;
    qFh[base] = hi;
    qFl[base] = lo;
  }
  if (tid < 512) {
    int brh2 = tid >> 8;            // branch
    int lh   = (tid >> 2) & 63;     // fragment "lane-half" row
    int j2   = tid & 3;             // packs d&7 = 2*j2, 2*j2+1
    int p    = lh >> 4;             // 0,1: hi planes; 2,3: lo planes
    int x    = lh & 15;
    int d0   = ((p & 1) << 3) | (j2 << 1);
    int Koff = brh2 ? 96 : 16;
    float v0 = proj_l[(Koff + d0)*16 + x];
    float v1 = proj_l[(Koff + d0 + 1)*16 + x];
    unsigned short h0 = bf16r(v0), h1 = bf16r(v1);
    unsigned short u0, u1;
    if (p < 2) { u0 = h0; u1 = h1; }
    else       { u0 = bf16r(v0 - bf16f(h0)); u1 = bf16r(v1 - bf16f(h1)); }
    unsigned int* dst = (unsigned int*)(kF + ((b*2 + brh2)*64 + mt)*512);
    dst[lh*4 + j2] = (unsigned)u0 | ((unsigned)u1 << 16);
  }
  {
    const int ks = y;
    const int g0 = x0 >> 3;         // 0 or 2
    int ct    = tid;                // 1024 tasks: brh(2) x nt(4) x li(32) x j2(4)
    int brh2  = (ct >> 9) & 1;
    int nt    = (ct >> 7) & 3;
    int li    = (ct >> 2) & 31;
    int j2    = ct & 3;
    int lane2 = g0*16 + li;
    int cch   = nt*16 + (lane2 & 15);
    int xx    = ((li >> 4) << 3) | (j2 << 1);
    int Voff  = brh2 ? 112 : 32;
    float v0 = proj_l[(Voff + cch)*16 + xx];
    float v1 = proj_l[(Voff + cch)*16 + xx + 1];
    unsigned short u0 = bf16r(v0), u1 = bf16r(v1);
    unsigned short* basep = vFh + (((b*2 + brh2)*32 + ks)*4 + nt)*512;
    ((unsigned int*)basep)[lane2*4 + j2] = (unsigned)u0 | ((unsigned)u1 << 16);
  }
}

// ---------- K2: dual attention via MFMA + MFMA combine + gating ----------
#define RED_OFF 0        // [16 waves][16 nl][66]  = 16896
#define PS_OFF  16896    // [16 waves][16][36]     = 9216
#define SMX_OFF 26112    // [2][8][16]             = 256
#define SSM_OFF 26368    // [2][8][16]             = 256
#define INV_OFF 26624    // [2][16]                = 32
#define S_TOT   28704

__global__ __launch_bounds__(1024, 4) void k2_attn(
    int t,
    const unsigned short* __restrict__ qFh, const unsigned short* __restrict__ qFl,
    const unsigned short* __restrict__ kF,
    const unsigned short* __restrict__ vFh,
    float* __restrict__ h_nxt, float* __restrict__ c_st,
    const unsigned short* __restrict__ zAhi, const unsigned short* __restrict__ zAlo,
    const unsigned short* __restrict__ mAhi, const unsigned short* __restrict__ mAlo,
    const float* __restrict__ z_b, const float* __restrict__ m_b,
    float* __restrict__ out)
{
  __shared__ __align__(16) float S[S_TOT];
  __shared__ __align__(16) unsigned short zBh[4*512];   // zz B-frags (4 ks)
  __shared__ __align__(16) unsigned short zBl[4*512];
  __shared__ __align__(16) unsigned short cbBh[6*512];  // comb B-frags (6 ks)
  __shared__ __align__(16) unsigned short cbBl[6*512];
  float* red  = S + RED_OFF;
  float* smMax= S + SMX_OFF;
  float* smSum= S + SSM_OFF;
  float* invL = S + INV_OFF;
  float* cbOut= S + 3072;       // [192][16] aliases red (after barrier)

  const int tid = threadIdx.x;
  const int bid = blockIdx.x;
  const int xcd = bid & 7;
  const int b = xcd >> 1;
  const int tile = ((bid >> 3) << 1) | (xcd & 1);   // 0..63
  const int n0 = tile * 16;

  const int wid  = tid >> 6;
  const int lane = tid & 63;
  const int brh  = wid >> 3;      // branch
  const int w    = wid & 7;       // wave within branch
  const int g    = lane >> 4;
  const int c16  = lane & 15;

  // ---- prefetch tail-phase inputs ----
  const int pc2 = tid >> 4;       // 0..63
  const int pn2 = n0 + (tid & 15);
  float pf_cst = c_st[(b*64 + pc2)*NN + pn2];
  float pf_h   = h_nxt[(b*64 + pc2)*NN + pn2];

  // ---- Q A-frags: direct b128 loads (pre-packed by k1) ----
  s8v qh1 = *(const s8v*)(qFh + ((long)(b*64 + tile)*64 + lane)*8);
  s8v ql2 = *(const s8v*)(qFl + ((long)(b*64 + tile)*64 + lane)*8);

  // ---- scores: 8 m-tiles per wave, 2 MFMA each (B = [Kh|Kl]) ----
  f4v acc[8];
  {
    const unsigned short* kp = kF + (((b*2 + brh)*64 + w*8)*64 + lane)*8;
    #pragma unroll
    for (int i = 0; i < 8; i++) {
      s8v bf = *(const s8v*)(kp + i*512);
      f4v z4 = {0.f, 0.f, 0.f, 0.f};
      z4 = __builtin_amdgcn_mfma_f32_16x16x32_bf16(ql2, bf, z4, 0, 0, 0);
      acc[i] = __builtin_amdgcn_mfma_f32_16x16x32_bf16(qh1, bf, z4, 0, 0, 0);
    }
  }

  // ---- softmax ----
  float Mrow[4];
  #pragma unroll
  for (int r = 0; r < 4; r++) {
    float m = acc[0][r];
    #pragma unroll
    for (int i = 1; i < 8; i++) m = fmaxf(m, acc[i][r]);
    m = fmaxf(m, __shfl_xor(m, 1));
    m = fmaxf(m, __shfl_xor(m, 2));
    m = fmaxf(m, __shfl_xor(m, 4));
    m = fmaxf(m, __shfl_xor(m, 8));
    if (c16 == 0) smMax[(brh*8 + w)*16 + g*4 + r] = m;
  }
  __syncthreads();
  #pragma unroll
  for (int r = 0; r < 4; r++) {
    float m = smMax[(brh*8 + 0)*16 + g*4 + r];
    #pragma unroll
    for (int w2 = 1; w2 < 8; w2++) m = fmaxf(m, smMax[(brh*8 + w2)*16 + g*4 + r]);
    Mrow[r] = m;
  }
  float rsum[4] = {0.f, 0.f, 0.f, 0.f};
  #pragma unroll
  for (int i = 0; i < 8; i++) {
    #pragma unroll
    for (int r = 0; r < 4; r++) {
      float p = __expf(acc[i][r] - Mrow[r]);
      acc[i][r] = p;
      rsum[r] += p;
    }
  }
  #pragma unroll
  for (int r = 0; r < 4; r++) {
    float s = rsum[r];
    s += __shfl_xor(s, 1); s += __shfl_xor(s, 2);
    s += __shfl_xor(s, 4); s += __shfl_xor(s, 8);
    if (c16 == 0) smSum[(brh*8 + w)*16 + g*4 + r] = s;
  }
  __syncthreads();
  if (w == 0 && c16 == 0) {
    #pragma unroll
    for (int r = 0; r < 4; r++) {
      float s = 0.f;
      #pragma unroll
      for (int w2 = 0; w2 < 8; w2++) s += smSum[(brh*8 + w2)*16 + g*4 + r];
      invL[brh*16 + g*4 + r] = 1.0f / s;
    }
  }

  // ---- PV: per wave, 4 k-steps of 32 m; wave-local P transpose; V hi-only ----
  f4v z0 = {0.f,0.f,0.f,0.f}, z1 = z0, z2 = z0, z3 = z0;
  float* myPS = S + PS_OFF + wid*576;   // [16][36]
  #pragma unroll
  for (int ks4 = 0; ks4 < 4; ks4++) {
    #pragma unroll
    for (int i2 = 0; i2 < 2; i2++) {
      #pragma unroll
      for (int r = 0; r < 4; r++)
        myPS[(g*4 + r)*36 + i2*16 + c16] = acc[ks4*2 + i2][r];
    }
    float4 pa = *(const float4*)&myPS[c16*36 + g*8];
    float4 pb = *(const float4*)&myPS[c16*36 + g*8 + 4];
    s8v ph, pl;
    {
      unsigned short h0 = bf16r(pa.x); ph[0] = (short)h0; pl[0] = (short)bf16r(pa.x - bf16f(h0));
      unsigned short h1 = bf16r(pa.y); ph[1] = (short)h1; pl[1] = (short)bf16r(pa.y - bf16f(h1));
      unsigned short h2 = bf16r(pa.z); ph[2] = (short)h2; pl[2] = (short)bf16r(pa.z - bf16f(h2));
      unsigned short h3 = bf16r(pa.w); ph[3] = (short)h3; pl[3] = (short)bf16r(pa.w - bf16f(h3));
      unsigned short h4 = bf16r(pb.x); ph[4] = (short)h4; pl[4] = (short)bf16r(pb.x - bf16f(h4));
      unsigned short h5 = bf16r(pb.y); ph[5] = (short)h5; pl[5] = (short)bf16r(pb.y - bf16f(h5));
      unsigned short h6 = bf16r(pb.z); ph[6] = (short)h6; pl[6] = (short)bf16r(pb.z - bf16f(h6));
      unsigned short h7 = bf16r(pb.w); ph[7] = (short)h7; pl[7] = (short)bf16r(pb.w - bf16f(h7));
    }
    const int ks = w*4 + ks4;
    const unsigned short* vph = vFh + ((((b*2 + brh)*32 + ks)*4)*64 + lane)*8;
    s8v vh0 = *(const s8v*)(vph);
    z0 = __builtin_amdgcn_mfma_f32_16x16x32_bf16(ph, vh0, z0, 0,0,0);
    z0 = __builtin_amdgcn_mfma_f32_16x16x32_bf16(pl, vh0, z0, 0,0,0);
    s8v vh1 = *(const s8v*)(vph + 512);
    z1 = __builtin_amdgcn_mfma_f32_16x16x32_bf16(ph, vh1, z1, 0,0,0);
    z1 = __builtin_amdgcn_mfma_f32_16x16x32_bf16(pl, vh1, z1, 0,0,0);
    s8v vh2 = *(const s8v*)(vph + 1024);
    z2 = __builtin_amdgcn_mfma_f32_16x16x32_bf16(ph, vh2, z2, 0,0,0);
    z2 = __builtin_amdgcn_mfma_f32_16x16x32_bf16(pl, vh2, z2, 0,0,0);
    s8v vh3 = *(const s8v*)(vph + 1536);
    z3 = __builtin_amdgcn_mfma_f32_16x16x32_bf16(ph, vh3, z3, 0,0,0);
    z3 = __builtin_amdgcn_mfma_f32_16x16x32_bf16(pl, vh3, z3, 0,0,0);
  }

  // ---- write partials, reduce 8 waves, normalize -> zz B-frags ----
  {
    float* rw = red + wid*1056;
    #pragma unroll
    for (int r = 0; r < 4; r++) {
      rw[(g*4 + r)*66 +  0 + c16] = z0[r];
      rw[(g*4 + r)*66 + 16 + c16] = z1[r];
      rw[(g*4 + r)*66 + 32 + c16] = z2[r];
      rw[(g*4 + r)*66 + 48 + c16] = z3[r];
    }
  }
  __syncthreads();
  {
    const int br2 = tid >> 9;
    const int sub = tid & 511;
    const int nlr = sub >> 5;
    const int cc0 = (sub & 31) * 2;
    float iv = invL[br2*16 + nlr];
    #pragma unroll
    for (int u = 0; u < 2; u++) {
      int cc = cc0 + u;
      float s = 0.f;
      #pragma unroll
      for (int w2 = 0; w2 < 8; w2++)
        s += red[(br2*8 + w2)*1056 + nlr*66 + cc];
      float v = s * iv;
      int k = br2*64 + cc;
      int ks = k >> 5, kk = k & 31;
      int pos = (ks*64 + (nlr | ((kk >> 3) << 4)))*8 + (kk & 7);
      unsigned short h = bf16r(v);
      zBh[pos] = h;
      zBl[pos] = bf16r(v - bf16f(h));
    }
  }
  __syncthreads();

  // ---- h rows into comb B-frags + zz via MFMA (waves 0..7) ----
  {
    int k = 128 + pc2;
    int ks = k >> 5, kk = k & 31;
    int pos = (ks*64 + ((tid & 15) | ((kk >> 3) << 4)))*8 + (kk & 7);
    unsigned short h = bf16r(pf_h);
    cbBh[pos] = h;
    cbBl[pos] = bf16r(pf_h - bf16f(h));
  }
  if (wid < 8) {
    f4v za = {0.f, 0.f, 0.f, 0.f};
    const s8v* Azh = (const s8v*)zAhi + (wid*4)*64 + lane;
    const s8v* Azl = (const s8v*)zAlo + (wid*4)*64 + lane;
    const s8v* Bzh = (const s8v*)zBh + lane;
    const s8v* Bzl = (const s8v*)zBl + lane;
    #pragma unroll
    for (int ks = 0; ks < 4; ks++) {
      s8v ah = Azh[ks*64];
      s8v al = Azl[ks*64];
      s8v bh = Bzh[ks*64];
      s8v bl = Bzl[ks*64];
      za = __builtin_amdgcn_mfma_f32_16x16x32_bf16(ah, bh, za, 0, 0, 0);
      za = __builtin_amdgcn_mfma_f32_16x16x32_bf16(al, bh, za, 0, 0, 0);
      za = __builtin_amdgcn_mfma_f32_16x16x32_bf16(ah, bl, za, 0, 0, 0);
    }
    #pragma unroll
    for (int r = 0; r < 4; r++) {
      int oc = wid*16 + g*4 + r;
      float v = za[r] + z_b[oc];
      int kk = oc & 31, ks2 = oc >> 5;
      int pos = (ks2*64 + (c16 | ((kk >> 3) << 4)))*8 + (kk & 7);
      unsigned short h = bf16r(v);
      cbBh[pos] = h;
      cbBl[pos] = bf16r(v - bf16f(h));
    }
  }
  __syncthreads();

  // ---- comb via MFMA (waves 0..11) ----
  if (wid < 12) {
    f4v ca = {0.f, 0.f, 0.f, 0.f};
    const s8v* Amh = (const s8v*)mAhi + (wid*6)*64 + lane;
    const s8v* Aml = (const s8v*)mAlo + (wid*6)*64 + lane;
    const s8v* Bch = (const s8v*)cbBh + lane;
    const s8v* Bcl = (const s8v*)cbBl + lane;
    #pragma unroll
    for (int ks = 0; ks < 6; ks++) {
      s8v ah = Amh[ks*64];
      s8v al = Aml[ks*64];
      s8v bh = Bch[ks*64];
      s8v bl = Bcl[ks*64];
      ca = __builtin_amdgcn_mfma_f32_16x16x32_bf16(ah, bh, ca, 0, 0, 0);
      ca = __builtin_amdgcn_mfma_f32_16x16x32_bf16(al, bh, ca, 0, 0, 0);
      ca = __builtin_amdgcn_mfma_f32_16x16x32_bf16(ah, bl, ca, 0, 0, 0);
    }
    #pragma unroll
    for (int r = 0; r < 4; r++) {
      int oc = wid*16 + g*4 + r;
      cbOut[oc*16 + c16] = ca[r] + m_b[oc];
    }
  }
  __syncthreads();

  // ---- gating ----
  {
    const int c = pc2, nn = tid & 15;
    const int n = n0 + nn;
    float mo = cbOut[c*16 + nn];
    float mg = cbOut[(64 + c)*16 + nn];
    float mi = cbOut[(128 + c)*16 + nn];
    float mf = pf_cst;
    float mis = sigm(mi);
    float nmf = (1.0f - mis)*mf + mis*tanh_f(mg);
    float nhf = sigm(mo)*nmf;
    c_st[(b*64 + c)*NN + n] = nmf;
    h_nxt[(b*64 + c)*NN + n] = nhf;
    out[((b*64 + c)*SS + t)*NN + n] = nhf;
  }
}

extern "C" void kernel_launch(void* const* d_in, const int* in_sizes, int n_in,
                              void* d_out, int out_size, void* d_ws, size_t ws_size,
                              hipStream_t stream) {
  const float* X      = (const float*)d_in[0];
  const float* conv_w = (const float*)d_in[1];
  const float* conv_b = (const float*)d_in[2];
  const float* W_ci   = (const float*)d_in[3];
  const float* W_cf   = (const float*)d_in[4];
  const float* W_co   = (const float*)d_in[5];
  const float* qw  = (const float*)d_in[6];
  const float* qb  = (const float*)d_in[7];
  const float* kw  = (const float*)d_in[8];
  const float* kb  = (const float*)d_in[9];
  const float* k2w = (const float*)d_in[10];
  const float* k2b = (const float*)d_in[11];
  const float* vw  = (const float*)d_in[12];
  const float* vb  = (const float*)d_in[13];
  const float* v2w = (const float*)d_in[14];
  const float* v2b = (const float*)d_in[15];
  const float* z_w = (const float*)d_in[16];
  const float* z_b = (const float*)d_in[17];
  const float* m_w = (const float*)d_in[18];
  const float* m_b = (const float*)d_in[19];
  float* out = (float*)d_out;

  float* ws = (float*)d_ws;
  unsigned short* Whi  = (unsigned short*)ws;  ws += 147456;   // 294912 ushorts
  unsigned short* Wlo  = (unsigned short*)ws;  ws += 147456;
  unsigned short* zAhi = (unsigned short*)ws;  ws += 8192;     // 16384 ushorts
  unsigned short* zAlo = (unsigned short*)ws;  ws += 8192;
  unsigned short* mAhi = (unsigned short*)ws;  ws += 18432;    // 36864 ushorts
  unsigned short* mAlo = (unsigned short*)ws;  ws += 18432;
  unsigned short* pAhi = (unsigned short*)ws;  ws += 5632;     // 11264 ushorts
  unsigned short* pAlo = (unsigned short*)ws;  ws += 5632;
  float* h_A    = ws;             ws += NB*64*NN;
  float* h_B    = ws;             ws += NB*64*NN;
  float* c_st   = ws;             ws += NB*64*NN;
  unsigned short* qFh = (unsigned short*)ws;  ws += 65536;    // 131072 ushorts
  unsigned short* qFl = (unsigned short*)ws;  ws += 65536;
  unsigned short* kF  = (unsigned short*)ws;  ws += 131072;   // 4b*2br*64mt*64*8 ushorts
  unsigned short* vFh = (unsigned short*)ws;  ws += 131072;   // 4b*2br*32ks*4nt*64*8
  unsigned short* gxh = (unsigned short*)ws;  ws += NB*SS*128*NN;  // 16.8M ushorts, 33.5 MB

  hipLaunchKernelGGL(k0_prep, dim3(256), dim3(256), 0, stream,
                     conv_w, z_w, m_w, qw, kw, vw, k2w, v2w,
                     Whi, Wlo, zAhi, zAlo, mAhi, mAlo, pAhi, pAlo, h_A, c_st);
  hipLaunchKernelGGL(k0b_gx, dim3(1024), dim3(1024), 0, stream,
                     X, Whi, gxh);
  for (int t = 0; t < 16; t++) {
    const float* h_cur = (t & 1) ? h_B : h_A;
    float* h_nxt       = (t & 1) ? h_A : h_B;
    hipLaunchKernelGGL(k1_conv_lstm_proj, dim3(256), dim3(1024), 0, stream,
        t, gxh, Whi, Wlo, pAhi, pAlo, conv_b, W_ci, W_cf, W_co,
        qb, kb, vb, k2b, v2b,
        h_cur, h_nxt, c_st, qFh, qFl, kF, vFh);
    hipLaunchKernelGGL(k2_attn, dim3(256), dim3(1024), 0, stream,
        t, qFh, qFl, kF, vFh, h_nxt, c_st,
        zAhi, zAlo, mAhi, mAlo, z_b, m_b, out);
  }
}

// Round 20
// 456.041 us; speedup vs baseline: 1.6883x; 1.0755x over previous
//
#include <hip/hip_runtime.h>
#include <math.h>

#define NB 4
#define SS 16
#define NN 1024        // H*W

typedef short s8v __attribute__((ext_vector_type(8)));    // 8 bf16 (4 VGPR)
typedef float f4v __attribute__((ext_vector_type(4)));    // MFMA accumulator

__device__ __forceinline__ float sigm(float x) {
  return 1.0f / (1.0f + __expf(-x));
}
__device__ __forceinline__ float tanh_f(float x) {
  float e = __expf(2.0f * x);
  return 1.0f - 2.0f / (1.0f + e);
}
__device__ __forceinline__ unsigned short bf16r(float x) {   // RNE float->bf16
  unsigned int u = __float_as_uint(x);
  u = (u + 0x7FFFu + ((u >> 16) & 1u)) >> 16;
  return (unsigned short)u;
}
__device__ __forceinline__ float bf16f(unsigned short h) {
  return __uint_as_float(((unsigned int)h) << 16);
}

// ---------- prep: weight split/pack (conv + proj + z_w + m_w A-frags) + zero states ----------
__global__ void k0_prep(const float* __restrict__ conv_w, const float* __restrict__ z_w,
                        const float* __restrict__ m_w,
                        const float* __restrict__ qw, const float* __restrict__ kw,
                        const float* __restrict__ vw, const float* __restrict__ k2w,
                        const float* __restrict__ v2w,
                        unsigned short* __restrict__ Whi, unsigned short* __restrict__ Wlo,
                        unsigned short* __restrict__ zAhi, unsigned short* __restrict__ zAlo,
                        unsigned short* __restrict__ mAhi, unsigned short* __restrict__ mAlo,
                        unsigned short* __restrict__ pAhi, unsigned short* __restrict__ pAlo,
                        float* __restrict__ h_A, float* __restrict__ c_st) {
  int stride = gridDim.x * blockDim.x;
  int i0 = blockIdx.x * blockDim.x + threadIdx.x;
  for (int i = i0; i < 256*1152; i += stride) {
    int oc = i / 1152, k = i - oc*1152;          // k = icComb*9 + ky*3 + kx
    float v = conv_w[i];
    unsigned short hi = bf16r(v);
    unsigned short lo = bf16r(v - bf16f(hi));
    int mt = oc >> 4, i16 = oc & 15;
    int ks = k >> 5, kk = k & 31;
    int lane = i16 | ((kk >> 3) << 4);
    int pos = ((mt*36 + ks)*64 + lane)*8 + (kk & 7);
    Whi[pos] = hi;
    Wlo[pos] = lo;
  }
  for (int i = i0; i < 128*128; i += stride) {   // z_w A-frags: 8 mt x 4 ks
    int oc = i >> 7, k = i & 127;
    float v = z_w[i];
    unsigned short hi = bf16r(v);
    unsigned short lo = bf16r(v - bf16f(hi));
    int mt = oc >> 4, i16 = oc & 15;
    int ks = k >> 5, kk = k & 31;
    int lane = i16 | ((kk >> 3) << 4);
    int pos = ((mt*4 + ks)*64 + lane)*8 + (kk & 7);
    zAhi[pos] = hi;
    zAlo[pos] = lo;
  }
  for (int i = i0; i < 192*192; i += stride) {   // m_w A-frags: 12 mt x 6 ks
    int oc = i / 192, k = i - oc*192;
    float v = m_w[i];
    unsigned short hi = bf16r(v);
    unsigned short lo = bf16r(v - bf16f(hi));
    int mt = oc >> 4, i16 = oc & 15;
    int ks = k >> 5, kk = k & 31;
    int lane = i16 | ((kk >> 3) << 4);
    int pos = ((mt*6 + ks)*64 + lane)*8 + (kk & 7);
    mAhi[pos] = hi;
    mAlo[pos] = lo;
  }
  for (int i = i0; i < 176*64; i += stride) {    // proj A-frags: 11 mt x 2 ks
    int po = i >> 6, c = i & 63;
    float v;
    if (po < 16)       v = qw[po*64 + c];
    else if (po < 32)  v = kw[(po-16)*64 + c];
    else if (po < 96)  v = vw[(po-32)*64 + c];
    else if (po < 112) v = k2w[(po-96)*64 + c];
    else               v = v2w[(po-112)*64 + c];
    unsigned short hi = bf16r(v);
    unsigned short lo = bf16r(v - bf16f(hi));
    int mt = po >> 4, i16 = po & 15;
    int ks = c >> 5, kk = c & 31;
    int lane = i16 | ((kk >> 3) << 4);
    int pos = ((mt*2 + ks)*64 + lane)*8 + (kk & 7);
    pAhi[pos] = hi;
    pAlo[pos] = lo;
  }
  for (int i = i0; i < NB*64*NN; i += stride) { h_A[i] = 0.0f; c_st[i] = 0.0f; }
}

// ---------- K0b v7: conv_x, N=64/block, hi-only, row-owned im2col, bf16 gx ----------
__global__ __launch_bounds__(1024, 2) void k0b_gx(
    const float* __restrict__ X,
    const unsigned short* __restrict__ Whi,
    unsigned short* __restrict__ gxh)
{
  __shared__ __align__(16) unsigned short Xhi_l[18*4*64*8];   // [ks][nt 0..3][lane][8] = 73728 B

  const int tid = threadIdx.x;
  const int bid = blockIdx.x;       // b*256 + t*16 + y2
  const int y2 = bid & 15;
  const int t  = (bid >> 4) & 15;
  const int b  = bid >> 8;
  const int y0 = y2 * 2;

  // ---- im2col: thread owns (row = ic*4+dy, quarter); constant bases per combo ----
  {
    const int row = tid >> 2;          // 0..255
    const int qtr = tid & 3;           // 0..3
    const int ic  = row >> 2;
    const int dy  = row & 3;           // halo row; gy = y0 + dy - 1
    const int gy  = y0 + dy - 1;
    const bool rowOk = ((unsigned)gy < 32u);
    const float* Xrow = X + (((b*64 + ic)*SS + t)*NN) + gy*32;
    int Kc[2][3];
    bool rv[2];
    #pragma unroll
    for (int r = 0; r < 2; r++) {
      int dyl = dy - r;
      rv[r] = ((unsigned)dyl < 3u);
      #pragma unroll
      for (int dx = 0; dx < 3; dx++) {
        int k = ic*9 + dyl*3 + dx;
        int ks = k >> 5, kk = k & 31;
        Kc[r][dx] = ks*2048 + ((kk >> 3) << 4)*8 + (kk & 7) + r*1024;
      }
    }
    const int c0 = qtr*9;
    const int c1 = (qtr == 3) ? 34 : c0 + 9;
    for (int col = c0; col < c1; col++) {
      int gxc = col - 1;
      float v = (rowOk && (unsigned)gxc < 32u) ? Xrow[gxc] : 0.0f;
      unsigned short hi = bf16r(v);
      #pragma unroll
      for (int r = 0; r < 2; r++) {
        if (rv[r]) {
          #pragma unroll
          for (int dx = 0; dx < 3; dx++) {
            int x = col - dx;
            if ((unsigned)x < 32u)
              Xhi_l[Kc[r][dx] + (x >> 4)*512 + (x & 15)*8] = hi;
          }
        }
      }
    }
  }
  __syncthreads();

  const int lane = tid & 63;
  const int mt = tid >> 6;          // 0..15
  f4v acc[4];
  #pragma unroll
  for (int nt = 0; nt < 4; nt++) acc[nt] = (f4v){0.f, 0.f, 0.f, 0.f};
  const s8v* Ah = (const s8v*)Whi + (mt*36)*64 + lane;
  const s8v* Bh = (const s8v*)Xhi_l + lane;
  #pragma unroll 3
  for (int ks = 0; ks < 18; ks++) {
    s8v ah = Ah[ks*64];
    #pragma unroll
    for (int nt = 0; nt < 4; nt++) {
      s8v bh = Bh[(ks*4 + nt)*64];
      acc[nt] = __builtin_amdgcn_mfma_f32_16x16x32_bf16(ah, bh, acc[nt], 0, 0, 0);
    }
  }
  const int c16 = lane & 15;
  const int rb  = (lane >> 4) * 4;
  unsigned short* gout = gxh + (((long)b*SS + t)*256)*NN;
  #pragma unroll
  for (int nt = 0; nt < 4; nt++) {
    #pragma unroll
    for (int r4 = 0; r4 < 4; r4++) {
      int oc = mt*16 + rb + r4;
      int n = nt*16 + c16;
      int py = y0 + (n >> 5);
      int px2 = n & 31;
      gout[oc*NN + py*32 + px2] = bf16r(acc[nt][r4]);
    }
  }
}

// ---------- K1: conv_h (W hi-only) + LSTM(+gx) + MFMA projections (1024 threads) ----------
__global__ __launch_bounds__(1024, 2) void k1_conv_lstm_proj(
    int t,
    const unsigned short* __restrict__ gxh,
    const unsigned short* __restrict__ Whi,
    const unsigned short* __restrict__ pAhi, const unsigned short* __restrict__ pAlo,
    const float* __restrict__ conv_b,
    const float* __restrict__ W_ci, const float* __restrict__ W_cf, const float* __restrict__ W_co,
    const float* __restrict__ qb, const float* __restrict__ kb,
    const float* __restrict__ vb, const float* __restrict__ k2b,
    const float* __restrict__ v2b,
    const float* __restrict__ h_cur, float* __restrict__ h_nxt,
    float* __restrict__ c_st,
    unsigned short* __restrict__ qFh, unsigned short* __restrict__ qFl,
    unsigned short* __restrict__ kF,
    unsigned short* __restrict__ vFh)
{
  __shared__ __align__(16) unsigned short Ihi_l[18*64*8];      // h-only im2col, B-frag order
  __shared__ __align__(16) unsigned short Ilo_l[18*64*8];
  __shared__ __align__(16) float gates_l[256*17];              // [oc][x]; later proj_l[176][16]
  __shared__ __align__(16) unsigned short hBh[2*64*8];         // h in B-frag layout (hi/lo)
  __shared__ __align__(16) unsigned short hBl[2*64*8];
  __shared__ __align__(16) unsigned short cBh[2*64*8];         // c in B-frag layout
  __shared__ __align__(16) unsigned short cBl[2*64*8];
  __shared__ __align__(16) float pb_l[176];

  const int tid = threadIdx.x;
  const int bid = blockIdx.x;
  const int b  = bid >> 6;
  const int y  = (bid >> 1) & 31;
  const int x0 = (bid & 1) * 16;
  const int mt = bid & 63;          // this block's 16-col m-tile (= n>>4)
  const int n0 = y*32 + x0;

  // ---- prefetch LSTM inputs + projection A-frags into registers ----
  const int px = tid & 15;
  const int pc = tid >> 4;          // 0..63
  const int pn = n0 + px;
  const unsigned short* gxp = gxh + (((long)b*SS + t)*256)*NN + pn;
  float pf_g0 = bf16f(gxp[(pc      )*NN]);
  float pf_g1 = bf16f(gxp[( 64 + pc)*NN]);
  float pf_g2 = bf16f(gxp[(128 + pc)*NN]);
  float pf_g3 = bf16f(gxp[(192 + pc)*NN]);
  float pf_cp  = c_st[(b*64 + pc)*NN + pn];
  float pf_wci = W_ci[pc*NN + pn];
  float pf_wcf = W_cf[pc*NN + pn];
  float pf_wco = W_co[pc*NN + pn];
  float pf_b0 = conv_b[pc];
  float pf_b1 = conv_b[ 64 + pc];
  float pf_b2 = conv_b[128 + pc];
  float pf_b3 = conv_b[192 + pc];
  const int lane_e = tid & 63;
  const int wv_e   = tid >> 6;
  const int wvc    = (wv_e < 11) ? wv_e : 0;
  s8v pf_a0h = *(const s8v*)(pAhi + ((wvc*2 + 0)*64 + lane_e)*8);
  s8v pf_a0l = *(const s8v*)(pAlo + ((wvc*2 + 0)*64 + lane_e)*8);
  s8v pf_a1h = *(const s8v*)(pAhi + ((wvc*2 + 1)*64 + lane_e)*8);
  s8v pf_a1l = *(const s8v*)(pAlo + ((wvc*2 + 1)*64 + lane_e)*8);

  // ---- phase 0: h-only im2col -> B-frags  +  stage proj biases ----
  for (int idx = tid; idx < 64*3*18; idx += 1024) {
    int col = idx % 18;
    int rest = idx / 18;
    int dy = rest % 3;
    int ic = rest / 3;                    // h channel 0..63
    int gy = y + dy - 1;
    int gxc = x0 + col - 1;
    float v = 0.0f;
    if ((unsigned)gy < 32u && (unsigned)gxc < 32u)
      v = h_cur[((b*64 + ic)*NN) + gy*32 + gxc];
    unsigned short hi = bf16r(v);
    unsigned short lo = bf16r(v - bf16f(hi));
    int kbase = ic*9 + dy*3;              // local k in [0,576)
    #pragma unroll
    for (int dx = 0; dx < 3; dx++) {
      int n = col - dx;
      if ((unsigned)n < 16u) {
        int k = kbase + dx;
        int ks = k >> 5, kk = k & 31;
        int pos = (ks*64 + (n | ((kk >> 3) << 4)))*8 + (kk & 7);
        Ihi_l[pos] = hi;
        Ilo_l[pos] = lo;
      }
    }
  }
  if (tid < 176) {
    int po = tid;
    float v;
    if (po < 16)       v = qb[po];
    else if (po < 32)  v = kb[po-16];
    else if (po < 96)  v = vb[po-32];
    else if (po < 112) v = k2b[po-96];
    else               v = v2b[po-112];
    pb_l[po] = v;
  }
  __syncthreads();

  // ---- phase 1: conv_h MFMA: 16 waves, 1 m-tile each; W hi-only, B hi+lo ----
  {
    const int lane = tid & 63;
    const int wv   = tid >> 6;        // 0..15 = m-tile
    f4v acc = {0.f, 0.f, 0.f, 0.f};
    const s8v* Ah = (const s8v*)Whi + (wv*36 + 18)*64 + lane;
    const s8v* Bh = (const s8v*)Ihi_l + lane;
    const s8v* Bl = (const s8v*)Ilo_l + lane;
    #pragma unroll 3
    for (int ks = 0; ks < 18; ks++) {
      s8v ah = Ah[ks*64];
      s8v bh = Bh[ks*64];
      s8v bl = Bl[ks*64];
      acc = __builtin_amdgcn_mfma_f32_16x16x32_bf16(ah, bh, acc, 0, 0, 0);
      acc = __builtin_amdgcn_mfma_f32_16x16x32_bf16(ah, bl, acc, 0, 0, 0);
    }
    const int colx = lane & 15;
    const int rb   = (lane >> 4) * 4;
    #pragma unroll
    for (int r = 0; r < 4; r++)
      gates_l[(wv*16 + rb + r)*17 + colx] = acc[r];
  }
  __syncthreads();

  // ---- phase 2: LSTM elementwise; write h/c into B-frag layout ----
  {
    const int x = px;
    const int c = pc;
    const int n = pn;
    float ig = gates_l[(c      )*17 + x] + pf_g0 + pf_b0;
    float fg = gates_l[( 64 + c)*17 + x] + pf_g1 + pf_b1;
    float gg = gates_l[(128 + c)*17 + x] + pf_g2 + pf_b2;
    float og = gates_l[(192 + c)*17 + x] + pf_g3 + pf_b3;
    float cp = pf_cp;
    float i_ = sigm(ig + pf_wci * cp);
    float f_ = sigm(fg + pf_wcf * cp);
    float cn = f_*cp + i_*tanh_f(gg);
    float o_ = sigm(og + pf_wco * cn);
    float hn = o_*tanh_f(cn);
    h_nxt[(b*64 + c)*NN + n] = hn;
    c_st[(b*64 + c)*NN + n] = cn;
    const int ksC = c >> 5, kkC = c & 31;
    const int posF = (ksC*64 + (x | ((kkC >> 3) << 4)))*8 + (kkC & 7);
    unsigned short hh = bf16r(hn);
    hBh[posF] = hh;
    hBl[posF] = bf16r(hn - bf16f(hh));
    unsigned short ch = bf16r(cn);
    cBh[posF] = ch;
    cBl[posF] = bf16r(cn - bf16f(ch));
  }
  __syncthreads();

  // ---- phase 3: projections via MFMA (11 waves, mt 0..5 from h, 6..10 from c) ----
  float* proj_l = gates_l;              // gates fully consumed in phase 2
  {
    const int lane = lane_e;
    const int wv   = wv_e;
    if (wv < 11) {
      const s8v* Bh_ = (const s8v*)((wv < 6) ? hBh : cBh) + lane;
      const s8v* Bl_ = (const s8v*)((wv < 6) ? hBl : cBl) + lane;
      f4v acc = {0.f, 0.f, 0.f, 0.f};
      s8v bh0 = Bh_[0];
      s8v bl0 = Bl_[0];
      s8v bh1 = Bh_[64];
      s8v bl1 = Bl_[64];
      acc = __builtin_amdgcn_mfma_f32_16x16x32_bf16(pf_a0h, bh0, acc, 0, 0, 0);
      acc = __builtin_amdgcn_mfma_f32_16x16x32_bf16(pf_a0l, bh0, acc, 0, 0, 0);
      acc = __builtin_amdgcn_mfma_f32_16x16x32_bf16(pf_a0h, bl0, acc, 0, 0, 0);
      acc = __builtin_amdgcn_mfma_f32_16x16x32_bf16(pf_a1h, bh1, acc, 0, 0, 0);
      acc = __builtin_amdgcn_mfma_f32_16x16x32_bf16(pf_a1l, bh1, acc, 0, 0, 0);
      acc = __builtin_amdgcn_mfma_f32_16x16x32_bf16(pf_a1h, bl1, acc, 0, 0, 0);
      const int colx = lane & 15;
      const int rb   = (lane >> 4) * 4;
      #pragma unroll
      for (int r = 0; r < 4; r++) {
        int po = wv*16 + rb + r;
        proj_l[po*16 + colx] = acc[r] + pb_l[po];
      }
    }
  }
  __syncthreads();

  // ---- phase 4: coalesced fragment emission ----
  // Q in A-frag layout (tid 512..1023)
  if (tid >= 512) {
    int qt = tid - 512;               // 0..511
    int lane = qt >> 3, j = qt & 7;
    int g = lane >> 4, c16l = lane & 15;
    int d = ((g & 1) << 3) + j;
    float qv = proj_l[d*16 + c16l];
    unsigned short hi = bf16r(qv);
    unsigned short lo = (g < 2) ? bf16r(qv - bf16f(hi)) : (unsigned short)0;
    long base = ((long)(b*64 + mt)*64 + lane)*8 + j;
    qFh[base] = hi;
    qFl[base] = lo;
  }
  if (tid < 512) {
    int brh2 = tid >> 8;            // branch
    int lh   = (tid >> 2) & 63;     // fragment "lane-half" row
    int j2   = tid & 3;             // packs d&7 = 2*j2, 2*j2+1
    int p    = lh >> 4;             // 0,1: hi planes; 2,3: lo planes
    int x    = lh & 15;
    int d0   = ((p & 1) << 3) | (j2 << 1);
    int Koff = brh2 ? 96 : 16;
    float v0 = proj_l[(Koff + d0)*16 + x];
    float v1 = proj_l[(Koff + d0 + 1)*16 + x];
    unsigned short h0 = bf16r(v0), h1 = bf16r(v1);
    unsigned short u0, u1;
    if (p < 2) { u0 = h0; u1 = h1; }
    else       { u0 = bf16r(v0 - bf16f(h0)); u1 = bf16r(v1 - bf16f(h1)); }
    unsigned int* dst = (unsigned int*)(kF + ((b*2 + brh2)*64 + mt)*512);
    dst[lh*4 + j2] = (unsigned)u0 | ((unsigned)u1 << 16);
  }
  {
    const int ks = y;
    const int g0 = x0 >> 3;         // 0 or 2
    int ct    = tid;                // 1024 tasks: brh(2) x nt(4) x li(32) x j2(4)
    int brh2  = (ct >> 9) & 1;
    int nt    = (ct >> 7) & 3;
    int li    = (ct >> 2) & 31;
    int j2    = ct & 3;
    int lane2 = g0*16 + li;
    int cch   = nt*16 + (lane2 & 15);
    int xx    = ((li >> 4) << 3) | (j2 << 1);
    int Voff  = brh2 ? 112 : 32;
    float v0 = proj_l[(Voff + cch)*16 + xx];
    float v1 = proj_l[(Voff + cch)*16 + xx + 1];
    unsigned short u0 = bf16r(v0), u1 = bf16r(v1);
    unsigned short* basep = vFh + (((b*2 + brh2)*32 + ks)*4 + nt)*512;
    ((unsigned int*)basep)[lane2*4 + j2] = (unsigned)u0 | ((unsigned)u1 << 16);
  }
}

// ---------- K2: dual attention via MFMA + MFMA combine + gating ----------
#define RED_OFF 0        // [16 waves][16 nl][66]  = 16896
#define PS_OFF  16896    // [16 waves][16][36]     = 9216
#define SMX_OFF 26112    // [2][8][16]             = 256
#define SSM_OFF 26368    // [2][8][16]             = 256
#define INV_OFF 26624    // [2][16]                = 32
#define S_TOT   28704

__global__ __launch_bounds__(1024, 4) void k2_attn(
    int t,
    const unsigned short* __restrict__ qFh, const unsigned short* __restrict__ qFl,
    const unsigned short* __restrict__ kF,
    const unsigned short* __restrict__ vFh,
    float* __restrict__ h_nxt, float* __restrict__ c_st,
    const unsigned short* __restrict__ zAhi, const unsigned short* __restrict__ zAlo,
    const unsigned short* __restrict__ mAhi, const unsigned short* __restrict__ mAlo,
    const float* __restrict__ z_b, const float* __restrict__ m_b,
    float* __restrict__ out)
{
  __shared__ __align__(16) float S[S_TOT];
  __shared__ __align__(16) unsigned short zBh[4*512];   // zz B-frags (4 ks)
  __shared__ __align__(16) unsigned short zBl[4*512];
  __shared__ __align__(16) unsigned short cbBh[6*512];  // comb B-frags (6 ks)
  __shared__ __align__(16) unsigned short cbBl[6*512];
  float* red  = S + RED_OFF;
  float* smMax= S + SMX_OFF;
  float* smSum= S + SSM_OFF;
  float* invL = S + INV_OFF;
  float* cbOut= S + 3072;       // [192][16] aliases red (after barrier)

  const int tid = threadIdx.x;
  const int bid = blockIdx.x;
  const int xcd = bid & 7;
  const int b = xcd >> 1;
  const int tile = ((bid >> 3) << 1) | (xcd & 1);   // 0..63
  const int n0 = tile * 16;

  const int wid  = tid >> 6;
  const int lane = tid & 63;
  const int brh  = wid >> 3;      // branch
  const int w    = wid & 7;       // wave within branch
  const int g    = lane >> 4;
  const int c16  = lane & 15;

  // ---- prefetch tail-phase inputs ----
  const int pc2 = tid >> 4;       // 0..63
  const int pn2 = n0 + (tid & 15);
  float pf_cst = c_st[(b*64 + pc2)*NN + pn2];
  float pf_h   = h_nxt[(b*64 + pc2)*NN + pn2];

  // ---- Q A-frags: direct b128 loads (pre-packed by k1) ----
  s8v qh1 = *(const s8v*)(qFh + ((long)(b*64 + tile)*64 + lane)*8);
  s8v ql2 = *(const s8v*)(qFl + ((long)(b*64 + tile)*64 + lane)*8);

  // ---- scores: 8 m-tiles per wave, 2 MFMA each (B = [Kh|Kl]) ----
  f4v acc[8];
  {
    const unsigned short* kp = kF + (((b*2 + brh)*64 + w*8)*64 + lane)*8;
    #pragma unroll
    for (int i = 0; i < 8; i++) {
      s8v bf = *(const s8v*)(kp + i*512);
      f4v z4 = {0.f, 0.f, 0.f, 0.f};
      z4 = __builtin_amdgcn_mfma_f32_16x16x32_bf16(ql2, bf, z4, 0, 0, 0);
      acc[i] = __builtin_amdgcn_mfma_f32_16x16x32_bf16(qh1, bf, z4, 0, 0, 0);
    }
  }

  // ---- softmax ----
  float Mrow[4];
  #pragma unroll
  for (int r = 0; r < 4; r++) {
    float m = acc[0][r];
    #pragma unroll
    for (int i = 1; i < 8; i++) m = fmaxf(m, acc[i][r]);
    m = fmaxf(m, __shfl_xor(m, 1));
    m = fmaxf(m, __shfl_xor(m, 2));
    m = fmaxf(m, __shfl_xor(m, 4));
    m = fmaxf(m, __shfl_xor(m, 8));
    if (c16 == 0) smMax[(brh*8 + w)*16 + g*4 + r] = m;
  }
  __syncthreads();
  #pragma unroll
  for (int r = 0; r < 4; r++) {
    float m = smMax[(brh*8 + 0)*16 + g*4 + r];
    #pragma unroll
    for (int w2 = 1; w2 < 8; w2++) m = fmaxf(m, smMax[(brh*8 + w2)*16 + g*4 + r]);
    Mrow[r] = m;
  }
  float rsum[4] = {0.f, 0.f, 0.f, 0.f};
  #pragma unroll
  for (int i = 0; i < 8; i++) {
    #pragma unroll
    for (int r = 0; r < 4; r++) {
      float p = __expf(acc[i][r] - Mrow[r]);
      acc[i][r] = p;
      rsum[r] += p;
    }
  }
  #pragma unroll
  for (int r = 0; r < 4; r++) {
    float s = rsum[r];
    s += __shfl_xor(s, 1); s += __shfl_xor(s, 2);
    s += __shfl_xor(s, 4); s += __shfl_xor(s, 8);
    if (c16 == 0) smSum[(brh*8 + w)*16 + g*4 + r] = s;
  }
  __syncthreads();
  if (w == 0 && c16 == 0) {
    #pragma unroll
    for (int r = 0; r < 4; r++) {
      float s = 0.f;
      #pragma unroll
      for (int w2 = 0; w2 < 8; w2++) s += smSum[(brh*8 + w2)*16 + g*4 + r];
      invL[brh*16 + g*4 + r] = 1.0f / s;
    }
  }

  // ---- PV: per wave, 4 k-steps of 32 m; wave-local P transpose; V hi-only ----
  f4v z0 = {0.f,0.f,0.f,0.f}, z1 = z0, z2 = z0, z3 = z0;
  float* myPS = S + PS_OFF + wid*576;   // [16][36]
  #pragma unroll
  for (int ks4 = 0; ks4 < 4; ks4++) {
    #pragma unroll
    for (int i2 = 0; i2 < 2; i2++) {
      #pragma unroll
      for (int r = 0; r < 4; r++)
        myPS[(g*4 + r)*36 + i2*16 + c16] = acc[ks4*2 + i2][r];
    }
    float4 pa = *(const float4*)&myPS[c16*36 + g*8];
    float4 pb = *(const float4*)&myPS[c16*36 + g*8 + 4];
    s8v ph, pl;
    {
      unsigned short h0 = bf16r(pa.x); ph[0] = (short)h0; pl[0] = (short)bf16r(pa.x - bf16f(h0));
      unsigned short h1 = bf16r(pa.y); ph[1] = (short)h1; pl[1] = (short)bf16r(pa.y - bf16f(h1));
      unsigned short h2 = bf16r(pa.z); ph[2] = (short)h2; pl[2] = (short)bf16r(pa.z - bf16f(h2));
      unsigned short h3 = bf16r(pa.w); ph[3] = (short)h3; pl[3] = (short)bf16r(pa.w - bf16f(h3));
      unsigned short h4 = bf16r(pb.x); ph[4] = (short)h4; pl[4] = (short)bf16r(pb.x - bf16f(h4));
      unsigned short h5 = bf16r(pb.y); ph[5] = (short)h5; pl[5] = (short)bf16r(pb.y - bf16f(h5));
      unsigned short h6 = bf16r(pb.z); ph[6] = (short)h6; pl[6] = (short)bf16r(pb.z - bf16f(h6));
      unsigned short h7 = bf16r(pb.w); ph[7] = (short)h7; pl[7] = (short)bf16r(pb.w - bf16f(h7));
    }
    const int ks = w*4 + ks4;
    const unsigned short* vph = vFh + ((((b*2 + brh)*32 + ks)*4)*64 + lane)*8;
    s8v vh0 = *(const s8v*)(vph);
    z0 = __builtin_amdgcn_mfma_f32_16x16x32_bf16(ph, vh0, z0, 0,0,0);
    z0 = __builtin_amdgcn_mfma_f32_16x16x32_bf16(pl, vh0, z0, 0,0,0);
    s8v vh1 = *(const s8v*)(vph + 512);
    z1 = __builtin_amdgcn_mfma_f32_16x16x32_bf16(ph, vh1, z1, 0,0,0);
    z1 = __builtin_amdgcn_mfma_f32_16x16x32_bf16(pl, vh1, z1, 0,0,0);
    s8v vh2 = *(const s8v*)(vph + 1024);
    z2 = __builtin_amdgcn_mfma_f32_16x16x32_bf16(ph, vh2, z2, 0,0,0);
    z2 = __builtin_amdgcn_mfma_f32_16x16x32_bf16(pl, vh2, z2, 0,0,0);
    s8v vh3 = *(const s8v*)(vph + 1536);
    z3 = __builtin_amdgcn_mfma_f32_16x16x32_bf16(ph, vh3, z3, 0,0,0);
    z3 = __builtin_amdgcn_mfma_f32_16x16x32_bf16(pl, vh3, z3, 0,0,0);
  }

  // ---- write partials, reduce 8 waves, normalize -> zz B-frags ----
  {
    float* rw = red + wid*1056;
    #pragma unroll
    for (int r = 0; r < 4; r++) {
      rw[(g*4 + r)*66 +  0 + c16] = z0[r];
      rw[(g*4 + r)*66 + 16 + c16] = z1[r];
      rw[(g*4 + r)*66 + 32 + c16] = z2[r];
      rw[(g*4 + r)*66 + 48 + c16] = z3[r];
    }
  }
  __syncthreads();
  {
    const int br2 = tid >> 9;
    const int sub = tid & 511;
    const int nlr = sub >> 5;
    const int cc0 = (sub & 31) * 2;
    float iv = invL[br2*16 + nlr];
    #pragma unroll
    for (int u = 0; u < 2; u++) {
      int cc = cc0 + u;
      float s = 0.f;
      #pragma unroll
      for (int w2 = 0; w2 < 8; w2++)
        s += red[(br2*8 + w2)*1056 + nlr*66 + cc];
      float v = s * iv;
      int k = br2*64 + cc;
      int ks = k >> 5, kk = k & 31;
      int pos = (ks*64 + (nlr | ((kk >> 3) << 4)))*8 + (kk & 7);
      unsigned short h = bf16r(v);
      zBh[pos] = h;
      zBl[pos] = bf16r(v - bf16f(h));
    }
  }
  __syncthreads();

  // ---- h rows into comb B-frags + zz via MFMA (waves 0..7) ----
  {
    int k = 128 + pc2;
    int ks = k >> 5, kk = k & 31;
    int pos = (ks*64 + ((tid & 15) | ((kk >> 3) << 4)))*8 + (kk & 7);
    unsigned short h = bf16r(pf_h);
    cbBh[pos] = h;
    cbBl[pos] = bf16r(pf_h - bf16f(h));
  }
  if (wid < 8) {
    f4v za = {0.f, 0.f, 0.f, 0.f};
    const s8v* Azh = (const s8v*)zAhi + (wid*4)*64 + lane;
    const s8v* Azl = (const s8v*)zAlo + (wid*4)*64 + lane;
    const s8v* Bzh = (const s8v*)zBh + lane;
    const s8v* Bzl = (const s8v*)zBl + lane;
    #pragma unroll
    for (int ks = 0; ks < 4; ks++) {
      s8v ah = Azh[ks*64];
      s8v al = Azl[ks*64];
      s8v bh = Bzh[ks*64];
      s8v bl = Bzl[ks*64];
      za = __builtin_amdgcn_mfma_f32_16x16x32_bf16(ah, bh, za, 0, 0, 0);
      za = __builtin_amdgcn_mfma_f32_16x16x32_bf16(al, bh, za, 0, 0, 0);
      za = __builtin_amdgcn_mfma_f32_16x16x32_bf16(ah, bl, za, 0, 0, 0);
    }
    #pragma unroll
    for (int r = 0; r < 4; r++) {
      int oc = wid*16 + g*4 + r;
      float v = za[r] + z_b[oc];
      int kk = oc & 31, ks2 = oc >> 5;
      int pos = (ks2*64 + (c16 | ((kk >> 3) << 4)))*8 + (kk & 7);
      unsigned short h = bf16r(v);
      cbBh[pos] = h;
      cbBl[pos] = bf16r(v - bf16f(h));
    }
  }
  __syncthreads();

  // ---- comb via MFMA (waves 0..11) ----
  if (wid < 12) {
    f4v ca = {0.f, 0.f, 0.f, 0.f};
    const s8v* Amh = (const s8v*)mAhi + (wid*6)*64 + lane;
    const s8v* Aml = (const s8v*)mAlo + (wid*6)*64 + lane;
    const s8v* Bch = (const s8v*)cbBh + lane;
    const s8v* Bcl = (const s8v*)cbBl + lane;
    #pragma unroll
    for (int ks = 0; ks < 6; ks++) {
      s8v ah = Amh[ks*64];
      s8v al = Aml[ks*64];
      s8v bh = Bch[ks*64];
      s8v bl = Bcl[ks*64];
      ca = __builtin_amdgcn_mfma_f32_16x16x32_bf16(ah, bh, ca, 0, 0, 0);
      ca = __builtin_amdgcn_mfma_f32_16x16x32_bf16(al, bh, ca, 0, 0, 0);
      ca = __builtin_amdgcn_mfma_f32_16x16x32_bf16(ah, bl, ca, 0, 0, 0);
    }
    #pragma unroll
    for (int r = 0; r < 4; r++) {
      int oc = wid*16 + g*4 + r;
      cbOut[oc*16 + c16] = ca[r] + m_b[oc];
    }
  }
  __syncthreads();

  // ---- gating ----
  {
    const int c = pc2, nn = tid & 15;
    const int n = n0 + nn;
    float mo = cbOut[c*16 + nn];
    float mg = cbOut[(64 + c)*16 + nn];
    float mi = cbOut[(128 + c)*16 + nn];
    float mf = pf_cst;
    float mis = sigm(mi);
    float nmf = (1.0f - mis)*mf + mis*tanh_f(mg);
    float nhf = sigm(mo)*nmf;
    c_st[(b*64 + c)*NN + n] = nmf;
    h_nxt[(b*64 + c)*NN + n] = nhf;
    out[((b*64 + c)*SS + t)*NN + n] = nhf;
  }
}

extern "C" void kernel_launch(void* const* d_in, const int* in_sizes, int n_in,
                              void* d_out, int out_size, void* d_ws, size_t ws_size,
                              hipStream_t stream) {
  const float* X      = (const float*)d_in[0];
  const float* conv_w = (const float*)d_in[1];
  const float* conv_b = (const float*)d_in[2];
  const float* W_ci   = (const float*)d_in[3];
  const float* W_cf   = (const float*)d_in[4];
  const float* W_co   = (const float*)d_in[5];
  const float* qw  = (const float*)d_in[6];
  const float* qb  = (const float*)d_in[7];
  const float* kw  = (const float*)d_in[8];
  const float* kb  = (const float*)d_in[9];
  const float* k2w = (const float*)d_in[10];
  const float* k2b = (const float*)d_in[11];
  const float* vw  = (const float*)d_in[12];
  const float* vb  = (const float*)d_in[13];
  const float* v2w = (const float*)d_in[14];
  const float* v2b = (const float*)d_in[15];
  const float* z_w = (const float*)d_in[16];
  const float* z_b = (const float*)d_in[17];
  const float* m_w = (const float*)d_in[18];
  const float* m_b = (const float*)d_in[19];
  float* out = (float*)d_out;

  float* ws = (float*)d_ws;
  unsigned short* Whi  = (unsigned short*)ws;  ws += 147456;   // 294912 ushorts
  unsigned short* Wlo  = (unsigned short*)ws;  ws += 147456;
  unsigned short* zAhi = (unsigned short*)ws;  ws += 8192;     // 16384 ushorts
  unsigned short* zAlo = (unsigned short*)ws;  ws += 8192;
  unsigned short* mAhi = (unsigned short*)ws;  ws += 18432;    // 36864 ushorts
  unsigned short* mAlo = (unsigned short*)ws;  ws += 18432;
  unsigned short* pAhi = (unsigned short*)ws;  ws += 5632;     // 11264 ushorts
  unsigned short* pAlo = (unsigned short*)ws;  ws += 5632;
  float* h_A    = ws;             ws += NB*64*NN;
  float* h_B    = ws;             ws += NB*64*NN;
  float* c_st   = ws;             ws += NB*64*NN;
  unsigned short* qFh = (unsigned short*)ws;  ws += 65536;    // 131072 ushorts
  unsigned short* qFl = (unsigned short*)ws;  ws += 65536;
  unsigned short* kF  = (unsigned short*)ws;  ws += 131072;   // 4b*2br*64mt*64*8 ushorts
  unsigned short* vFh = (unsigned short*)ws;  ws += 131072;   // 4b*2br*32ks*4nt*64*8
  unsigned short* gxh = (unsigned short*)ws;  ws += NB*SS*128*NN;  // 16.8M ushorts, 33.5 MB

  hipLaunchKernelGGL(k0_prep, dim3(256), dim3(256), 0, stream,
                     conv_w, z_w, m_w, qw, kw, vw, k2w, v2w,
                     Whi, Wlo, zAhi, zAlo, mAhi, mAlo, pAhi, pAlo, h_A, c_st);
  hipLaunchKernelGGL(k0b_gx, dim3(1024), dim3(1024), 0, stream,
                     X, Whi, gxh);
  for (int t = 0; t < 16; t++) {
    const float* h_cur = (t & 1) ? h_B : h_A;
    float* h_nxt       = (t & 1) ? h_A : h_B;
    hipLaunchKernelGGL(k1_conv_lstm_proj, dim3(256), dim3(1024), 0, stream,
        t, gxh, Whi, pAhi, pAlo, conv_b, W_ci, W_cf, W_co,
        qb, kb, vb, k2b, v2b,
        h_cur, h_nxt, c_st, qFh, qFl, kF, vFh);
    hipLaunchKernelGGL(k2_attn, dim3(256), dim3(1024), 0, stream,
        t, qFh, qFl, kF, vFh, h_nxt, c_st,
        zAhi, zAlo, mAhi, mAlo, z_b, m_b, out);
  }
}

// Round 21
// 440.337 us; speedup vs baseline: 1.7485x; 1.0357x over previous
//
#include <hip/hip_runtime.h>
#include <math.h>

#define NB 4
#define SS 16
#define NN 1024        // H*W

typedef short s8v __attribute__((ext_vector_type(8)));    // 8 bf16 (4 VGPR)
typedef float f4v __attribute__((ext_vector_type(4)));    // MFMA accumulator

__device__ __forceinline__ float sigm(float x) {
  return 1.0f / (1.0f + __expf(-x));
}
__device__ __forceinline__ float tanh_f(float x) {
  float e = __expf(2.0f * x);
  return 1.0f - 2.0f / (1.0f + e);
}
__device__ __forceinline__ unsigned short bf16r(float x) {   // RNE float->bf16
  unsigned int u = __float_as_uint(x);
  u = (u + 0x7FFFu + ((u >> 16) & 1u)) >> 16;
  return (unsigned short)u;
}
__device__ __forceinline__ float bf16f(unsigned short h) {
  return __uint_as_float(((unsigned int)h) << 16);
}

// ---------- prep: weight split/pack (conv + proj + z_w + m_w A-frags) + zero states ----------
__global__ void k0_prep(const float* __restrict__ conv_w, const float* __restrict__ z_w,
                        const float* __restrict__ m_w,
                        const float* __restrict__ qw, const float* __restrict__ kw,
                        const float* __restrict__ vw, const float* __restrict__ k2w,
                        const float* __restrict__ v2w,
                        unsigned short* __restrict__ Whi, unsigned short* __restrict__ Wlo,
                        unsigned short* __restrict__ zAhi, unsigned short* __restrict__ zAlo,
                        unsigned short* __restrict__ mAhi, unsigned short* __restrict__ mAlo,
                        unsigned short* __restrict__ pAhi, unsigned short* __restrict__ pAlo,
                        float* __restrict__ h_A, float* __restrict__ c_st) {
  int stride = gridDim.x * blockDim.x;
  int i0 = blockIdx.x * blockDim.x + threadIdx.x;
  for (int i = i0; i < 256*1152; i += stride) {
    int oc = i / 1152, k = i - oc*1152;          // k = icComb*9 + ky*3 + kx
    float v = conv_w[i];
    unsigned short hi = bf16r(v);
    unsigned short lo = bf16r(v - bf16f(hi));
    int mt = oc >> 4, i16 = oc & 15;
    int ks = k >> 5, kk = k & 31;
    int lane = i16 | ((kk >> 3) << 4);
    int pos = ((mt*36 + ks)*64 + lane)*8 + (kk & 7);
    Whi[pos] = hi;
    Wlo[pos] = lo;
  }
  for (int i = i0; i < 128*128; i += stride) {   // z_w A-frags: 8 mt x 4 ks
    int oc = i >> 7, k = i & 127;
    float v = z_w[i];
    unsigned short hi = bf16r(v);
    unsigned short lo = bf16r(v - bf16f(hi));
    int mt = oc >> 4, i16 = oc & 15;
    int ks = k >> 5, kk = k & 31;
    int lane = i16 | ((kk >> 3) << 4);
    int pos = ((mt*4 + ks)*64 + lane)*8 + (kk & 7);
    zAhi[pos] = hi;
    zAlo[pos] = lo;
  }
  for (int i = i0; i < 192*192; i += stride) {   // m_w A-frags: 12 mt x 6 ks
    int oc = i / 192, k = i - oc*192;
    float v = m_w[i];
    unsigned short hi = bf16r(v);
    unsigned short lo = bf16r(v - bf16f(hi));
    int mt = oc >> 4, i16 = oc & 15;
    int ks = k >> 5, kk = k & 31;
    int lane = i16 | ((kk >> 3) << 4);
    int pos = ((mt*6 + ks)*64 + lane)*8 + (kk & 7);
    mAhi[pos] = hi;
    mAlo[pos] = lo;
  }
  for (int i = i0; i < 176*64; i += stride) {    // proj A-frags: 11 mt x 2 ks
    int po = i >> 6, c = i & 63;
    float v;
    if (po < 16)       v = qw[po*64 + c];
    else if (po < 32)  v = kw[(po-16)*64 + c];
    else if (po < 96)  v = vw[(po-32)*64 + c];
    else if (po < 112) v = k2w[(po-96)*64 + c];
    else               v = v2w[(po-112)*64 + c];
    unsigned short hi = bf16r(v);
    unsigned short lo = bf16r(v - bf16f(hi));
    int mt = po >> 4, i16 = po & 15;
    int ks = c >> 5, kk = c & 31;
    int lane = i16 | ((kk >> 3) << 4);
    int pos = ((mt*2 + ks)*64 + lane)*8 + (kk & 7);
    pAhi[pos] = hi;
    pAlo[pos] = lo;
  }
  for (int i = i0; i < NB*64*NN; i += stride) { h_A[i] = 0.0f; c_st[i] = 0.0f; }
}

// ---------- K0b v7: conv_x, N=64/block, hi-only, row-owned im2col, bf16 gx ----------
__global__ __launch_bounds__(1024, 2) void k0b_gx(
    const float* __restrict__ X,
    const unsigned short* __restrict__ Whi,
    unsigned short* __restrict__ gxh)
{
  __shared__ __align__(16) unsigned short Xhi_l[18*4*64*8];   // [ks][nt 0..3][lane][8] = 73728 B

  const int tid = threadIdx.x;
  const int bid = blockIdx.x;       // b*256 + t*16 + y2
  const int y2 = bid & 15;
  const int t  = (bid >> 4) & 15;
  const int b  = bid >> 8;
  const int y0 = y2 * 2;

  // ---- im2col: thread owns (row = ic*4+dy, quarter); constant bases per combo ----
  {
    const int row = tid >> 2;          // 0..255
    const int qtr = tid & 3;           // 0..3
    const int ic  = row >> 2;
    const int dy  = row & 3;           // halo row; gy = y0 + dy - 1
    const int gy  = y0 + dy - 1;
    const bool rowOk = ((unsigned)gy < 32u);
    const float* Xrow = X + (((b*64 + ic)*SS + t)*NN) + gy*32;
    int Kc[2][3];
    bool rv[2];
    #pragma unroll
    for (int r = 0; r < 2; r++) {
      int dyl = dy - r;
      rv[r] = ((unsigned)dyl < 3u);
      #pragma unroll
      for (int dx = 0; dx < 3; dx++) {
        int k = ic*9 + dyl*3 + dx;
        int ks = k >> 5, kk = k & 31;
        Kc[r][dx] = ks*2048 + ((kk >> 3) << 4)*8 + (kk & 7) + r*1024;
      }
    }
    const int c0 = qtr*9;
    const int c1 = (qtr == 3) ? 34 : c0 + 9;
    for (int col = c0; col < c1; col++) {
      int gxc = col - 1;
      float v = (rowOk && (unsigned)gxc < 32u) ? Xrow[gxc] : 0.0f;
      unsigned short hi = bf16r(v);
      #pragma unroll
      for (int r = 0; r < 2; r++) {
        if (rv[r]) {
          #pragma unroll
          for (int dx = 0; dx < 3; dx++) {
            int x = col - dx;
            if ((unsigned)x < 32u)
              Xhi_l[Kc[r][dx] + (x >> 4)*512 + (x & 15)*8] = hi;
          }
        }
      }
    }
  }
  __syncthreads();

  const int lane = tid & 63;
  const int mt = tid >> 6;          // 0..15
  f4v acc[4];
  #pragma unroll
  for (int nt = 0; nt < 4; nt++) acc[nt] = (f4v){0.f, 0.f, 0.f, 0.f};
  const s8v* Ah = (const s8v*)Whi + (mt*36)*64 + lane;
  const s8v* Bh = (const s8v*)Xhi_l + lane;
  #pragma unroll 3
  for (int ks = 0; ks < 18; ks++) {
    s8v ah = Ah[ks*64];
    #pragma unroll
    for (int nt = 0; nt < 4; nt++) {
      s8v bh = Bh[(ks*4 + nt)*64];
      acc[nt] = __builtin_amdgcn_mfma_f32_16x16x32_bf16(ah, bh, acc[nt], 0, 0, 0);
    }
  }
  const int c16 = lane & 15;
  const int rb  = (lane >> 4) * 4;
  unsigned short* gout = gxh + (((long)b*SS + t)*256)*NN;
  #pragma unroll
  for (int nt = 0; nt < 4; nt++) {
    #pragma unroll
    for (int r4 = 0; r4 < 4; r4++) {
      int oc = mt*16 + rb + r4;
      int n = nt*16 + c16;
      int py = y0 + (n >> 5);
      int px2 = n & 31;
      gout[oc*NN + py*32 + px2] = bf16r(acc[nt][r4]);
    }
  }
}

// ---------- K1: conv_h (W hi, h hi) + LSTM(+gx) + MFMA projections (1024 threads) ----------
__global__ __launch_bounds__(1024, 2) void k1_conv_lstm_proj(
    int t,
    const unsigned short* __restrict__ gxh,
    const unsigned short* __restrict__ Whi,
    const unsigned short* __restrict__ pAhi, const unsigned short* __restrict__ pAlo,
    const float* __restrict__ conv_b,
    const float* __restrict__ W_ci, const float* __restrict__ W_cf, const float* __restrict__ W_co,
    const float* __restrict__ qb, const float* __restrict__ kb,
    const float* __restrict__ vb, const float* __restrict__ k2b,
    const float* __restrict__ v2b,
    const float* __restrict__ h_cur, float* __restrict__ h_nxt,
    float* __restrict__ c_st,
    unsigned short* __restrict__ qFh, unsigned short* __restrict__ qFl,
    unsigned short* __restrict__ kF,
    unsigned short* __restrict__ vFh)
{
  __shared__ __align__(16) unsigned short Ihi_l[18*64*8];      // h-only im2col (hi plane)
  __shared__ __align__(16) float gates_l[256*17];              // [oc][x]; later proj_l[176][16]
  __shared__ __align__(16) unsigned short hBh[2*64*8];         // h in B-frag layout (hi/lo)
  __shared__ __align__(16) unsigned short hBl[2*64*8];
  __shared__ __align__(16) unsigned short cBh[2*64*8];         // c in B-frag layout
  __shared__ __align__(16) unsigned short cBl[2*64*8];
  __shared__ __align__(16) float pb_l[176];

  const int tid = threadIdx.x;
  const int bid = blockIdx.x;
  const int b  = bid >> 6;
  const int y  = (bid >> 1) & 31;
  const int x0 = (bid & 1) * 16;
  const int mt = bid & 63;          // this block's 16-col m-tile (= n>>4)
  const int n0 = y*32 + x0;

  // ---- prefetch LSTM inputs + projection A-frags into registers ----
  const int px = tid & 15;
  const int pc = tid >> 4;          // 0..63
  const int pn = n0 + px;
  const unsigned short* gxp = gxh + (((long)b*SS + t)*256)*NN + pn;
  float pf_g0 = bf16f(gxp[(pc      )*NN]);
  float pf_g1 = bf16f(gxp[( 64 + pc)*NN]);
  float pf_g2 = bf16f(gxp[(128 + pc)*NN]);
  float pf_g3 = bf16f(gxp[(192 + pc)*NN]);
  float pf_cp  = c_st[(b*64 + pc)*NN + pn];
  float pf_wci = W_ci[pc*NN + pn];
  float pf_wcf = W_cf[pc*NN + pn];
  float pf_wco = W_co[pc*NN + pn];
  float pf_b0 = conv_b[pc];
  float pf_b1 = conv_b[ 64 + pc];
  float pf_b2 = conv_b[128 + pc];
  float pf_b3 = conv_b[192 + pc];
  const int lane_e = tid & 63;
  const int wv_e   = tid >> 6;
  const int wvc    = (wv_e < 11) ? wv_e : 0;
  s8v pf_a0h = *(const s8v*)(pAhi + ((wvc*2 + 0)*64 + lane_e)*8);
  s8v pf_a0l = *(const s8v*)(pAlo + ((wvc*2 + 0)*64 + lane_e)*8);
  s8v pf_a1h = *(const s8v*)(pAhi + ((wvc*2 + 1)*64 + lane_e)*8);
  s8v pf_a1l = *(const s8v*)(pAlo + ((wvc*2 + 1)*64 + lane_e)*8);

  // ---- phase 0: h-only im2col (hi plane) -> B-frags  +  stage proj biases ----
  for (int idx = tid; idx < 64*3*18; idx += 1024) {
    int col = idx % 18;
    int rest = idx / 18;
    int dy = rest % 3;
    int ic = rest / 3;                    // h channel 0..63
    int gy = y + dy - 1;
    int gxc = x0 + col - 1;
    float v = 0.0f;
    if ((unsigned)gy < 32u && (unsigned)gxc < 32u)
      v = h_cur[((b*64 + ic)*NN) + gy*32 + gxc];
    unsigned short hi = bf16r(v);
    int kbase = ic*9 + dy*3;              // local k in [0,576)
    #pragma unroll
    for (int dx = 0; dx < 3; dx++) {
      int n = col - dx;
      if ((unsigned)n < 16u) {
        int k = kbase + dx;
        int ks = k >> 5, kk = k & 31;
        int pos = (ks*64 + (n | ((kk >> 3) << 4)))*8 + (kk & 7);
        Ihi_l[pos] = hi;
      }
    }
  }
  if (tid < 176) {
    int po = tid;
    float v;
    if (po < 16)       v = qb[po];
    else if (po < 32)  v = kb[po-16];
    else if (po < 96)  v = vb[po-32];
    else if (po < 112) v = k2b[po-96];
    else               v = v2b[po-112];
    pb_l[po] = v;
  }
  __syncthreads();

  // ---- phase 1: conv_h MFMA: 16 waves, 1 m-tile each; W hi-only, h hi-only ----
  {
    const int lane = tid & 63;
    const int wv   = tid >> 6;        // 0..15 = m-tile
    f4v acc = {0.f, 0.f, 0.f, 0.f};
    const s8v* Ah = (const s8v*)Whi + (wv*36 + 18)*64 + lane;
    const s8v* Bh = (const s8v*)Ihi_l + lane;
    #pragma unroll 6
    for (int ks = 0; ks < 18; ks++) {
      s8v ah = Ah[ks*64];
      s8v bh = Bh[ks*64];
      acc = __builtin_amdgcn_mfma_f32_16x16x32_bf16(ah, bh, acc, 0, 0, 0);
    }
    const int colx = lane & 15;
    const int rb   = (lane >> 4) * 4;
    #pragma unroll
    for (int r = 0; r < 4; r++)
      gates_l[(wv*16 + rb + r)*17 + colx] = acc[r];
  }
  __syncthreads();

  // ---- phase 2: LSTM elementwise; write h/c into B-frag layout ----
  {
    const int x = px;
    const int c = pc;
    const int n = pn;
    float ig = gates_l[(c      )*17 + x] + pf_g0 + pf_b0;
    float fg = gates_l[( 64 + c)*17 + x] + pf_g1 + pf_b1;
    float gg = gates_l[(128 + c)*17 + x] + pf_g2 + pf_b2;
    float og = gates_l[(192 + c)*17 + x] + pf_g3 + pf_b3;
    float cp = pf_cp;
    float i_ = sigm(ig + pf_wci * cp);
    float f_ = sigm(fg + pf_wcf * cp);
    float cn = f_*cp + i_*tanh_f(gg);
    float o_ = sigm(og + pf_wco * cn);
    float hn = o_*tanh_f(cn);
    h_nxt[(b*64 + c)*NN + n] = hn;
    c_st[(b*64 + c)*NN + n] = cn;
    const int ksC = c >> 5, kkC = c & 31;
    const int posF = (ksC*64 + (x | ((kkC >> 3) << 4)))*8 + (kkC & 7);
    unsigned short hh = bf16r(hn);
    hBh[posF] = hh;
    hBl[posF] = bf16r(hn - bf16f(hh));
    unsigned short ch = bf16r(cn);
    cBh[posF] = ch;
    cBl[posF] = bf16r(cn - bf16f(ch));
  }
  __syncthreads();

  // ---- phase 3: projections via MFMA (11 waves, mt 0..5 from h, 6..10 from c) ----
  float* proj_l = gates_l;              // gates fully consumed in phase 2
  {
    const int lane = lane_e;
    const int wv   = wv_e;
    if (wv < 11) {
      const s8v* Bh_ = (const s8v*)((wv < 6) ? hBh : cBh) + lane;
      const s8v* Bl_ = (const s8v*)((wv < 6) ? hBl : cBl) + lane;
      f4v acc = {0.f, 0.f, 0.f, 0.f};
      s8v bh0 = Bh_[0];
      s8v bl0 = Bl_[0];
      s8v bh1 = Bh_[64];
      s8v bl1 = Bl_[64];
      acc = __builtin_amdgcn_mfma_f32_16x16x32_bf16(pf_a0h, bh0, acc, 0, 0, 0);
      acc = __builtin_amdgcn_mfma_f32_16x16x32_bf16(pf_a0l, bh0, acc, 0, 0, 0);
      acc = __builtin_amdgcn_mfma_f32_16x16x32_bf16(pf_a0h, bl0, acc, 0, 0, 0);
      acc = __builtin_amdgcn_mfma_f32_16x16x32_bf16(pf_a1h, bh1, acc, 0, 0, 0);
      acc = __builtin_amdgcn_mfma_f32_16x16x32_bf16(pf_a1l, bh1, acc, 0, 0, 0);
      acc = __builtin_amdgcn_mfma_f32_16x16x32_bf16(pf_a1h, bl1, acc, 0, 0, 0);
      const int colx = lane & 15;
      const int rb   = (lane >> 4) * 4;
      #pragma unroll
      for (int r = 0; r < 4; r++) {
        int po = wv*16 + rb + r;
        proj_l[po*16 + colx] = acc[r] + pb_l[po];
      }
    }
  }
  __syncthreads();

  // ---- phase 4: coalesced fragment emission ----
  // Q in A-frag layout (tid 512..1023)
  if (tid >= 512) {
    int qt = tid - 512;               // 0..511
    int lane = qt >> 3, j = qt & 7;
    int g = lane >> 4, c16l = lane & 15;
    int d = ((g & 1) << 3) + j;
    float qv = proj_l[d*16 + c16l];
    unsigned short hi = bf16r(qv);
    unsigned short lo = (g < 2) ? bf16r(qv - bf16f(hi)) : (unsigned short)0;
    long base = ((long)(b*64 + mt)*64 + lane)*8 + j;
    qFh[base] = hi;
    qFl[base] = lo;
  }
  if (tid < 512) {
    int brh2 = tid >> 8;            // branch
    int lh   = (tid >> 2) & 63;     // fragment "lane-half" row
    int j2   = tid & 3;             // packs d&7 = 2*j2, 2*j2+1
    int p    = lh >> 4;             // 0,1: hi planes; 2,3: lo planes
    int x    = lh & 15;
    int d0   = ((p & 1) << 3) | (j2 << 1);
    int Koff = brh2 ? 96 : 16;
    float v0 = proj_l[(Koff + d0)*16 + x];
    float v1 = proj_l[(Koff + d0 + 1)*16 + x];
    unsigned short h0 = bf16r(v0), h1 = bf16r(v1);
    unsigned short u0, u1;
    if (p < 2) { u0 = h0; u1 = h1; }
    else       { u0 = bf16r(v0 - bf16f(h0)); u1 = bf16r(v1 - bf16f(h1)); }
    unsigned int* dst = (unsigned int*)(kF + ((b*2 + brh2)*64 + mt)*512);
    dst[lh*4 + j2] = (unsigned)u0 | ((unsigned)u1 << 16);
  }
  {
    const int ks = y;
    const int g0 = x0 >> 3;         // 0 or 2
    int ct    = tid;                // 1024 tasks: brh(2) x nt(4) x li(32) x j2(4)
    int brh2  = (ct >> 9) & 1;
    int nt    = (ct >> 7) & 3;
    int li    = (ct >> 2) & 31;
    int j2    = ct & 3;
    int lane2 = g0*16 + li;
    int cch   = nt*16 + (lane2 & 15);
    int xx    = ((li >> 4) << 3) | (j2 << 1);
    int Voff  = brh2 ? 112 : 32;
    float v0 = proj_l[(Voff + cch)*16 + xx];
    float v1 = proj_l[(Voff + cch)*16 + xx + 1];
    unsigned short u0 = bf16r(v0), u1 = bf16r(v1);
    unsigned short* basep = vFh + (((b*2 + brh2)*32 + ks)*4 + nt)*512;
    ((unsigned int*)basep)[lane2*4 + j2] = (unsigned)u0 | ((unsigned)u1 << 16);
  }
}

// ---------- K2: dual attention via MFMA + MFMA combine + gating ----------
#define RED_OFF 0        // [16 waves][16 nl][66]  = 16896
#define PS_OFF  16896    // [16 waves][16][36]     = 9216
#define SMX_OFF 26112    // [2][8][16]             = 256
#define SSM_OFF 26368    // [2][8][16]             = 256
#define INV_OFF 26624    // [2][16]                = 32
#define S_TOT   28704

__global__ __launch_bounds__(1024, 4) void k2_attn(
    int t,
    const unsigned short* __restrict__ qFh, const unsigned short* __restrict__ qFl,
    const unsigned short* __restrict__ kF,
    const unsigned short* __restrict__ vFh,
    float* __restrict__ h_nxt, float* __restrict__ c_st,
    const unsigned short* __restrict__ zAhi, const unsigned short* __restrict__ zAlo,
    const unsigned short* __restrict__ mAhi, const unsigned short* __restrict__ mAlo,
    const float* __restrict__ z_b, const float* __restrict__ m_b,
    float* __restrict__ out)
{
  __shared__ __align__(16) float S[S_TOT];
  __shared__ __align__(16) unsigned short zBh[4*512];   // zz B-frags (4 ks)
  __shared__ __align__(16) unsigned short zBl[4*512];
  __shared__ __align__(16) unsigned short cbBh[6*512];  // comb B-frags (6 ks)
  __shared__ __align__(16) unsigned short cbBl[6*512];
  float* red  = S + RED_OFF;
  float* smMax= S + SMX_OFF;
  float* smSum= S + SSM_OFF;
  float* invL = S + INV_OFF;
  float* cbOut= S + 3072;       // [192][16] aliases red (after barrier)

  const int tid = threadIdx.x;
  const int bid = blockIdx.x;
  const int xcd = bid & 7;
  const int b = xcd >> 1;
  const int tile = ((bid >> 3) << 1) | (xcd & 1);   // 0..63
  const int n0 = tile * 16;

  const int wid  = tid >> 6;
  const int lane = tid & 63;
  const int brh  = wid >> 3;      // branch
  const int w    = wid & 7;       // wave within branch
  const int g    = lane >> 4;
  const int c16  = lane & 15;

  // ---- prefetch tail-phase inputs ----
  const int pc2 = tid >> 4;       // 0..63
  const int pn2 = n0 + (tid & 15);
  float pf_cst = c_st[(b*64 + pc2)*NN + pn2];
  float pf_h   = h_nxt[(b*64 + pc2)*NN + pn2];

  // ---- Q A-frags: direct b128 loads (pre-packed by k1) ----
  s8v qh1 = *(const s8v*)(qFh + ((long)(b*64 + tile)*64 + lane)*8);
  s8v ql2 = *(const s8v*)(qFl + ((long)(b*64 + tile)*64 + lane)*8);

  // ---- scores: 8 m-tiles per wave, 2 MFMA each (B = [Kh|Kl]) ----
  f4v acc[8];
  {
    const unsigned short* kp = kF + (((b*2 + brh)*64 + w*8)*64 + lane)*8;
    #pragma unroll
    for (int i = 0; i < 8; i++) {
      s8v bf = *(const s8v*)(kp + i*512);
      f4v z4 = {0.f, 0.f, 0.f, 0.f};
      z4 = __builtin_amdgcn_mfma_f32_16x16x32_bf16(ql2, bf, z4, 0, 0, 0);
      acc[i] = __builtin_amdgcn_mfma_f32_16x16x32_bf16(qh1, bf, z4, 0, 0, 0);
    }
  }

  // ---- softmax ----
  float Mrow[4];
  #pragma unroll
  for (int r = 0; r < 4; r++) {
    float m = acc[0][r];
    #pragma unroll
    for (int i = 1; i < 8; i++) m = fmaxf(m, acc[i][r]);
    m = fmaxf(m, __shfl_xor(m, 1));
    m = fmaxf(m, __shfl_xor(m, 2));
    m = fmaxf(m, __shfl_xor(m, 4));
    m = fmaxf(m, __shfl_xor(m, 8));
    if (c16 == 0) smMax[(brh*8 + w)*16 + g*4 + r] = m;
  }
  __syncthreads();
  #pragma unroll
  for (int r = 0; r < 4; r++) {
    float m = smMax[(brh*8 + 0)*16 + g*4 + r];
    #pragma unroll
    for (int w2 = 1; w2 < 8; w2++) m = fmaxf(m, smMax[(brh*8 + w2)*16 + g*4 + r]);
    Mrow[r] = m;
  }
  float rsum[4] = {0.f, 0.f, 0.f, 0.f};
  #pragma unroll
  for (int i = 0; i < 8; i++) {
    #pragma unroll
    for (int r = 0; r < 4; r++) {
      float p = __expf(acc[i][r] - Mrow[r]);
      acc[i][r] = p;
      rsum[r] += p;
    }
  }
  #pragma unroll
  for (int r = 0; r < 4; r++) {
    float s = rsum[r];
    s += __shfl_xor(s, 1); s += __shfl_xor(s, 2);
    s += __shfl_xor(s, 4); s += __shfl_xor(s, 8);
    if (c16 == 0) smSum[(brh*8 + w)*16 + g*4 + r] = s;
  }
  __syncthreads();
  if (w == 0 && c16 == 0) {
    #pragma unroll
    for (int r = 0; r < 4; r++) {
      float s = 0.f;
      #pragma unroll
      for (int w2 = 0; w2 < 8; w2++) s += smSum[(brh*8 + w2)*16 + g*4 + r];
      invL[brh*16 + g*4 + r] = 1.0f / s;
    }
  }

  // ---- PV: per wave, 4 k-steps of 32 m; wave-local P transpose; V hi-only ----
  f4v z0 = {0.f,0.f,0.f,0.f}, z1 = z0, z2 = z0, z3 = z0;
  float* myPS = S + PS_OFF + wid*576;   // [16][36]
  #pragma unroll
  for (int ks4 = 0; ks4 < 4; ks4++) {
    #pragma unroll
    for (int i2 = 0; i2 < 2; i2++) {
      #pragma unroll
      for (int r = 0; r < 4; r++)
        myPS[(g*4 + r)*36 + i2*16 + c16] = acc[ks4*2 + i2][r];
    }
    float4 pa = *(const float4*)&myPS[c16*36 + g*8];
    float4 pb = *(const float4*)&myPS[c16*36 + g*8 + 4];
    s8v ph, pl;
    {
      unsigned short h0 = bf16r(pa.x); ph[0] = (short)h0; pl[0] = (short)bf16r(pa.x - bf16f(h0));
      unsigned short h1 = bf16r(pa.y); ph[1] = (short)h1; pl[1] = (short)bf16r(pa.y - bf16f(h1));
      unsigned short h2 = bf16r(pa.z); ph[2] = (short)h2; pl[2] = (short)bf16r(pa.z - bf16f(h2));
      unsigned short h3 = bf16r(pa.w); ph[3] = (short)h3; pl[3] = (short)bf16r(pa.w - bf16f(h3));
      unsigned short h4 = bf16r(pb.x); ph[4] = (short)h4; pl[4] = (short)bf16r(pb.x - bf16f(h4));
      unsigned short h5 = bf16r(pb.y); ph[5] = (short)h5; pl[5] = (short)bf16r(pb.y - bf16f(h5));
      unsigned short h6 = bf16r(pb.z); ph[6] = (short)h6; pl[6] = (short)bf16r(pb.z - bf16f(h6));
      unsigned short h7 = bf16r(pb.w); ph[7] = (short)h7; pl[7] = (short)bf16r(pb.w - bf16f(h7));
    }
    const int ks = w*4 + ks4;
    const unsigned short* vph = vFh + ((((b*2 + brh)*32 + ks)*4)*64 + lane)*8;
    s8v vh0 = *(const s8v*)(vph);
    z0 = __builtin_amdgcn_mfma_f32_16x16x32_bf16(ph, vh0, z0, 0,0,0);
    z0 = __builtin_amdgcn_mfma_f32_16x16x32_bf16(pl, vh0, z0, 0,0,0);
    s8v vh1 = *(const s8v*)(vph + 512);
    z1 = __builtin_amdgcn_mfma_f32_16x16x32_bf16(ph, vh1, z1, 0,0,0);
    z1 = __builtin_amdgcn_mfma_f32_16x16x32_bf16(pl, vh1, z1, 0,0,0);
    s8v vh2 = *(const s8v*)(vph + 1024);
    z2 = __builtin_amdgcn_mfma_f32_16x16x32_bf16(ph, vh2, z2, 0,0,0);
    z2 = __builtin_amdgcn_mfma_f32_16x16x32_bf16(pl, vh2, z2, 0,0,0);
    s8v vh3 = *(const s8v*)(vph + 1536);
    z3 = __builtin_amdgcn_mfma_f32_16x16x32_bf16(ph, vh3, z3, 0,0,0);
    z3 = __builtin_amdgcn_mfma_f32_16x16x32_bf16(pl, vh3, z3, 0,0,0);
  }

  // ---- write partials, reduce 8 waves, normalize -> zz B-frags ----
  {
    float* rw = red + wid*1056;
    #pragma unroll
    for (int r = 0; r < 4; r++) {
      rw[(g*4 + r)*66 +  0 + c16] = z0[r];
      rw[(g*4 + r)*66 + 16 + c16] = z1[r];
      rw[(g*4 + r)*66 + 32 + c16] = z2[r];
      rw[(g*4 + r)*66 + 48 + c16] = z3[r];
    }
  }
  __syncthreads();
  {
    const int br2 = tid >> 9;
    const int sub = tid & 511;
    const int nlr = sub >> 5;
    const int cc0 = (sub & 31) * 2;
    float iv = invL[br2*16 + nlr];
    #pragma unroll
    for (int u = 0; u < 2; u++) {
      int cc = cc0 + u;
      float s = 0.f;
      #pragma unroll
      for (int w2 = 0; w2 < 8; w2++)
        s += red[(br2*8 + w2)*1056 + nlr*66 + cc];
      float v = s * iv;
      int k = br2*64 + cc;
      int ks = k >> 5, kk = k & 31;
      int pos = (ks*64 + (nlr | ((kk >> 3) << 4)))*8 + (kk & 7);
      unsigned short h = bf16r(v);
      zBh[pos] = h;
      zBl[pos] = bf16r(v - bf16f(h));
    }
  }
  __syncthreads();

  // ---- h rows into comb B-frags + zz via MFMA (waves 0..7) ----
  {
    int k = 128 + pc2;
    int ks = k >> 5, kk = k & 31;
    int pos = (ks*64 + ((tid & 15) | ((kk >> 3) << 4)))*8 + (kk & 7);
    unsigned short h = bf16r(pf_h);
    cbBh[pos] = h;
    cbBl[pos] = bf16r(pf_h - bf16f(h));
  }
  if (wid < 8) {
    f4v za = {0.f, 0.f, 0.f, 0.f};
    const s8v* Azh = (const s8v*)zAhi + (wid*4)*64 + lane;
    const s8v* Azl = (const s8v*)zAlo + (wid*4)*64 + lane;
    const s8v* Bzh = (const s8v*)zBh + lane;
    const s8v* Bzl = (const s8v*)zBl + lane;
    #pragma unroll
    for (int ks = 0; ks < 4; ks++) {
      s8v ah = Azh[ks*64];
      s8v al = Azl[ks*64];
      s8v bh = Bzh[ks*64];
      s8v bl = Bzl[ks*64];
      za = __builtin_amdgcn_mfma_f32_16x16x32_bf16(ah, bh, za, 0, 0, 0);
      za = __builtin_amdgcn_mfma_f32_16x16x32_bf16(al, bh, za, 0, 0, 0);
      za = __builtin_amdgcn_mfma_f32_16x16x32_bf16(ah, bl, za, 0, 0, 0);
    }
    #pragma unroll
    for (int r = 0; r < 4; r++) {
      int oc = wid*16 + g*4 + r;
      float v = za[r] + z_b[oc];
      int kk = oc & 31, ks2 = oc >> 5;
      int pos = (ks2*64 + (c16 | ((kk >> 3) << 4)))*8 + (kk & 7);
      unsigned short h = bf16r(v);
      cbBh[pos] = h;
      cbBl[pos] = bf16r(v - bf16f(h));
    }
  }
  __syncthreads();

  // ---- comb via MFMA (waves 0..11) ----
  if (wid < 12) {
    f4v ca = {0.f, 0.f, 0.f, 0.f};
    const s8v* Amh = (const s8v*)mAhi + (wid*6)*64 + lane;
    const s8v* Aml = (const s8v*)mAlo + (wid*6)*64 + lane;
    const s8v* Bch = (const s8v*)cbBh + lane;
    const s8v* Bcl = (const s8v*)cbBl + lane;
    #pragma unroll
    for (int ks = 0; ks < 6; ks++) {
      s8v ah = Amh[ks*64];
      s8v al = Aml[ks*64];
      s8v bh = Bch[ks*64];
      s8v bl = Bcl[ks*64];
      ca = __builtin_amdgcn_mfma_f32_16x16x32_bf16(ah, bh, ca, 0, 0, 0);
      ca = __builtin_amdgcn_mfma_f32_16x16x32_bf16(al, bh, ca, 0, 0, 0);
      ca = __builtin_amdgcn_mfma_f32_16x16x32_bf16(ah, bl, ca, 0, 0, 0);
    }
    #pragma unroll
    for (int r = 0; r < 4; r++) {
      int oc = wid*16 + g*4 + r;
      cbOut[oc*16 + c16] = ca[r] + m_b[oc];
    }
  }
  __syncthreads();

  // ---- gating ----
  {
    const int c = pc2, nn = tid & 15;
    const int n = n0 + nn;
    float mo = cbOut[c*16 + nn];
    float mg = cbOut[(64 + c)*16 + nn];
    float mi = cbOut[(128 + c)*16 + nn];
    float mf = pf_cst;
    float mis = sigm(mi);
    float nmf = (1.0f - mis)*mf + mis*tanh_f(mg);
    float nhf = sigm(mo)*nmf;
    c_st[(b*64 + c)*NN + n] = nmf;
    h_nxt[(b*64 + c)*NN + n] = nhf;
    out[((b*64 + c)*SS + t)*NN + n] = nhf;
  }
}

extern "C" void kernel_launch(void* const* d_in, const int* in_sizes, int n_in,
                              void* d_out, int out_size, void* d_ws, size_t ws_size,
                              hipStream_t stream) {
  const float* X      = (const float*)d_in[0];
  const float* conv_w = (const float*)d_in[1];
  const float* conv_b = (const float*)d_in[2];
  const float* W_ci   = (const float*)d_in[3];
  const float* W_cf   = (const float*)d_in[4];
  const float* W_co   = (const float*)d_in[5];
  const float* qw  = (const float*)d_in[6];
  const float* qb  = (const float*)d_in[7];
  const float* kw  = (const float*)d_in[8];
  const float* kb  = (const float*)d_in[9];
  const float* k2w = (const float*)d_in[10];
  const float* k2b = (const float*)d_in[11];
  const float* vw  = (const float*)d_in[12];
  const float* vb  = (const float*)d_in[13];
  const float* v2w = (const float*)d_in[14];
  const float* v2b = (const float*)d_in[15];
  const float* z_w = (const float*)d_in[16];
  const float* z_b = (const float*)d_in[17];
  const float* m_w = (const float*)d_in[18];
  const float* m_b = (const float*)d_in[19];
  float* out = (float*)d_out;

  float* ws = (float*)d_ws;
  unsigned short* Whi  = (unsigned short*)ws;  ws += 147456;   // 294912 ushorts
  unsigned short* Wlo  = (unsigned short*)ws;  ws += 147456;
  unsigned short* zAhi = (unsigned short*)ws;  ws += 8192;     // 16384 ushorts
  unsigned short* zAlo = (unsigned short*)ws;  ws += 8192;
  unsigned short* mAhi = (unsigned short*)ws;  ws += 18432;    // 36864 ushorts
  unsigned short* mAlo = (unsigned short*)ws;  ws += 18432;
  unsigned short* pAhi = (unsigned short*)ws;  ws += 5632;     // 11264 ushorts
  unsigned short* pAlo = (unsigned short*)ws;  ws += 5632;
  float* h_A    = ws;             ws += NB*64*NN;
  float* h_B    = ws;             ws += NB*64*NN;
  float* c_st   = ws;             ws += NB*64*NN;
  unsigned short* qFh = (unsigned short*)ws;  ws += 65536;    // 131072 ushorts
  unsigned short* qFl = (unsigned short*)ws;  ws += 65536;
  unsigned short* kF  = (unsigned short*)ws;  ws += 131072;   // 4b*2br*64mt*64*8 ushorts
  unsigned short* vFh = (unsigned short*)ws;  ws += 131072;   // 4b*2br*32ks*4nt*64*8
  unsigned short* gxh = (unsigned short*)ws;  ws += NB*SS*128*NN;  // 16.8M ushorts, 33.5 MB

  hipLaunchKernelGGL(k0_prep, dim3(256), dim3(256), 0, stream,
                     conv_w, z_w, m_w, qw, kw, vw, k2w, v2w,
                     Whi, Wlo, zAhi, zAlo, mAhi, mAlo, pAhi, pAlo, h_A, c_st);
  hipLaunchKernelGGL(k0b_gx, dim3(1024), dim3(1024), 0, stream,
                     X, Whi, gxh);
  for (int t = 0; t < 16; t++) {
    const float* h_cur = (t & 1) ? h_B : h_A;
    float* h_nxt       = (t & 1) ? h_A : h_B;
    hipLaunchKernelGGL(k1_conv_lstm_proj, dim3(256), dim3(1024), 0, stream,
        t, gxh, Whi, pAhi, pAlo, conv_b, W_ci, W_cf, W_co,
        qb, kb, vb, k2b, v2b,
        h_cur, h_nxt, c_st, qFh, qFl, kF, vFh);
    hipLaunchKernelGGL(k2_attn, dim3(256), dim3(1024), 0, stream,
        t, qFh, qFl, kF, vFh, h_nxt, c_st,
        zAhi, zAlo, mAhi, mAlo, z_b, m_b, out);
  }
}

// Round 22
// 428.937 us; speedup vs baseline: 1.7949x; 1.0266x over previous
//
#include <hip/hip_runtime.h>
#include <math.h>

#define NB 4
#define SS 16
#define NN 1024        // H*W

typedef short s8v __attribute__((ext_vector_type(8)));    // 8 bf16 (4 VGPR)
typedef float f4v __attribute__((ext_vector_type(4)));    // MFMA accumulator

__device__ __forceinline__ float sigm(float x) {
  return 1.0f / (1.0f + __expf(-x));
}
__device__ __forceinline__ float tanh_f(float x) {
  float e = __expf(2.0f * x);
  return 1.0f - 2.0f / (1.0f + e);
}
__device__ __forceinline__ unsigned short bf16r(float x) {   // RNE float->bf16
  unsigned int u = __float_as_uint(x);
  u = (u + 0x7FFFu + ((u >> 16) & 1u)) >> 16;
  return (unsigned short)u;
}
__device__ __forceinline__ float bf16f(unsigned short h) {
  return __uint_as_float(((unsigned int)h) << 16);
}

// ---------- prep: weight split/pack (conv + proj + z_w + m_w A-frags) + zero states ----------
__global__ void k0_prep(const float* __restrict__ conv_w, const float* __restrict__ z_w,
                        const float* __restrict__ m_w,
                        const float* __restrict__ qw, const float* __restrict__ kw,
                        const float* __restrict__ vw, const float* __restrict__ k2w,
                        const float* __restrict__ v2w,
                        unsigned short* __restrict__ Whi, unsigned short* __restrict__ Wlo,
                        unsigned short* __restrict__ zAhi, unsigned short* __restrict__ zAlo,
                        unsigned short* __restrict__ mAhi, unsigned short* __restrict__ mAlo,
                        unsigned short* __restrict__ pAhi, unsigned short* __restrict__ pAlo,
                        float* __restrict__ h_A, float* __restrict__ c_st) {
  int stride = gridDim.x * blockDim.x;
  int i0 = blockIdx.x * blockDim.x + threadIdx.x;
  for (int i = i0; i < 256*1152; i += stride) {
    int oc = i / 1152, k = i - oc*1152;          // k = icComb*9 + ky*3 + kx
    float v = conv_w[i];
    unsigned short hi = bf16r(v);
    unsigned short lo = bf16r(v - bf16f(hi));
    int mt = oc >> 4, i16 = oc & 15;
    int ks = k >> 5, kk = k & 31;
    int lane = i16 | ((kk >> 3) << 4);
    int pos = ((mt*36 + ks)*64 + lane)*8 + (kk & 7);
    Whi[pos] = hi;
    Wlo[pos] = lo;
  }
  for (int i = i0; i < 128*128; i += stride) {   // z_w A-frags: 8 mt x 4 ks
    int oc = i >> 7, k = i & 127;
    float v = z_w[i];
    unsigned short hi = bf16r(v);
    unsigned short lo = bf16r(v - bf16f(hi));
    int mt = oc >> 4, i16 = oc & 15;
    int ks = k >> 5, kk = k & 31;
    int lane = i16 | ((kk >> 3) << 4);
    int pos = ((mt*4 + ks)*64 + lane)*8 + (kk & 7);
    zAhi[pos] = hi;
    zAlo[pos] = lo;
  }
  for (int i = i0; i < 192*192; i += stride) {   // m_w A-frags: 12 mt x 6 ks
    int oc = i / 192, k = i - oc*192;
    float v = m_w[i];
    unsigned short hi = bf16r(v);
    unsigned short lo = bf16r(v - bf16f(hi));
    int mt = oc >> 4, i16 = oc & 15;
    int ks = k >> 5, kk = k & 31;
    int lane = i16 | ((kk >> 3) << 4);
    int pos = ((mt*6 + ks)*64 + lane)*8 + (kk & 7);
    mAhi[pos] = hi;
    mAlo[pos] = lo;
  }
  for (int i = i0; i < 176*64; i += stride) {    // proj A-frags: 11 mt x 2 ks
    int po = i >> 6, c = i & 63;
    float v;
    if (po < 16)       v = qw[po*64 + c];
    else if (po < 32)  v = kw[(po-16)*64 + c];
    else if (po < 96)  v = vw[(po-32)*64 + c];
    else if (po < 112) v = k2w[(po-96)*64 + c];
    else               v = v2w[(po-112)*64 + c];
    unsigned short hi = bf16r(v);
    unsigned short lo = bf16r(v - bf16f(hi));
    int mt = po >> 4, i16 = po & 15;
    int ks = c >> 5, kk = c & 31;
    int lane = i16 | ((kk >> 3) << 4);
    int pos = ((mt*2 + ks)*64 + lane)*8 + (kk & 7);
    pAhi[pos] = hi;
    pAlo[pos] = lo;
  }
  for (int i = i0; i < NB*64*NN; i += stride) { h_A[i] = 0.0f; c_st[i] = 0.0f; }
}

// ---------- K0b v7: conv_x, N=64/block, hi-only, row-owned im2col, bf16 gx ----------
__global__ __launch_bounds__(1024, 2) void k0b_gx(
    const float* __restrict__ X,
    const unsigned short* __restrict__ Whi,
    unsigned short* __restrict__ gxh)
{
  __shared__ __align__(16) unsigned short Xhi_l[18*4*64*8];   // [ks][nt 0..3][lane][8] = 73728 B

  const int tid = threadIdx.x;
  const int bid = blockIdx.x;       // b*256 + t*16 + y2
  const int y2 = bid & 15;
  const int t  = (bid >> 4) & 15;
  const int b  = bid >> 8;
  const int y0 = y2 * 2;

  // ---- im2col: thread owns (row = ic*4+dy, quarter); constant bases per combo ----
  {
    const int row = tid >> 2;          // 0..255
    const int qtr = tid & 3;           // 0..3
    const int ic  = row >> 2;
    const int dy  = row & 3;           // halo row; gy = y0 + dy - 1
    const int gy  = y0 + dy - 1;
    const bool rowOk = ((unsigned)gy < 32u);
    const float* Xrow = X + (((b*64 + ic)*SS + t)*NN) + gy*32;
    int Kc[2][3];
    bool rv[2];
    #pragma unroll
    for (int r = 0; r < 2; r++) {
      int dyl = dy - r;
      rv[r] = ((unsigned)dyl < 3u);
      #pragma unroll
      for (int dx = 0; dx < 3; dx++) {
        int k = ic*9 + dyl*3 + dx;
        int ks = k >> 5, kk = k & 31;
        Kc[r][dx] = ks*2048 + ((kk >> 3) << 4)*8 + (kk & 7) + r*1024;
      }
    }
    const int c0 = qtr*9;
    const int c1 = (qtr == 3) ? 34 : c0 + 9;
    for (int col = c0; col < c1; col++) {
      int gxc = col - 1;
      float v = (rowOk && (unsigned)gxc < 32u) ? Xrow[gxc] : 0.0f;
      unsigned short hi = bf16r(v);
      #pragma unroll
      for (int r = 0; r < 2; r++) {
        if (rv[r]) {
          #pragma unroll
          for (int dx = 0; dx < 3; dx++) {
            int x = col - dx;
            if ((unsigned)x < 32u)
              Xhi_l[Kc[r][dx] + (x >> 4)*512 + (x & 15)*8] = hi;
          }
        }
      }
    }
  }
  __syncthreads();

  const int lane = tid & 63;
  const int mt = tid >> 6;          // 0..15
  f4v acc[4];
  #pragma unroll
  for (int nt = 0; nt < 4; nt++) acc[nt] = (f4v){0.f, 0.f, 0.f, 0.f};
  const s8v* Ah = (const s8v*)Whi + (mt*36)*64 + lane;
  const s8v* Bh = (const s8v*)Xhi_l + lane;
  #pragma unroll 3
  for (int ks = 0; ks < 18; ks++) {
    s8v ah = Ah[ks*64];
    #pragma unroll
    for (int nt = 0; nt < 4; nt++) {
      s8v bh = Bh[(ks*4 + nt)*64];
      acc[nt] = __builtin_amdgcn_mfma_f32_16x16x32_bf16(ah, bh, acc[nt], 0, 0, 0);
    }
  }
  const int c16 = lane & 15;
  const int rb  = (lane >> 4) * 4;
  unsigned short* gout = gxh + (((long)b*SS + t)*256)*NN;
  #pragma unroll
  for (int nt = 0; nt < 4; nt++) {
    #pragma unroll
    for (int r4 = 0; r4 < 4; r4++) {
      int oc = mt*16 + rb + r4;
      int n = nt*16 + c16;
      int py = y0 + (n >> 5);
      int px2 = n & 31;
      gout[oc*NN + py*32 + px2] = bf16r(acc[nt][r4]);
    }
  }
}

// ---------- K1: conv_h (hi-only) + LSTM(+gx) + MFMA projections (1024 threads) ----------
__global__ __launch_bounds__(1024, 2) void k1_conv_lstm_proj(
    int t,
    const unsigned short* __restrict__ gxh,
    const unsigned short* __restrict__ Whi,
    const unsigned short* __restrict__ pAhi, const unsigned short* __restrict__ pAlo,
    const float* __restrict__ conv_b,
    const float* __restrict__ W_ci, const float* __restrict__ W_cf, const float* __restrict__ W_co,
    const float* __restrict__ qb, const float* __restrict__ kb,
    const float* __restrict__ vb, const float* __restrict__ k2b,
    const float* __restrict__ v2b,
    const float* __restrict__ h_cur, float* __restrict__ h_nxt,
    float* __restrict__ c_st,
    unsigned short* __restrict__ qFh,
    unsigned short* __restrict__ kF,
    unsigned short* __restrict__ vFh)
{
  __shared__ __align__(16) unsigned short Ihi_l[18*64*8];      // h-only im2col (hi plane)
  __shared__ __align__(16) float gates_l[256*17];              // [oc][x]; later proj_l[176][16]
  __shared__ __align__(16) unsigned short hBh[2*64*8];         // h in B-frag layout (hi)
  __shared__ __align__(16) unsigned short cBh[2*64*8];         // c in B-frag layout (hi)
  __shared__ __align__(16) float pb_l[176];

  const int tid = threadIdx.x;
  const int bid = blockIdx.x;
  const int b  = bid >> 6;
  const int y  = (bid >> 1) & 31;
  const int x0 = (bid & 1) * 16;
  const int mt = bid & 63;          // this block's 16-col m-tile (= n>>4)
  const int n0 = y*32 + x0;

  // ---- prefetch LSTM inputs + projection A-frags into registers ----
  const int px = tid & 15;
  const int pc = tid >> 4;          // 0..63
  const int pn = n0 + px;
  const unsigned short* gxp = gxh + (((long)b*SS + t)*256)*NN + pn;
  float pf_g0 = bf16f(gxp[(pc      )*NN]);
  float pf_g1 = bf16f(gxp[( 64 + pc)*NN]);
  float pf_g2 = bf16f(gxp[(128 + pc)*NN]);
  float pf_g3 = bf16f(gxp[(192 + pc)*NN]);
  float pf_cp  = c_st[(b*64 + pc)*NN + pn];
  float pf_wci = W_ci[pc*NN + pn];
  float pf_wcf = W_cf[pc*NN + pn];
  float pf_wco = W_co[pc*NN + pn];
  float pf_b0 = conv_b[pc];
  float pf_b1 = conv_b[ 64 + pc];
  float pf_b2 = conv_b[128 + pc];
  float pf_b3 = conv_b[192 + pc];
  const int lane_e = tid & 63;
  const int wv_e   = tid >> 6;
  const int wvc    = (wv_e < 11) ? wv_e : 0;
  s8v pf_a0h = *(const s8v*)(pAhi + ((wvc*2 + 0)*64 + lane_e)*8);
  s8v pf_a0l = *(const s8v*)(pAlo + ((wvc*2 + 0)*64 + lane_e)*8);
  s8v pf_a1h = *(const s8v*)(pAhi + ((wvc*2 + 1)*64 + lane_e)*8);
  s8v pf_a1l = *(const s8v*)(pAlo + ((wvc*2 + 1)*64 + lane_e)*8);

  // ---- phase 0: h-only im2col (hi plane) -> B-frags  +  stage proj biases ----
  for (int idx = tid; idx < 64*3*18; idx += 1024) {
    int col = idx % 18;
    int rest = idx / 18;
    int dy = rest % 3;
    int ic = rest / 3;                    // h channel 0..63
    int gy = y + dy - 1;
    int gxc = x0 + col - 1;
    float v = 0.0f;
    if ((unsigned)gy < 32u && (unsigned)gxc < 32u)
      v = h_cur[((b*64 + ic)*NN) + gy*32 + gxc];
    unsigned short hi = bf16r(v);
    int kbase = ic*9 + dy*3;              // local k in [0,576)
    #pragma unroll
    for (int dx = 0; dx < 3; dx++) {
      int n = col - dx;
      if ((unsigned)n < 16u) {
        int k = kbase + dx;
        int ks = k >> 5, kk = k & 31;
        int pos = (ks*64 + (n | ((kk >> 3) << 4)))*8 + (kk & 7);
        Ihi_l[pos] = hi;
      }
    }
  }
  if (tid < 176) {
    int po = tid;
    float v;
    if (po < 16)       v = qb[po];
    else if (po < 32)  v = kb[po-16];
    else if (po < 96)  v = vb[po-32];
    else if (po < 112) v = k2b[po-96];
    else               v = v2b[po-112];
    pb_l[po] = v;
  }
  __syncthreads();

  // ---- phase 1: conv_h MFMA: 16 waves, 1 m-tile each; W hi-only, h hi-only ----
  {
    const int lane = tid & 63;
    const int wv   = tid >> 6;        // 0..15 = m-tile
    f4v acc = {0.f, 0.f, 0.f, 0.f};
    const s8v* Ah = (const s8v*)Whi + (wv*36 + 18)*64 + lane;
    const s8v* Bh = (const s8v*)Ihi_l + lane;
    #pragma unroll 6
    for (int ks = 0; ks < 18; ks++) {
      s8v ah = Ah[ks*64];
      s8v bh = Bh[ks*64];
      acc = __builtin_amdgcn_mfma_f32_16x16x32_bf16(ah, bh, acc, 0, 0, 0);
    }
    const int colx = lane & 15;
    const int rb   = (lane >> 4) * 4;
    #pragma unroll
    for (int r = 0; r < 4; r++)
      gates_l[(wv*16 + rb + r)*17 + colx] = acc[r];
  }
  __syncthreads();

  // ---- phase 2: LSTM elementwise; write h/c into B-frag layout (hi only) ----
  {
    const int x = px;
    const int c = pc;
    const int n = pn;
    float ig = gates_l[(c      )*17 + x] + pf_g0 + pf_b0;
    float fg = gates_l[( 64 + c)*17 + x] + pf_g1 + pf_b1;
    float gg = gates_l[(128 + c)*17 + x] + pf_g2 + pf_b2;
    float og = gates_l[(192 + c)*17 + x] + pf_g3 + pf_b3;
    float cp = pf_cp;
    float i_ = sigm(ig + pf_wci * cp);
    float f_ = sigm(fg + pf_wcf * cp);
    float cn = f_*cp + i_*tanh_f(gg);
    float o_ = sigm(og + pf_wco * cn);
    float hn = o_*tanh_f(cn);
    h_nxt[(b*64 + c)*NN + n] = hn;
    c_st[(b*64 + c)*NN + n] = cn;
    const int ksC = c >> 5, kkC = c & 31;
    const int posF = (ksC*64 + (x | ((kkC >> 3) << 4)))*8 + (kkC & 7);
    hBh[posF] = bf16r(hn);
    cBh[posF] = bf16r(cn);
  }
  __syncthreads();

  // ---- phase 3: projections via MFMA (11 waves; A hi+lo, B hi-only) ----
  float* proj_l = gates_l;              // gates fully consumed in phase 2
  {
    const int lane = lane_e;
    const int wv   = wv_e;
    if (wv < 11) {
      const s8v* Bh_ = (const s8v*)((wv < 6) ? hBh : cBh) + lane;
      f4v acc = {0.f, 0.f, 0.f, 0.f};
      s8v bh0 = Bh_[0];
      s8v bh1 = Bh_[64];
      acc = __builtin_amdgcn_mfma_f32_16x16x32_bf16(pf_a0h, bh0, acc, 0, 0, 0);
      acc = __builtin_amdgcn_mfma_f32_16x16x32_bf16(pf_a0l, bh0, acc, 0, 0, 0);
      acc = __builtin_amdgcn_mfma_f32_16x16x32_bf16(pf_a1h, bh1, acc, 0, 0, 0);
      acc = __builtin_amdgcn_mfma_f32_16x16x32_bf16(pf_a1l, bh1, acc, 0, 0, 0);
      const int colx = lane & 15;
      const int rb   = (lane >> 4) * 4;
      #pragma unroll
      for (int r = 0; r < 4; r++) {
        int po = wv*16 + rb + r;
        proj_l[po*16 + colx] = acc[r] + pb_l[po];
      }
    }
  }
  __syncthreads();

  // ---- phase 4: coalesced fragment emission ----
  // Q in A-frag layout, hi-only (tid 512..1023)
  if (tid >= 512) {
    int qt = tid - 512;               // 0..511
    int lane = qt >> 3, j = qt & 7;
    int g = lane >> 4, c16l = lane & 15;
    int d = ((g & 1) << 3) + j;
    float qv = proj_l[d*16 + c16l];
    long base = ((long)(b*64 + mt)*64 + lane)*8 + j;
    qFh[base] = bf16r(qv);
  }
  if (tid < 512) {
    int brh2 = tid >> 8;            // branch
    int lh   = (tid >> 2) & 63;     // fragment "lane-half" row
    int j2   = tid & 3;             // packs d&7 = 2*j2, 2*j2+1
    int p    = lh >> 4;             // 0,1: hi planes; 2,3: lo planes
    int x    = lh & 15;
    int d0   = ((p & 1) << 3) | (j2 << 1);
    int Koff = brh2 ? 96 : 16;
    float v0 = proj_l[(Koff + d0)*16 + x];
    float v1 = proj_l[(Koff + d0 + 1)*16 + x];
    unsigned short h0 = bf16r(v0), h1 = bf16r(v1);
    unsigned short u0, u1;
    if (p < 2) { u0 = h0; u1 = h1; }
    else       { u0 = bf16r(v0 - bf16f(h0)); u1 = bf16r(v1 - bf16f(h1)); }
    unsigned int* dst = (unsigned int*)(kF + ((b*2 + brh2)*64 + mt)*512);
    dst[lh*4 + j2] = (unsigned)u0 | ((unsigned)u1 << 16);
  }
  {
    const int ks = y;
    const int g0 = x0 >> 3;         // 0 or 2
    int ct    = tid;                // 1024 tasks: brh(2) x nt(4) x li(32) x j2(4)
    int brh2  = (ct >> 9) & 1;
    int nt    = (ct >> 7) & 3;
    int li    = (ct >> 2) & 31;
    int j2    = ct & 3;
    int lane2 = g0*16 + li;
    int cch   = nt*16 + (lane2 & 15);
    int xx    = ((li >> 4) << 3) | (j2 << 1);
    int Voff  = brh2 ? 112 : 32;
    float v0 = proj_l[(Voff + cch)*16 + xx];
    float v1 = proj_l[(Voff + cch)*16 + xx + 1];
    unsigned short u0 = bf16r(v0), u1 = bf16r(v1);
    unsigned short* basep = vFh + (((b*2 + brh2)*32 + ks)*4 + nt)*512;
    ((unsigned int*)basep)[lane2*4 + j2] = (unsigned)u0 | ((unsigned)u1 << 16);
  }
}

// ---------- K2: dual attention via MFMA + MFMA combine + gating ----------
#define RED_OFF 0        // [16 waves][16 nl][66]  = 16896
#define PS_OFF  16896    // [16 waves][16][36]     = 9216
#define SMX_OFF 26112    // [2][8][16]             = 256
#define SSM_OFF 26368    // [2][8][16]             = 256
#define INV_OFF 26624    // [2][16]                = 32
#define S_TOT   28704

__global__ __launch_bounds__(1024, 4) void k2_attn(
    int t,
    const unsigned short* __restrict__ qFh,
    const unsigned short* __restrict__ kF,
    const unsigned short* __restrict__ vFh,
    float* __restrict__ h_nxt, float* __restrict__ c_st,
    const unsigned short* __restrict__ zAhi, const unsigned short* __restrict__ zAlo,
    const unsigned short* __restrict__ mAhi, const unsigned short* __restrict__ mAlo,
    const float* __restrict__ z_b, const float* __restrict__ m_b,
    float* __restrict__ out)
{
  __shared__ __align__(16) float S[S_TOT];
  __shared__ __align__(16) unsigned short zBh[4*512];   // zz B-frags (4 ks)
  __shared__ __align__(16) unsigned short zBl[4*512];
  __shared__ __align__(16) unsigned short cbBh[6*512];  // comb B-frags (6 ks)
  __shared__ __align__(16) unsigned short cbBl[6*512];
  float* red  = S + RED_OFF;
  float* smMax= S + SMX_OFF;
  float* smSum= S + SSM_OFF;
  float* invL = S + INV_OFF;
  float* cbOut= S + 3072;       // [192][16] aliases red (after barrier)

  const int tid = threadIdx.x;
  const int bid = blockIdx.x;
  const int xcd = bid & 7;
  const int b = xcd >> 1;
  const int tile = ((bid >> 3) << 1) | (xcd & 1);   // 0..63
  const int n0 = tile * 16;

  const int wid  = tid >> 6;
  const int lane = tid & 63;
  const int brh  = wid >> 3;      // branch
  const int w    = wid & 7;       // wave within branch
  const int g    = lane >> 4;
  const int c16  = lane & 15;

  // ---- prefetch tail-phase inputs ----
  const int pc2 = tid >> 4;       // 0..63
  const int pn2 = n0 + (tid & 15);
  float pf_cst = c_st[(b*64 + pc2)*NN + pn2];
  float pf_h   = h_nxt[(b*64 + pc2)*NN + pn2];

  // ---- Q A-frag: direct b128 load (hi-only, pre-packed by k1) ----
  s8v qh1 = *(const s8v*)(qFh + ((long)(b*64 + tile)*64 + lane)*8);

  // ---- scores: 8 m-tiles per wave, 1 MFMA each (B = [Kh|Kl], A = [Qh|Qh]) ----
  f4v acc[8];
  {
    const unsigned short* kp = kF + (((b*2 + brh)*64 + w*8)*64 + lane)*8;
    #pragma unroll
    for (int i = 0; i < 8; i++) {
      s8v bf = *(const s8v*)(kp + i*512);
      f4v z4 = {0.f, 0.f, 0.f, 0.f};
      acc[i] = __builtin_amdgcn_mfma_f32_16x16x32_bf16(qh1, bf, z4, 0, 0, 0);
    }
  }

  // ---- softmax ----
  float Mrow[4];
  #pragma unroll
  for (int r = 0; r < 4; r++) {
    float m = acc[0][r];
    #pragma unroll
    for (int i = 1; i < 8; i++) m = fmaxf(m, acc[i][r]);
    m = fmaxf(m, __shfl_xor(m, 1));
    m = fmaxf(m, __shfl_xor(m, 2));
    m = fmaxf(m, __shfl_xor(m, 4));
    m = fmaxf(m, __shfl_xor(m, 8));
    if (c16 == 0) smMax[(brh*8 + w)*16 + g*4 + r] = m;
  }
  __syncthreads();
  #pragma unroll
  for (int r = 0; r < 4; r++) {
    float m = smMax[(brh*8 + 0)*16 + g*4 + r];
    #pragma unroll
    for (int w2 = 1; w2 < 8; w2++) m = fmaxf(m, smMax[(brh*8 + w2)*16 + g*4 + r]);
    Mrow[r] = m;
  }
  float rsum[4] = {0.f, 0.f, 0.f, 0.f};
  #pragma unroll
  for (int i = 0; i < 8; i++) {
    #pragma unroll
    for (int r = 0; r < 4; r++) {
      float p = __expf(acc[i][r] - Mrow[r]);
      acc[i][r] = p;
      rsum[r] += p;
    }
  }
  #pragma unroll
  for (int r = 0; r < 4; r++) {
    float s = rsum[r];
    s += __shfl_xor(s, 1); s += __shfl_xor(s, 2);
    s += __shfl_xor(s, 4); s += __shfl_xor(s, 8);
    if (c16 == 0) smSum[(brh*8 + w)*16 + g*4 + r] = s;
  }
  __syncthreads();
  if (w == 0 && c16 == 0) {
    #pragma unroll
    for (int r = 0; r < 4; r++) {
      float s = 0.f;
      #pragma unroll
      for (int w2 = 0; w2 < 8; w2++) s += smSum[(brh*8 + w2)*16 + g*4 + r];
      invL[brh*16 + g*4 + r] = 1.0f / s;
    }
  }

  // ---- PV: per wave, 4 k-steps of 32 m; wave-local P transpose; P hi, V hi ----
  f4v z0 = {0.f,0.f,0.f,0.f}, z1 = z0, z2 = z0, z3 = z0;
  float* myPS = S + PS_OFF + wid*576;   // [16][36]
  #pragma unroll
  for (int ks4 = 0; ks4 < 4; ks4++) {
    #pragma unroll
    for (int i2 = 0; i2 < 2; i2++) {
      #pragma unroll
      for (int r = 0; r < 4; r++)
        myPS[(g*4 + r)*36 + i2*16 + c16] = acc[ks4*2 + i2][r];
    }
    float4 pa = *(const float4*)&myPS[c16*36 + g*8];
    float4 pb = *(const float4*)&myPS[c16*36 + g*8 + 4];
    s8v ph;
    ph[0] = (short)bf16r(pa.x);
    ph[1] = (short)bf16r(pa.y);
    ph[2] = (short)bf16r(pa.z);
    ph[3] = (short)bf16r(pa.w);
    ph[4] = (short)bf16r(pb.x);
    ph[5] = (short)bf16r(pb.y);
    ph[6] = (short)bf16r(pb.z);
    ph[7] = (short)bf16r(pb.w);
    const int ks = w*4 + ks4;
    const unsigned short* vph = vFh + ((((b*2 + brh)*32 + ks)*4)*64 + lane)*8;
    s8v vh0 = *(const s8v*)(vph);
    z0 = __builtin_amdgcn_mfma_f32_16x16x32_bf16(ph, vh0, z0, 0,0,0);
    s8v vh1 = *(const s8v*)(vph + 512);
    z1 = __builtin_amdgcn_mfma_f32_16x16x32_bf16(ph, vh1, z1, 0,0,0);
    s8v vh2 = *(const s8v*)(vph + 1024);
    z2 = __builtin_amdgcn_mfma_f32_16x16x32_bf16(ph, vh2, z2, 0,0,0);
    s8v vh3 = *(const s8v*)(vph + 1536);
    z3 = __builtin_amdgcn_mfma_f32_16x16x32_bf16(ph, vh3, z3, 0,0,0);
  }

  // ---- write partials, reduce 8 waves, normalize -> zz B-frags ----
  {
    float* rw = red + wid*1056;
    #pragma unroll
    for (int r = 0; r < 4; r++) {
      rw[(g*4 + r)*66 +  0 + c16] = z0[r];
      rw[(g*4 + r)*66 + 16 + c16] = z1[r];
      rw[(g*4 + r)*66 + 32 + c16] = z2[r];
      rw[(g*4 + r)*66 + 48 + c16] = z3[r];
    }
  }
  __syncthreads();
  {
    const int br2 = tid >> 9;
    const int sub = tid & 511;
    const int nlr = sub >> 5;
    const int cc0 = (sub & 31) * 2;
    float iv = invL[br2*16 + nlr];
    #pragma unroll
    for (int u = 0; u < 2; u++) {
      int cc = cc0 + u;
      float s = 0.f;
      #pragma unroll
      for (int w2 = 0; w2 < 8; w2++)
        s += red[(br2*8 + w2)*1056 + nlr*66 + cc];
      float v = s * iv;
      int k = br2*64 + cc;
      int ks = k >> 5, kk = k & 31;
      int pos = (ks*64 + (nlr | ((kk >> 3) << 4)))*8 + (kk & 7);
      unsigned short h = bf16r(v);
      zBh[pos] = h;
      zBl[pos] = bf16r(v - bf16f(h));
    }
  }
  __syncthreads();

  // ---- h rows into comb B-frags + zz via MFMA (waves 0..7) ----
  {
    int k = 128 + pc2;
    int ks = k >> 5, kk = k & 31;
    int pos = (ks*64 + ((tid & 15) | ((kk >> 3) << 4)))*8 + (kk & 7);
    unsigned short h = bf16r(pf_h);
    cbBh[pos] = h;
    cbBl[pos] = bf16r(pf_h - bf16f(h));
  }
  if (wid < 8) {
    f4v za = {0.f, 0.f, 0.f, 0.f};
    const s8v* Azh = (const s8v*)zAhi + (wid*4)*64 + lane;
    const s8v* Azl = (const s8v*)zAlo + (wid*4)*64 + lane;
    const s8v* Bzh = (const s8v*)zBh + lane;
    const s8v* Bzl = (const s8v*)zBl + lane;
    #pragma unroll
    for (int ks = 0; ks < 4; ks++) {
      s8v ah = Azh[ks*64];
      s8v al = Azl[ks*64];
      s8v bh = Bzh[ks*64];
      s8v bl = Bzl[ks*64];
      za = __builtin_amdgcn_mfma_f32_16x16x32_bf16(ah, bh, za, 0, 0, 0);
      za = __builtin_amdgcn_mfma_f32_16x16x32_bf16(al, bh, za, 0, 0, 0);
      za = __builtin_amdgcn_mfma_f32_16x16x32_bf16(ah, bl, za, 0, 0, 0);
    }
    #pragma unroll
    for (int r = 0; r < 4; r++) {
      int oc = wid*16 + g*4 + r;
      float v = za[r] + z_b[oc];
      int kk = oc & 31, ks2 = oc >> 5;
      int pos = (ks2*64 + (c16 | ((kk >> 3) << 4)))*8 + (kk & 7);
      unsigned short h = bf16r(v);
      cbBh[pos] = h;
      cbBl[pos] = bf16r(v - bf16f(h));
    }
  }
  __syncthreads();

  // ---- comb via MFMA (waves 0..11) ----
  if (wid < 12) {
    f4v ca = {0.f, 0.f, 0.f, 0.f};
    const s8v* Amh = (const s8v*)mAhi + (wid*6)*64 + lane;
    const s8v* Aml = (const s8v*)mAlo + (wid*6)*64 + lane;
    const s8v* Bch = (const s8v*)cbBh + lane;
    const s8v* Bcl = (const s8v*)cbBl + lane;
    #pragma unroll
    for (int ks = 0; ks < 6; ks++) {
      s8v ah = Amh[ks*64];
      s8v al = Aml[ks*64];
      s8v bh = Bch[ks*64];
      s8v bl = Bcl[ks*64];
      ca = __builtin_amdgcn_mfma_f32_16x16x32_bf16(ah, bh, ca, 0, 0, 0);
      ca = __builtin_amdgcn_mfma_f32_16x16x32_bf16(al, bh, ca, 0, 0, 0);
      ca = __builtin_amdgcn_mfma_f32_16x16x32_bf16(ah, bl, ca, 0, 0, 0);
    }
    #pragma unroll
    for (int r = 0; r < 4; r++) {
      int oc = wid*16 + g*4 + r;
      cbOut[oc*16 + c16] = ca[r] + m_b[oc];
    }
  }
  __syncthreads();

  // ---- gating ----
  {
    const int c = pc2, nn = tid & 15;
    const int n = n0 + nn;
    float mo = cbOut[c*16 + nn];
    float mg = cbOut[(64 + c)*16 + nn];
    float mi = cbOut[(128 + c)*16 + nn];
    float mf = pf_cst;
    float mis = sigm(mi);
    float nmf = (1.0f - mis)*mf + mis*tanh_f(mg);
    float nhf = sigm(mo)*nmf;
    c_st[(b*64 + c)*NN + n] = nmf;
    h_nxt[(b*64 + c)*NN + n] = nhf;
    out[((b*64 + c)*SS + t)*NN + n] = nhf;
  }
}

extern "C" void kernel_launch(void* const* d_in, const int* in_sizes, int n_in,
                              void* d_out, int out_size, void* d_ws, size_t ws_size,
                              hipStream_t stream) {
  const float* X      = (const float*)d_in[0];
  const float* conv_w = (const float*)d_in[1];
  const float* conv_b = (const float*)d_in[2];
  const float* W_ci   = (const float*)d_in[3];
  const float* W_cf   = (const float*)d_in[4];
  const float* W_co   = (const float*)d_in[5];
  const float* qw  = (const float*)d_in[6];
  const float* qb  = (const float*)d_in[7];
  const float* kw  = (const float*)d_in[8];
  const float* kb  = (const float*)d_in[9];
  const float* k2w = (const float*)d_in[10];
  const float* k2b = (const float*)d_in[11];
  const float* vw  = (const float*)d_in[12];
  const float* vb  = (const float*)d_in[13];
  const float* v2w = (const float*)d_in[14];
  const float* v2b = (const float*)d_in[15];
  const float* z_w = (const float*)d_in[16];
  const float* z_b = (const float*)d_in[17];
  const float* m_w = (const float*)d_in[18];
  const float* m_b = (const float*)d_in[19];
  float* out = (float*)d_out;

  float* ws = (float*)d_ws;
  unsigned short* Whi  = (unsigned short*)ws;  ws += 147456;   // 294912 ushorts
  unsigned short* Wlo  = (unsigned short*)ws;  ws += 147456;
  unsigned short* zAhi = (unsigned short*)ws;  ws += 8192;     // 16384 ushorts
  unsigned short* zAlo = (unsigned short*)ws;  ws += 8192;
  unsigned short* mAhi = (unsigned short*)ws;  ws += 18432;    // 36864 ushorts
  unsigned short* mAlo = (unsigned short*)ws;  ws += 18432;
  unsigned short* pAhi = (unsigned short*)ws;  ws += 5632;     // 11264 ushorts
  unsigned short* pAlo = (unsigned short*)ws;  ws += 5632;
  float* h_A    = ws;             ws += NB*64*NN;
  float* h_B    = ws;             ws += NB*64*NN;
  float* c_st   = ws;             ws += NB*64*NN;
  unsigned short* qFh = (unsigned short*)ws;  ws += 65536;    // 131072 ushorts
  unsigned short* kF  = (unsigned short*)ws;  ws += 131072;   // 4b*2br*64mt*64*8 ushorts
  unsigned short* vFh = (unsigned short*)ws;  ws += 131072;   // 4b*2br*32ks*4nt*64*8
  unsigned short* gxh = (unsigned short*)ws;  ws += NB*SS*128*NN;  // 16.8M ushorts, 33.5 MB

  hipLaunchKernelGGL(k0_prep, dim3(256), dim3(256), 0, stream,
                     conv_w, z_w, m_w, qw, kw, vw, k2w, v2w,
                     Whi, Wlo, zAhi, zAlo, mAhi, mAlo, pAhi, pAlo, h_A, c_st);
  hipLaunchKernelGGL(k0b_gx, dim3(1024), dim3(1024), 0, stream,
                     X, Whi, gxh);
  for (int t = 0; t < 16; t++) {
    const float* h_cur = (t & 1) ? h_B : h_A;
    float* h_nxt       = (t & 1) ? h_A : h_B;
    hipLaunchKernelGGL(k1_conv_lstm_proj, dim3(256), dim3(1024), 0, stream,
        t, gxh, Whi, pAhi, pAlo, conv_b, W_ci, W_cf, W_co,
        qb, kb, vb, k2b, v2b,
        h_cur, h_nxt, c_st, qFh, kF, vFh);
    hipLaunchKernelGGL(k2_attn, dim3(256), dim3(1024), 0, stream,
        t, qFh, kF, vFh, h_nxt, c_st,
        zAhi, zAlo, mAhi, mAlo, z_b, m_b, out);
  }
}